// Round 1
// baseline (403.633 us; speedup 1.0000x reference)
//
#include <hip/hip_runtime.h>
#include <hip/hip_bf16.h>
#include <stdint.h>

// Problem constants: b=1, s=2048, hidden=2048, H=16, d=128
#define SEQ   2048
#define HIDN  2048
#define NHEAD 16
#define HDIM  128
#define HEAVY 204   // int(0.1*2048)
#define RECENT 204

typedef __attribute__((ext_vector_type(4))) float f32x4;
typedef __attribute__((ext_vector_type(8))) short bf16x8;
typedef unsigned short u16;
typedef unsigned int   u32;

static __device__ __forceinline__ u16 f2bf(float f){
  union { float f; u32 u; } v; v.f = f;
  u32 r = (v.u + 0x7FFFu + ((v.u >> 16) & 1u)) >> 16;
  return (u16)r;
}
static __device__ __forceinline__ float bf2f(u16 u){
  union { u32 u; float f; } v; v.u = ((u32)u) << 16;
  return v.f;
}

// global -> LDS direct 16B load (dest is wave-uniform base + lane*16)
static __device__ __forceinline__ void gload16(const void* g, void* l){
  __builtin_amdgcn_global_load_lds((const __attribute__((address_space(1))) u32*)g,
                                   (__attribute__((address_space(3))) u32*)l, 16, 0, 0);
}

// ---------------- converts + RoPE tables ----------------
__global__ void k_f32_to_bf16(const float* __restrict__ in, u16* __restrict__ out, int n){
  int i = (blockIdx.x * 256 + threadIdx.x) * 4;
  if (i >= n) return;
  float4 v = *(const float4*)(in + i);
  ushort4 o;
  o.x = f2bf(v.x); o.y = f2bf(v.y); o.z = f2bf(v.z); o.w = f2bf(v.w);
  *(ushort4*)(out + i) = o;
}

__global__ void k_rope_tab(float* __restrict__ cosT, float* __restrict__ sinT){
  int i = blockIdx.x * 256 + threadIdx.x;        // 2048*64
  int pos = i >> 6, j = i & 63;
  float invf = powf(10000.0f, -(float)j * (1.0f / 64.0f));
  float a = (float)pos * invf;
  cosT[i] = cosf(a);
  sinT[i] = sinf(a);
}

// apply rotary in-place on [2048][16*128] bf16 (pairs j, j+64 within each head)
__global__ void k_rope_apply(u16* __restrict__ M, const float* __restrict__ cosT,
                             const float* __restrict__ sinT){
  int gid = blockIdx.x * 256 + threadIdx.x;      // 2048*16*16
  int pos = gid >> 8, rem = gid & 255;
  int h = rem >> 4, j4 = (rem & 15) * 4;
  u16* p = M + (size_t)pos * HIDN + h * HDIM + j4;
  ushort4 lo = *(ushort4*)p;
  ushort4 hi = *(ushort4*)(p + 64);
  float4 c = *(const float4*)(cosT + pos * 64 + j4);
  float4 s = *(const float4*)(sinT + pos * 64 + j4);
  float l0 = bf2f(lo.x), l1 = bf2f(lo.y), l2 = bf2f(lo.z), l3 = bf2f(lo.w);
  float h0 = bf2f(hi.x), h1 = bf2f(hi.y), h2 = bf2f(hi.z), h3 = bf2f(hi.w);
  ushort4 nlo, nhi;
  nlo.x = f2bf(l0 * c.x - h0 * s.x);  nhi.x = f2bf(h0 * c.x + l0 * s.x);
  nlo.y = f2bf(l1 * c.y - h1 * s.y);  nhi.y = f2bf(h1 * c.y + l1 * s.y);
  nlo.z = f2bf(l2 * c.z - h2 * s.z);  nhi.z = f2bf(h2 * c.z + l2 * s.z);
  nlo.w = f2bf(l3 * c.w - h3 * s.w);  nhi.w = f2bf(h3 * c.w + l3 * s.w);
  *(ushort4*)p = nlo;
  *(ushort4*)(p + 64) = nhi;
}

// ---------------- GEMM: C = A @ B^T, A[2048][2048] bf16, B[2048][2048] bf16 ----------------
// m97 structure: 128x128 tile, BK=32, 4 waves (2x2), 16x16x32 bf16 MFMA
template<int OUTF32>
__global__ __launch_bounds__(256)
void k_gemm_bt(const u16* __restrict__ A, const u16* __restrict__ B, void* __restrict__ C){
  __shared__ __align__(16) u16 As[128 * 32];
  __shared__ __align__(16) u16 Bs[128 * 32];
  const int tid = threadIdx.x;
  const int w = tid >> 6, lane = tid & 63;
  const int wr = w >> 1, wc = w & 1;
  const int g = lane >> 4, c15 = lane & 15;
  const int brow = blockIdx.y * 128, bcol = blockIdx.x * 128;
  const int wbase = tid & ~63;

  f32x4 acc[4][4];
#pragma unroll
  for (int m = 0; m < 4; m++)
#pragma unroll
    for (int n = 0; n < 4; n++) acc[m][n] = (f32x4){0.f, 0.f, 0.f, 0.f};

  for (int kt = 0; kt < 64; ++kt){
    const int k0 = kt * 32;
#pragma unroll
    for (int it = 0; it < 2; ++it){
      int m = it * 256 + tid;
      int row = m >> 2, q = m & 3;
      gload16(A + (size_t)(brow + row) * 2048 + k0 + q * 8, As + (it * 256 + wbase) * 8);
      gload16(B + (size_t)(bcol + row) * 2048 + k0 + q * 8, Bs + (it * 256 + wbase) * 8);
    }
    __syncthreads();
    bf16x8 af[4], bfr[4];
#pragma unroll
    for (int m = 0; m < 4; m++) af[m] = *(const bf16x8*)(As + (wr * 64 + m * 16 + c15) * 32 + g * 8);
#pragma unroll
    for (int n = 0; n < 4; n++) bfr[n] = *(const bf16x8*)(Bs + (wc * 64 + n * 16 + c15) * 32 + g * 8);
#pragma unroll
    for (int m = 0; m < 4; m++)
#pragma unroll
      for (int n = 0; n < 4; n++)
        acc[m][n] = __builtin_amdgcn_mfma_f32_16x16x32_bf16(af[m], bfr[n], acc[m][n], 0, 0, 0);
    __syncthreads();
  }
#pragma unroll
  for (int m = 0; m < 4; m++)
#pragma unroll
    for (int n = 0; n < 4; n++)
#pragma unroll
      for (int r = 0; r < 4; r++){
        int row = brow + wr * 64 + m * 16 + g * 4 + r;
        int col = bcol + wc * 64 + n * 16 + c15;
        float val = acc[m][n][r];
        if (OUTF32) ((float*)C)[(size_t)row * 2048 + col] = val;
        else        ((u16*)C)[(size_t)row * 2048 + col] = f2bf(val);
      }
}

// ---------------- transpose V: [2048 s][2048 hd] -> [2048 hd][2048 s] ----------------
__global__ void k_transpose_v(const u16* __restrict__ V, u16* __restrict__ Vt){
  __shared__ u16 t[32][33];
  int s0 = blockIdx.x * 32, c0 = blockIdx.y * 32;
  int tid = threadIdx.x;
  int r = tid >> 3, cc = (tid & 7) * 4;
  ushort4 v = *(const ushort4*)(V + (size_t)(s0 + r) * 2048 + c0 + cc);
  t[r][cc] = v.x; t[r][cc + 1] = v.y; t[r][cc + 2] = v.z; t[r][cc + 3] = v.w;
  __syncthreads();
  int co = tid >> 3, ro = (tid & 7) * 4;
  ushort4 o;
  o.x = t[ro][co]; o.y = t[ro + 1][co]; o.z = t[ro + 2][co]; o.w = t[ro + 3][co];
  *(ushort4*)(Vt + (size_t)(c0 + co) * 2048 + s0 + ro) = o;
}

__global__ void k_zero(float* __restrict__ p, int n){
  int i = blockIdx.x * 256 + threadIdx.x;
  if (i < n) p[i] = 0.f;
}

// ---------------- pass 1: full causal softmax column sums ----------------
// grid (32 qblocks, 16 heads), 256 threads. Two sweeps over k-tiles (recompute QK^T).
__global__ __launch_bounds__(256)
void k_pass1(const u16* __restrict__ Q, const u16* __restrict__ K, float* __restrict__ colsum){
  __shared__ __align__(16) u16 Qs[64 * 128];
  __shared__ __align__(16) u16 Ks[64 * 128];
  __shared__ float cs[2048];
  const int tid = threadIdx.x;
  const int w = tid >> 6, lane = tid & 63;
  const int g = lane >> 4, c15 = lane & 15;
  const int qb = blockIdx.x, h = blockIdx.y;
  const int i0 = qb * 64;
  const int wbase = tid & ~63;
  const float scale = 0.08838834764831845f;   // 1/sqrt(128)

#pragma unroll
  for (int it = 0; it < 4; ++it){              // stage Q tile, swizzled source
    int m = it * 256 + tid;
    int row = m >> 4, cp = m & 15;
    gload16(Q + (size_t)(i0 + row) * 2048 + h * HDIM + ((cp ^ (row & 7)) * 8),
            Qs + (it * 256 + wbase) * 8);
  }
  for (int i = tid; i < 2048; i += 256) cs[i] = 0.f;

  const int nkt = qb + 1;
  float lsum[4] = {0.f, 0.f, 0.f, 0.f};
  const int arow = w * 16 + c15;

  // ---- sweep 1: row sums of exp(s) ----
  for (int kt = 0; kt < nkt; ++kt){
    int k0 = kt * 64;
#pragma unroll
    for (int it = 0; it < 4; ++it){
      int m = it * 256 + tid;
      int row = m >> 4, cp = m & 15;
      gload16(K + (size_t)(k0 + row) * 2048 + h * HDIM + ((cp ^ (row & 7)) * 8),
              Ks + (it * 256 + wbase) * 8);
    }
    __syncthreads();
    f32x4 sacc[4];
#pragma unroll
    for (int n = 0; n < 4; n++) sacc[n] = (f32x4){0.f, 0.f, 0.f, 0.f};
#pragma unroll
    for (int ks = 0; ks < 4; ++ks){
      bf16x8 a = *(const bf16x8*)(Qs + arow * 128 + ((ks * 32 + g * 8) ^ ((arow & 7) << 3)));
#pragma unroll
      for (int n = 0; n < 4; n++){
        int brw = n * 16 + c15;
        bf16x8 b = *(const bf16x8*)(Ks + brw * 128 + ((ks * 32 + g * 8) ^ ((brw & 7) << 3)));
        sacc[n] = __builtin_amdgcn_mfma_f32_16x16x32_bf16(a, b, sacc[n], 0, 0, 0);
      }
    }
    float rs[4] = {0.f, 0.f, 0.f, 0.f};
#pragma unroll
    for (int n = 0; n < 4; n++){
      int col = k0 + n * 16 + c15;
#pragma unroll
      for (int r = 0; r < 4; r++){
        int rowg = i0 + w * 16 + g * 4 + r;
        float e = (col <= rowg) ? __expf(sacc[n][r] * scale) : 0.f;
        rs[r] += e;
      }
    }
#pragma unroll
    for (int r = 0; r < 4; r++){
      float v = rs[r];
      v += __shfl_xor(v, 1); v += __shfl_xor(v, 2);
      v += __shfl_xor(v, 4); v += __shfl_xor(v, 8);
      lsum[r] += v;
    }
    __syncthreads();
  }
  float rinv[4];
#pragma unroll
  for (int r = 0; r < 4; r++) rinv[r] = 1.0f / lsum[r];

  // ---- sweep 2: accumulate normalized column sums ----
  for (int kt = 0; kt < nkt; ++kt){
    int k0 = kt * 64;
#pragma unroll
    for (int it = 0; it < 4; ++it){
      int m = it * 256 + tid;
      int row = m >> 4, cp = m & 15;
      gload16(K + (size_t)(k0 + row) * 2048 + h * HDIM + ((cp ^ (row & 7)) * 8),
              Ks + (it * 256 + wbase) * 8);
    }
    __syncthreads();
    f32x4 sacc[4];
#pragma unroll
    for (int n = 0; n < 4; n++) sacc[n] = (f32x4){0.f, 0.f, 0.f, 0.f};
#pragma unroll
    for (int ks = 0; ks < 4; ++ks){
      bf16x8 a = *(const bf16x8*)(Qs + arow * 128 + ((ks * 32 + g * 8) ^ ((arow & 7) << 3)));
#pragma unroll
      for (int n = 0; n < 4; n++){
        int brw = n * 16 + c15;
        bf16x8 b = *(const bf16x8*)(Ks + brw * 128 + ((ks * 32 + g * 8) ^ ((brw & 7) << 3)));
        sacc[n] = __builtin_amdgcn_mfma_f32_16x16x32_bf16(a, b, sacc[n], 0, 0, 0);
      }
    }
    float cp4[4];
#pragma unroll
    for (int n = 0; n < 4; n++){
      int col = k0 + n * 16 + c15;
      float cpart = 0.f;
#pragma unroll
      for (int r = 0; r < 4; r++){
        int rowg = i0 + w * 16 + g * 4 + r;
        float e = (col <= rowg) ? __expf(sacc[n][r] * scale) * rinv[r] : 0.f;
        cpart += e;
      }
      cpart += __shfl_xor(cpart, 16);
      cpart += __shfl_xor(cpart, 32);
      cp4[n] = cpart;
    }
    if (g == 0){
#pragma unroll
      for (int n = 0; n < 4; n++) atomicAdd(&cs[k0 + n * 16 + c15], cp4[n]);
    }
    __syncthreads();
  }
  for (int i = tid; i < i0 + 64; i += 256) atomicAdd(&colsum[h * 2048 + i], cs[i]);
}

// ---------------- top-k (204) per head via bitonic sort ----------------
__global__ __launch_bounds__(256)
void k_topk(const float* __restrict__ colsum, unsigned char* __restrict__ heavy,
            unsigned char* __restrict__ htile){
  __shared__ float v[2048];
  __shared__ short ix[2048];
  __shared__ unsigned char fl[2048];
  __shared__ int tf[32];
  const int tid = threadIdx.x;
  const int h = blockIdx.x;
  for (int i = tid; i < 2048; i += 256){ v[i] = colsum[h * 2048 + i]; ix[i] = (short)i; fl[i] = 0; }
  if (tid < 32) tf[tid] = 0;
  __syncthreads();
  for (int k = 2; k <= 2048; k <<= 1){
    for (int j = k >> 1; j > 0; j >>= 1){
      for (int n = tid; n < 1024; n += 256){
        int i = ((n / j) * (j << 1)) + (n % j);
        int l = i + j;
        float vi = v[i], vl = v[l];
        short ii = ix[i], il = ix[l];
        bool before_i = (vi > vl) || (vi == vl && ii < il);  // i ranks before l (descending, idx tiebreak)
        bool dir = (i & k) == 0;
        if (dir ? !before_i : before_i){ v[i] = vl; v[l] = vi; ix[i] = il; ix[l] = ii; }
      }
      __syncthreads();
    }
  }
  if (tid < HEAVY){ int id = ix[tid]; fl[id] = 1; atomicOr(&tf[id >> 6], 1); }
  __syncthreads();
  for (int i = tid; i < 2048; i += 256) heavy[h * 2048 + i] = fl[i];
  if (tid < 32) htile[h * 32 + tid] = (unsigned char)(tf[tid] ? 1 : 0);
}

// ---------------- pass 2: masked flash attention ----------------
__global__ __launch_bounds__(256)
void k_pass2(const u16* __restrict__ Q, const u16* __restrict__ K, const u16* __restrict__ Vt,
             const unsigned char* __restrict__ heavy, const unsigned char* __restrict__ htile,
             u16* __restrict__ attn){
  __shared__ __align__(16) u16 Qs[64 * 128];
  __shared__ __align__(16) u16 Ks[64 * 128];
  __shared__ __align__(16) u16 Vs[128 * 64];
  __shared__ __align__(16) u16 Ps[4][16 * 64];
  __shared__ unsigned char hf[64];
  const int tid = threadIdx.x;
  const int w = tid >> 6, lane = tid & 63;
  const int g = lane >> 4, c15 = lane & 15;
  const int qb = blockIdx.x, h = blockIdx.y;
  const int i0 = qb * 64;
  const int wbase = tid & ~63;
  const float scale = 0.08838834764831845f;

#pragma unroll
  for (int it = 0; it < 4; ++it){
    int m = it * 256 + tid;
    int row = m >> 4, cp = m & 15;
    gload16(Q + (size_t)(i0 + row) * 2048 + h * HDIM + ((cp ^ (row & 7)) * 8),
            Qs + (it * 256 + wbase) * 8);
  }

  f32x4 oacc[8];
#pragma unroll
  for (int f = 0; f < 8; f++) oacc[f] = (f32x4){0.f, 0.f, 0.f, 0.f};
  float lsum[4] = {0.f, 0.f, 0.f, 0.f};
  const int arow = w * 16 + c15;
  const int nkt = qb + 1;

  for (int kt = 0; kt < nkt; ++kt){
    int k0 = kt * 64;
    bool band = (k0 + 63 >= i0 - RECENT);
    bool hv = htile[h * 32 + kt] != 0;
    if (!band && !hv) continue;
#pragma unroll
    for (int it = 0; it < 4; ++it){
      int m = it * 256 + tid;
      int row = m >> 4, cp = m & 15;
      gload16(K + (size_t)(k0 + row) * 2048 + h * HDIM + ((cp ^ (row & 7)) * 8),
              Ks + (it * 256 + wbase) * 8);
      int rowv = m >> 3, cpv = m & 7;
      gload16(Vt + ((size_t)h * HDIM + rowv) * 2048 + k0 + ((cpv ^ (rowv & 7)) * 8),
              Vs + (it * 256 + wbase) * 8);
    }
    if (tid < 64) hf[tid] = heavy[h * 2048 + k0 + tid];
    __syncthreads();

    f32x4 sacc[4];
#pragma unroll
    for (int n = 0; n < 4; n++) sacc[n] = (f32x4){0.f, 0.f, 0.f, 0.f};
#pragma unroll
    for (int ks = 0; ks < 4; ++ks){
      bf16x8 a = *(const bf16x8*)(Qs + arow * 128 + ((ks * 32 + g * 8) ^ ((arow & 7) << 3)));
#pragma unroll
      for (int n = 0; n < 4; n++){
        int brw = n * 16 + c15;
        bf16x8 b = *(const bf16x8*)(Ks + brw * 128 + ((ks * 32 + g * 8) ^ ((brw & 7) << 3)));
        sacc[n] = __builtin_amdgcn_mfma_f32_16x16x32_bf16(a, b, sacc[n], 0, 0, 0);
      }
    }
    float rs[4] = {0.f, 0.f, 0.f, 0.f};
#pragma unroll
    for (int n = 0; n < 4; n++){
      int col = k0 + n * 16 + c15;
      int hfv = hf[n * 16 + c15];
#pragma unroll
      for (int r = 0; r < 4; r++){
        int rowg = i0 + w * 16 + g * 4 + r;
        bool valid = (col <= rowg) && (hfv || (rowg - col) <= RECENT);
        float e = valid ? __expf(sacc[n][r] * scale) : 0.f;
        rs[r] += e;
        int prow = g * 4 + r;
        Ps[w][prow * 64 + ((n * 16 + c15) ^ ((prow & 7) << 3))] = f2bf(e);
      }
    }
#pragma unroll
    for (int r = 0; r < 4; r++){
      float vv = rs[r];
      vv += __shfl_xor(vv, 1); vv += __shfl_xor(vv, 2);
      vv += __shfl_xor(vv, 4); vv += __shfl_xor(vv, 8);
      lsum[r] += vv;
    }
    // PV: O += P @ V  (P: [16 q][64 k], Vt tile: [128 d][64 k])
#pragma unroll
    for (int ks2 = 0; ks2 < 2; ++ks2){
      bf16x8 pa = *(const bf16x8*)(&Ps[w][c15 * 64 + ((ks2 * 32 + g * 8) ^ ((c15 & 7) << 3))]);
#pragma unroll
      for (int f = 0; f < 8; ++f){
        int vrow = f * 16 + c15;
        bf16x8 vb = *(const bf16x8*)(Vs + vrow * 64 + ((ks2 * 32 + g * 8) ^ ((vrow & 7) << 3)));
        oacc[f] = __builtin_amdgcn_mfma_f32_16x16x32_bf16(pa, vb, oacc[f], 0, 0, 0);
      }
    }
    __syncthreads();
  }
  float rinv[4];
#pragma unroll
  for (int r = 0; r < 4; r++) rinv[r] = 1.0f / lsum[r];
#pragma unroll
  for (int f = 0; f < 8; f++)
#pragma unroll
    for (int r = 0; r < 4; r++){
      int rowg = i0 + w * 16 + g * 4 + r;
      attn[(size_t)rowg * 2048 + h * HDIM + f * 16 + c15] = f2bf(oacc[f][r] * rinv[r]);
    }
}

// ---------------- host launcher ----------------
extern "C" void kernel_launch(void* const* d_in, const int* in_sizes, int n_in,
                              void* d_out, int out_size, void* d_ws, size_t ws_size,
                              hipStream_t stream){
  const float* X  = (const float*)d_in[0];
  const float* Wq = (const float*)d_in[1];
  const float* Wk = (const float*)d_in[2];
  const float* Wv = (const float*)d_in[3];
  const float* Wo = (const float*)d_in[4];

  char* w = (char*)d_ws;
  const size_t MB = (size_t)2048 * 2048 * 2;   // one bf16 matrix = 8 MiB
  u16* Xb  = (u16*)(w);
  u16* Wqb = (u16*)(w + 1 * MB);
  u16* Wkb = (u16*)(w + 2 * MB);
  u16* Wvb = (u16*)(w + 3 * MB);
  u16* Wob = (u16*)(w + 4 * MB);
  u16* Qb  = (u16*)(w + 5 * MB);
  u16* Kb  = (u16*)(w + 6 * MB);
  u16* Vb  = (u16*)(w + 7 * MB);
  u16* Vtb   = Wqb;   // Wq dead after Q projection
  u16* attnb = Xb;    // X dead after V projection
  float* cosT   = (float*)(w + 8 * MB);
  float* sinT   = (float*)(w + 8 * MB + 524288);
  float* colsum = (float*)(w + 8 * MB + 1048576);
  unsigned char* heavy = (unsigned char*)(w + 8 * MB + 1048576 + 131072);
  unsigned char* htile = heavy + 16 * 2048;

  dim3 b256(256);
  const int NEL = 2048 * 2048;

  k_f32_to_bf16<<<4096, b256, 0, stream>>>(X,  Xb,  NEL);
  k_f32_to_bf16<<<4096, b256, 0, stream>>>(Wq, Wqb, NEL);
  k_f32_to_bf16<<<4096, b256, 0, stream>>>(Wk, Wkb, NEL);
  k_f32_to_bf16<<<4096, b256, 0, stream>>>(Wv, Wvb, NEL);
  k_f32_to_bf16<<<4096, b256, 0, stream>>>(Wo, Wob, NEL);
  k_rope_tab<<<512, b256, 0, stream>>>(cosT, sinT);

  k_gemm_bt<0><<<dim3(16, 16), b256, 0, stream>>>(Xb, Wqb, Qb);
  k_gemm_bt<0><<<dim3(16, 16), b256, 0, stream>>>(Xb, Wkb, Kb);
  k_gemm_bt<0><<<dim3(16, 16), b256, 0, stream>>>(Xb, Wvb, Vb);

  k_rope_apply<<<2048, b256, 0, stream>>>(Qb, cosT, sinT);
  k_rope_apply<<<2048, b256, 0, stream>>>(Kb, cosT, sinT);
  k_transpose_v<<<dim3(64, 64), b256, 0, stream>>>(Vb, Vtb);

  k_zero<<<128, b256, 0, stream>>>(colsum, 16 * 2048);
  k_pass1<<<dim3(32, 16), b256, 0, stream>>>(Qb, Kb, colsum);
  k_topk<<<16, b256, 0, stream>>>(colsum, heavy, htile);
  k_pass2<<<dim3(32, 16), b256, 0, stream>>>(Qb, Kb, Vtb, heavy, htile, attnb);

  k_gemm_bt<1><<<dim3(16, 16), b256, 0, stream>>>(attnb, Wob, d_out);
}

// Round 2
// 362.272 us; speedup vs baseline: 1.1142x; 1.1142x over previous
//
#include <hip/hip_runtime.h>
#include <hip/hip_bf16.h>
#include <stdint.h>

// Problem constants: b=1, s=2048, hidden=2048, H=16, d=128
#define SEQ   2048
#define HIDN  2048
#define NHEAD 16
#define HDIM  128
#define HEAVY 204   // int(0.1*2048)
#define RECENT 204

typedef __attribute__((ext_vector_type(4))) float f32x4;
typedef __attribute__((ext_vector_type(8))) short bf16x8;
typedef unsigned short u16;
typedef unsigned int   u32;

static __device__ __forceinline__ u16 f2bf(float f){
  union { float f; u32 u; } v; v.f = f;
  u32 r = (v.u + 0x7FFFu + ((v.u >> 16) & 1u)) >> 16;
  return (u16)r;
}
static __device__ __forceinline__ float bf2f(u16 u){
  union { u32 u; float f; } v; v.u = ((u32)u) << 16;
  return v.f;
}

// global -> LDS direct 16B load (dest is wave-uniform base + lane*16)
static __device__ __forceinline__ void gload16(const void* g, void* l){
  __builtin_amdgcn_global_load_lds((const __attribute__((address_space(1))) u32*)g,
                                   (__attribute__((address_space(3))) u32*)l, 16, 0, 0);
}

// stage a 64x128 bf16 tile (XOR-swizzled source so swizzled ds_read is conflict-free)
static __device__ __forceinline__ void stage_tile(const u16* __restrict__ base, int row0,
                                                  u16* __restrict__ lds, int tid){
  const int wbase = tid & ~63;
#pragma unroll
  for (int it = 0; it < 4; ++it){
    int m = it * 256 + tid;
    int row = m >> 4, cp = m & 15;
    gload16(base + (size_t)(row0 + row) * 2048 + ((cp ^ (row & 7)) * 8),
            lds + (it * 256 + wbase) * 8);
  }
}

// triangle chunk mapping: bx -> (t, c) where t has t>>LOG2CH)+1 chunks
template<int LOG2CH>
static __device__ __forceinline__ void tri_map(int bx, int& t, int& c){
  int rem = bx; int q = 0;
  while (rem >= ((q >> LOG2CH) + 1)){ rem -= (q >> LOG2CH) + 1; q++; }
  t = q; c = rem;
}

// ---------------- converts + RoPE ----------------
__global__ void k_cvt5(const float* __restrict__ A0, const float* __restrict__ A1,
                       const float* __restrict__ A2, const float* __restrict__ A3,
                       const float* __restrict__ A4, u16* __restrict__ out){
  int id = blockIdx.x * 256 + threadIdx.x;         // 5 * 1048576 ids, 4 elems each
  int sel = id >> 20, off = (id & 1048575) * 4;
  const float* src = sel == 0 ? A0 : sel == 1 ? A1 : sel == 2 ? A2 : sel == 3 ? A3 : A4;
  float4 v = *(const float4*)(src + off);
  ushort4 o;
  o.x = f2bf(v.x); o.y = f2bf(v.y); o.z = f2bf(v.z); o.w = f2bf(v.w);
  *(ushort4*)(out + (size_t)sel * 4194304 + off) = o;
}

__global__ void k_rope_tab(float* __restrict__ cosT, float* __restrict__ sinT){
  int i = blockIdx.x * 256 + threadIdx.x;        // 2048*64
  int pos = i >> 6, j = i & 63;
  float invf = powf(10000.0f, -(float)j * (1.0f / 64.0f));
  float a = (float)pos * invf;
  cosT[i] = cosf(a);
  sinT[i] = sinf(a);
}

// rotary in-place on Q and K (sel by gid), pairs (j, j+64) within each head
__global__ void k_rope2(u16* __restrict__ Qm, u16* __restrict__ Km,
                        const float* __restrict__ cosT, const float* __restrict__ sinT){
  int gid = blockIdx.x * 256 + threadIdx.x;      // 2 * 524288
  u16* M = (gid < 524288) ? Qm : Km;
  int id = gid & 524287;
  int pos = id >> 8, rem = id & 255;
  int h = rem >> 4, j4 = (rem & 15) * 4;
  u16* p = M + (size_t)pos * HIDN + h * HDIM + j4;
  ushort4 lo = *(ushort4*)p;
  ushort4 hi = *(ushort4*)(p + 64);
  float4 c = *(const float4*)(cosT + pos * 64 + j4);
  float4 s = *(const float4*)(sinT + pos * 64 + j4);
  float l0 = bf2f(lo.x), l1 = bf2f(lo.y), l2 = bf2f(lo.z), l3 = bf2f(lo.w);
  float h0 = bf2f(hi.x), h1 = bf2f(hi.y), h2 = bf2f(hi.z), h3 = bf2f(hi.w);
  ushort4 nlo, nhi;
  nlo.x = f2bf(l0 * c.x - h0 * s.x);  nhi.x = f2bf(h0 * c.x + l0 * s.x);
  nlo.y = f2bf(l1 * c.y - h1 * s.y);  nhi.y = f2bf(h1 * c.y + l1 * s.y);
  nlo.z = f2bf(l2 * c.z - h2 * s.z);  nhi.z = f2bf(h2 * c.z + l2 * s.z);
  nlo.w = f2bf(l3 * c.w - h3 * s.w);  nhi.w = f2bf(h3 * c.w + l3 * s.w);
  *(ushort4*)p = nlo;
  *(ushort4*)(p + 64) = nhi;
}

__global__ void k_zero4(float* __restrict__ p, int n4){
  for (int i = blockIdx.x * 256 + threadIdx.x; i < n4; i += gridDim.x * 256)
    ((float4*)p)[i] = (float4){0.f, 0.f, 0.f, 0.f};
}

// ---------------- GEMM pieces (128x128 tile, BK=32, 2-phase dbuf) ----------------
static __device__ __forceinline__ void stage_g(const u16* __restrict__ A, const u16* __restrict__ B,
                                               int brow, int bcol, int k0,
                                               u16* __restrict__ as, u16* __restrict__ bs, int tid){
  const int wbase = tid & ~63;
#pragma unroll
  for (int it = 0; it < 2; ++it){
    int m = it * 256 + tid;
    int row = m >> 2, q = m & 3;
    gload16(A + (size_t)(brow + row) * 2048 + k0 + q * 8, as + (it * 256 + wbase) * 8);
    gload16(B + (size_t)(bcol + row) * 2048 + k0 + q * 8, bs + (it * 256 + wbase) * 8);
  }
}

// batched Q/K/V projection: grid (16,16,3)
__global__ __launch_bounds__(256)
void k_proj3(const u16* __restrict__ X, const u16* __restrict__ W0, const u16* __restrict__ W1,
             const u16* __restrict__ W2, u16* __restrict__ C0, u16* __restrict__ C1,
             u16* __restrict__ C2){
  __shared__ __align__(16) u16 As[2][128 * 32];
  __shared__ __align__(16) u16 Bs[2][128 * 32];
  const u16* B = blockIdx.z == 0 ? W0 : blockIdx.z == 1 ? W1 : W2;
  u16* C = blockIdx.z == 0 ? C0 : blockIdx.z == 1 ? C1 : C2;
  const int tid = threadIdx.x;
  const int w = tid >> 6, lane = tid & 63;
  const int wr = w >> 1, wc = w & 1;
  const int g = lane >> 4, c15 = lane & 15;
  const int brow = blockIdx.y * 128, bcol = blockIdx.x * 128;

  f32x4 acc[4][4];
#pragma unroll
  for (int m = 0; m < 4; m++)
#pragma unroll
    for (int n = 0; n < 4; n++) acc[m][n] = (f32x4){0.f, 0.f, 0.f, 0.f};

  stage_g(X, B, brow, bcol, 0, As[0], Bs[0], tid);
  __syncthreads();
  int cur = 0;
  for (int kt = 0; kt < 64; ++kt){
    if (kt + 1 < 64) stage_g(X, B, brow, bcol, (kt + 1) * 32, As[cur ^ 1], Bs[cur ^ 1], tid);
    bf16x8 af[4], bfr[4];
#pragma unroll
    for (int m = 0; m < 4; m++) af[m] = *(const bf16x8*)(As[cur] + (wr * 64 + m * 16 + c15) * 32 + g * 8);
#pragma unroll
    for (int n = 0; n < 4; n++) bfr[n] = *(const bf16x8*)(Bs[cur] + (wc * 64 + n * 16 + c15) * 32 + g * 8);
#pragma unroll
    for (int m = 0; m < 4; m++)
#pragma unroll
      for (int n = 0; n < 4; n++)
        acc[m][n] = __builtin_amdgcn_mfma_f32_16x16x32_bf16(af[m], bfr[n], acc[m][n], 0, 0, 0);
    __syncthreads();
    cur ^= 1;
  }
#pragma unroll
  for (int m = 0; m < 4; m++)
#pragma unroll
    for (int n = 0; n < 4; n++)
#pragma unroll
      for (int r = 0; r < 4; r++){
        int row = brow + wr * 64 + m * 16 + g * 4 + r;
        int col = bcol + wc * 64 + n * 16 + c15;
        C[(size_t)row * 2048 + col] = f2bf(acc[m][n][r]);
      }
}

// output GEMM split-K=2: grid (16,16,2), atomicAdd f32 into zeroed d_out
__global__ __launch_bounds__(256)
void k_gemm_out(const u16* __restrict__ A, const u16* __restrict__ B, float* __restrict__ C){
  __shared__ __align__(16) u16 As[2][128 * 32];
  __shared__ __align__(16) u16 Bs[2][128 * 32];
  const int tid = threadIdx.x;
  const int w = tid >> 6, lane = tid & 63;
  const int wr = w >> 1, wc = w & 1;
  const int g = lane >> 4, c15 = lane & 15;
  const int brow = blockIdx.y * 128, bcol = blockIdx.x * 128;
  const int kbase = blockIdx.z * 1024;

  f32x4 acc[4][4];
#pragma unroll
  for (int m = 0; m < 4; m++)
#pragma unroll
    for (int n = 0; n < 4; n++) acc[m][n] = (f32x4){0.f, 0.f, 0.f, 0.f};

  stage_g(A, B, brow, bcol, kbase, As[0], Bs[0], tid);
  __syncthreads();
  int cur = 0;
  for (int kt = 0; kt < 32; ++kt){
    if (kt + 1 < 32) stage_g(A, B, brow, bcol, kbase + (kt + 1) * 32, As[cur ^ 1], Bs[cur ^ 1], tid);
    bf16x8 af[4], bfr[4];
#pragma unroll
    for (int m = 0; m < 4; m++) af[m] = *(const bf16x8*)(As[cur] + (wr * 64 + m * 16 + c15) * 32 + g * 8);
#pragma unroll
    for (int n = 0; n < 4; n++) bfr[n] = *(const bf16x8*)(Bs[cur] + (wc * 64 + n * 16 + c15) * 32 + g * 8);
#pragma unroll
    for (int m = 0; m < 4; m++)
#pragma unroll
      for (int n = 0; n < 4; n++)
        acc[m][n] = __builtin_amdgcn_mfma_f32_16x16x32_bf16(af[m], bfr[n], acc[m][n], 0, 0, 0);
    __syncthreads();
    cur ^= 1;
  }
#pragma unroll
  for (int m = 0; m < 4; m++)
#pragma unroll
    for (int n = 0; n < 4; n++)
#pragma unroll
      for (int r = 0; r < 4; r++){
        int row = brow + wr * 64 + m * 16 + g * 4 + r;
        int col = bcol + wc * 64 + n * 16 + c15;
        atomicAdd(&C[(size_t)row * 2048 + col], acc[m][n][r]);
      }
}

// ---------------- transpose V: [2048 s][2048 hd] -> [2048 hd][2048 s] ----------------
__global__ void k_transpose_v(const u16* __restrict__ V, u16* __restrict__ Vt){
  __shared__ u16 t[32][33];
  int s0 = blockIdx.x * 32, c0 = blockIdx.y * 32;
  int tid = threadIdx.x;
  int r = tid >> 3, cc = (tid & 7) * 4;
  ushort4 v = *(const ushort4*)(V + (size_t)(s0 + r) * 2048 + c0 + cc);
  t[r][cc] = v.x; t[r][cc + 1] = v.y; t[r][cc + 2] = v.z; t[r][cc + 3] = v.w;
  __syncthreads();
  int co = tid >> 3, ro = (tid & 7) * 4;
  ushort4 o;
  o.x = t[ro][co]; o.y = t[ro + 1][co]; o.z = t[ro + 2][co]; o.w = t[ro + 3][co];
  *(ushort4*)(Vt + (size_t)(c0 + co) * 2048 + s0 + ro) = o;
}

// ---------------- pass 1a: rowsum of exp (causal), triangle-chunked ----------------
// grid (80, 16): bx -> (qb, chunk of 8 k-tiles)
__global__ __launch_bounds__(256)
void k_pass1a(const u16* __restrict__ Q, const u16* __restrict__ K, float* __restrict__ rowsum){
  __shared__ __align__(16) u16 Qs[64 * 128];
  __shared__ __align__(16) u16 Ks[2][64 * 128];
  const int tid = threadIdx.x;
  const int w = tid >> 6, lane = tid & 63;
  const int g = lane >> 4, c15 = lane & 15;
  const int h = blockIdx.y;
  int qb, c; tri_map<3>(blockIdx.x, qb, c);
  const int i0 = qb * 64;
  const int kt0 = c * 8;
  const int kt1 = (qb + 1 < kt0 + 8) ? (qb + 1) : (kt0 + 8);
  const u16* Qh = Q + h * HDIM;
  const u16* Kh = K + h * HDIM;
  const float scale = 0.08838834764831845f;
  const int arow = w * 16 + c15;

  stage_tile(Qh, i0, Qs, tid);
  stage_tile(Kh, kt0 * 64, Ks[0], tid);
  __syncthreads();

  float lsum[4] = {0.f, 0.f, 0.f, 0.f};
  int cur = 0;
  for (int kt = kt0; kt < kt1; ++kt){
    if (kt + 1 < kt1) stage_tile(Kh, (kt + 1) * 64, Ks[cur ^ 1], tid);
    const int k0 = kt * 64;
    f32x4 sacc[4];
#pragma unroll
    for (int n = 0; n < 4; n++) sacc[n] = (f32x4){0.f, 0.f, 0.f, 0.f};
#pragma unroll
    for (int ks = 0; ks < 4; ++ks){
      bf16x8 a = *(const bf16x8*)(Qs + arow * 128 + ((ks * 32 + g * 8) ^ ((arow & 7) << 3)));
#pragma unroll
      for (int n = 0; n < 4; n++){
        int brw = n * 16 + c15;
        bf16x8 b = *(const bf16x8*)(Ks[cur] + brw * 128 + ((ks * 32 + g * 8) ^ ((brw & 7) << 3)));
        sacc[n] = __builtin_amdgcn_mfma_f32_16x16x32_bf16(a, b, sacc[n], 0, 0, 0);
      }
    }
    float rs[4] = {0.f, 0.f, 0.f, 0.f};
#pragma unroll
    for (int n = 0; n < 4; n++){
      int col = k0 + n * 16 + c15;
#pragma unroll
      for (int r = 0; r < 4; r++){
        int rowg = i0 + w * 16 + g * 4 + r;
        rs[r] += (col <= rowg) ? __expf(sacc[n][r] * scale) : 0.f;
      }
    }
#pragma unroll
    for (int r = 0; r < 4; r++){
      float v = rs[r];
      v += __shfl_xor(v, 1); v += __shfl_xor(v, 2);
      v += __shfl_xor(v, 4); v += __shfl_xor(v, 8);
      lsum[r] += v;
    }
    __syncthreads();
    cur ^= 1;
  }
  if (c15 == 0){
#pragma unroll
    for (int r = 0; r < 4; r++)
      atomicAdd(&rowsum[h * 2048 + i0 + w * 16 + g * 4 + r], lsum[r]);
  }
}

// ---------------- pass 1b: colsum of normalized exp, triangle-chunked over q ----------------
// grid (80, 16): bx -> (t, c), kb = 31 - t, q-tiles [kb + c*8, ...)
__global__ __launch_bounds__(256)
void k_pass1b(const u16* __restrict__ Q, const u16* __restrict__ K,
              const float* __restrict__ rowsum, float* __restrict__ colsum){
  __shared__ __align__(16) u16 Ks[64 * 128];
  __shared__ __align__(16) u16 Qs[2][64 * 128];
  __shared__ float cw[4][64];
  const int tid = threadIdx.x;
  const int w = tid >> 6, lane = tid & 63;
  const int g = lane >> 4, c15 = lane & 15;
  const int h = blockIdx.y;
  int t, c; tri_map<3>(blockIdx.x, t, c);
  const int kb = 31 - t;
  const int k0 = kb * 64;
  const int qstart = kb + c * 8;
  const int qend = (qstart + 8 < 32) ? (qstart + 8) : 32;
  const u16* Qh = Q + h * HDIM;
  const u16* Kh = K + h * HDIM;
  const float scale = 0.08838834764831845f;
  const int arow = w * 16 + c15;

  stage_tile(Kh, k0, Ks, tid);
  stage_tile(Qh, qstart * 64, Qs[0], tid);
  __syncthreads();

  float racc[4] = {0.f, 0.f, 0.f, 0.f};
  int cur = 0;
  for (int qt = qstart; qt < qend; ++qt){
    if (qt + 1 < qend) stage_tile(Qh, (qt + 1) * 64, Qs[cur ^ 1], tid);
    const int i0 = qt * 64;
    float rinv[4];
#pragma unroll
    for (int r = 0; r < 4; r++)
      rinv[r] = 1.0f / rowsum[h * 2048 + i0 + w * 16 + g * 4 + r];
    f32x4 sacc[4];
#pragma unroll
    for (int n = 0; n < 4; n++) sacc[n] = (f32x4){0.f, 0.f, 0.f, 0.f};
#pragma unroll
    for (int ks = 0; ks < 4; ++ks){
      bf16x8 a = *(const bf16x8*)(Qs[cur] + arow * 128 + ((ks * 32 + g * 8) ^ ((arow & 7) << 3)));
#pragma unroll
      for (int n = 0; n < 4; n++){
        int brw = n * 16 + c15;
        bf16x8 b = *(const bf16x8*)(Ks + brw * 128 + ((ks * 32 + g * 8) ^ ((brw & 7) << 3)));
        sacc[n] = __builtin_amdgcn_mfma_f32_16x16x32_bf16(a, b, sacc[n], 0, 0, 0);
      }
    }
#pragma unroll
    for (int n = 0; n < 4; n++){
      int col = k0 + n * 16 + c15;
      float cpart = 0.f;
#pragma unroll
      for (int r = 0; r < 4; r++){
        int rowg = i0 + w * 16 + g * 4 + r;
        cpart += (col <= rowg) ? __expf(sacc[n][r] * scale) * rinv[r] : 0.f;
      }
      cpart += __shfl_xor(cpart, 16);
      cpart += __shfl_xor(cpart, 32);
      racc[n] += cpart;
    }
    __syncthreads();
    cur ^= 1;
  }
  if (g == 0){
#pragma unroll
    for (int n = 0; n < 4; n++) cw[w][n * 16 + c15] = racc[n];
  }
  __syncthreads();
  if (tid < 64){
    float s = cw[0][tid] + cw[1][tid] + cw[2][tid] + cw[3][tid];
    atomicAdd(&colsum[h * 2048 + k0 + tid], s);
  }
}

// ---------------- top-k (204) per head via bitonic sort ----------------
__global__ __launch_bounds__(256)
void k_topk(const float* __restrict__ colsum, unsigned char* __restrict__ heavy,
            unsigned char* __restrict__ htile){
  __shared__ float v[2048];
  __shared__ short ix[2048];
  __shared__ unsigned char fl[2048];
  __shared__ int tf[32];
  const int tid = threadIdx.x;
  const int h = blockIdx.x;
  for (int i = tid; i < 2048; i += 256){ v[i] = colsum[h * 2048 + i]; ix[i] = (short)i; fl[i] = 0; }
  if (tid < 32) tf[tid] = 0;
  __syncthreads();
  for (int k = 2; k <= 2048; k <<= 1){
    for (int j = k >> 1; j > 0; j >>= 1){
      for (int n = tid; n < 1024; n += 256){
        int i = ((n / j) * (j << 1)) + (n % j);
        int l = i + j;
        float vi = v[i], vl = v[l];
        short ii = ix[i], il = ix[l];
        bool before_i = (vi > vl) || (vi == vl && ii < il);
        bool dir = (i & k) == 0;
        if (dir ? !before_i : before_i){ v[i] = vl; v[l] = vi; ix[i] = il; ix[l] = ii; }
      }
      __syncthreads();
    }
  }
  if (tid < HEAVY){ int id = ix[tid]; fl[id] = 1; atomicOr(&tf[id >> 6], 1); }
  __syncthreads();
  for (int i = tid; i < 2048; i += 256) heavy[h * 2048 + i] = fl[i];
  if (tid < 32) htile[h * 32 + tid] = (unsigned char)(tf[tid] ? 1 : 0);
}

// ---------------- pass 2: masked attention, triangle-chunked (CH=16), atomic O accumulate ----
// grid (48, 16)
__global__ __launch_bounds__(256)
void k_pass2(const u16* __restrict__ Q, const u16* __restrict__ K, const u16* __restrict__ Vt,
             const unsigned char* __restrict__ heavy, const unsigned char* __restrict__ htile,
             float* __restrict__ Oacc, float* __restrict__ rowsum2){
  __shared__ __align__(16) u16 Qs[64 * 128];
  __shared__ __align__(16) u16 Ks[2][64 * 128];
  __shared__ __align__(16) u16 Ps[4][16 * 64];
  __shared__ unsigned char hfa[16][64];
  __shared__ int lists[16];
  __shared__ int nact_s;
  const int tid = threadIdx.x;
  const int w = tid >> 6, lane = tid & 63;
  const int g = lane >> 4, c15 = lane & 15;
  const int h = blockIdx.y;
  int qb, c; tri_map<4>(blockIdx.x, qb, c);
  const int i0 = qb * 64;
  const int kt0 = c * 16;
  const int kt1 = (qb + 1 < kt0 + 16) ? (qb + 1) : (kt0 + 16);
  const u16* Qh = Q + h * HDIM;
  const u16* Kh = K + h * HDIM;
  const float scale = 0.08838834764831845f;
  const int arow = w * 16 + c15;

  if (tid == 0){
    int n = 0;
    for (int kt = kt0; kt < kt1; ++kt){
      bool band = (kt * 64 + 63 >= i0 - RECENT);
      bool hv = htile[h * 32 + kt] != 0;
      if (band || hv) lists[n++] = kt;
    }
    nact_s = n;
  }
  __syncthreads();
  const int nact = nact_s;
  if (nact == 0) return;

  for (int idx = tid; idx < nact * 64; idx += 256)
    hfa[idx >> 6][idx & 63] = heavy[h * 2048 + lists[idx >> 6] * 64 + (idx & 63)];
  stage_tile(Qh, i0, Qs, tid);
  stage_tile(Kh, lists[0] * 64, Ks[0], tid);
  __syncthreads();

  f32x4 oacc[8];
#pragma unroll
  for (int f = 0; f < 8; f++) oacc[f] = (f32x4){0.f, 0.f, 0.f, 0.f};
  float lsum[4] = {0.f, 0.f, 0.f, 0.f};

  int cur = 0;
  for (int i = 0; i < nact; ++i){
    const int kt = lists[i];
    const int k0 = kt * 64;
    if (i + 1 < nact) stage_tile(Kh, lists[i + 1] * 64, Ks[cur ^ 1], tid);
    // V fragments straight from global (L2-resident), issued early
    bf16x8 vf[2][8];
#pragma unroll
    for (int ks2 = 0; ks2 < 2; ++ks2)
#pragma unroll
      for (int f = 0; f < 8; ++f){
        int vrow = f * 16 + c15;
        vf[ks2][f] = *(const bf16x8*)(Vt + ((size_t)h * HDIM + vrow) * 2048 + k0 + ks2 * 32 + g * 8);
      }
    // QK^T
    f32x4 sacc[4];
#pragma unroll
    for (int n = 0; n < 4; n++) sacc[n] = (f32x4){0.f, 0.f, 0.f, 0.f};
#pragma unroll
    for (int ks = 0; ks < 4; ++ks){
      bf16x8 a = *(const bf16x8*)(Qs + arow * 128 + ((ks * 32 + g * 8) ^ ((arow & 7) << 3)));
#pragma unroll
      for (int n = 0; n < 4; n++){
        int brw = n * 16 + c15;
        bf16x8 b = *(const bf16x8*)(Ks[cur] + brw * 128 + ((ks * 32 + g * 8) ^ ((brw & 7) << 3)));
        sacc[n] = __builtin_amdgcn_mfma_f32_16x16x32_bf16(a, b, sacc[n], 0, 0, 0);
      }
    }
    // masked exp -> P (LDS, per-wave private), row sums
    float rs[4] = {0.f, 0.f, 0.f, 0.f};
#pragma unroll
    for (int n = 0; n < 4; n++){
      int col = k0 + n * 16 + c15;
      int hfv = hfa[i][n * 16 + c15];
#pragma unroll
      for (int r = 0; r < 4; r++){
        int rowg = i0 + w * 16 + g * 4 + r;
        bool valid = (col <= rowg) && (hfv || (rowg - col) <= RECENT);
        float e = valid ? __expf(sacc[n][r] * scale) : 0.f;
        rs[r] += e;
        int prow = g * 4 + r;
        Ps[w][prow * 64 + ((n * 16 + c15) ^ ((prow & 7) << 3))] = f2bf(e);
      }
    }
#pragma unroll
    for (int r = 0; r < 4; r++){
      float vv = rs[r];
      vv += __shfl_xor(vv, 1); vv += __shfl_xor(vv, 2);
      vv += __shfl_xor(vv, 4); vv += __shfl_xor(vv, 8);
      lsum[r] += vv;
    }
    // PV: O += P @ V
#pragma unroll
    for (int ks2 = 0; ks2 < 2; ++ks2){
      bf16x8 pa = *(const bf16x8*)(&Ps[w][c15 * 64 + ((ks2 * 32 + g * 8) ^ ((c15 & 7) << 3))]);
#pragma unroll
      for (int f = 0; f < 8; ++f)
        oacc[f] = __builtin_amdgcn_mfma_f32_16x16x32_bf16(pa, vf[ks2][f], oacc[f], 0, 0, 0);
    }
    __syncthreads();
    cur ^= 1;
  }
#pragma unroll
  for (int f = 0; f < 8; f++)
#pragma unroll
    for (int r = 0; r < 4; r++){
      int rowg = i0 + w * 16 + g * 4 + r;
      atomicAdd(&Oacc[(size_t)rowg * 2048 + h * HDIM + f * 16 + c15], oacc[f][r]);
    }
  if (c15 == 0){
#pragma unroll
    for (int r = 0; r < 4; r++)
      atomicAdd(&rowsum2[h * 2048 + i0 + w * 16 + g * 4 + r], lsum[r]);
  }
}

// ---------------- normalize: attn_bf16 = Oacc * (1/rowsum2) ----------------
__global__ void k_norm(const float* __restrict__ Oacc, const float* __restrict__ rowsum2,
                       u16* __restrict__ attn){
  int gid = blockIdx.x * 256 + threadIdx.x;      // 2048*512
  int row = gid >> 9;
  int c4 = (gid & 511) * 4;
  int h = c4 >> 7;
  float rinv = 1.0f / rowsum2[h * 2048 + row];
  float4 o = *(const float4*)(Oacc + (size_t)row * 2048 + c4);
  ushort4 ov;
  ov.x = f2bf(o.x * rinv); ov.y = f2bf(o.y * rinv);
  ov.z = f2bf(o.z * rinv); ov.w = f2bf(o.w * rinv);
  *(ushort4*)(attn + (size_t)row * 2048 + c4) = ov;
}

// ---------------- host launcher ----------------
extern "C" void kernel_launch(void* const* d_in, const int* in_sizes, int n_in,
                              void* d_out, int out_size, void* d_ws, size_t ws_size,
                              hipStream_t stream){
  const float* X  = (const float*)d_in[0];
  const float* Wq = (const float*)d_in[1];
  const float* Wk = (const float*)d_in[2];
  const float* Wv = (const float*)d_in[3];
  const float* Wo = (const float*)d_in[4];

  char* w = (char*)d_ws;
  const size_t MB8 = (size_t)2048 * 2048 * 2;   // one bf16 matrix = 8 MiB
  u16* Xb  = (u16*)(w);
  u16* Wqb = (u16*)(w + 1 * MB8);
  u16* Wkb = (u16*)(w + 2 * MB8);
  u16* Wvb = (u16*)(w + 3 * MB8);
  u16* Wob = (u16*)(w + 4 * MB8);
  u16* Qb  = (u16*)(w + 5 * MB8);
  u16* Kb  = (u16*)(w + 6 * MB8);
  u16* Vb  = (u16*)(w + 7 * MB8);
  u16* Vtb   = Wqb;   // Wq dead after projections
  u16* attnb = Xb;    // X dead after projections
  float* cosT = (float*)(w + 8 * MB8);                    // 512 KiB
  float* sinT = (float*)(w + 8 * MB8 + 524288);           // 512 KiB
  // stats region (zeroed as one range): Oacc 16MB, colsum/rowsum/rowsum2 128KB each
  float* Oacc    = (float*)(w + 8 * MB8 + 1048576);
  float* colsum  = Oacc + 4194304;
  float* rowsum  = colsum + 32768;
  float* rowsum2 = rowsum + 32768;
  unsigned char* heavy = (unsigned char*)(rowsum2 + 32768);
  unsigned char* htile = heavy + 16 * 2048;

  dim3 b256(256);

  k_cvt5<<<20480, b256, 0, stream>>>(X, Wq, Wk, Wv, Wo, Xb);
  k_rope_tab<<<512, b256, 0, stream>>>(cosT, sinT);
  k_zero4<<<2048, b256, 0, stream>>>(Oacc, (4194304 + 3 * 32768) / 4);
  k_zero4<<<2048, b256, 0, stream>>>((float*)d_out, 4194304 / 4);

  k_proj3<<<dim3(16, 16, 3), b256, 0, stream>>>(Xb, Wqb, Wkb, Wvb, Qb, Kb, Vb);
  k_rope2<<<4096, b256, 0, stream>>>(Qb, Kb, cosT, sinT);
  k_transpose_v<<<dim3(64, 64), b256, 0, stream>>>(Vb, Vtb);

  k_pass1a<<<dim3(80, 16), b256, 0, stream>>>(Qb, Kb, rowsum);
  k_pass1b<<<dim3(80, 16), b256, 0, stream>>>(Qb, Kb, rowsum, colsum);
  k_topk<<<16, b256, 0, stream>>>(colsum, heavy, htile);
  k_pass2<<<dim3(48, 16), b256, 0, stream>>>(Qb, Kb, Vtb, heavy, htile, Oacc, rowsum2);
  k_norm<<<4096, b256, 0, stream>>>(Oacc, rowsum2, attnb);

  k_gemm_out<<<dim3(16, 16, 2), b256, 0, stream>>>(attnb, Wob, (float*)d_out);
}

// Round 3
// 353.381 us; speedup vs baseline: 1.1422x; 1.0252x over previous
//
#include <hip/hip_runtime.h>
#include <hip/hip_bf16.h>
#include <stdint.h>

// Problem constants: b=1, s=2048, hidden=2048, H=16, d=128
#define SEQ   2048
#define HIDN  2048
#define NHEAD 16
#define HDIM  128
#define HEAVY 204   // int(0.1*2048)
#define RECENT 204

typedef __attribute__((ext_vector_type(4))) float f32x4;
typedef __attribute__((ext_vector_type(8))) short bf16x8;
typedef unsigned short u16;
typedef unsigned int   u32;

static __device__ __forceinline__ u16 f2bf(float f){
  union { float f; u32 u; } v; v.f = f;
  u32 r = (v.u + 0x7FFFu + ((v.u >> 16) & 1u)) >> 16;
  return (u16)r;
}
static __device__ __forceinline__ float bf2f(u16 u){
  union { u32 u; float f; } v; v.u = ((u32)u) << 16;
  return v.f;
}

// global -> LDS direct 16B load (dest is wave-uniform base + lane*16)
static __device__ __forceinline__ void gload16(const void* g, void* l){
  __builtin_amdgcn_global_load_lds((const __attribute__((address_space(1))) u32*)g,
                                   (__attribute__((address_space(3))) u32*)l, 16, 0, 0);
}

#define WAITVM(N) asm volatile("s_waitcnt vmcnt(" #N ")" ::: "memory")
#define LGKM0     do { asm volatile("s_waitcnt lgkmcnt(0)" ::: "memory"); __builtin_amdgcn_sched_barrier(0); } while(0)
#define BARRAW    __builtin_amdgcn_s_barrier()
#define PRIO1     __builtin_amdgcn_s_setprio(1)
#define PRIO0     __builtin_amdgcn_s_setprio(0)

// stage a 64x128 bf16 tile (XOR-swizzled source so swizzled ds_read is conflict-free)
static __device__ __forceinline__ void stage_tile(const u16* __restrict__ base, int row0,
                                                  u16* __restrict__ lds, int tid){
  const int wbase = tid & ~63;
#pragma unroll
  for (int it = 0; it < 4; ++it){
    int m = it * 256 + tid;
    int row = m >> 4, cp = m & 15;
    gload16(base + (size_t)(row0 + row) * 2048 + ((cp ^ (row & 7)) * 8),
            lds + (it * 256 + wbase) * 8);
  }
}

// stage a 128-row x 64-col bf16 half-tile with 512 threads (2 x 16B per thread)
static __device__ __forceinline__ void stage_half(const u16* __restrict__ mat, int grow0, int gcol0,
                                                  u16* __restrict__ ldsbase, int tid){
#pragma unroll
  for (int it = 0; it < 2; ++it){
    int m = it * 512 + tid;
    int row = m >> 3, cp = m & 7;
    gload16(mat + (size_t)(grow0 + row) * 2048 + gcol0 + ((cp ^ (row & 7)) * 8),
            ldsbase + (it * 512 + (tid & ~63)) * 8);
  }
}

// triangle chunk mapping: bx -> (t, c) where t has (t>>LOG2CH)+1 chunks
template<int LOG2CH>
static __device__ __forceinline__ void tri_map(int bx, int& t, int& c){
  int rem = bx; int q = 0;
  while (rem >= ((q >> LOG2CH) + 1)){ rem -= (q >> LOG2CH) + 1; q++; }
  t = q; c = rem;
}

// ---------------- converts + RoPE ----------------
__global__ void k_cvt5(const float* __restrict__ A0, const float* __restrict__ A1,
                       const float* __restrict__ A2, const float* __restrict__ A3,
                       const float* __restrict__ A4, u16* __restrict__ out){
  int id = blockIdx.x * 256 + threadIdx.x;         // 5 * 1048576 ids, 4 elems each
  int sel = id >> 20, off = (id & 1048575) * 4;
  const float* src = sel == 0 ? A0 : sel == 1 ? A1 : sel == 2 ? A2 : sel == 3 ? A3 : A4;
  float4 v = *(const float4*)(src + off);
  ushort4 o;
  o.x = f2bf(v.x); o.y = f2bf(v.y); o.z = f2bf(v.z); o.w = f2bf(v.w);
  *(ushort4*)(out + (size_t)sel * 4194304 + off) = o;
}

__global__ void k_rope_tab(float* __restrict__ cosT, float* __restrict__ sinT){
  int i = blockIdx.x * 256 + threadIdx.x;        // 2048*64
  int pos = i >> 6, j = i & 63;
  float invf = powf(10000.0f, -(float)j * (1.0f / 64.0f));
  float a = (float)pos * invf;
  cosT[i] = cosf(a);
  sinT[i] = sinf(a);
}

// rotary in-place on Q and K (sel by gid), pairs (j, j+64) within each head
__global__ void k_rope2(u16* __restrict__ Qm, u16* __restrict__ Km,
                        const float* __restrict__ cosT, const float* __restrict__ sinT){
  int gid = blockIdx.x * 256 + threadIdx.x;      // 2 * 524288
  u16* M = (gid < 524288) ? Qm : Km;
  int id = gid & 524287;
  int pos = id >> 8, rem = id & 255;
  int h = rem >> 4, j4 = (rem & 15) * 4;
  u16* p = M + (size_t)pos * HIDN + h * HDIM + j4;
  ushort4 lo = *(ushort4*)p;
  ushort4 hi = *(ushort4*)(p + 64);
  float4 c = *(const float4*)(cosT + pos * 64 + j4);
  float4 s = *(const float4*)(sinT + pos * 64 + j4);
  float l0 = bf2f(lo.x), l1 = bf2f(lo.y), l2 = bf2f(lo.z), l3 = bf2f(lo.w);
  float h0 = bf2f(hi.x), h1 = bf2f(hi.y), h2 = bf2f(hi.z), h3 = bf2f(hi.w);
  ushort4 nlo, nhi;
  nlo.x = f2bf(l0 * c.x - h0 * s.x);  nhi.x = f2bf(h0 * c.x + l0 * s.x);
  nlo.y = f2bf(l1 * c.y - h1 * s.y);  nhi.y = f2bf(h1 * c.y + l1 * s.y);
  nlo.z = f2bf(l2 * c.z - h2 * s.z);  nhi.z = f2bf(h2 * c.z + l2 * s.z);
  nlo.w = f2bf(l3 * c.w - h3 * s.w);  nhi.w = f2bf(h3 * c.w + l3 * s.w);
  *(ushort4*)p = nlo;
  *(ushort4*)(p + 64) = nhi;
}

__global__ void k_zero4(float* __restrict__ p, int n4){
  for (int i = blockIdx.x * 256 + threadIdx.x; i < n4; i += gridDim.x * 256)
    ((float4*)p)[i] = (float4){0.f, 0.f, 0.f, 0.f};
}

// ---------------- 256x256 8-phase GEMM (C = A @ B^T), BK=64, 8 waves ----------------
// MODE 0: z in {0,1,2} selects (B,C) pair, full K, bf16 out.
// MODE 1: z = K-split of 4 (each 512 wide), f32 atomicAdd out.
template<int MODE>
__global__ __launch_bounds__(512, 2)
void k_g256(const u16* __restrict__ A, const u16* __restrict__ B0, const u16* __restrict__ B1,
            const u16* __restrict__ B2, u16* __restrict__ C0, u16* __restrict__ C1,
            u16* __restrict__ C2, float* __restrict__ Cf){
  __shared__ __align__(16) u16 LA[2][256 * 64];
  __shared__ __align__(16) u16 LB[2][256 * 64];
  const int tid = threadIdx.x;
  const int lane = tid & 63, wv = tid >> 6;
  const int wm = wv >> 2, wn = wv & 3;
  const int g = lane >> 4, c15 = lane & 15;
  const int brow = blockIdx.y * 256, bcol = blockIdx.x * 256;
  const u16* Bg; u16* Cb = nullptr; int kstart;
  const int NT = (MODE == 0) ? 32 : 8;
  if (MODE == 0){
    Bg = blockIdx.z == 0 ? B0 : blockIdx.z == 1 ? B1 : B2;
    Cb = blockIdx.z == 0 ? C0 : blockIdx.z == 1 ? C1 : C2;
    kstart = 0;
  } else {
    Bg = B0;
    kstart = blockIdx.z * 512;
  }

  f32x4 acc[8][4];
#pragma unroll
  for (int m = 0; m < 8; m++)
#pragma unroll
    for (int n = 0; n < 4; n++) acc[m][n] = (f32x4){0.f, 0.f, 0.f, 0.f};

  const int cc0 = ((g ^ (c15 & 7)) * 8);
  bf16x8 af[4][2], bf[4][2];

#define RDA(buf, mibase) \
  _Pragma("unroll") for (int mi2 = 0; mi2 < 4; ++mi2){ \
    const u16* pr = &LA[buf][0] + (size_t)(wm * 128 + ((mibase) + mi2) * 16 + c15) * 64; \
    af[mi2][0] = *(const bf16x8*)(pr + cc0); \
    af[mi2][1] = *(const bf16x8*)(pr + (cc0 ^ 32)); \
  }
#define RDB(buf, nibase) \
  _Pragma("unroll") for (int ni2 = 0; ni2 < 2; ++ni2){ \
    const u16* pr = &LB[buf][0] + (size_t)(wn * 64 + ((nibase) + ni2) * 16 + c15) * 64; \
    bf[(nibase) + ni2][0] = *(const bf16x8*)(pr + cc0); \
    bf[(nibase) + ni2][1] = *(const bf16x8*)(pr + (cc0 ^ 32)); \
  }
#define MM(mibase, nibase) \
  _Pragma("unroll") for (int mi2 = 0; mi2 < 4; ++mi2) \
  _Pragma("unroll") for (int ni2 = 0; ni2 < 2; ++ni2) \
  _Pragma("unroll") for (int kk = 0; kk < 2; ++kk) \
    acc[(mibase) + mi2][(nibase) + ni2] = __builtin_amdgcn_mfma_f32_16x16x32_bf16( \
        af[mi2][kk], bf[(nibase) + ni2][kk], acc[(mibase) + mi2][(nibase) + ni2], 0, 0, 0);

  // prologue: tile0 (A+B) + tile1 (B halves); A[t1] staged at t0.ph1-2 per schedule
  stage_half(A,  brow,       kstart,      &LA[0][0],            tid);
  stage_half(A,  brow + 128, kstart,      &LA[0][0] + 128 * 64, tid);
  stage_half(Bg, bcol,       kstart,      &LB[0][0],            tid);
  stage_half(Bg, bcol + 128, kstart,      &LB[0][0] + 128 * 64, tid);
  stage_half(Bg, bcol,       kstart + 64, &LB[1][0],            tid);
  stage_half(Bg, bcol + 128, kstart + 64, &LB[1][0] + 128 * 64, tid);
  WAITVM(4);
  BARRAW;

  for (int t = 0; t < NT; t += 2){
    const int kn1 = kstart + (t + 1) * 64;
    const int kn2 = kstart + (t + 2) * 64;
    const int kn3 = kstart + (t + 3) * 64;
    // ===== tile t (buf 0) =====
    // ph1
    RDA(0, 0); RDB(0, 0);
    stage_half(A, brow, kn1, &LA[1][0], tid);
    BARRAW; LGKM0; PRIO1; MM(0, 0); PRIO0; BARRAW;
    // ph2
    RDB(0, 2);
    stage_half(A, brow + 128, kn1, &LA[1][0] + 128 * 64, tid);
    BARRAW; LGKM0; PRIO1; MM(0, 2); PRIO0; BARRAW;
    // ph3
    RDA(0, 4);
    if (t + 2 < NT) stage_half(Bg, bcol, kn2, &LB[0][0], tid);
    BARRAW; LGKM0; PRIO1; MM(4, 2); PRIO0; BARRAW;
    // ph4
    if (t + 2 < NT){ stage_half(Bg, bcol + 128, kn2, &LB[0][0] + 128 * 64, tid); WAITVM(4); }
    else            { WAITVM(0); }
    BARRAW; PRIO1; MM(4, 0); PRIO0; BARRAW;
    // ===== tile t+1 (buf 1) =====
    // ph5
    RDA(1, 0); RDB(1, 0);
    if (t + 2 < NT) stage_half(A, brow, kn2, &LA[0][0], tid);
    BARRAW; LGKM0; PRIO1; MM(0, 0); PRIO0; BARRAW;
    // ph6
    RDB(1, 2);
    if (t + 2 < NT) stage_half(A, brow + 128, kn2, &LA[0][0] + 128 * 64, tid);
    BARRAW; LGKM0; PRIO1; MM(0, 2); PRIO0; BARRAW;
    // ph7
    RDA(1, 4);
    if (t + 3 < NT) stage_half(Bg, bcol, kn3, &LB[1][0], tid);
    BARRAW; LGKM0; PRIO1; MM(4, 2); PRIO0; BARRAW;
    // ph8
    if (t + 3 < NT){ stage_half(Bg, bcol + 128, kn3, &LB[1][0] + 128 * 64, tid); WAITVM(4); }
    else if (t + 2 < NT){ WAITVM(0); }
    BARRAW; PRIO1; MM(4, 0); PRIO0; BARRAW;
  }
#undef RDA
#undef RDB
#undef MM

#pragma unroll
  for (int mi = 0; mi < 8; ++mi)
#pragma unroll
    for (int ni = 0; ni < 4; ++ni)
#pragma unroll
      for (int r = 0; r < 4; ++r){
        int row = brow + wm * 128 + mi * 16 + g * 4 + r;
        int col = bcol + wn * 64 + ni * 16 + c15;
        if (MODE == 0) Cb[(size_t)row * 2048 + col] = f2bf(acc[mi][ni][r]);
        else           atomicAdd(&Cf[(size_t)row * 2048 + col], acc[mi][ni][r]);
      }
}

// ---------------- transpose V: [2048 s][2048 hd] -> [2048 hd][2048 s] ----------------
__global__ void k_transpose_v(const u16* __restrict__ V, u16* __restrict__ Vt){
  __shared__ u16 t[32][33];
  int s0 = blockIdx.x * 32, c0 = blockIdx.y * 32;
  int tid = threadIdx.x;
  int r = tid >> 3, cc = (tid & 7) * 4;
  ushort4 v = *(const ushort4*)(V + (size_t)(s0 + r) * 2048 + c0 + cc);
  t[r][cc] = v.x; t[r][cc + 1] = v.y; t[r][cc + 2] = v.z; t[r][cc + 3] = v.w;
  __syncthreads();
  int co = tid >> 3, ro = (tid & 7) * 4;
  ushort4 o;
  o.x = t[ro][co]; o.y = t[ro + 1][co]; o.z = t[ro + 2][co]; o.w = t[ro + 3][co];
  *(ushort4*)(Vt + (size_t)(c0 + co) * 2048 + s0 + ro) = o;
}

// ---------------- pass 1a: rowsum of exp (causal), triangle-chunked ----------------
// grid (80, 16): bx -> (qb, chunk of 8 k-tiles)
__global__ __launch_bounds__(256)
void k_pass1a(const u16* __restrict__ Q, const u16* __restrict__ K, float* __restrict__ rowsum){
  __shared__ __align__(16) u16 Qs[64 * 128];
  __shared__ __align__(16) u16 Ks[2][64 * 128];
  const int tid = threadIdx.x;
  const int w = tid >> 6, lane = tid & 63;
  const int g = lane >> 4, c15 = lane & 15;
  const int h = blockIdx.y;
  int qb, c; tri_map<3>(blockIdx.x, qb, c);
  const int i0 = qb * 64;
  const int kt0 = c * 8;
  const int kt1 = (qb + 1 < kt0 + 8) ? (qb + 1) : (kt0 + 8);
  const u16* Qh = Q + h * HDIM;
  const u16* Kh = K + h * HDIM;
  const float scale = 0.08838834764831845f;   // 1/sqrt(128)
  const int arow = w * 16 + c15;

  stage_tile(Qh, i0, Qs, tid);
  stage_tile(Kh, kt0 * 64, Ks[0], tid);
  __syncthreads();

  float lsum[4] = {0.f, 0.f, 0.f, 0.f};
  int cur = 0;
  for (int kt = kt0; kt < kt1; ++kt){
    if (kt + 1 < kt1) stage_tile(Kh, (kt + 1) * 64, Ks[cur ^ 1], tid);
    const int k0 = kt * 64;
    f32x4 sacc[4];
#pragma unroll
    for (int n = 0; n < 4; n++) sacc[n] = (f32x4){0.f, 0.f, 0.f, 0.f};
#pragma unroll
    for (int ks = 0; ks < 4; ++ks){
      bf16x8 a = *(const bf16x8*)(Qs + arow * 128 + ((ks * 32 + g * 8) ^ ((arow & 7) << 3)));
#pragma unroll
      for (int n = 0; n < 4; n++){
        int brw = n * 16 + c15;
        bf16x8 b = *(const bf16x8*)(Ks[cur] + brw * 128 + ((ks * 32 + g * 8) ^ ((brw & 7) << 3)));
        sacc[n] = __builtin_amdgcn_mfma_f32_16x16x32_bf16(a, b, sacc[n], 0, 0, 0);
      }
    }
    float rs[4] = {0.f, 0.f, 0.f, 0.f};
#pragma unroll
    for (int n = 0; n < 4; n++){
      int col = k0 + n * 16 + c15;
#pragma unroll
      for (int r = 0; r < 4; r++){
        int rowg = i0 + w * 16 + g * 4 + r;
        rs[r] += (col <= rowg) ? __expf(sacc[n][r] * scale) : 0.f;
      }
    }
#pragma unroll
    for (int r = 0; r < 4; r++){
      float v = rs[r];
      v += __shfl_xor(v, 1); v += __shfl_xor(v, 2);
      v += __shfl_xor(v, 4); v += __shfl_xor(v, 8);
      lsum[r] += v;
    }
    __syncthreads();
    cur ^= 1;
  }
  if (c15 == 0){
#pragma unroll
    for (int r = 0; r < 4; r++)
      atomicAdd(&rowsum[h * 2048 + i0 + w * 16 + g * 4 + r], lsum[r]);
  }
}

// ---------------- pass 1b: colsum of normalized exp, triangle-chunked over q ----------------
// grid (80, 16): bx -> (t, c), kb = 31 - t, q-tiles [kb + c*8, ...)
__global__ __launch_bounds__(256)
void k_pass1b(const u16* __restrict__ Q, const u16* __restrict__ K,
              const float* __restrict__ rowsum, float* __restrict__ colsum){
  __shared__ __align__(16) u16 Ks[64 * 128];
  __shared__ __align__(16) u16 Qs[2][64 * 128];
  __shared__ float cw[4][64];
  const int tid = threadIdx.x;
  const int w = tid >> 6, lane = tid & 63;
  const int g = lane >> 4, c15 = lane & 15;
  const int h = blockIdx.y;
  int t, c; tri_map<3>(blockIdx.x, t, c);
  const int kb = 31 - t;
  const int k0 = kb * 64;
  const int qstart = kb + c * 8;
  const int qend = (qstart + 8 < 32) ? (qstart + 8) : 32;
  const u16* Qh = Q + h * HDIM;
  const u16* Kh = K + h * HDIM;
  const float scale = 0.08838834764831845f;
  const int arow = w * 16 + c15;

  stage_tile(Kh, k0, Ks, tid);
  stage_tile(Qh, qstart * 64, Qs[0], tid);
  __syncthreads();

  float racc[4] = {0.f, 0.f, 0.f, 0.f};
  int cur = 0;
  for (int qt = qstart; qt < qend; ++qt){
    if (qt + 1 < qend) stage_tile(Qh, (qt + 1) * 64, Qs[cur ^ 1], tid);
    const int i0 = qt * 64;
    float rinv[4];
#pragma unroll
    for (int r = 0; r < 4; r++)
      rinv[r] = 1.0f / rowsum[h * 2048 + i0 + w * 16 + g * 4 + r];
    f32x4 sacc[4];
#pragma unroll
    for (int n = 0; n < 4; n++) sacc[n] = (f32x4){0.f, 0.f, 0.f, 0.f};
#pragma unroll
    for (int ks = 0; ks < 4; ++ks){
      bf16x8 a = *(const bf16x8*)(Qs[cur] + arow * 128 + ((ks * 32 + g * 8) ^ ((arow & 7) << 3)));
#pragma unroll
      for (int n = 0; n < 4; n++){
        int brw = n * 16 + c15;
        bf16x8 b = *(const bf16x8*)(Ks + brw * 128 + ((ks * 32 + g * 8) ^ ((brw & 7) << 3)));
        sacc[n] = __builtin_amdgcn_mfma_f32_16x16x32_bf16(a, b, sacc[n], 0, 0, 0);
      }
    }
#pragma unroll
    for (int n = 0; n < 4; n++){
      int col = k0 + n * 16 + c15;
      float cpart = 0.f;
#pragma unroll
      for (int r = 0; r < 4; r++){
        int rowg = i0 + w * 16 + g * 4 + r;
        cpart += (col <= rowg) ? __expf(sacc[n][r] * scale) * rinv[r] : 0.f;
      }
      cpart += __shfl_xor(cpart, 16);
      cpart += __shfl_xor(cpart, 32);
      racc[n] += cpart;
    }
    __syncthreads();
    cur ^= 1;
  }
  if (g == 0){
#pragma unroll
    for (int n = 0; n < 4; n++) cw[w][n * 16 + c15] = racc[n];
  }
  __syncthreads();
  if (tid < 64){
    float s = cw[0][tid] + cw[1][tid] + cw[2][tid] + cw[3][tid];
    atomicAdd(&colsum[h * 2048 + k0 + tid], s);
  }
}

// ---------------- top-k (204) per head via bitonic sort, 1024 threads ----------------
__global__ __launch_bounds__(1024)
void k_topk(const float* __restrict__ colsum, unsigned char* __restrict__ heavy,
            unsigned char* __restrict__ htile){
  __shared__ float v[2048];
  __shared__ short ix[2048];
  __shared__ unsigned char fl[2048];
  __shared__ int tf[32];
  const int tid = threadIdx.x;
  const int h = blockIdx.x;
  for (int i = tid; i < 2048; i += 1024){ v[i] = colsum[h * 2048 + i]; ix[i] = (short)i; fl[i] = 0; }
  if (tid < 32) tf[tid] = 0;
  __syncthreads();
  for (int k = 2; k <= 2048; k <<= 1){
    for (int j = k >> 1; j > 0; j >>= 1){
      int i = ((tid / j) * (j << 1)) + (tid % j);
      int l = i + j;
      float vi = v[i], vl = v[l];
      short ii = ix[i], il = ix[l];
      bool before_i = (vi > vl) || (vi == vl && ii < il);
      bool dir = (i & k) == 0;
      if (dir ? !before_i : before_i){ v[i] = vl; v[l] = vi; ix[i] = il; ix[l] = ii; }
      __syncthreads();
    }
  }
  if (tid < HEAVY){ int id = ix[tid]; fl[id] = 1; atomicOr(&tf[id >> 6], 1); }
  __syncthreads();
  for (int i = tid; i < 2048; i += 1024) heavy[h * 2048 + i] = fl[i];
  if (tid < 32) htile[h * 32 + tid] = (unsigned char)(tf[tid] ? 1 : 0);
}

// ---------------- pass 2: masked attention, triangle-chunked (CH=16), atomic O accumulate ----
// grid (48, 16)
__global__ __launch_bounds__(256)
void k_pass2(const u16* __restrict__ Q, const u16* __restrict__ K, const u16* __restrict__ Vt,
             const unsigned char* __restrict__ heavy, const unsigned char* __restrict__ htile,
             float* __restrict__ Oacc, float* __restrict__ rowsum2){
  __shared__ __align__(16) u16 Qs[64 * 128];
  __shared__ __align__(16) u16 Ks[2][64 * 128];
  __shared__ __align__(16) u16 Ps[4][16 * 64];
  __shared__ unsigned char hfa[16][64];
  __shared__ int lists[16];
  __shared__ int nact_s;
  const int tid = threadIdx.x;
  const int w = tid >> 6, lane = tid & 63;
  const int g = lane >> 4, c15 = lane & 15;
  const int h = blockIdx.y;
  int qb, c; tri_map<4>(blockIdx.x, qb, c);
  const int i0 = qb * 64;
  const int kt0 = c * 16;
  const int kt1 = (qb + 1 < kt0 + 16) ? (qb + 1) : (kt0 + 16);
  const u16* Qh = Q + h * HDIM;
  const u16* Kh = K + h * HDIM;
  const float scale = 0.08838834764831845f;
  const int arow = w * 16 + c15;

  if (tid == 0){
    int n = 0;
    for (int kt = kt0; kt < kt1; ++kt){
      bool band = (kt * 64 + 63 >= i0 - RECENT);
      bool hv = htile[h * 32 + kt] != 0;
      if (band || hv) lists[n++] = kt;
    }
    nact_s = n;
  }
  __syncthreads();
  const int nact = nact_s;
  if (nact == 0) return;

  for (int idx = tid; idx < nact * 64; idx += 256)
    hfa[idx >> 6][idx & 63] = heavy[h * 2048 + lists[idx >> 6] * 64 + (idx & 63)];
  stage_tile(Qh, i0, Qs, tid);
  stage_tile(Kh, lists[0] * 64, Ks[0], tid);
  __syncthreads();

  f32x4 oacc[8];
#pragma unroll
  for (int f = 0; f < 8; f++) oacc[f] = (f32x4){0.f, 0.f, 0.f, 0.f};
  float lsum[4] = {0.f, 0.f, 0.f, 0.f};

  int cur = 0;
  for (int i = 0; i < nact; ++i){
    const int kt = lists[i];
    const int k0 = kt * 64;
    if (i + 1 < nact) stage_tile(Kh, lists[i + 1] * 64, Ks[cur ^ 1], tid);
    // V fragments straight from global (L2-resident), issued early
    bf16x8 vf[2][8];
#pragma unroll
    for (int ks2 = 0; ks2 < 2; ++ks2)
#pragma unroll
      for (int f = 0; f < 8; ++f){
        int vrow = f * 16 + c15;
        vf[ks2][f] = *(const bf16x8*)(Vt + ((size_t)h * HDIM + vrow) * 2048 + k0 + ks2 * 32 + g * 8);
      }
    // QK^T
    f32x4 sacc[4];
#pragma unroll
    for (int n = 0; n < 4; n++) sacc[n] = (f32x4){0.f, 0.f, 0.f, 0.f};
#pragma unroll
    for (int ks = 0; ks < 4; ++ks){
      bf16x8 a = *(const bf16x8*)(Qs + arow * 128 + ((ks * 32 + g * 8) ^ ((arow & 7) << 3)));
#pragma unroll
      for (int n = 0; n < 4; n++){
        int brw = n * 16 + c15;
        bf16x8 b = *(const bf16x8*)(Ks[cur] + brw * 128 + ((ks * 32 + g * 8) ^ ((brw & 7) << 3)));
        sacc[n] = __builtin_amdgcn_mfma_f32_16x16x32_bf16(a, b, sacc[n], 0, 0, 0);
      }
    }
    // masked exp -> P (LDS, per-wave private), row sums
    float rs[4] = {0.f, 0.f, 0.f, 0.f};
#pragma unroll
    for (int n = 0; n < 4; n++){
      int col = k0 + n * 16 + c15;
      int hfv = hfa[i][n * 16 + c15];
#pragma unroll
      for (int r = 0; r < 4; r++){
        int rowg = i0 + w * 16 + g * 4 + r;
        bool valid = (col <= rowg) && (hfv || (rowg - col) <= RECENT);
        float e = valid ? __expf(sacc[n][r] * scale) : 0.f;
        rs[r] += e;
        int prow = g * 4 + r;
        Ps[w][prow * 64 + ((n * 16 + c15) ^ ((prow & 7) << 3))] = f2bf(e);
      }
    }
#pragma unroll
    for (int r = 0; r < 4; r++){
      float vv = rs[r];
      vv += __shfl_xor(vv, 1); vv += __shfl_xor(vv, 2);
      vv += __shfl_xor(vv, 4); vv += __shfl_xor(vv, 8);
      lsum[r] += vv;
    }
    // PV: O += P @ V
#pragma unroll
    for (int ks2 = 0; ks2 < 2; ++ks2){
      bf16x8 pa = *(const bf16x8*)(&Ps[w][c15 * 64 + ((ks2 * 32 + g * 8) ^ ((c15 & 7) << 3))]);
#pragma unroll
      for (int f = 0; f < 8; ++f)
        oacc[f] = __builtin_amdgcn_mfma_f32_16x16x32_bf16(pa, vf[ks2][f], oacc[f], 0, 0, 0);
    }
    __syncthreads();
    cur ^= 1;
  }
#pragma unroll
  for (int f = 0; f < 8; f++)
#pragma unroll
    for (int r = 0; r < 4; r++){
      int rowg = i0 + w * 16 + g * 4 + r;
      atomicAdd(&Oacc[(size_t)rowg * 2048 + h * HDIM + f * 16 + c15], oacc[f][r]);
    }
  if (c15 == 0){
#pragma unroll
    for (int r = 0; r < 4; r++)
      atomicAdd(&rowsum2[h * 2048 + i0 + w * 16 + g * 4 + r], lsum[r]);
  }
}

// ---------------- normalize: attn_bf16 = Oacc * (1/rowsum2) ----------------
__global__ void k_norm(const float* __restrict__ Oacc, const float* __restrict__ rowsum2,
                       u16* __restrict__ attn){
  int gid = blockIdx.x * 256 + threadIdx.x;      // 2048*512
  int row = gid >> 9;
  int c4 = (gid & 511) * 4;
  int h = c4 >> 7;
  float rinv = 1.0f / rowsum2[h * 2048 + row];
  float4 o = *(const float4*)(Oacc + (size_t)row * 2048 + c4);
  ushort4 ov;
  ov.x = f2bf(o.x * rinv); ov.y = f2bf(o.y * rinv);
  ov.z = f2bf(o.z * rinv); ov.w = f2bf(o.w * rinv);
  *(ushort4*)(attn + (size_t)row * 2048 + c4) = ov;
}

// ---------------- host launcher ----------------
extern "C" void kernel_launch(void* const* d_in, const int* in_sizes, int n_in,
                              void* d_out, int out_size, void* d_ws, size_t ws_size,
                              hipStream_t stream){
  const float* X  = (const float*)d_in[0];
  const float* Wq = (const float*)d_in[1];
  const float* Wk = (const float*)d_in[2];
  const float* Wv = (const float*)d_in[3];
  const float* Wo = (const float*)d_in[4];

  char* w = (char*)d_ws;
  const size_t MB8 = (size_t)2048 * 2048 * 2;   // one bf16 matrix = 8 MiB
  u16* Xb  = (u16*)(w);
  u16* Wqb = (u16*)(w + 1 * MB8);
  u16* Wkb = (u16*)(w + 2 * MB8);
  u16* Wvb = (u16*)(w + 3 * MB8);
  u16* Wob = (u16*)(w + 4 * MB8);
  u16* Qb  = (u16*)(w + 5 * MB8);
  u16* Kb  = (u16*)(w + 6 * MB8);
  u16* Vb  = (u16*)(w + 7 * MB8);
  u16* Vtb   = Wqb;   // Wq dead after projections
  u16* attnb = Xb;    // X dead after projections
  float* cosT = (float*)(w + 8 * MB8);                    // 512 KiB
  float* sinT = (float*)(w + 8 * MB8 + 524288);           // 512 KiB
  float* Oacc    = (float*)(w + 8 * MB8 + 1048576);       // 16 MiB
  float* colsum  = Oacc + 4194304;
  float* rowsum  = colsum + 32768;
  float* rowsum2 = rowsum + 32768;
  unsigned char* heavy = (unsigned char*)(rowsum2 + 32768);
  unsigned char* htile = heavy + 16 * 2048;

  dim3 b256(256);

  k_cvt5<<<20480, b256, 0, stream>>>(X, Wq, Wk, Wv, Wo, Xb);
  k_rope_tab<<<512, b256, 0, stream>>>(cosT, sinT);
  k_zero4<<<2048, b256, 0, stream>>>(Oacc, (4194304 + 3 * 32768) / 4);
  k_zero4<<<2048, b256, 0, stream>>>((float*)d_out, 4194304 / 4);

  k_g256<0><<<dim3(8, 8, 3), dim3(512), 0, stream>>>(Xb, Wqb, Wkb, Wvb, Qb, Kb, Vb, nullptr);
  k_rope2<<<4096, b256, 0, stream>>>(Qb, Kb, cosT, sinT);
  k_transpose_v<<<dim3(64, 64), b256, 0, stream>>>(Vb, Vtb);

  k_pass1a<<<dim3(80, 16), b256, 0, stream>>>(Qb, Kb, rowsum);
  k_pass1b<<<dim3(80, 16), b256, 0, stream>>>(Qb, Kb, rowsum, colsum);
  k_topk<<<16, dim3(1024), 0, stream>>>(colsum, heavy, htile);
  k_pass2<<<dim3(48, 16), b256, 0, stream>>>(Qb, Kb, Vtb, heavy, htile, Oacc, rowsum2);
  k_norm<<<4096, b256, 0, stream>>>(Oacc, rowsum2, attnb);

  k_g256<1><<<dim3(8, 8, 4), dim3(512), 0, stream>>>(attnb, Wob, nullptr, nullptr,
                                                     nullptr, nullptr, nullptr, (float*)d_out);
}

// Round 4
// 328.852 us; speedup vs baseline: 1.2274x; 1.0746x over previous
//
#include <hip/hip_runtime.h>
#include <hip/hip_bf16.h>
#include <stdint.h>

// Problem constants: b=1, s=2048, hidden=2048, H=16, d=128
#define SEQ   2048
#define HIDN  2048
#define NHEAD 16
#define HDIM  128
#define HEAVY 204   // int(0.1*2048)
#define RECENT 204

typedef __attribute__((ext_vector_type(4))) float f32x4;
typedef __attribute__((ext_vector_type(8))) short bf16x8;
typedef unsigned short u16;
typedef unsigned int   u32;

static __device__ __forceinline__ u16 f2bf(float f){
  union { float f; u32 u; } v; v.f = f;
  u32 r = (v.u + 0x7FFFu + ((v.u >> 16) & 1u)) >> 16;
  return (u16)r;
}
static __device__ __forceinline__ float bf2f(u16 u){
  union { u32 u; float f; } v; v.u = ((u32)u) << 16;
  return v.f;
}

// global -> LDS direct 16B load (dest is wave-uniform base + lane*16)
static __device__ __forceinline__ void gload16(const void* g, void* l){
  __builtin_amdgcn_global_load_lds((const __attribute__((address_space(1))) u32*)g,
                                   (__attribute__((address_space(3))) u32*)l, 16, 0, 0);
}

#define WAITVM(N) asm volatile("s_waitcnt vmcnt(" #N ")" ::: "memory")
#define BARRAW    __builtin_amdgcn_s_barrier()
#define PRIO1     __builtin_amdgcn_s_setprio(1)
#define PRIO0     __builtin_amdgcn_s_setprio(0)

// stage a 64x128 bf16 tile (XOR-swizzled source so swizzled ds_read is conflict-free)
static __device__ __forceinline__ void stage_tile(const u16* __restrict__ base, int row0,
                                                  u16* __restrict__ lds, int tid){
  const int wbase = tid & ~63;
#pragma unroll
  for (int it = 0; it < 4; ++it){
    int m = it * 256 + tid;
    int row = m >> 4, cp = m & 15;
    gload16(base + (size_t)(row0 + row) * 2048 + ((cp ^ (row & 7)) * 8),
            lds + (it * 256 + wbase) * 8);
  }
}

// stage a 128-row x 64-col bf16 half-tile with 512 threads (2 x 16B per thread)
static __device__ __forceinline__ void stage_half(const u16* __restrict__ mat, int grow0, int gcol0,
                                                  u16* __restrict__ ldsbase, int tid){
#pragma unroll
  for (int it = 0; it < 2; ++it){
    int m = it * 512 + tid;
    int row = m >> 3, cp = m & 7;
    gload16(mat + (size_t)(grow0 + row) * 2048 + gcol0 + ((cp ^ (row & 7)) * 8),
            ldsbase + (it * 512 + (tid & ~63)) * 8);
  }
}

// triangle chunk mapping: bx -> (t, c) where t has (t>>LOG2CH)+1 chunks
template<int LOG2CH>
static __device__ __forceinline__ void tri_map(int bx, int& t, int& c){
  int rem = bx; int q = 0;
  while (rem >= ((q >> LOG2CH) + 1)){ rem -= (q >> LOG2CH) + 1; q++; }
  t = q; c = rem;
}

// ---------------- converts + RoPE ----------------
__global__ void k_cvt5(const float* __restrict__ A0, const float* __restrict__ A1,
                       const float* __restrict__ A2, const float* __restrict__ A3,
                       const float* __restrict__ A4, u16* __restrict__ out){
  int id = blockIdx.x * 256 + threadIdx.x;         // 5 * 1048576 ids, 4 elems each
  int sel = id >> 20, off = (id & 1048575) * 4;
  const float* src = sel == 0 ? A0 : sel == 1 ? A1 : sel == 2 ? A2 : sel == 3 ? A3 : A4;
  float4 v = *(const float4*)(src + off);
  ushort4 o;
  o.x = f2bf(v.x); o.y = f2bf(v.y); o.z = f2bf(v.z); o.w = f2bf(v.w);
  *(ushort4*)(out + (size_t)sel * 4194304 + off) = o;
}

__global__ void k_rope_tab(float* __restrict__ cosT, float* __restrict__ sinT){
  int i = blockIdx.x * 256 + threadIdx.x;        // 2048*64
  int pos = i >> 6, j = i & 63;
  float invf = powf(10000.0f, -(float)j * (1.0f / 64.0f));
  float a = (float)pos * invf;
  cosT[i] = cosf(a);
  sinT[i] = sinf(a);
}

// rotary in-place on Q and K (sel by gid), pairs (j, j+64) within each head
__global__ void k_rope2(u16* __restrict__ Qm, u16* __restrict__ Km,
                        const float* __restrict__ cosT, const float* __restrict__ sinT){
  int gid = blockIdx.x * 256 + threadIdx.x;      // 2 * 524288
  u16* M = (gid < 524288) ? Qm : Km;
  int id = gid & 524287;
  int pos = id >> 8, rem = id & 255;
  int h = rem >> 4, j4 = (rem & 15) * 4;
  u16* p = M + (size_t)pos * HIDN + h * HDIM + j4;
  ushort4 lo = *(ushort4*)p;
  ushort4 hi = *(ushort4*)(p + 64);
  float4 c = *(const float4*)(cosT + pos * 64 + j4);
  float4 s = *(const float4*)(sinT + pos * 64 + j4);
  float l0 = bf2f(lo.x), l1 = bf2f(lo.y), l2 = bf2f(lo.z), l3 = bf2f(lo.w);
  float h0 = bf2f(hi.x), h1 = bf2f(hi.y), h2 = bf2f(hi.z), h3 = bf2f(hi.w);
  ushort4 nlo, nhi;
  nlo.x = f2bf(l0 * c.x - h0 * s.x);  nhi.x = f2bf(h0 * c.x + l0 * s.x);
  nlo.y = f2bf(l1 * c.y - h1 * s.y);  nhi.y = f2bf(h1 * c.y + l1 * s.y);
  nlo.z = f2bf(l2 * c.z - h2 * s.z);  nhi.z = f2bf(h2 * c.z + l2 * s.z);
  nlo.w = f2bf(l3 * c.w - h3 * s.w);  nhi.w = f2bf(h3 * c.w + l3 * s.w);
  *(ushort4*)p = nlo;
  *(ushort4*)(p + 64) = nhi;
}

__global__ void k_zero4(float* __restrict__ p, int n4){
  for (int i = blockIdx.x * 256 + threadIdx.x; i < n4; i += gridDim.x * 256)
    ((float4*)p)[i] = (float4){0.f, 0.f, 0.f, 0.f};
}

// ---------------- 256x256 8-phase GEMM (C = A @ B^T), BK=64, 8 waves ----------------
// z in {0,1,2} selects (B,C) pair; full K=2048; bf16 out.
// Counted vmcnt + raw barriers + setprio; NO lgkmcnt drain / sched_barrier
// (compiler handles ds_read->MFMA deps; pinning them was the m141-class regression).
__global__ __launch_bounds__(512, 2)
void k_g256(const u16* __restrict__ A, const u16* __restrict__ B0, const u16* __restrict__ B1,
            const u16* __restrict__ B2, u16* __restrict__ C0, u16* __restrict__ C1,
            u16* __restrict__ C2){
  __shared__ __align__(16) u16 LA[2][256 * 64];
  __shared__ __align__(16) u16 LB[2][256 * 64];
  const int tid = threadIdx.x;
  const int lane = tid & 63, wv = tid >> 6;
  const int wm = wv >> 2, wn = wv & 3;
  const int g = lane >> 4, c15 = lane & 15;
  const int brow = blockIdx.y * 256, bcol = blockIdx.x * 256;
  const u16* Bg = blockIdx.z == 0 ? B0 : blockIdx.z == 1 ? B1 : B2;
  u16* Cb = blockIdx.z == 0 ? C0 : blockIdx.z == 1 ? C1 : C2;
  const int NT = 32;

  f32x4 acc[8][4];
#pragma unroll
  for (int m = 0; m < 8; m++)
#pragma unroll
    for (int n = 0; n < 4; n++) acc[m][n] = (f32x4){0.f, 0.f, 0.f, 0.f};

  const int cc0 = ((g ^ (c15 & 7)) * 8);
  bf16x8 af[4][2], bf[4][2];

#define RDA(buf, mibase) \
  _Pragma("unroll") for (int mi2 = 0; mi2 < 4; ++mi2){ \
    const u16* pr = &LA[buf][0] + (size_t)(wm * 128 + ((mibase) + mi2) * 16 + c15) * 64; \
    af[mi2][0] = *(const bf16x8*)(pr + cc0); \
    af[mi2][1] = *(const bf16x8*)(pr + (cc0 ^ 32)); \
  }
#define RDB(buf, nibase) \
  _Pragma("unroll") for (int ni2 = 0; ni2 < 2; ++ni2){ \
    const u16* pr = &LB[buf][0] + (size_t)(wn * 64 + ((nibase) + ni2) * 16 + c15) * 64; \
    bf[(nibase) + ni2][0] = *(const bf16x8*)(pr + cc0); \
    bf[(nibase) + ni2][1] = *(const bf16x8*)(pr + (cc0 ^ 32)); \
  }
#define MM(mibase, nibase) \
  _Pragma("unroll") for (int mi2 = 0; mi2 < 4; ++mi2) \
  _Pragma("unroll") for (int ni2 = 0; ni2 < 2; ++ni2) \
  _Pragma("unroll") for (int kk = 0; kk < 2; ++kk) \
    acc[(mibase) + mi2][(nibase) + ni2] = __builtin_amdgcn_mfma_f32_16x16x32_bf16( \
        af[mi2][kk], bf[(nibase) + ni2][kk], acc[(mibase) + mi2][(nibase) + ni2], 0, 0, 0);

  // prologue: tile0 (A+B) + tile1 (B halves)
  stage_half(A,  brow,       0,  &LA[0][0],            tid);
  stage_half(A,  brow + 128, 0,  &LA[0][0] + 128 * 64, tid);
  stage_half(Bg, bcol,       0,  &LB[0][0],            tid);
  stage_half(Bg, bcol + 128, 0,  &LB[0][0] + 128 * 64, tid);
  stage_half(Bg, bcol,       64, &LB[1][0],            tid);
  stage_half(Bg, bcol + 128, 64, &LB[1][0] + 128 * 64, tid);
  WAITVM(4);
  BARRAW;

  for (int t = 0; t < NT; t += 2){
    const int kn1 = (t + 1) * 64;
    const int kn2 = (t + 2) * 64;
    const int kn3 = (t + 3) * 64;
    // ===== tile t (buf 0) =====
    // ph1
    RDA(0, 0); RDB(0, 0);
    stage_half(A, brow, kn1, &LA[1][0], tid);
    BARRAW; PRIO1; MM(0, 0); PRIO0; BARRAW;
    // ph2
    RDB(0, 2);
    stage_half(A, brow + 128, kn1, &LA[1][0] + 128 * 64, tid);
    BARRAW; PRIO1; MM(0, 2); PRIO0; BARRAW;
    // ph3
    RDA(0, 4);
    if (t + 2 < NT) stage_half(Bg, bcol, kn2, &LB[0][0], tid);
    BARRAW; PRIO1; MM(4, 2); PRIO0; BARRAW;
    // ph4
    if (t + 2 < NT){ stage_half(Bg, bcol + 128, kn2, &LB[0][0] + 128 * 64, tid); WAITVM(4); }
    else            { WAITVM(0); }
    BARRAW; PRIO1; MM(4, 0); PRIO0; BARRAW;
    // ===== tile t+1 (buf 1) =====
    // ph5
    RDA(1, 0); RDB(1, 0);
    if (t + 2 < NT) stage_half(A, brow, kn2, &LA[0][0], tid);
    BARRAW; PRIO1; MM(0, 0); PRIO0; BARRAW;
    // ph6
    RDB(1, 2);
    if (t + 2 < NT) stage_half(A, brow + 128, kn2, &LA[0][0] + 128 * 64, tid);
    BARRAW; PRIO1; MM(0, 2); PRIO0; BARRAW;
    // ph7
    RDA(1, 4);
    if (t + 3 < NT) stage_half(Bg, bcol, kn3, &LB[1][0], tid);
    BARRAW; PRIO1; MM(4, 2); PRIO0; BARRAW;
    // ph8
    if (t + 3 < NT){ stage_half(Bg, bcol + 128, kn3, &LB[1][0] + 128 * 64, tid); WAITVM(4); }
    else if (t + 2 < NT){ WAITVM(0); }
    BARRAW; PRIO1; MM(4, 0); PRIO0; BARRAW;
  }
#undef RDA
#undef RDB
#undef MM

#pragma unroll
  for (int mi = 0; mi < 8; ++mi)
#pragma unroll
    for (int ni = 0; ni < 4; ++ni)
#pragma unroll
      for (int r = 0; r < 4; ++r){
        int row = brow + wm * 128 + mi * 16 + g * 4 + r;
        int col = bcol + wn * 64 + ni * 16 + c15;
        Cb[(size_t)row * 2048 + col] = f2bf(acc[mi][ni][r]);
      }
}

// ---------------- m97-style staging for 256-thread GEMM ----------------
static __device__ __forceinline__ void stage_g(const u16* __restrict__ A, const u16* __restrict__ B,
                                               int brow, int bcol, int k0,
                                               u16* __restrict__ as, u16* __restrict__ bs, int tid){
  const int wbase = tid & ~63;
#pragma unroll
  for (int it = 0; it < 2; ++it){
    int m = it * 256 + tid;
    int row = m >> 2, q = m & 3;
    gload16(A + (size_t)(brow + row) * 2048 + k0 + q * 8, as + (it * 256 + wbase) * 8);
    gload16(B + (size_t)(bcol + row) * 2048 + k0 + q * 8, bs + (it * 256 + wbase) * 8);
  }
}

// output GEMM split-K=2: grid (16,16,2), atomicAdd f32 into zeroed d_out
__global__ __launch_bounds__(256)
void k_gemm_out(const u16* __restrict__ A, const u16* __restrict__ B, float* __restrict__ C){
  __shared__ __align__(16) u16 As[2][128 * 32];
  __shared__ __align__(16) u16 Bs[2][128 * 32];
  const int tid = threadIdx.x;
  const int w = tid >> 6, lane = tid & 63;
  const int wr = w >> 1, wc = w & 1;
  const int g = lane >> 4, c15 = lane & 15;
  const int brow = blockIdx.y * 128, bcol = blockIdx.x * 128;
  const int kbase = blockIdx.z * 1024;

  f32x4 acc[4][4];
#pragma unroll
  for (int m = 0; m < 4; m++)
#pragma unroll
    for (int n = 0; n < 4; n++) acc[m][n] = (f32x4){0.f, 0.f, 0.f, 0.f};

  stage_g(A, B, brow, bcol, kbase, As[0], Bs[0], tid);
  __syncthreads();
  int cur = 0;
  for (int kt = 0; kt < 32; ++kt){
    if (kt + 1 < 32) stage_g(A, B, brow, bcol, kbase + (kt + 1) * 32, As[cur ^ 1], Bs[cur ^ 1], tid);
    bf16x8 af[4], bfr[4];
#pragma unroll
    for (int m = 0; m < 4; m++) af[m] = *(const bf16x8*)(As[cur] + (wr * 64 + m * 16 + c15) * 32 + g * 8);
#pragma unroll
    for (int n = 0; n < 4; n++) bfr[n] = *(const bf16x8*)(Bs[cur] + (wc * 64 + n * 16 + c15) * 32 + g * 8);
#pragma unroll
    for (int m = 0; m < 4; m++)
#pragma unroll
      for (int n = 0; n < 4; n++)
        acc[m][n] = __builtin_amdgcn_mfma_f32_16x16x32_bf16(af[m], bfr[n], acc[m][n], 0, 0, 0);
    __syncthreads();
    cur ^= 1;
  }
#pragma unroll
  for (int m = 0; m < 4; m++)
#pragma unroll
    for (int n = 0; n < 4; n++)
#pragma unroll
      for (int r = 0; r < 4; r++){
        int row = brow + wr * 64 + m * 16 + g * 4 + r;
        int col = bcol + wc * 64 + n * 16 + c15;
        atomicAdd(&C[(size_t)row * 2048 + col], acc[m][n][r]);
      }
}

// ---------------- transpose V: [2048 s][2048 hd] -> [2048 hd][2048 s] ----------------
__global__ void k_transpose_v(const u16* __restrict__ V, u16* __restrict__ Vt){
  __shared__ u16 t[32][33];
  int s0 = blockIdx.x * 32, c0 = blockIdx.y * 32;
  int tid = threadIdx.x;
  int r = tid >> 3, cc = (tid & 7) * 4;
  ushort4 v = *(const ushort4*)(V + (size_t)(s0 + r) * 2048 + c0 + cc);
  t[r][cc] = v.x; t[r][cc + 1] = v.y; t[r][cc + 2] = v.z; t[r][cc + 3] = v.w;
  __syncthreads();
  int co = tid >> 3, ro = (tid & 7) * 4;
  ushort4 o;
  o.x = t[ro][co]; o.y = t[ro + 1][co]; o.z = t[ro + 2][co]; o.w = t[ro + 3][co];
  *(ushort4*)(Vt + (size_t)(c0 + co) * 2048 + s0 + ro) = o;
}

// ---------------- pass 1a: rowsum of exp (causal), triangle-chunked ----------------
// grid (80, 16): bx -> (qb, chunk of 8 k-tiles)
__global__ __launch_bounds__(256)
void k_pass1a(const u16* __restrict__ Q, const u16* __restrict__ K, float* __restrict__ rowsum){
  __shared__ __align__(16) u16 Qs[64 * 128];
  __shared__ __align__(16) u16 Ks[2][64 * 128];
  const int tid = threadIdx.x;
  const int w = tid >> 6, lane = tid & 63;
  const int g = lane >> 4, c15 = lane & 15;
  const int h = blockIdx.y;
  int qb, c; tri_map<3>(blockIdx.x, qb, c);
  const int i0 = qb * 64;
  const int kt0 = c * 8;
  const int kt1 = (qb + 1 < kt0 + 8) ? (qb + 1) : (kt0 + 8);
  const u16* Qh = Q + h * HDIM;
  const u16* Kh = K + h * HDIM;
  const float scale = 0.08838834764831845f;   // 1/sqrt(128)
  const int arow = w * 16 + c15;

  stage_tile(Qh, i0, Qs, tid);
  stage_tile(Kh, kt0 * 64, Ks[0], tid);
  __syncthreads();

  float lsum[4] = {0.f, 0.f, 0.f, 0.f};
  int cur = 0;
  for (int kt = kt0; kt < kt1; ++kt){
    if (kt + 1 < kt1) stage_tile(Kh, (kt + 1) * 64, Ks[cur ^ 1], tid);
    const int k0 = kt * 64;
    f32x4 sacc[4];
#pragma unroll
    for (int n = 0; n < 4; n++) sacc[n] = (f32x4){0.f, 0.f, 0.f, 0.f};
#pragma unroll
    for (int ks = 0; ks < 4; ++ks){
      bf16x8 a = *(const bf16x8*)(Qs + arow * 128 + ((ks * 32 + g * 8) ^ ((arow & 7) << 3)));
#pragma unroll
      for (int n = 0; n < 4; n++){
        int brw = n * 16 + c15;
        bf16x8 b = *(const bf16x8*)(Ks[cur] + brw * 128 + ((ks * 32 + g * 8) ^ ((brw & 7) << 3)));
        sacc[n] = __builtin_amdgcn_mfma_f32_16x16x32_bf16(a, b, sacc[n], 0, 0, 0);
      }
    }
    float rs[4] = {0.f, 0.f, 0.f, 0.f};
#pragma unroll
    for (int n = 0; n < 4; n++){
      int col = k0 + n * 16 + c15;
#pragma unroll
      for (int r = 0; r < 4; r++){
        int rowg = i0 + w * 16 + g * 4 + r;
        rs[r] += (col <= rowg) ? __expf(sacc[n][r] * scale) : 0.f;
      }
    }
#pragma unroll
    for (int r = 0; r < 4; r++){
      float v = rs[r];
      v += __shfl_xor(v, 1); v += __shfl_xor(v, 2);
      v += __shfl_xor(v, 4); v += __shfl_xor(v, 8);
      lsum[r] += v;
    }
    __syncthreads();
    cur ^= 1;
  }
  if (c15 == 0){
#pragma unroll
    for (int r = 0; r < 4; r++)
      atomicAdd(&rowsum[h * 2048 + i0 + w * 16 + g * 4 + r], lsum[r]);
  }
}

// ---------------- pass 1b: colsum of normalized exp, triangle-chunked over q ----------------
// grid (80, 16): bx -> (t, c), kb = 31 - t, q-tiles [kb + c*8, ...)
__global__ __launch_bounds__(256)
void k_pass1b(const u16* __restrict__ Q, const u16* __restrict__ K,
              const float* __restrict__ rowsum, float* __restrict__ colsum){
  __shared__ __align__(16) u16 Ks[64 * 128];
  __shared__ __align__(16) u16 Qs[2][64 * 128];
  __shared__ float cw[4][64];
  const int tid = threadIdx.x;
  const int w = tid >> 6, lane = tid & 63;
  const int g = lane >> 4, c15 = lane & 15;
  const int h = blockIdx.y;
  int t, c; tri_map<3>(blockIdx.x, t, c);
  const int kb = 31 - t;
  const int k0 = kb * 64;
  const int qstart = kb + c * 8;
  const int qend = (qstart + 8 < 32) ? (qstart + 8) : 32;
  const u16* Qh = Q + h * HDIM;
  const u16* Kh = K + h * HDIM;
  const float scale = 0.08838834764831845f;
  const int arow = w * 16 + c15;

  stage_tile(Kh, k0, Ks, tid);
  stage_tile(Qh, qstart * 64, Qs[0], tid);
  __syncthreads();

  float racc[4] = {0.f, 0.f, 0.f, 0.f};
  int cur = 0;
  for (int qt = qstart; qt < qend; ++qt){
    if (qt + 1 < qend) stage_tile(Qh, (qt + 1) * 64, Qs[cur ^ 1], tid);
    const int i0 = qt * 64;
    float rinv[4];
#pragma unroll
    for (int r = 0; r < 4; r++)
      rinv[r] = 1.0f / rowsum[h * 2048 + i0 + w * 16 + g * 4 + r];
    f32x4 sacc[4];
#pragma unroll
    for (int n = 0; n < 4; n++) sacc[n] = (f32x4){0.f, 0.f, 0.f, 0.f};
#pragma unroll
    for (int ks = 0; ks < 4; ++ks){
      bf16x8 a = *(const bf16x8*)(Qs[cur] + arow * 128 + ((ks * 32 + g * 8) ^ ((arow & 7) << 3)));
#pragma unroll
      for (int n = 0; n < 4; n++){
        int brw = n * 16 + c15;
        bf16x8 b = *(const bf16x8*)(Ks + brw * 128 + ((ks * 32 + g * 8) ^ ((brw & 7) << 3)));
        sacc[n] = __builtin_amdgcn_mfma_f32_16x16x32_bf16(a, b, sacc[n], 0, 0, 0);
      }
    }
#pragma unroll
    for (int n = 0; n < 4; n++){
      int col = k0 + n * 16 + c15;
      float cpart = 0.f;
#pragma unroll
      for (int r = 0; r < 4; r++){
        int rowg = i0 + w * 16 + g * 4 + r;
        cpart += (col <= rowg) ? __expf(sacc[n][r] * scale) * rinv[r] : 0.f;
      }
      cpart += __shfl_xor(cpart, 16);
      cpart += __shfl_xor(cpart, 32);
      racc[n] += cpart;
    }
    __syncthreads();
    cur ^= 1;
  }
  if (g == 0){
#pragma unroll
    for (int n = 0; n < 4; n++) cw[w][n * 16 + c15] = racc[n];
  }
  __syncthreads();
  if (tid < 64){
    float s = cw[0][tid] + cw[1][tid] + cw[2][tid] + cw[3][tid];
    atomicAdd(&colsum[h * 2048 + k0 + tid], s);
  }
}

// ---------------- top-k (204) per head via bitonic sort, 1024 threads ----------------
__global__ __launch_bounds__(1024)
void k_topk(const float* __restrict__ colsum, unsigned char* __restrict__ heavy,
            unsigned char* __restrict__ htile){
  __shared__ float v[2048];
  __shared__ short ix[2048];
  __shared__ unsigned char fl[2048];
  __shared__ int tf[32];
  const int tid = threadIdx.x;
  const int h = blockIdx.x;
  for (int i = tid; i < 2048; i += 1024){ v[i] = colsum[h * 2048 + i]; ix[i] = (short)i; fl[i] = 0; }
  if (tid < 32) tf[tid] = 0;
  __syncthreads();
  for (int k = 2; k <= 2048; k <<= 1){
    for (int j = k >> 1; j > 0; j >>= 1){
      int i = ((tid / j) * (j << 1)) + (tid % j);
      int l = i + j;
      float vi = v[i], vl = v[l];
      short ii = ix[i], il = ix[l];
      bool before_i = (vi > vl) || (vi == vl && ii < il);
      bool dir = (i & k) == 0;
      if (dir ? !before_i : before_i){ v[i] = vl; v[l] = vi; ix[i] = il; ix[l] = ii; }
      __syncthreads();
    }
  }
  if (tid < HEAVY){ int id = ix[tid]; fl[id] = 1; atomicOr(&tf[id >> 6], 1); }
  __syncthreads();
  for (int i = tid; i < 2048; i += 1024) heavy[h * 2048 + i] = fl[i];
  if (tid < 32) htile[h * 32 + tid] = (unsigned char)(tf[tid] ? 1 : 0);
}

// ---------------- pass 2: masked attention, triangle-chunked (CH=16), atomic O accumulate ----
// grid (48, 16)
__global__ __launch_bounds__(256)
void k_pass2(const u16* __restrict__ Q, const u16* __restrict__ K, const u16* __restrict__ Vt,
             const unsigned char* __restrict__ heavy, const unsigned char* __restrict__ htile,
             float* __restrict__ Oacc, float* __restrict__ rowsum2){
  __shared__ __align__(16) u16 Qs[64 * 128];
  __shared__ __align__(16) u16 Ks[2][64 * 128];
  __shared__ __align__(16) u16 Ps[4][16 * 64];
  __shared__ unsigned char hfa[16][64];
  __shared__ int lists[16];
  __shared__ int nact_s;
  const int tid = threadIdx.x;
  const int w = tid >> 6, lane = tid & 63;
  const int g = lane >> 4, c15 = lane & 15;
  const int h = blockIdx.y;
  int qb, c; tri_map<4>(blockIdx.x, qb, c);
  const int i0 = qb * 64;
  const int kt0 = c * 16;
  const int kt1 = (qb + 1 < kt0 + 16) ? (qb + 1) : (kt0 + 16);
  const u16* Qh = Q + h * HDIM;
  const u16* Kh = K + h * HDIM;
  const float scale = 0.08838834764831845f;
  const int arow = w * 16 + c15;

  if (tid == 0){
    int n = 0;
    for (int kt = kt0; kt < kt1; ++kt){
      bool band = (kt * 64 + 63 >= i0 - RECENT);
      bool hv = htile[h * 32 + kt] != 0;
      if (band || hv) lists[n++] = kt;
    }
    nact_s = n;
  }
  __syncthreads();
  const int nact = nact_s;
  if (nact == 0) return;

  for (int idx = tid; idx < nact * 64; idx += 256)
    hfa[idx >> 6][idx & 63] = heavy[h * 2048 + lists[idx >> 6] * 64 + (idx & 63)];
  stage_tile(Qh, i0, Qs, tid);
  stage_tile(Kh, lists[0] * 64, Ks[0], tid);
  __syncthreads();

  f32x4 oacc[8];
#pragma unroll
  for (int f = 0; f < 8; f++) oacc[f] = (f32x4){0.f, 0.f, 0.f, 0.f};
  float lsum[4] = {0.f, 0.f, 0.f, 0.f};

  int cur = 0;
  for (int i = 0; i < nact; ++i){
    const int kt = lists[i];
    const int k0 = kt * 64;
    if (i + 1 < nact) stage_tile(Kh, lists[i + 1] * 64, Ks[cur ^ 1], tid);
    // V fragments straight from global (L2-resident), issued early
    bf16x8 vf[2][8];
#pragma unroll
    for (int ks2 = 0; ks2 < 2; ++ks2)
#pragma unroll
      for (int f = 0; f < 8; ++f){
        int vrow = f * 16 + c15;
        vf[ks2][f] = *(const bf16x8*)(Vt + ((size_t)h * HDIM + vrow) * 2048 + k0 + ks2 * 32 + g * 8);
      }
    // QK^T
    f32x4 sacc[4];
#pragma unroll
    for (int n = 0; n < 4; n++) sacc[n] = (f32x4){0.f, 0.f, 0.f, 0.f};
#pragma unroll
    for (int ks = 0; ks < 4; ++ks){
      bf16x8 a = *(const bf16x8*)(Qs + arow * 128 + ((ks * 32 + g * 8) ^ ((arow & 7) << 3)));
#pragma unroll
      for (int n = 0; n < 4; n++){
        int brw = n * 16 + c15;
        bf16x8 b = *(const bf16x8*)(Ks[cur] + brw * 128 + ((ks * 32 + g * 8) ^ ((brw & 7) << 3)));
        sacc[n] = __builtin_amdgcn_mfma_f32_16x16x32_bf16(a, b, sacc[n], 0, 0, 0);
      }
    }
    // masked exp -> P (LDS, per-wave private), row sums
    float rs[4] = {0.f, 0.f, 0.f, 0.f};
#pragma unroll
    for (int n = 0; n < 4; n++){
      int col = k0 + n * 16 + c15;
      int hfv = hfa[i][n * 16 + c15];
#pragma unroll
      for (int r = 0; r < 4; r++){
        int rowg = i0 + w * 16 + g * 4 + r;
        bool valid = (col <= rowg) && (hfv || (rowg - col) <= RECENT);
        float e = valid ? __expf(sacc[n][r] * scale) : 0.f;
        rs[r] += e;
        int prow = g * 4 + r;
        Ps[w][prow * 64 + ((n * 16 + c15) ^ ((prow & 7) << 3))] = f2bf(e);
      }
    }
#pragma unroll
    for (int r = 0; r < 4; r++){
      float vv = rs[r];
      vv += __shfl_xor(vv, 1); vv += __shfl_xor(vv, 2);
      vv += __shfl_xor(vv, 4); vv += __shfl_xor(vv, 8);
      lsum[r] += vv;
    }
    // PV: O += P @ V
#pragma unroll
    for (int ks2 = 0; ks2 < 2; ++ks2){
      bf16x8 pa = *(const bf16x8*)(&Ps[w][c15 * 64 + ((ks2 * 32 + g * 8) ^ ((c15 & 7) << 3))]);
#pragma unroll
      for (int f = 0; f < 8; ++f)
        oacc[f] = __builtin_amdgcn_mfma_f32_16x16x32_bf16(pa, vf[ks2][f], oacc[f], 0, 0, 0);
    }
    __syncthreads();
    cur ^= 1;
  }
#pragma unroll
  for (int f = 0; f < 8; f++)
#pragma unroll
    for (int r = 0; r < 4; r++){
      int rowg = i0 + w * 16 + g * 4 + r;
      atomicAdd(&Oacc[(size_t)rowg * 2048 + h * HDIM + f * 16 + c15], oacc[f][r]);
    }
  if (c15 == 0){
#pragma unroll
    for (int r = 0; r < 4; r++)
      atomicAdd(&rowsum2[h * 2048 + i0 + w * 16 + g * 4 + r], lsum[r]);
  }
}

// ---------------- normalize: attn_bf16 = Oacc * (1/rowsum2) ----------------
__global__ void k_norm(const float* __restrict__ Oacc, const float* __restrict__ rowsum2,
                       u16* __restrict__ attn){
  int gid = blockIdx.x * 256 + threadIdx.x;      // 2048*512
  int row = gid >> 9;
  int c4 = (gid & 511) * 4;
  int h = c4 >> 7;
  float rinv = 1.0f / rowsum2[h * 2048 + row];
  float4 o = *(const float4*)(Oacc + (size_t)row * 2048 + c4);
  ushort4 ov;
  ov.x = f2bf(o.x * rinv); ov.y = f2bf(o.y * rinv);
  ov.z = f2bf(o.z * rinv); ov.w = f2bf(o.w * rinv);
  *(ushort4*)(attn + (size_t)row * 2048 + c4) = ov;
}

// ---------------- host launcher ----------------
extern "C" void kernel_launch(void* const* d_in, const int* in_sizes, int n_in,
                              void* d_out, int out_size, void* d_ws, size_t ws_size,
                              hipStream_t stream){
  const float* X  = (const float*)d_in[0];
  const float* Wq = (const float*)d_in[1];
  const float* Wk = (const float*)d_in[2];
  const float* Wv = (const float*)d_in[3];
  const float* Wo = (const float*)d_in[4];

  char* w = (char*)d_ws;
  const size_t MB8 = (size_t)2048 * 2048 * 2;   // one bf16 matrix = 8 MiB
  u16* Xb  = (u16*)(w);
  u16* Wqb = (u16*)(w + 1 * MB8);
  u16* Wkb = (u16*)(w + 2 * MB8);
  u16* Wvb = (u16*)(w + 3 * MB8);
  u16* Wob = (u16*)(w + 4 * MB8);
  u16* Qb  = (u16*)(w + 5 * MB8);
  u16* Kb  = (u16*)(w + 6 * MB8);
  u16* Vb  = (u16*)(w + 7 * MB8);
  u16* Vtb   = Wqb;   // Wq dead after projections
  u16* attnb = Xb;    // X dead after projections
  float* cosT = (float*)(w + 8 * MB8);                    // 512 KiB
  float* sinT = (float*)(w + 8 * MB8 + 524288);           // 512 KiB
  float* Oacc    = (float*)(w + 8 * MB8 + 1048576);       // 16 MiB
  float* colsum  = Oacc + 4194304;
  float* rowsum  = colsum + 32768;
  float* rowsum2 = rowsum + 32768;
  unsigned char* heavy = (unsigned char*)(rowsum2 + 32768);
  unsigned char* htile = heavy + 16 * 2048;

  dim3 b256(256);

  k_cvt5<<<20480, b256, 0, stream>>>(X, Wq, Wk, Wv, Wo, Xb);
  k_rope_tab<<<512, b256, 0, stream>>>(cosT, sinT);
  k_zero4<<<2048, b256, 0, stream>>>(Oacc, (4194304 + 3 * 32768) / 4);
  k_zero4<<<2048, b256, 0, stream>>>((float*)d_out, 4194304 / 4);

  k_g256<<<dim3(8, 8, 3), dim3(512), 0, stream>>>(Xb, Wqb, Wkb, Wvb, Qb, Kb, Vb);
  k_rope2<<<4096, b256, 0, stream>>>(Qb, Kb, cosT, sinT);
  k_transpose_v<<<dim3(64, 64), b256, 0, stream>>>(Vb, Vtb);

  k_pass1a<<<dim3(80, 16), b256, 0, stream>>>(Qb, Kb, rowsum);
  k_pass1b<<<dim3(80, 16), b256, 0, stream>>>(Qb, Kb, rowsum, colsum);
  k_topk<<<16, dim3(1024), 0, stream>>>(colsum, heavy, htile);
  k_pass2<<<dim3(48, 16), b256, 0, stream>>>(Qb, Kb, Vtb, heavy, htile, Oacc, rowsum2);
  k_norm<<<4096, b256, 0, stream>>>(Oacc, rowsum2, attnb);

  k_gemm_out<<<dim3(16, 16, 2), b256, 0, stream>>>(attnb, Wob, (float*)d_out);
}

// Round 5
// 303.582 us; speedup vs baseline: 1.3296x; 1.0832x over previous
//
#include <hip/hip_runtime.h>
#include <hip/hip_bf16.h>
#include <stdint.h>

// Problem constants: b=1, s=2048, hidden=2048, H=16, d=128
#define SEQ   2048
#define HIDN  2048
#define NHEAD 16
#define HDIM  128
#define HEAVY 204   // int(0.1*2048)
#define RECENT 204

typedef __attribute__((ext_vector_type(4))) float f32x4;
typedef __attribute__((ext_vector_type(8))) short bf16x8;
typedef unsigned short u16;
typedef unsigned int   u32;

static __device__ __forceinline__ u16 f2bf(float f){
  union { float f; u32 u; } v; v.f = f;
  u32 r = (v.u + 0x7FFFu + ((v.u >> 16) & 1u)) >> 16;
  return (u16)r;
}
static __device__ __forceinline__ float bf2f(u16 u){
  union { u32 u; float f; } v; v.u = ((u32)u) << 16;
  return v.f;
}

// global -> LDS direct 16B load (dest is wave-uniform base + lane*16)
static __device__ __forceinline__ void gload16(const void* g, void* l){
  __builtin_amdgcn_global_load_lds((const __attribute__((address_space(1))) u32*)g,
                                   (__attribute__((address_space(3))) u32*)l, 16, 0, 0);
}

#define WAITVM(N) asm volatile("s_waitcnt vmcnt(" #N ")" ::: "memory")
#define BARRAW    __builtin_amdgcn_s_barrier()
#define PRIO1     __builtin_amdgcn_s_setprio(1)
#define PRIO0     __builtin_amdgcn_s_setprio(0)

// stage a 64x128 bf16 tile with 256 threads, runtime row stride (XOR-swizzled source)
static __device__ __forceinline__ void stage_tile(const u16* __restrict__ base, size_t stride,
                                                  int row0, u16* __restrict__ lds, int tid){
  const int wbase = tid & ~63;
#pragma unroll
  for (int it = 0; it < 4; ++it){
    int m = it * 256 + tid;
    int row = m >> 4, cp = m & 15;
    gload16(base + (size_t)(row0 + row) * stride + ((cp ^ (row & 7)) * 8),
            lds + (it * 256 + wbase) * 8);
  }
}

// stage 64x128 / 128x128 tiles with 512 threads (stride 2048)
static __device__ __forceinline__ void stage64_512(const u16* __restrict__ base, int row0,
                                                   u16* __restrict__ lds, int tid){
#pragma unroll
  for (int it = 0; it < 2; ++it){
    int m = it * 512 + tid;
    int row = m >> 4, cp = m & 15;
    gload16(base + (size_t)(row0 + row) * 2048 + ((cp ^ (row & 7)) * 8),
            lds + (it * 512 + (tid & ~63)) * 8);
  }
}
static __device__ __forceinline__ void stage128_512(const u16* __restrict__ base, int row0,
                                                    u16* __restrict__ lds, int tid){
#pragma unroll
  for (int it = 0; it < 4; ++it){
    int m = it * 512 + tid;
    int row = m >> 4, cp = m & 15;
    gload16(base + (size_t)(row0 + row) * 2048 + ((cp ^ (row & 7)) * 8),
            lds + (it * 512 + (tid & ~63)) * 8);
  }
}

// ---------------- converts + RoPE ----------------
__global__ void k_cvt5(const float* __restrict__ A0, const float* __restrict__ A1,
                       const float* __restrict__ A2, const float* __restrict__ A3,
                       const float* __restrict__ A4, u16* __restrict__ out){
  int id = blockIdx.x * 256 + threadIdx.x;         // 5 * 1048576 ids, 4 elems each
  int sel = id >> 20, off = (id & 1048575) * 4;
  const float* src = sel == 0 ? A0 : sel == 1 ? A1 : sel == 2 ? A2 : sel == 3 ? A3 : A4;
  float4 v = *(const float4*)(src + off);
  ushort4 o;
  o.x = f2bf(v.x); o.y = f2bf(v.y); o.z = f2bf(v.z); o.w = f2bf(v.w);
  *(ushort4*)(out + (size_t)sel * 4194304 + off) = o;
}

__global__ void k_rope_tab(float* __restrict__ cosT, float* __restrict__ sinT){
  int i = blockIdx.x * 256 + threadIdx.x;        // 2048*64
  int pos = i >> 6, j = i & 63;
  float invf = powf(10000.0f, -(float)j * (1.0f / 64.0f));
  float a = (float)pos * invf;
  cosT[i] = cosf(a);
  sinT[i] = sinf(a);
}

// rotary in-place on Q and K (sel by gid), pairs (j, j+64) within each head
__global__ void k_rope2(u16* __restrict__ Qm, u16* __restrict__ Km,
                        const float* __restrict__ cosT, const float* __restrict__ sinT){
  int gid = blockIdx.x * 256 + threadIdx.x;      // 2 * 524288
  u16* M = (gid < 524288) ? Qm : Km;
  int id = gid & 524287;
  int pos = id >> 8, rem = id & 255;
  int h = rem >> 4, j4 = (rem & 15) * 4;
  u16* p = M + (size_t)pos * HIDN + h * HDIM + j4;
  ushort4 lo = *(ushort4*)p;
  ushort4 hi = *(ushort4*)(p + 64);
  float4 c = *(const float4*)(cosT + pos * 64 + j4);
  float4 s = *(const float4*)(sinT + pos * 64 + j4);
  float l0 = bf2f(lo.x), l1 = bf2f(lo.y), l2 = bf2f(lo.z), l3 = bf2f(lo.w);
  float h0 = bf2f(hi.x), h1 = bf2f(hi.y), h2 = bf2f(hi.z), h3 = bf2f(hi.w);
  ushort4 nlo, nhi;
  nlo.x = f2bf(l0 * c.x - h0 * s.x);  nhi.x = f2bf(h0 * c.x + l0 * s.x);
  nlo.y = f2bf(l1 * c.y - h1 * s.y);  nhi.y = f2bf(h1 * c.y + l1 * s.y);
  nlo.z = f2bf(l2 * c.z - h2 * s.z);  nhi.z = f2bf(h2 * c.z + l2 * s.z);
  nlo.w = f2bf(l3 * c.w - h3 * s.w);  nhi.w = f2bf(h3 * c.w + l3 * s.w);
  *(ushort4*)p = nlo;
  *(ushort4*)(p + 64) = nhi;
}

__global__ void k_zero4(float* __restrict__ p, int n4){
  for (int i = blockIdx.x * 256 + threadIdx.x; i < n4; i += gridDim.x * 256)
    ((float4*)p)[i] = (float4){0.f, 0.f, 0.f, 0.f};
}

// ---------------- 256x256 8-phase GEMM (C = A @ B^T), BK=64, 8 waves ----------------
__global__ __launch_bounds__(512, 2)
void k_g256(const u16* __restrict__ A, const u16* __restrict__ B0, const u16* __restrict__ B1,
            const u16* __restrict__ B2, u16* __restrict__ C0, u16* __restrict__ C1,
            u16* __restrict__ C2){
  __shared__ __align__(16) u16 LA[2][256 * 64];
  __shared__ __align__(16) u16 LB[2][256 * 64];
  const int tid = threadIdx.x;
  const int lane = tid & 63, wv = tid >> 6;
  const int wm = wv >> 2, wn = wv & 3;
  const int g = lane >> 4, c15 = lane & 15;
  const int brow = blockIdx.y * 256, bcol = blockIdx.x * 256;
  const u16* Bg = blockIdx.z == 0 ? B0 : blockIdx.z == 1 ? B1 : B2;
  u16* Cb = blockIdx.z == 0 ? C0 : blockIdx.z == 1 ? C1 : C2;
  const int NT = 32;

  f32x4 acc[8][4];
#pragma unroll
  for (int m = 0; m < 8; m++)
#pragma unroll
    for (int n = 0; n < 4; n++) acc[m][n] = (f32x4){0.f, 0.f, 0.f, 0.f};

  const int cc0 = ((g ^ (c15 & 7)) * 8);
  bf16x8 af[4][2], bf[4][2];

// stage a 128-row x 64-col half-tile with 512 threads
#define STG(mat, grow0, gcol0, ldsb) do { \
  _Pragma("unroll") for (int it = 0; it < 2; ++it){ \
    int m_ = it * 512 + tid; \
    int row_ = m_ >> 3, cp_ = m_ & 7; \
    gload16((mat) + (size_t)((grow0) + row_) * 2048 + (gcol0) + ((cp_ ^ (row_ & 7)) * 8), \
            (ldsb) + (it * 512 + (tid & ~63)) * 8); \
  } } while(0)
#define RDA(buf, mibase) \
  _Pragma("unroll") for (int mi2 = 0; mi2 < 4; ++mi2){ \
    const u16* pr = &LA[buf][0] + (size_t)(wm * 128 + ((mibase) + mi2) * 16 + c15) * 64; \
    af[mi2][0] = *(const bf16x8*)(pr + cc0); \
    af[mi2][1] = *(const bf16x8*)(pr + (cc0 ^ 32)); \
  }
#define RDB(buf, nibase) \
  _Pragma("unroll") for (int ni2 = 0; ni2 < 2; ++ni2){ \
    const u16* pr = &LB[buf][0] + (size_t)(wn * 64 + ((nibase) + ni2) * 16 + c15) * 64; \
    bf[(nibase) + ni2][0] = *(const bf16x8*)(pr + cc0); \
    bf[(nibase) + ni2][1] = *(const bf16x8*)(pr + (cc0 ^ 32)); \
  }
#define MM(mibase, nibase) \
  _Pragma("unroll") for (int mi2 = 0; mi2 < 4; ++mi2) \
  _Pragma("unroll") for (int ni2 = 0; ni2 < 2; ++ni2) \
  _Pragma("unroll") for (int kk = 0; kk < 2; ++kk) \
    acc[(mibase) + mi2][(nibase) + ni2] = __builtin_amdgcn_mfma_f32_16x16x32_bf16( \
        af[mi2][kk], bf[(nibase) + ni2][kk], acc[(mibase) + mi2][(nibase) + ni2], 0, 0, 0);

  STG(A,  brow,       0,  &LA[0][0]);
  STG(A,  brow + 128, 0,  &LA[0][0] + 128 * 64);
  STG(Bg, bcol,       0,  &LB[0][0]);
  STG(Bg, bcol + 128, 0,  &LB[0][0] + 128 * 64);
  STG(Bg, bcol,       64, &LB[1][0]);
  STG(Bg, bcol + 128, 64, &LB[1][0] + 128 * 64);
  WAITVM(4);
  BARRAW;

  for (int t = 0; t < NT; t += 2){
    const int kn1 = (t + 1) * 64;
    const int kn2 = (t + 2) * 64;
    const int kn3 = (t + 3) * 64;
    // ===== tile t (buf 0) =====
    RDA(0, 0); RDB(0, 0);
    STG(A, brow, kn1, &LA[1][0]);
    BARRAW; PRIO1; MM(0, 0); PRIO0; BARRAW;
    RDB(0, 2);
    STG(A, brow + 128, kn1, &LA[1][0] + 128 * 64);
    BARRAW; PRIO1; MM(0, 2); PRIO0; BARRAW;
    RDA(0, 4);
    if (t + 2 < NT) STG(Bg, bcol, kn2, &LB[0][0]);
    BARRAW; PRIO1; MM(4, 2); PRIO0; BARRAW;
    if (t + 2 < NT){ STG(Bg, bcol + 128, kn2, &LB[0][0] + 128 * 64); WAITVM(4); }
    else            { WAITVM(0); }
    BARRAW; PRIO1; MM(4, 0); PRIO0; BARRAW;
    // ===== tile t+1 (buf 1) =====
    RDA(1, 0); RDB(1, 0);
    if (t + 2 < NT) STG(A, brow, kn2, &LA[0][0]);
    BARRAW; PRIO1; MM(0, 0); PRIO0; BARRAW;
    RDB(1, 2);
    if (t + 2 < NT) STG(A, brow + 128, kn2, &LA[0][0] + 128 * 64);
    BARRAW; PRIO1; MM(0, 2); PRIO0; BARRAW;
    RDA(1, 4);
    if (t + 3 < NT) STG(Bg, bcol, kn3, &LB[1][0]);
    BARRAW; PRIO1; MM(4, 2); PRIO0; BARRAW;
    if (t + 3 < NT){ STG(Bg, bcol + 128, kn3, &LB[1][0] + 128 * 64); WAITVM(4); }
    else if (t + 2 < NT){ WAITVM(0); }
    BARRAW; PRIO1; MM(4, 0); PRIO0; BARRAW;
  }
#undef STG
#undef RDA
#undef RDB
#undef MM

#pragma unroll
  for (int mi = 0; mi < 8; ++mi)
#pragma unroll
    for (int ni = 0; ni < 4; ++ni)
#pragma unroll
      for (int r = 0; r < 4; ++r){
        int row = brow + wm * 128 + mi * 16 + g * 4 + r;
        int col = bcol + wn * 64 + ni * 16 + c15;
        Cb[(size_t)row * 2048 + col] = f2bf(acc[mi][ni][r]);
      }
}

// ---------------- m97-style staging for 256-thread GEMM ----------------
static __device__ __forceinline__ void stage_g(const u16* __restrict__ A, const u16* __restrict__ B,
                                               int brow, int bcol, int k0,
                                               u16* __restrict__ as, u16* __restrict__ bs, int tid){
  const int wbase = tid & ~63;
#pragma unroll
  for (int it = 0; it < 2; ++it){
    int m = it * 256 + tid;
    int row = m >> 2, q = m & 3;
    gload16(A + (size_t)(brow + row) * 2048 + k0 + q * 8, as + (it * 256 + wbase) * 8);
    gload16(B + (size_t)(bcol + row) * 2048 + k0 + q * 8, bs + (it * 256 + wbase) * 8);
  }
}

// output GEMM split-K=2: grid (16,16,2), atomicAdd f32 into zeroed d_out
__global__ __launch_bounds__(256)
void k_gemm_out(const u16* __restrict__ A, const u16* __restrict__ B, float* __restrict__ C){
  __shared__ __align__(16) u16 As[2][128 * 32];
  __shared__ __align__(16) u16 Bs[2][128 * 32];
  const int tid = threadIdx.x;
  const int w = tid >> 6, lane = tid & 63;
  const int wr = w >> 1, wc = w & 1;
  const int g = lane >> 4, c15 = lane & 15;
  const int brow = blockIdx.y * 128, bcol = blockIdx.x * 128;
  const int kbase = blockIdx.z * 1024;

  f32x4 acc[4][4];
#pragma unroll
  for (int m = 0; m < 4; m++)
#pragma unroll
    for (int n = 0; n < 4; n++) acc[m][n] = (f32x4){0.f, 0.f, 0.f, 0.f};

  stage_g(A, B, brow, bcol, kbase, As[0], Bs[0], tid);
  __syncthreads();
  int cur = 0;
  for (int kt = 0; kt < 32; ++kt){
    if (kt + 1 < 32) stage_g(A, B, brow, bcol, kbase + (kt + 1) * 32, As[cur ^ 1], Bs[cur ^ 1], tid);
    bf16x8 af[4], bfr[4];
#pragma unroll
    for (int m = 0; m < 4; m++) af[m] = *(const bf16x8*)(As[cur] + (wr * 64 + m * 16 + c15) * 32 + g * 8);
#pragma unroll
    for (int n = 0; n < 4; n++) bfr[n] = *(const bf16x8*)(Bs[cur] + (wc * 64 + n * 16 + c15) * 32 + g * 8);
#pragma unroll
    for (int m = 0; m < 4; m++)
#pragma unroll
      for (int n = 0; n < 4; n++)
        acc[m][n] = __builtin_amdgcn_mfma_f32_16x16x32_bf16(af[m], bfr[n], acc[m][n], 0, 0, 0);
    __syncthreads();
    cur ^= 1;
  }
#pragma unroll
  for (int m = 0; m < 4; m++)
#pragma unroll
    for (int n = 0; n < 4; n++)
#pragma unroll
      for (int r = 0; r < 4; r++){
        int row = brow + wr * 64 + m * 16 + g * 4 + r;
        int col = bcol + wc * 64 + n * 16 + c15;
        atomicAdd(&C[(size_t)row * 2048 + col], acc[m][n][r]);
      }
}

// ---------------- transpose V: [2048 s][2048 hd] -> [2048 hd][2048 s] ----------------
__global__ void k_transpose_v(const u16* __restrict__ V, u16* __restrict__ Vt){
  __shared__ u16 t[32][33];
  int s0 = blockIdx.x * 32, c0 = blockIdx.y * 32;
  int tid = threadIdx.x;
  int r = tid >> 3, cc = (tid & 7) * 4;
  ushort4 v = *(const ushort4*)(V + (size_t)(s0 + r) * 2048 + c0 + cc);
  t[r][cc] = v.x; t[r][cc + 1] = v.y; t[r][cc + 2] = v.z; t[r][cc + 3] = v.w;
  __syncthreads();
  int co = tid >> 3, ro = (tid & 7) * 4;
  ushort4 o;
  o.x = t[ro][co]; o.y = t[ro + 1][co]; o.z = t[ro + 2][co]; o.w = t[ro + 3][co];
  *(ushort4*)(Vt + (size_t)(c0 + co) * 2048 + s0 + ro) = o;
}

// ---------------- pass 1a: rowsum of exp (causal), QBLK=128, 8 waves ----------------
// grid (40, 16)
__global__ __launch_bounds__(512)
void k_pass1a(const u16* __restrict__ Q, const u16* __restrict__ K, float* __restrict__ rowsum){
  __shared__ __align__(16) u16 Qs[128 * 128];
  __shared__ __align__(16) u16 Ks[2][64 * 128];
  const int tid = threadIdx.x;
  const int wv = tid >> 6, lane = tid & 63;
  const int g = lane >> 4, c15 = lane & 15;
  const int h = blockIdx.y;
  int qb = 0, c = 0;
  { int rem = blockIdx.x; int q = 0;
    while (rem >= ((2 * q + 9) >> 3)){ rem -= (2 * q + 9) >> 3; q++; }
    qb = q; c = rem; }
  const int i0 = qb * 128;
  const int ktend = 2 * qb + 2;
  const int kt0 = c * 8;
  const int kt1 = (ktend < kt0 + 8) ? ktend : (kt0 + 8);
  const u16* Qh = Q + h * HDIM;
  const u16* Kh = K + h * HDIM;
  const float scale = 0.08838834764831845f;   // 1/sqrt(128)
  const int arow = wv * 16 + c15;

  stage128_512(Qh, i0, Qs, tid);
  stage64_512(Kh, kt0 * 64, Ks[0], tid);
  __syncthreads();

  float lsum[4] = {0.f, 0.f, 0.f, 0.f};
  int cur = 0;
  for (int kt = kt0; kt < kt1; ++kt){
    if (kt + 1 < kt1) stage64_512(Kh, (kt + 1) * 64, Ks[cur ^ 1], tid);
    const int k0 = kt * 64;
    f32x4 sacc[4];
#pragma unroll
    for (int n = 0; n < 4; n++) sacc[n] = (f32x4){0.f, 0.f, 0.f, 0.f};
#pragma unroll
    for (int ks = 0; ks < 4; ++ks){
      bf16x8 a = *(const bf16x8*)(Qs + arow * 128 + ((ks * 32 + g * 8) ^ ((arow & 7) << 3)));
#pragma unroll
      for (int n = 0; n < 4; n++){
        int brw = n * 16 + c15;
        bf16x8 b = *(const bf16x8*)(Ks[cur] + brw * 128 + ((ks * 32 + g * 8) ^ ((brw & 7) << 3)));
        sacc[n] = __builtin_amdgcn_mfma_f32_16x16x32_bf16(a, b, sacc[n], 0, 0, 0);
      }
    }
#pragma unroll
    for (int n = 0; n < 4; n++){
      int col = k0 + n * 16 + c15;
#pragma unroll
      for (int r = 0; r < 4; r++){
        int rowg = i0 + wv * 16 + g * 4 + r;
        lsum[r] += (col <= rowg) ? __expf(sacc[n][r] * scale) : 0.f;
      }
    }
    __syncthreads();
    cur ^= 1;
  }
#pragma unroll
  for (int r = 0; r < 4; r++){
    float v = lsum[r];
    v += __shfl_xor(v, 1); v += __shfl_xor(v, 2);
    v += __shfl_xor(v, 4); v += __shfl_xor(v, 8);
    lsum[r] = v;
  }
  if (c15 == 0){
#pragma unroll
    for (int r = 0; r < 4; r++)
      atomicAdd(&rowsum[h * 2048 + i0 + wv * 16 + g * 4 + r], lsum[r]);
  }
}

// ---------------- pass 1b: colsum of normalized exp, KBLK=128, 8 waves ----------------
// grid (40, 16)
__global__ __launch_bounds__(512)
void k_pass1b(const u16* __restrict__ Q, const u16* __restrict__ K,
              const float* __restrict__ rowsum, float* __restrict__ colsum){
  __shared__ __align__(16) u16 Ks[128 * 128];
  __shared__ __align__(16) u16 Qs[2][64 * 128];
  __shared__ float rsb[2][64];
  const int tid = threadIdx.x;
  const int wv = tid >> 6, lane = tid & 63;
  const int g = lane >> 4, c15 = lane & 15;
  const int h = blockIdx.y;
  int kb = 0, c = 0;
  { int rem = blockIdx.x; int q = 0;
    while (rem >= ((39 - 2 * q) >> 3)){ rem -= (39 - 2 * q) >> 3; q++; }
    kb = q; c = rem; }
  const int k0 = kb * 128;
  const int qt0 = 2 * kb + c * 8;
  const int qt1 = (2 * kb + c * 8 + 8 < 32) ? (2 * kb + c * 8 + 8) : 32;
  const u16* Qh = Q + h * HDIM;
  const u16* Kh = K + h * HDIM;
  const float scale = 0.08838834764831845f;
  const int bcol = wv * 16 + c15;

  stage128_512(Kh, k0, Ks, tid);
  stage64_512(Qh, qt0 * 64, Qs[0], tid);
  if (tid < 64) rsb[0][tid] = 1.0f / rowsum[h * 2048 + qt0 * 64 + tid];
  __syncthreads();

  float racc = 0.f;
  int cur = 0;
  for (int qt = qt0; qt < qt1; ++qt){
    if (qt + 1 < qt1){
      stage64_512(Qh, (qt + 1) * 64, Qs[cur ^ 1], tid);
      if (tid < 64) rsb[cur ^ 1][tid] = 1.0f / rowsum[h * 2048 + (qt + 1) * 64 + tid];
    }
    const int i0q = qt * 64;
    f32x4 sacc[4];
#pragma unroll
    for (int m = 0; m < 4; m++) sacc[m] = (f32x4){0.f, 0.f, 0.f, 0.f};
#pragma unroll
    for (int ks = 0; ks < 4; ++ks){
      bf16x8 b = *(const bf16x8*)(Ks + bcol * 128 + ((ks * 32 + g * 8) ^ ((bcol & 7) << 3)));
#pragma unroll
      for (int m = 0; m < 4; m++){
        int arw = m * 16 + c15;
        bf16x8 a = *(const bf16x8*)(Qs[cur] + arw * 128 + ((ks * 32 + g * 8) ^ ((arw & 7) << 3)));
        sacc[m] = __builtin_amdgcn_mfma_f32_16x16x32_bf16(a, b, sacc[m], 0, 0, 0);
      }
    }
    const int col = k0 + bcol;
#pragma unroll
    for (int m = 0; m < 4; m++)
#pragma unroll
      for (int r = 0; r < 4; r++){
        int rl = m * 16 + g * 4 + r;
        int rowg = i0q + rl;
        racc += (col <= rowg) ? __expf(sacc[m][r] * scale) * rsb[cur][rl] : 0.f;
      }
    __syncthreads();
    cur ^= 1;
  }
  racc += __shfl_xor(racc, 16);
  racc += __shfl_xor(racc, 32);
  if (g == 0) atomicAdd(&colsum[h * 2048 + k0 + bcol], racc);
}

// ---------------- top-k (204) per head: value-sort + ascending index list ----------------
__global__ __launch_bounds__(1024)
void k_topk(const float* __restrict__ colsum, short* __restrict__ cidx){
  __shared__ float v[2048];
  __shared__ short ix[2048];
  __shared__ short sx[256];
  const int tid = threadIdx.x;
  const int h = blockIdx.x;
  for (int i = tid; i < 2048; i += 1024){ v[i] = colsum[h * 2048 + i]; ix[i] = (short)i; }
  __syncthreads();
  for (int k = 2; k <= 2048; k <<= 1){
    for (int j = k >> 1; j > 0; j >>= 1){
      int i = ((tid / j) * (j << 1)) + (tid % j);
      int l = i + j;
      float vi = v[i], vl = v[l];
      short ii = ix[i], il = ix[l];
      bool before_i = (vi > vl) || (vi == vl && ii < il);
      bool dir = (i & k) == 0;
      if (dir ? !before_i : before_i){ v[i] = vl; v[l] = vi; ix[i] = il; ix[l] = ii; }
      __syncthreads();
    }
  }
  if (tid < 256) sx[tid] = (tid < HEAVY) ? ix[tid] : (short)32767;
  __syncthreads();
  for (int k = 2; k <= 256; k <<= 1){
    for (int j = k >> 1; j > 0; j >>= 1){
      if (tid < 128){
        int i = ((tid / j) * (j << 1)) + (tid % j);
        int l = i + j;
        short a = sx[i], b = sx[l];
        bool asc = (i & k) == 0;
        if (asc ? (a > b) : (a < b)){ sx[i] = b; sx[l] = a; }
      }
      __syncthreads();
    }
  }
  if (tid < 256) cidx[h * 256 + tid] = sx[tid];
}

// ---------------- gather heavy K rows: Kg[h][slot][d] ----------------
__global__ void k_gatherK(const u16* __restrict__ Kb, const short* __restrict__ cidx,
                          u16* __restrict__ Kg){
  int gid = blockIdx.x * 256 + threadIdx.x;    // 16h * 256slot * 16chunk = 65536
  int h = gid >> 12, rem = gid & 4095;
  int slot = rem >> 4, cp = rem & 15;
  int cid = cidx[h * 256 + slot];
  bf16x8 z = (bf16x8){0,0,0,0,0,0,0,0};
  bf16x8 val = (cid < 2048) ? *(const bf16x8*)(Kb + (size_t)cid * 2048 + h * 128 + cp * 8) : z;
  *(bf16x8*)(Kg + ((size_t)h * 256 + slot) * 128 + cp * 8) = val;
}

// ---------------- gather heavy V cols (transposed): Vg[h][d][slot] ----------------
__global__ void k_gatherV(const u16* __restrict__ Vb, const short* __restrict__ cidx,
                          u16* __restrict__ Vg){
  __shared__ __align__(16) u16 t[32][136];
  int h = blockIdx.x >> 3, s0 = (blockIdx.x & 7) * 32;
  int tid = threadIdx.x;
#pragma unroll
  for (int it = 0; it < 2; ++it){
    int m = it * 256 + tid;                    // 512 chunks = 32 slots x 16 chunks
    int s = m >> 4, cp = m & 15;
    int cid = cidx[h * 256 + s0 + s];
    bf16x8 z = (bf16x8){0,0,0,0,0,0,0,0};
    bf16x8 val = (cid < 2048) ? *(const bf16x8*)(Vb + (size_t)cid * 2048 + h * 128 + cp * 8) : z;
    *(bf16x8*)(&t[s][cp * 8]) = val;
  }
  __syncthreads();
#pragma unroll
  for (int i = 0; i < 16; ++i){
    int idx = i * 256 + tid;                   // 4096 = 128 d x 32 s
    int d = idx >> 5, s = idx & 31;
    Vg[((size_t)h * 128 + d) * 256 + s0 + s] = t[s][d];
  }
}

// ---------------- pass 2: band + gathered-heavy masked attention, direct O write ----
// grid (32, 16), 256 thr
__global__ __launch_bounds__(256)
void k_pass2(const u16* __restrict__ Q, const u16* __restrict__ K, const u16* __restrict__ Vt,
             const u16* __restrict__ Kg, const u16* __restrict__ Vg,
             const short* __restrict__ cidx, u16* __restrict__ attn){
  __shared__ __align__(16) u16 Qs[64 * 128];
  __shared__ __align__(16) u16 Ks[2][64 * 128];
  __shared__ __align__(16) u16 Ps[4][16 * 64];
  __shared__ int lists[12];
  __shared__ int nact_s;
  const int tid = threadIdx.x;
  const int w = tid >> 6, lane = tid & 63;
  const int g = lane >> 4, c15 = lane & 15;
  const int qb = blockIdx.x, h = blockIdx.y;
  const int i0 = qb * 64;
  const u16* Qh = Q + h * HDIM;
  const u16* Kh = K + h * HDIM;
  const u16* Kgh = Kg + (size_t)h * 256 * 128;
  const float scale = 0.08838834764831845f;
  const int arow = w * 16 + c15;

  if (tid == 0){
    int n = 0;
    int ktb0 = (i0 > RECENT) ? ((i0 - RECENT) >> 6) : 0;
    for (int kt = ktb0; kt <= qb; ++kt) lists[n++] = kt;
    for (int gt = 0; gt < 4; ++gt)
      if ((int)cidx[h * 256 + gt * 64] <= i0 - RECENT + 62) lists[n++] = 100 + gt;
    nact_s = n;
  }
  __syncthreads();
  const int nact = nact_s;

  stage_tile(Qh, 2048, i0, Qs, tid);
  { int e = lists[0];
    if (e < 100) stage_tile(Kh, 2048, e * 64, Ks[0], tid);
    else         stage_tile(Kgh, 128, (e - 100) * 64, Ks[0], tid); }
  __syncthreads();

  f32x4 oacc[8];
#pragma unroll
  for (int f = 0; f < 8; f++) oacc[f] = (f32x4){0.f, 0.f, 0.f, 0.f};
  float lsum[4] = {0.f, 0.f, 0.f, 0.f};

  int cur = 0;
  for (int i = 0; i < nact; ++i){
    const int e = lists[i];
    const bool isg = (e >= 100);
    if (i + 1 < nact){
      int e2 = lists[i + 1];
      if (e2 < 100) stage_tile(Kh, 2048, e2 * 64, Ks[cur ^ 1], tid);
      else          stage_tile(Kgh, 128, (e2 - 100) * 64, Ks[cur ^ 1], tid);
    }
    // column ids for masking
    int cidv[4];
#pragma unroll
    for (int n = 0; n < 4; n++)
      cidv[n] = isg ? (int)cidx[h * 256 + (e - 100) * 64 + n * 16 + c15]
                    : (e * 64 + n * 16 + c15);
    // V fragments straight from global (L2-resident), issued early
    bf16x8 vf[2][8];
#pragma unroll
    for (int ks2 = 0; ks2 < 2; ++ks2)
#pragma unroll
      for (int f = 0; f < 8; ++f){
        int vrow = f * 16 + c15;
        vf[ks2][f] = isg
          ? *(const bf16x8*)(Vg + ((size_t)h * 128 + vrow) * 256 + (e - 100) * 64 + ks2 * 32 + g * 8)
          : *(const bf16x8*)(Vt + ((size_t)h * 128 + vrow) * 2048 + e * 64 + ks2 * 32 + g * 8);
      }
    // QK^T
    f32x4 sacc[4];
#pragma unroll
    for (int n = 0; n < 4; n++) sacc[n] = (f32x4){0.f, 0.f, 0.f, 0.f};
#pragma unroll
    for (int ks = 0; ks < 4; ++ks){
      bf16x8 a = *(const bf16x8*)(Qs + arow * 128 + ((ks * 32 + g * 8) ^ ((arow & 7) << 3)));
#pragma unroll
      for (int n = 0; n < 4; n++){
        int brw = n * 16 + c15;
        bf16x8 b = *(const bf16x8*)(Ks[cur] + brw * 128 + ((ks * 32 + g * 8) ^ ((brw & 7) << 3)));
        sacc[n] = __builtin_amdgcn_mfma_f32_16x16x32_bf16(a, b, sacc[n], 0, 0, 0);
      }
    }
    // masked exp -> P (LDS), row sums
#pragma unroll
    for (int n = 0; n < 4; n++){
      int cid = cidv[n];
#pragma unroll
      for (int r = 0; r < 4; r++){
        int rowg = i0 + w * 16 + g * 4 + r;
        int dist = rowg - cid;
        bool valid = (cid <= rowg) && (isg ? (dist > RECENT) : (dist <= RECENT));
        float ev = valid ? __expf(sacc[n][r] * scale) : 0.f;
        lsum[r] += ev;
        int prow = g * 4 + r;
        Ps[w][prow * 64 + ((n * 16 + c15) ^ ((prow & 7) << 3))] = f2bf(ev);
      }
    }
    // PV: O += P @ V
#pragma unroll
    for (int ks2 = 0; ks2 < 2; ++ks2){
      bf16x8 pa = *(const bf16x8*)(&Ps[w][c15 * 64 + ((ks2 * 32 + g * 8) ^ ((c15 & 7) << 3))]);
#pragma unroll
      for (int f = 0; f < 8; ++f)
        oacc[f] = __builtin_amdgcn_mfma_f32_16x16x32_bf16(pa, vf[ks2][f], oacc[f], 0, 0, 0);
    }
    __syncthreads();
    cur ^= 1;
  }
  float rinv[4];
#pragma unroll
  for (int r = 0; r < 4; r++){
    float v = lsum[r];
    v += __shfl_xor(v, 1); v += __shfl_xor(v, 2);
    v += __shfl_xor(v, 4); v += __shfl_xor(v, 8);
    rinv[r] = 1.0f / v;
  }
#pragma unroll
  for (int f = 0; f < 8; f++)
#pragma unroll
    for (int r = 0; r < 4; r++){
      int rowg = i0 + w * 16 + g * 4 + r;
      attn[(size_t)rowg * 2048 + h * HDIM + f * 16 + c15] = f2bf(oacc[f][r] * rinv[r]);
    }
}

// ---------------- host launcher ----------------
extern "C" void kernel_launch(void* const* d_in, const int* in_sizes, int n_in,
                              void* d_out, int out_size, void* d_ws, size_t ws_size,
                              hipStream_t stream){
  const float* X  = (const float*)d_in[0];
  const float* Wq = (const float*)d_in[1];
  const float* Wk = (const float*)d_in[2];
  const float* Wv = (const float*)d_in[3];
  const float* Wo = (const float*)d_in[4];

  char* w = (char*)d_ws;
  const size_t MB8 = (size_t)2048 * 2048 * 2;   // one bf16 matrix = 8 MiB
  u16* Xb  = (u16*)(w);
  u16* Wqb = (u16*)(w + 1 * MB8);
  u16* Wkb = (u16*)(w + 2 * MB8);
  u16* Wvb = (u16*)(w + 3 * MB8);
  u16* Wob = (u16*)(w + 4 * MB8);
  u16* Qb  = (u16*)(w + 5 * MB8);
  u16* Kb  = (u16*)(w + 6 * MB8);
  u16* Vb  = (u16*)(w + 7 * MB8);
  u16* Vtb   = Wqb;   // Wq dead after projections
  u16* attnb = Xb;    // X dead after projections
  char* p = w + 8 * MB8;
  float* cosT = (float*)p;              p += 524288;
  float* sinT = (float*)p;              p += 524288;
  float* colsum = (float*)p;            p += 131072;   // zeroed
  float* rowsum = (float*)p;            p += 131072;   // zeroed
  short* cidx  = (short*)p;             p += 16 * 256 * 2;
  u16*   Kg    = (u16*)p;               p += (size_t)16 * 256 * 128 * 2;
  u16*   Vg    = (u16*)p;

  dim3 b256(256);

  k_cvt5<<<20480, b256, 0, stream>>>(X, Wq, Wk, Wv, Wo, Xb);
  k_rope_tab<<<512, b256, 0, stream>>>(cosT, sinT);
  k_zero4<<<64, b256, 0, stream>>>(colsum, 65536 / 4);
  k_zero4<<<2048, b256, 0, stream>>>((float*)d_out, 4194304 / 4);

  k_g256<<<dim3(8, 8, 3), dim3(512), 0, stream>>>(Xb, Wqb, Wkb, Wvb, Qb, Kb, Vb);
  k_rope2<<<4096, b256, 0, stream>>>(Qb, Kb, cosT, sinT);
  k_transpose_v<<<dim3(64, 64), b256, 0, stream>>>(Vb, Vtb);

  k_pass1a<<<dim3(40, 16), dim3(512), 0, stream>>>(Qb, Kb, rowsum);
  k_pass1b<<<dim3(40, 16), dim3(512), 0, stream>>>(Qb, Kb, rowsum, colsum);
  k_topk<<<16, dim3(1024), 0, stream>>>(colsum, cidx);
  k_gatherK<<<256, b256, 0, stream>>>(Kb, cidx, Kg);
  k_gatherV<<<128, b256, 0, stream>>>(Vb, cidx, Vg);
  k_pass2<<<dim3(32, 16), b256, 0, stream>>>(Qb, Kb, Vtb, Kg, Vg, cidx, attnb);

  k_gemm_out<<<dim3(16, 16, 2), b256, 0, stream>>>(attnb, Wob, (float*)d_out);
}

// Round 6
// 285.321 us; speedup vs baseline: 1.4147x; 1.0640x over previous
//
#include <hip/hip_runtime.h>
#include <hip/hip_bf16.h>
#include <stdint.h>

// Problem constants: b=1, s=2048, hidden=2048, H=16, d=128
#define SEQ   2048
#define HIDN  2048
#define NHEAD 16
#define HDIM  128
#define HEAVY 204   // int(0.1*2048)
#define RECENT 204

typedef __attribute__((ext_vector_type(4))) float f32x4;
typedef __attribute__((ext_vector_type(8))) short bf16x8;
typedef unsigned short u16;
typedef unsigned int   u32;

static __device__ __forceinline__ u16 f2bf(float f){
  union { float f; u32 u; } v; v.f = f;
  u32 r = (v.u + 0x7FFFu + ((v.u >> 16) & 1u)) >> 16;
  return (u16)r;
}
static __device__ __forceinline__ float bf2f(u16 u){
  union { u32 u; float f; } v; v.u = ((u32)u) << 16;
  return v.f;
}

// global -> LDS direct 16B load (dest is wave-uniform base + lane*16)
static __device__ __forceinline__ void gload16(const void* g, void* l){
  __builtin_amdgcn_global_load_lds((const __attribute__((address_space(1))) u32*)g,
                                   (__attribute__((address_space(3))) u32*)l, 16, 0, 0);
}

#define WAITVM(N) asm volatile("s_waitcnt vmcnt(" #N ")" ::: "memory")
#define BARRAW    __builtin_amdgcn_s_barrier()
#define PRIO1     __builtin_amdgcn_s_setprio(1)
#define PRIO0     __builtin_amdgcn_s_setprio(0)

// stage a 64x128 bf16 tile with 256 threads, runtime row stride (XOR-swizzled source)
static __device__ __forceinline__ void stage_tile(const u16* __restrict__ base, size_t stride,
                                                  int row0, u16* __restrict__ lds, int tid){
  const int wbase = tid & ~63;
#pragma unroll
  for (int it = 0; it < 4; ++it){
    int m = it * 256 + tid;
    int row = m >> 4, cp = m & 15;
    gload16(base + (size_t)(row0 + row) * stride + ((cp ^ (row & 7)) * 8),
            lds + (it * 256 + wbase) * 8);
  }
}

// stage 64x128 / 128x128 tiles with 512 threads (stride 2048)
static __device__ __forceinline__ void stage64_512(const u16* __restrict__ base, int row0,
                                                   u16* __restrict__ lds, int tid){
#pragma unroll
  for (int it = 0; it < 2; ++it){
    int m = it * 512 + tid;
    int row = m >> 4, cp = m & 15;
    gload16(base + (size_t)(row0 + row) * 2048 + ((cp ^ (row & 7)) * 8),
            lds + (it * 512 + (tid & ~63)) * 8);
  }
}
static __device__ __forceinline__ void stage128_512(const u16* __restrict__ base, int row0,
                                                    u16* __restrict__ lds, int tid){
#pragma unroll
  for (int it = 0; it < 4; ++it){
    int m = it * 512 + tid;
    int row = m >> 4, cp = m & 15;
    gload16(base + (size_t)(row0 + row) * 2048 + ((cp ^ (row & 7)) * 8),
            lds + (it * 512 + (tid & ~63)) * 8);
  }
}

// ---------------- converts + RoPE ----------------
__global__ void k_cvt5(const float* __restrict__ A0, const float* __restrict__ A1,
                       const float* __restrict__ A2, const float* __restrict__ A3,
                       const float* __restrict__ A4, u16* __restrict__ out){
  int id = blockIdx.x * 256 + threadIdx.x;         // 5 * 1048576 ids, 4 elems each
  int sel = id >> 20, off = (id & 1048575) * 4;
  const float* src = sel == 0 ? A0 : sel == 1 ? A1 : sel == 2 ? A2 : sel == 3 ? A3 : A4;
  float4 v = *(const float4*)(src + off);
  ushort4 o;
  o.x = f2bf(v.x); o.y = f2bf(v.y); o.z = f2bf(v.z); o.w = f2bf(v.w);
  *(ushort4*)(out + (size_t)sel * 4194304 + off) = o;
}

__global__ void k_rope_tab(float* __restrict__ cosT, float* __restrict__ sinT){
  int i = blockIdx.x * 256 + threadIdx.x;        // 2048*64
  int pos = i >> 6, j = i & 63;
  float invf = powf(10000.0f, -(float)j * (1.0f / 64.0f));
  float a = (float)pos * invf;
  cosT[i] = cosf(a);
  sinT[i] = sinf(a);
}

// rotary in-place on Q and K (sel by gid), pairs (j, j+64) within each head
__global__ void k_rope2(u16* __restrict__ Qm, u16* __restrict__ Km,
                        const float* __restrict__ cosT, const float* __restrict__ sinT){
  int gid = blockIdx.x * 256 + threadIdx.x;      // 2 * 524288
  u16* M = (gid < 524288) ? Qm : Km;
  int id = gid & 524287;
  int pos = id >> 8, rem = id & 255;
  int h = rem >> 4, j4 = (rem & 15) * 4;
  u16* p = M + (size_t)pos * HIDN + h * HDIM + j4;
  ushort4 lo = *(ushort4*)p;
  ushort4 hi = *(ushort4*)(p + 64);
  float4 c = *(const float4*)(cosT + pos * 64 + j4);
  float4 s = *(const float4*)(sinT + pos * 64 + j4);
  float l0 = bf2f(lo.x), l1 = bf2f(lo.y), l2 = bf2f(lo.z), l3 = bf2f(lo.w);
  float h0 = bf2f(hi.x), h1 = bf2f(hi.y), h2 = bf2f(hi.z), h3 = bf2f(hi.w);
  ushort4 nlo, nhi;
  nlo.x = f2bf(l0 * c.x - h0 * s.x);  nhi.x = f2bf(h0 * c.x + l0 * s.x);
  nlo.y = f2bf(l1 * c.y - h1 * s.y);  nhi.y = f2bf(h1 * c.y + l1 * s.y);
  nlo.z = f2bf(l2 * c.z - h2 * s.z);  nhi.z = f2bf(h2 * c.z + l2 * s.z);
  nlo.w = f2bf(l3 * c.w - h3 * s.w);  nhi.w = f2bf(h3 * c.w + l3 * s.w);
  *(ushort4*)p = nlo;
  *(ushort4*)(p + 64) = nhi;
}

__global__ void k_zero4(float* __restrict__ p, int n4){
  for (int i = blockIdx.x * 256 + threadIdx.x; i < n4; i += gridDim.x * 256)
    ((float4*)p)[i] = (float4){0.f, 0.f, 0.f, 0.f};
}

// ---------------- fused projection GEMM: C[2048][6144] = X @ [Wq;Wk;Wv]^T ----------------
// 256x192 tile, BK=64, 8 waves (2M x 4N, 3 N-frags/wave), 8-phase, counted vmcnt.
// grid (32, 8) = 256 perfectly balanced blocks -> full CU fill.
__global__ __launch_bounds__(512, 1)
void k_g256(const u16* __restrict__ X, const u16* __restrict__ Wq, const u16* __restrict__ Wk,
            const u16* __restrict__ Wv, u16* __restrict__ C0, u16* __restrict__ C1,
            u16* __restrict__ C2){
  __shared__ __align__(16) u16 LA[2][256 * 64];
  __shared__ __align__(16) u16 LB[2][192 * 64];
  const int tid = threadIdx.x;
  const int lane = tid & 63, wvi = tid >> 6;
  const int wm = wvi >> 2, wn = wvi & 3;
  const int g = lane >> 4, c15 = lane & 15;
  const int brow = blockIdx.y * 256;       // [0,2048)
  const int bcol = blockIdx.x * 192;       // [0,6144)
  const int NT = 32;

  f32x4 acc[8][3];
#pragma unroll
  for (int m = 0; m < 8; m++)
#pragma unroll
    for (int n = 0; n < 3; n++) acc[m][n] = (f32x4){0.f, 0.f, 0.f, 0.f};

  const int cc0 = ((g ^ (c15 & 7)) * 8);
  bf16x8 af[4][2], bf[3][2];

#define BPTR(rB_) (rB_ < 2048 ? Wq + (size_t)(rB_) * 2048 \
                 : rB_ < 4096 ? Wk + (size_t)((rB_) - 2048) * 2048 \
                              : Wv + (size_t)((rB_) - 4096) * 2048)
// A half-tile: 128 rows x 64 cols, 2 loads/thread
#define STGA(grow0, gcol0, ldsb) do { \
  _Pragma("unroll") for (int it = 0; it < 2; ++it){ \
    int m_ = it * 512 + tid; \
    int row_ = m_ >> 3, cp_ = m_ & 7; \
    gload16(X + (size_t)((grow0) + row_) * 2048 + (gcol0) + ((cp_ ^ (row_ & 7)) * 8), \
            (ldsb) + (it * 512 + (tid & ~63)) * 8); \
  } } while(0)
// B rows 0..127 of panel, 2 loads/thread
#define STGB128(gcol0, ldsb) do { \
  _Pragma("unroll") for (int it = 0; it < 2; ++it){ \
    int m_ = it * 512 + tid; \
    int row_ = m_ >> 3, cp_ = m_ & 7; \
    int rB_ = bcol + row_; \
    const u16* bp_ = BPTR(rB_); \
    gload16(bp_ + (gcol0) + ((cp_ ^ (row_ & 7)) * 8), \
            (ldsb) + (it * 512 + (tid & ~63)) * 8); \
  } } while(0)
// B rows 128..191 of panel, 1 load/thread
#define STGB64(gcol0, ldsb) do { \
    int row_ = 128 + (tid >> 3), cp_ = tid & 7; \
    int rB_ = bcol + row_; \
    const u16* bp_ = BPTR(rB_); \
    gload16(bp_ + (gcol0) + ((cp_ ^ (row_ & 7)) * 8), \
            (ldsb) + (tid & ~63) * 8); \
  } while(0)
#define RDA(buf, mibase) \
  _Pragma("unroll") for (int mi2 = 0; mi2 < 4; ++mi2){ \
    const u16* pr = &LA[buf][0] + (size_t)(wm * 128 + ((mibase) + mi2) * 16 + c15) * 64; \
    af[mi2][0] = *(const bf16x8*)(pr + cc0); \
    af[mi2][1] = *(const bf16x8*)(pr + (cc0 ^ 32)); \
  }
#define RDB2(buf) \
  _Pragma("unroll") for (int ni2 = 0; ni2 < 2; ++ni2){ \
    const u16* pr = &LB[buf][0] + (size_t)(wn * 48 + ni2 * 16 + c15) * 64; \
    bf[ni2][0] = *(const bf16x8*)(pr + cc0); \
    bf[ni2][1] = *(const bf16x8*)(pr + (cc0 ^ 32)); \
  }
#define RDB1(buf) do { \
    const u16* pr = &LB[buf][0] + (size_t)(wn * 48 + 32 + c15) * 64; \
    bf[2][0] = *(const bf16x8*)(pr + cc0); \
    bf[2][1] = *(const bf16x8*)(pr + (cc0 ^ 32)); \
  } while(0)
#define MM2(mibase) \
  _Pragma("unroll") for (int mi2 = 0; mi2 < 4; ++mi2) \
  _Pragma("unroll") for (int ni2 = 0; ni2 < 2; ++ni2) \
  _Pragma("unroll") for (int kk = 0; kk < 2; ++kk) \
    acc[(mibase) + mi2][ni2] = __builtin_amdgcn_mfma_f32_16x16x32_bf16( \
        af[mi2][kk], bf[ni2][kk], acc[(mibase) + mi2][ni2], 0, 0, 0);
#define MM1(mibase) \
  _Pragma("unroll") for (int mi2 = 0; mi2 < 4; ++mi2) \
  _Pragma("unroll") for (int kk = 0; kk < 2; ++kk) \
    acc[(mibase) + mi2][2] = __builtin_amdgcn_mfma_f32_16x16x32_bf16( \
        af[mi2][kk], bf[2][kk], acc[(mibase) + mi2][2], 0, 0, 0);

  // prologue: A(0)->LA0, B(0)->LB0, B(1)->LB1. 10 loads; WAITVM(3) retires A0,B0.
  STGA(brow,       0, &LA[0][0]);
  STGA(brow + 128, 0, &LA[0][0] + 128 * 64);
  STGB128(0,  &LB[0][0]);
  STGB64(0,   &LB[0][0] + 128 * 64);
  STGB128(64, &LB[1][0]);
  STGB64(64,  &LB[1][0] + 128 * 64);
  WAITVM(3);
  BARRAW;

  for (int t = 0; t < NT; t += 2){
    const int kn1 = (t + 1) * 64;
    const int kn2 = (t + 2) * 64;
    const int kn3 = (t + 3) * 64;
    // ===== tile t (buf 0) =====
    RDA(0, 0); RDB2(0);
    STGA(brow, kn1, &LA[1][0]);
    BARRAW; PRIO1; MM2(0); PRIO0; BARRAW;
    RDB1(0);
    STGA(brow + 128, kn1, &LA[1][0] + 128 * 64);
    BARRAW; PRIO1; MM1(0); PRIO0; BARRAW;
    RDA(0, 4);
    if (t + 2 < NT) STGB128(kn2, &LB[0][0]);
    BARRAW; PRIO1; MM1(4); PRIO0; BARRAW;
    if (t + 2 < NT){ STGB64(kn2, &LB[0][0] + 128 * 64); WAITVM(3); }
    else            { WAITVM(0); }
    BARRAW; PRIO1; MM2(4); PRIO0; BARRAW;
    // ===== tile t+1 (buf 1) =====
    RDA(1, 0); RDB2(1);
    if (t + 2 < NT) STGA(brow, kn2, &LA[0][0]);
    BARRAW; PRIO1; MM2(0); PRIO0; BARRAW;
    RDB1(1);
    if (t + 2 < NT) STGA(brow + 128, kn2, &LA[0][0] + 128 * 64);
    BARRAW; PRIO1; MM1(0); PRIO0; BARRAW;
    RDA(1, 4);
    if (t + 3 < NT) STGB128(kn3, &LB[1][0]);
    BARRAW; PRIO1; MM1(4); PRIO0; BARRAW;
    if (t + 3 < NT){ STGB64(kn3, &LB[1][0] + 128 * 64); WAITVM(3); }
    else if (t + 2 < NT){ WAITVM(0); }
    BARRAW; PRIO1; MM2(4); PRIO0; BARRAW;
  }
#undef BPTR
#undef STGA
#undef STGB128
#undef STGB64
#undef RDA
#undef RDB2
#undef RDB1
#undef MM2
#undef MM1

#pragma unroll
  for (int mi = 0; mi < 8; ++mi)
#pragma unroll
    for (int ni = 0; ni < 3; ++ni){
      int colbase = bcol + wn * 48 + ni * 16;      // 2048-boundary is 16-aligned
      int proj = colbase >> 11;
      u16* Cb = proj == 0 ? C0 : proj == 1 ? C1 : C2;
      int lc = (colbase & 2047) + c15;
#pragma unroll
      for (int r = 0; r < 4; ++r){
        int row = brow + wm * 128 + mi * 16 + g * 4 + r;
        Cb[(size_t)row * 2048 + lc] = f2bf(acc[mi][ni][r]);
      }
    }
}

// ---------------- m97-style staging for 256-thread GEMM ----------------
static __device__ __forceinline__ void stage_g(const u16* __restrict__ A, const u16* __restrict__ B,
                                               int brow, int bcol, int k0,
                                               u16* __restrict__ as, u16* __restrict__ bs, int tid){
  const int wbase = tid & ~63;
#pragma unroll
  for (int it = 0; it < 2; ++it){
    int m = it * 256 + tid;
    int row = m >> 2, q = m & 3;
    gload16(A + (size_t)(brow + row) * 2048 + k0 + q * 8, as + (it * 256 + wbase) * 8);
    gload16(B + (size_t)(bcol + row) * 2048 + k0 + q * 8, bs + (it * 256 + wbase) * 8);
  }
}

// output GEMM, full K, direct f32 store: grid (16,16) = 256 balanced blocks
__global__ __launch_bounds__(256)
void k_gemm_out(const u16* __restrict__ A, const u16* __restrict__ B, float* __restrict__ C){
  __shared__ __align__(16) u16 As[2][128 * 32];
  __shared__ __align__(16) u16 Bs[2][128 * 32];
  const int tid = threadIdx.x;
  const int w = tid >> 6, lane = tid & 63;
  const int wr = w >> 1, wc = w & 1;
  const int g = lane >> 4, c15 = lane & 15;
  const int brow = blockIdx.y * 128, bcol = blockIdx.x * 128;

  f32x4 acc[4][4];
#pragma unroll
  for (int m = 0; m < 4; m++)
#pragma unroll
    for (int n = 0; n < 4; n++) acc[m][n] = (f32x4){0.f, 0.f, 0.f, 0.f};

  stage_g(A, B, brow, bcol, 0, As[0], Bs[0], tid);
  __syncthreads();
  int cur = 0;
  for (int kt = 0; kt < 64; ++kt){
    if (kt + 1 < 64) stage_g(A, B, brow, bcol, (kt + 1) * 32, As[cur ^ 1], Bs[cur ^ 1], tid);
    bf16x8 af[4], bfr[4];
#pragma unroll
    for (int m = 0; m < 4; m++) af[m] = *(const bf16x8*)(As[cur] + (wr * 64 + m * 16 + c15) * 32 + g * 8);
#pragma unroll
    for (int n = 0; n < 4; n++) bfr[n] = *(const bf16x8*)(Bs[cur] + (wc * 64 + n * 16 + c15) * 32 + g * 8);
#pragma unroll
    for (int m = 0; m < 4; m++)
#pragma unroll
      for (int n = 0; n < 4; n++)
        acc[m][n] = __builtin_amdgcn_mfma_f32_16x16x32_bf16(af[m], bfr[n], acc[m][n], 0, 0, 0);
    __syncthreads();
    cur ^= 1;
  }
#pragma unroll
  for (int m = 0; m < 4; m++)
#pragma unroll
    for (int n = 0; n < 4; n++)
#pragma unroll
      for (int r = 0; r < 4; r++){
        int row = brow + wr * 64 + m * 16 + g * 4 + r;
        int col = bcol + wc * 64 + n * 16 + c15;
        C[(size_t)row * 2048 + col] = acc[m][n][r];
      }
}

// ---------------- transpose V: [2048 s][2048 hd] -> [2048 hd][2048 s] ----------------
__global__ void k_transpose_v(const u16* __restrict__ V, u16* __restrict__ Vt){
  __shared__ u16 t[32][33];
  int s0 = blockIdx.x * 32, c0 = blockIdx.y * 32;
  int tid = threadIdx.x;
  int r = tid >> 3, cc = (tid & 7) * 4;
  ushort4 v = *(const ushort4*)(V + (size_t)(s0 + r) * 2048 + c0 + cc);
  t[r][cc] = v.x; t[r][cc + 1] = v.y; t[r][cc + 2] = v.z; t[r][cc + 3] = v.w;
  __syncthreads();
  int co = tid >> 3, ro = (tid & 7) * 4;
  ushort4 o;
  o.x = t[ro][co]; o.y = t[ro + 1][co]; o.z = t[ro + 2][co]; o.w = t[ro + 3][co];
  *(ushort4*)(Vt + (size_t)(c0 + co) * 2048 + s0 + ro) = o;
}

// ---------------- pass 1a: rowsum of exp (causal), QBLK=128, 8 waves ----------------
// grid (40, 16)
__global__ __launch_bounds__(512)
void k_pass1a(const u16* __restrict__ Q, const u16* __restrict__ K, float* __restrict__ rowsum){
  __shared__ __align__(16) u16 Qs[128 * 128];
  __shared__ __align__(16) u16 Ks[2][64 * 128];
  const int tid = threadIdx.x;
  const int wv = tid >> 6, lane = tid & 63;
  const int g = lane >> 4, c15 = lane & 15;
  const int h = blockIdx.y;
  int qb = 0, c = 0;
  { int rem = blockIdx.x; int q = 0;
    while (rem >= ((2 * q + 9) >> 3)){ rem -= (2 * q + 9) >> 3; q++; }
    qb = q; c = rem; }
  const int i0 = qb * 128;
  const int ktend = 2 * qb + 2;
  const int kt0 = c * 8;
  const int kt1 = (ktend < kt0 + 8) ? ktend : (kt0 + 8);
  const u16* Qh = Q + h * HDIM;
  const u16* Kh = K + h * HDIM;
  const float scale = 0.08838834764831845f;   // 1/sqrt(128)
  const int arow = wv * 16 + c15;

  stage128_512(Qh, i0, Qs, tid);
  stage64_512(Kh, kt0 * 64, Ks[0], tid);
  __syncthreads();

  float lsum[4] = {0.f, 0.f, 0.f, 0.f};
  int cur = 0;
  for (int kt = kt0; kt < kt1; ++kt){
    if (kt + 1 < kt1) stage64_512(Kh, (kt + 1) * 64, Ks[cur ^ 1], tid);
    const int k0 = kt * 64;
    f32x4 sacc[4];
#pragma unroll
    for (int n = 0; n < 4; n++) sacc[n] = (f32x4){0.f, 0.f, 0.f, 0.f};
#pragma unroll
    for (int ks = 0; ks < 4; ++ks){
      bf16x8 a = *(const bf16x8*)(Qs + arow * 128 + ((ks * 32 + g * 8) ^ ((arow & 7) << 3)));
#pragma unroll
      for (int n = 0; n < 4; n++){
        int brw = n * 16 + c15;
        bf16x8 b = *(const bf16x8*)(Ks[cur] + brw * 128 + ((ks * 32 + g * 8) ^ ((brw & 7) << 3)));
        sacc[n] = __builtin_amdgcn_mfma_f32_16x16x32_bf16(a, b, sacc[n], 0, 0, 0);
      }
    }
#pragma unroll
    for (int n = 0; n < 4; n++){
      int col = k0 + n * 16 + c15;
#pragma unroll
      for (int r = 0; r < 4; r++){
        int rowg = i0 + wv * 16 + g * 4 + r;
        lsum[r] += (col <= rowg) ? __expf(sacc[n][r] * scale) : 0.f;
      }
    }
    __syncthreads();
    cur ^= 1;
  }
#pragma unroll
  for (int r = 0; r < 4; r++){
    float v = lsum[r];
    v += __shfl_xor(v, 1); v += __shfl_xor(v, 2);
    v += __shfl_xor(v, 4); v += __shfl_xor(v, 8);
    lsum[r] = v;
  }
  if (c15 == 0){
#pragma unroll
    for (int r = 0; r < 4; r++)
      atomicAdd(&rowsum[h * 2048 + i0 + wv * 16 + g * 4 + r], lsum[r]);
  }
}

// ---------------- pass 1b: colsum of normalized exp, KBLK=128, 8 waves ----------------
// grid (40, 16)
__global__ __launch_bounds__(512)
void k_pass1b(const u16* __restrict__ Q, const u16* __restrict__ K,
              const float* __restrict__ rowsum, float* __restrict__ colsum){
  __shared__ __align__(16) u16 Ks[128 * 128];
  __shared__ __align__(16) u16 Qs[2][64 * 128];
  __shared__ float rsb[2][64];
  const int tid = threadIdx.x;
  const int wv = tid >> 6, lane = tid & 63;
  const int g = lane >> 4, c15 = lane & 15;
  const int h = blockIdx.y;
  int kb = 0, c = 0;
  { int rem = blockIdx.x; int q = 0;
    while (rem >= ((39 - 2 * q) >> 3)){ rem -= (39 - 2 * q) >> 3; q++; }
    kb = q; c = rem; }
  const int k0 = kb * 128;
  const int qt0 = 2 * kb + c * 8;
  const int qt1 = (2 * kb + c * 8 + 8 < 32) ? (2 * kb + c * 8 + 8) : 32;
  const u16* Qh = Q + h * HDIM;
  const u16* Kh = K + h * HDIM;
  const float scale = 0.08838834764831845f;
  const int bcol = wv * 16 + c15;

  stage128_512(Kh, k0, Ks, tid);
  stage64_512(Qh, qt0 * 64, Qs[0], tid);
  if (tid < 64) rsb[0][tid] = 1.0f / rowsum[h * 2048 + qt0 * 64 + tid];
  __syncthreads();

  float racc = 0.f;
  int cur = 0;
  for (int qt = qt0; qt < qt1; ++qt){
    if (qt + 1 < qt1){
      stage64_512(Qh, (qt + 1) * 64, Qs[cur ^ 1], tid);
      if (tid < 64) rsb[cur ^ 1][tid] = 1.0f / rowsum[h * 2048 + (qt + 1) * 64 + tid];
    }
    const int i0q = qt * 64;
    f32x4 sacc[4];
#pragma unroll
    for (int m = 0; m < 4; m++) sacc[m] = (f32x4){0.f, 0.f, 0.f, 0.f};
#pragma unroll
    for (int ks = 0; ks < 4; ++ks){
      bf16x8 b = *(const bf16x8*)(Ks + bcol * 128 + ((ks * 32 + g * 8) ^ ((bcol & 7) << 3)));
#pragma unroll
      for (int m = 0; m < 4; m++){
        int arw = m * 16 + c15;
        bf16x8 a = *(const bf16x8*)(Qs[cur] + arw * 128 + ((ks * 32 + g * 8) ^ ((arw & 7) << 3)));
        sacc[m] = __builtin_amdgcn_mfma_f32_16x16x32_bf16(a, b, sacc[m], 0, 0, 0);
      }
    }
    const int col = k0 + bcol;
#pragma unroll
    for (int m = 0; m < 4; m++)
#pragma unroll
      for (int r = 0; r < 4; r++){
        int rl = m * 16 + g * 4 + r;
        int rowg = i0q + rl;
        racc += (col <= rowg) ? __expf(sacc[m][r] * scale) * rsb[cur][rl] : 0.f;
      }
    __syncthreads();
    cur ^= 1;
  }
  racc += __shfl_xor(racc, 16);
  racc += __shfl_xor(racc, 32);
  if (g == 0) atomicAdd(&colsum[h * 2048 + k0 + bcol], racc);
}

// ---------------- top-k (204) per head: value-sort + ascending index list ----------------
__global__ __launch_bounds__(1024)
void k_topk(const float* __restrict__ colsum, short* __restrict__ cidx){
  __shared__ float v[2048];
  __shared__ short ix[2048];
  __shared__ short sx[256];
  const int tid = threadIdx.x;
  const int h = blockIdx.x;
  for (int i = tid; i < 2048; i += 1024){ v[i] = colsum[h * 2048 + i]; ix[i] = (short)i; }
  __syncthreads();
  for (int k = 2; k <= 2048; k <<= 1){
    for (int j = k >> 1; j > 0; j >>= 1){
      int i = ((tid / j) * (j << 1)) + (tid % j);
      int l = i + j;
      float vi = v[i], vl = v[l];
      short ii = ix[i], il = ix[l];
      bool before_i = (vi > vl) || (vi == vl && ii < il);
      bool dir = (i & k) == 0;
      if (dir ? !before_i : before_i){ v[i] = vl; v[l] = vi; ix[i] = il; ix[l] = ii; }
      __syncthreads();
    }
  }
  if (tid < 256) sx[tid] = (tid < HEAVY) ? ix[tid] : (short)32767;
  __syncthreads();
  for (int k = 2; k <= 256; k <<= 1){
    for (int j = k >> 1; j > 0; j >>= 1){
      if (tid < 128){
        int i = ((tid / j) * (j << 1)) + (tid % j);
        int l = i + j;
        short a = sx[i], b = sx[l];
        bool asc = (i & k) == 0;
        if (asc ? (a > b) : (a < b)){ sx[i] = b; sx[l] = a; }
      }
      __syncthreads();
    }
  }
  if (tid < 256) cidx[h * 256 + tid] = sx[tid];
}

// ---------------- gather heavy K rows: Kg[h][slot][d] ----------------
__global__ void k_gatherK(const u16* __restrict__ Kb, const short* __restrict__ cidx,
                          u16* __restrict__ Kg){
  int gid = blockIdx.x * 256 + threadIdx.x;    // 16h * 256slot * 16chunk = 65536
  int h = gid >> 12, rem = gid & 4095;
  int slot = rem >> 4, cp = rem & 15;
  int cid = cidx[h * 256 + slot];
  bf16x8 z = (bf16x8){0,0,0,0,0,0,0,0};
  bf16x8 val = (cid < 2048) ? *(const bf16x8*)(Kb + (size_t)cid * 2048 + h * 128 + cp * 8) : z;
  *(bf16x8*)(Kg + ((size_t)h * 256 + slot) * 128 + cp * 8) = val;
}

// ---------------- gather heavy V cols (transposed): Vg[h][d][slot] ----------------
__global__ void k_gatherV(const u16* __restrict__ Vb, const short* __restrict__ cidx,
                          u16* __restrict__ Vg){
  __shared__ __align__(16) u16 t[32][136];
  int h = blockIdx.x >> 3, s0 = (blockIdx.x & 7) * 32;
  int tid = threadIdx.x;
#pragma unroll
  for (int it = 0; it < 2; ++it){
    int m = it * 256 + tid;                    // 512 chunks = 32 slots x 16 chunks
    int s = m >> 4, cp = m & 15;
    int cid = cidx[h * 256 + s0 + s];
    bf16x8 z = (bf16x8){0,0,0,0,0,0,0,0};
    bf16x8 val = (cid < 2048) ? *(const bf16x8*)(Vb + (size_t)cid * 2048 + h * 128 + cp * 8) : z;
    *(bf16x8*)(&t[s][cp * 8]) = val;
  }
  __syncthreads();
#pragma unroll
  for (int i = 0; i < 16; ++i){
    int idx = i * 256 + tid;                   // 4096 = 128 d x 32 s
    int d = idx >> 5, s = idx & 31;
    Vg[((size_t)h * 128 + d) * 256 + s0 + s] = t[s][d];
  }
}

// ---------------- pass 2: band + gathered-heavy masked attention, direct O write ----
// grid (32, 16), 256 thr
__global__ __launch_bounds__(256)
void k_pass2(const u16* __restrict__ Q, const u16* __restrict__ K, const u16* __restrict__ Vt,
             const u16* __restrict__ Kg, const u16* __restrict__ Vg,
             const short* __restrict__ cidx, u16* __restrict__ attn){
  __shared__ __align__(16) u16 Qs[64 * 128];
  __shared__ __align__(16) u16 Ks[2][64 * 128];
  __shared__ __align__(16) u16 Ps[4][16 * 64];
  __shared__ int lists[12];
  __shared__ int nact_s;
  const int tid = threadIdx.x;
  const int w = tid >> 6, lane = tid & 63;
  const int g = lane >> 4, c15 = lane & 15;
  const int qb = blockIdx.x, h = blockIdx.y;
  const int i0 = qb * 64;
  const u16* Qh = Q + h * HDIM;
  const u16* Kh = K + h * HDIM;
  const u16* Kgh = Kg + (size_t)h * 256 * 128;
  const float scale = 0.08838834764831845f;
  const int arow = w * 16 + c15;

  if (tid == 0){
    int n = 0;
    int ktb0 = (i0 > RECENT) ? ((i0 - RECENT) >> 6) : 0;
    for (int kt = ktb0; kt <= qb; ++kt) lists[n++] = kt;
    for (int gt = 0; gt < 4; ++gt)
      if ((int)cidx[h * 256 + gt * 64] <= i0 - RECENT + 62) lists[n++] = 100 + gt;
    nact_s = n;
  }
  __syncthreads();
  const int nact = nact_s;

  stage_tile(Qh, 2048, i0, Qs, tid);
  { int e = lists[0];
    if (e < 100) stage_tile(Kh, 2048, e * 64, Ks[0], tid);
    else         stage_tile(Kgh, 128, (e - 100) * 64, Ks[0], tid); }
  __syncthreads();

  f32x4 oacc[8];
#pragma unroll
  for (int f = 0; f < 8; f++) oacc[f] = (f32x4){0.f, 0.f, 0.f, 0.f};
  float lsum[4] = {0.f, 0.f, 0.f, 0.f};

  int cur = 0;
  for (int i = 0; i < nact; ++i){
    const int e = lists[i];
    const bool isg = (e >= 100);
    if (i + 1 < nact){
      int e2 = lists[i + 1];
      if (e2 < 100) stage_tile(Kh, 2048, e2 * 64, Ks[cur ^ 1], tid);
      else          stage_tile(Kgh, 128, (e2 - 100) * 64, Ks[cur ^ 1], tid);
    }
    // column ids for masking
    int cidv[4];
#pragma unroll
    for (int n = 0; n < 4; n++)
      cidv[n] = isg ? (int)cidx[h * 256 + (e - 100) * 64 + n * 16 + c15]
                    : (e * 64 + n * 16 + c15);
    // V fragments straight from global (L2-resident), issued early
    bf16x8 vf[2][8];
#pragma unroll
    for (int ks2 = 0; ks2 < 2; ++ks2)
#pragma unroll
      for (int f = 0; f < 8; ++f){
        int vrow = f * 16 + c15;
        vf[ks2][f] = isg
          ? *(const bf16x8*)(Vg + ((size_t)h * 128 + vrow) * 256 + (e - 100) * 64 + ks2 * 32 + g * 8)
          : *(const bf16x8*)(Vt + ((size_t)h * 128 + vrow) * 2048 + e * 64 + ks2 * 32 + g * 8);
      }
    // QK^T
    f32x4 sacc[4];
#pragma unroll
    for (int n = 0; n < 4; n++) sacc[n] = (f32x4){0.f, 0.f, 0.f, 0.f};
#pragma unroll
    for (int ks = 0; ks < 4; ++ks){
      bf16x8 a = *(const bf16x8*)(Qs + arow * 128 + ((ks * 32 + g * 8) ^ ((arow & 7) << 3)));
#pragma unroll
      for (int n = 0; n < 4; n++){
        int brw = n * 16 + c15;
        bf16x8 b = *(const bf16x8*)(Ks[cur] + brw * 128 + ((ks * 32 + g * 8) ^ ((brw & 7) << 3)));
        sacc[n] = __builtin_amdgcn_mfma_f32_16x16x32_bf16(a, b, sacc[n], 0, 0, 0);
      }
    }
    // masked exp -> P (LDS), row sums
#pragma unroll
    for (int n = 0; n < 4; n++){
      int cid = cidv[n];
#pragma unroll
      for (int r = 0; r < 4; r++){
        int rowg = i0 + w * 16 + g * 4 + r;
        int dist = rowg - cid;
        bool valid = (cid <= rowg) && (isg ? (dist > RECENT) : (dist <= RECENT));
        float ev = valid ? __expf(sacc[n][r] * scale) : 0.f;
        lsum[r] += ev;
        int prow = g * 4 + r;
        Ps[w][prow * 64 + ((n * 16 + c15) ^ ((prow & 7) << 3))] = f2bf(ev);
      }
    }
    // PV: O += P @ V
#pragma unroll
    for (int ks2 = 0; ks2 < 2; ++ks2){
      bf16x8 pa = *(const bf16x8*)(&Ps[w][c15 * 64 + ((ks2 * 32 + g * 8) ^ ((c15 & 7) << 3))]);
#pragma unroll
      for (int f = 0; f < 8; ++f)
        oacc[f] = __builtin_amdgcn_mfma_f32_16x16x32_bf16(pa, vf[ks2][f], oacc[f], 0, 0, 0);
    }
    __syncthreads();
    cur ^= 1;
  }
  float rinv[4];
#pragma unroll
  for (int r = 0; r < 4; r++){
    float v = lsum[r];
    v += __shfl_xor(v, 1); v += __shfl_xor(v, 2);
    v += __shfl_xor(v, 4); v += __shfl_xor(v, 8);
    rinv[r] = 1.0f / v;
  }
#pragma unroll
  for (int f = 0; f < 8; f++)
#pragma unroll
    for (int r = 0; r < 4; r++){
      int rowg = i0 + w * 16 + g * 4 + r;
      attn[(size_t)rowg * 2048 + h * HDIM + f * 16 + c15] = f2bf(oacc[f][r] * rinv[r]);
    }
}

// ---------------- host launcher ----------------
extern "C" void kernel_launch(void* const* d_in, const int* in_sizes, int n_in,
                              void* d_out, int out_size, void* d_ws, size_t ws_size,
                              hipStream_t stream){
  const float* X  = (const float*)d_in[0];
  const float* Wq = (const float*)d_in[1];
  const float* Wk = (const float*)d_in[2];
  const float* Wv = (const float*)d_in[3];
  const float* Wo = (const float*)d_in[4];

  char* w = (char*)d_ws;
  const size_t MB8 = (size_t)2048 * 2048 * 2;   // one bf16 matrix = 8 MiB
  u16* Xb  = (u16*)(w);
  u16* Wqb = (u16*)(w + 1 * MB8);
  u16* Wkb = (u16*)(w + 2 * MB8);
  u16* Wvb = (u16*)(w + 3 * MB8);
  u16* Wob = (u16*)(w + 4 * MB8);
  u16* Qb  = (u16*)(w + 5 * MB8);
  u16* Kb  = (u16*)(w + 6 * MB8);
  u16* Vb  = (u16*)(w + 7 * MB8);
  u16* Vtb   = Wqb;   // Wq dead after projections
  u16* attnb = Xb;    // X dead after projections
  char* p = w + 8 * MB8;
  float* cosT = (float*)p;              p += 524288;
  float* sinT = (float*)p;              p += 524288;
  float* colsum = (float*)p;            p += 131072;   // zeroed
  float* rowsum = (float*)p;            p += 131072;   // zeroed
  short* cidx  = (short*)p;             p += 16 * 256 * 2;
  u16*   Kg    = (u16*)p;               p += (size_t)16 * 256 * 128 * 2;
  u16*   Vg    = (u16*)p;

  dim3 b256(256);

  k_cvt5<<<20480, b256, 0, stream>>>(X, Wq, Wk, Wv, Wo, Xb);
  k_rope_tab<<<512, b256, 0, stream>>>(cosT, sinT);
  k_zero4<<<64, b256, 0, stream>>>(colsum, 65536 / 4);

  k_g256<<<dim3(32, 8), dim3(512), 0, stream>>>(Xb, Wqb, Wkb, Wvb, Qb, Kb, Vb);
  k_rope2<<<4096, b256, 0, stream>>>(Qb, Kb, cosT, sinT);
  k_transpose_v<<<dim3(64, 64), b256, 0, stream>>>(Vb, Vtb);

  k_pass1a<<<dim3(40, 16), dim3(512), 0, stream>>>(Qb, Kb, rowsum);
  k_pass1b<<<dim3(40, 16), dim3(512), 0, stream>>>(Qb, Kb, rowsum, colsum);
  k_topk<<<16, dim3(1024), 0, stream>>>(colsum, cidx);
  k_gatherK<<<256, b256, 0, stream>>>(Kb, cidx, Kg);
  k_gatherV<<<128, b256, 0, stream>>>(Vb, cidx, Vg);
  k_pass2<<<dim3(32, 16), b256, 0, stream>>>(Qb, Kb, Vtb, Kg, Vg, cidx, attnb);

  k_gemm_out<<<dim3(16, 16), b256, 0, stream>>>(attnb, Wob, (float*)d_out);
}

// Round 7
// 278.916 us; speedup vs baseline: 1.4471x; 1.0230x over previous
//
#include <hip/hip_runtime.h>
#include <hip/hip_bf16.h>
#include <stdint.h>

// Problem constants: b=1, s=2048, hidden=2048, H=16, d=128
#define SEQ   2048
#define HIDN  2048
#define NHEAD 16
#define HDIM  128
#define HEAVY 204   // int(0.1*2048)
#define RECENT 204

typedef __attribute__((ext_vector_type(4))) float f32x4;
typedef __attribute__((ext_vector_type(8))) short bf16x8;
typedef unsigned short u16;
typedef unsigned int   u32;

static __device__ __forceinline__ u16 f2bf(float f){
  union { float f; u32 u; } v; v.f = f;
  u32 r = (v.u + 0x7FFFu + ((v.u >> 16) & 1u)) >> 16;
  return (u16)r;
}
static __device__ __forceinline__ float bf2f(u16 u){
  union { u32 u; float f; } v; v.u = ((u32)u) << 16;
  return v.f;
}

// global -> LDS direct 16B load (dest is wave-uniform base + lane*16)
static __device__ __forceinline__ void gload16(const void* g, void* l){
  __builtin_amdgcn_global_load_lds((const __attribute__((address_space(1))) u32*)g,
                                   (__attribute__((address_space(3))) u32*)l, 16, 0, 0);
}

#define WAITVM(N) asm volatile("s_waitcnt vmcnt(" #N ")" ::: "memory")
#define LGKM0RAW  asm volatile("s_waitcnt lgkmcnt(0)" ::: "memory")
#define BARRAW    __builtin_amdgcn_s_barrier()
#define PRIO1     __builtin_amdgcn_s_setprio(1)
#define PRIO0     __builtin_amdgcn_s_setprio(0)

// stage a 64x128 bf16 tile with 256 threads, runtime row stride (XOR-swizzled source)
static __device__ __forceinline__ void stage_tile(const u16* __restrict__ base, size_t stride,
                                                  int row0, u16* __restrict__ lds, int tid){
  const int wbase = tid & ~63;
#pragma unroll
  for (int it = 0; it < 4; ++it){
    int m = it * 256 + tid;
    int row = m >> 4, cp = m & 15;
    gload16(base + (size_t)(row0 + row) * stride + ((cp ^ (row & 7)) * 8),
            lds + (it * 256 + wbase) * 8);
  }
}

// stage 64x128 / 128x128 tiles with 512 threads (stride 2048)
static __device__ __forceinline__ void stage64_512(const u16* __restrict__ base, int row0,
                                                   u16* __restrict__ lds, int tid){
#pragma unroll
  for (int it = 0; it < 2; ++it){
    int m = it * 512 + tid;
    int row = m >> 4, cp = m & 15;
    gload16(base + (size_t)(row0 + row) * 2048 + ((cp ^ (row & 7)) * 8),
            lds + (it * 512 + (tid & ~63)) * 8);
  }
}
static __device__ __forceinline__ void stage128_512(const u16* __restrict__ base, int row0,
                                                    u16* __restrict__ lds, int tid){
#pragma unroll
  for (int it = 0; it < 4; ++it){
    int m = it * 512 + tid;
    int row = m >> 4, cp = m & 15;
    gload16(base + (size_t)(row0 + row) * 2048 + ((cp ^ (row & 7)) * 8),
            lds + (it * 512 + (tid & ~63)) * 8);
  }
}

// ---------------- converts + RoPE ----------------
__global__ void k_cvt5(const float* __restrict__ A0, const float* __restrict__ A1,
                       const float* __restrict__ A2, const float* __restrict__ A3,
                       const float* __restrict__ A4, u16* __restrict__ out){
  int id = blockIdx.x * 256 + threadIdx.x;         // 5 * 1048576 ids, 4 elems each
  int sel = id >> 20, off = (id & 1048575) * 4;
  const float* src = sel == 0 ? A0 : sel == 1 ? A1 : sel == 2 ? A2 : sel == 3 ? A3 : A4;
  float4 v = *(const float4*)(src + off);
  ushort4 o;
  o.x = f2bf(v.x); o.y = f2bf(v.y); o.z = f2bf(v.z); o.w = f2bf(v.w);
  *(ushort4*)(out + (size_t)sel * 4194304 + off) = o;
}

__global__ void k_rope_tab(float* __restrict__ cosT, float* __restrict__ sinT){
  int i = blockIdx.x * 256 + threadIdx.x;        // 2048*64
  int pos = i >> 6, j = i & 63;
  float invf = powf(10000.0f, -(float)j * (1.0f / 64.0f));
  float a = (float)pos * invf;
  cosT[i] = cosf(a);
  sinT[i] = sinf(a);
}

// rotary in-place on Q and K (sel by gid), pairs (j, j+64) within each head
__global__ void k_rope2(u16* __restrict__ Qm, u16* __restrict__ Km,
                        const float* __restrict__ cosT, const float* __restrict__ sinT){
  int gid = blockIdx.x * 256 + threadIdx.x;      // 2 * 524288
  u16* M = (gid < 524288) ? Qm : Km;
  int id = gid & 524287;
  int pos = id >> 8, rem = id & 255;
  int h = rem >> 4, j4 = (rem & 15) * 4;
  u16* p = M + (size_t)pos * HIDN + h * HDIM + j4;
  ushort4 lo = *(ushort4*)p;
  ushort4 hi = *(ushort4*)(p + 64);
  float4 c = *(const float4*)(cosT + pos * 64 + j4);
  float4 s = *(const float4*)(sinT + pos * 64 + j4);
  float l0 = bf2f(lo.x), l1 = bf2f(lo.y), l2 = bf2f(lo.z), l3 = bf2f(lo.w);
  float h0 = bf2f(hi.x), h1 = bf2f(hi.y), h2 = bf2f(hi.z), h3 = bf2f(hi.w);
  ushort4 nlo, nhi;
  nlo.x = f2bf(l0 * c.x - h0 * s.x);  nhi.x = f2bf(h0 * c.x + l0 * s.x);
  nlo.y = f2bf(l1 * c.y - h1 * s.y);  nhi.y = f2bf(h1 * c.y + l1 * s.y);
  nlo.z = f2bf(l2 * c.z - h2 * s.z);  nhi.z = f2bf(h2 * c.z + l2 * s.z);
  nlo.w = f2bf(l3 * c.w - h3 * s.w);  nhi.w = f2bf(h3 * c.w + l3 * s.w);
  *(ushort4*)p = nlo;
  *(ushort4*)(p + 64) = nhi;
}

__global__ void k_zero4(float* __restrict__ p, int n4){
  for (int i = blockIdx.x * 256 + threadIdx.x; i < n4; i += gridDim.x * 256)
    ((float4*)p)[i] = (float4){0.f, 0.f, 0.f, 0.f};
}

// ---------------- fused projection GEMM: C[2048][6144] = X @ [Wq;Wk;Wv]^T ----------------
// 256x192 tile, BK=64, 8 waves (2M x 4N, 3 N-frags/wave), 8-phase, counted vmcnt.
// grid (32, 8) = 256 perfectly balanced blocks -> full CU fill.
__global__ __launch_bounds__(512, 1)
void k_g256(const u16* __restrict__ X, const u16* __restrict__ Wq, const u16* __restrict__ Wk,
            const u16* __restrict__ Wv, u16* __restrict__ C0, u16* __restrict__ C1,
            u16* __restrict__ C2){
  __shared__ __align__(16) u16 LA[2][256 * 64];
  __shared__ __align__(16) u16 LB[2][192 * 64];
  const int tid = threadIdx.x;
  const int lane = tid & 63, wvi = tid >> 6;
  const int wm = wvi >> 2, wn = wvi & 3;
  const int g = lane >> 4, c15 = lane & 15;
  const int brow = blockIdx.y * 256;       // [0,2048)
  const int bcol = blockIdx.x * 192;       // [0,6144)
  const int NT = 32;

  f32x4 acc[8][3];
#pragma unroll
  for (int m = 0; m < 8; m++)
#pragma unroll
    for (int n = 0; n < 3; n++) acc[m][n] = (f32x4){0.f, 0.f, 0.f, 0.f};

  const int cc0 = ((g ^ (c15 & 7)) * 8);
  bf16x8 af[4][2], bf[3][2];

#define BPTR(rB_) (rB_ < 2048 ? Wq + (size_t)(rB_) * 2048 \
                 : rB_ < 4096 ? Wk + (size_t)((rB_) - 2048) * 2048 \
                              : Wv + (size_t)((rB_) - 4096) * 2048)
#define STGA(grow0, gcol0, ldsb) do { \
  _Pragma("unroll") for (int it = 0; it < 2; ++it){ \
    int m_ = it * 512 + tid; \
    int row_ = m_ >> 3, cp_ = m_ & 7; \
    gload16(X + (size_t)((grow0) + row_) * 2048 + (gcol0) + ((cp_ ^ (row_ & 7)) * 8), \
            (ldsb) + (it * 512 + (tid & ~63)) * 8); \
  } } while(0)
#define STGB128(gcol0, ldsb) do { \
  _Pragma("unroll") for (int it = 0; it < 2; ++it){ \
    int m_ = it * 512 + tid; \
    int row_ = m_ >> 3, cp_ = m_ & 7; \
    int rB_ = bcol + row_; \
    const u16* bp_ = BPTR(rB_); \
    gload16(bp_ + (gcol0) + ((cp_ ^ (row_ & 7)) * 8), \
            (ldsb) + (it * 512 + (tid & ~63)) * 8); \
  } } while(0)
#define STGB64(gcol0, ldsb) do { \
    int row_ = 128 + (tid >> 3), cp_ = tid & 7; \
    int rB_ = bcol + row_; \
    const u16* bp_ = BPTR(rB_); \
    gload16(bp_ + (gcol0) + ((cp_ ^ (row_ & 7)) * 8), \
            (ldsb) + (tid & ~63) * 8); \
  } while(0)
#define RDA(buf, mibase) \
  _Pragma("unroll") for (int mi2 = 0; mi2 < 4; ++mi2){ \
    const u16* pr = &LA[buf][0] + (size_t)(wm * 128 + ((mibase) + mi2) * 16 + c15) * 64; \
    af[mi2][0] = *(const bf16x8*)(pr + cc0); \
    af[mi2][1] = *(const bf16x8*)(pr + (cc0 ^ 32)); \
  }
#define RDB2(buf) \
  _Pragma("unroll") for (int ni2 = 0; ni2 < 2; ++ni2){ \
    const u16* pr = &LB[buf][0] + (size_t)(wn * 48 + ni2 * 16 + c15) * 64; \
    bf[ni2][0] = *(const bf16x8*)(pr + cc0); \
    bf[ni2][1] = *(const bf16x8*)(pr + (cc0 ^ 32)); \
  }
#define RDB1(buf) do { \
    const u16* pr = &LB[buf][0] + (size_t)(wn * 48 + 32 + c15) * 64; \
    bf[2][0] = *(const bf16x8*)(pr + cc0); \
    bf[2][1] = *(const bf16x8*)(pr + (cc0 ^ 32)); \
  } while(0)
#define MM2(mibase) \
  _Pragma("unroll") for (int mi2 = 0; mi2 < 4; ++mi2) \
  _Pragma("unroll") for (int ni2 = 0; ni2 < 2; ++ni2) \
  _Pragma("unroll") for (int kk = 0; kk < 2; ++kk) \
    acc[(mibase) + mi2][ni2] = __builtin_amdgcn_mfma_f32_16x16x32_bf16( \
        af[mi2][kk], bf[ni2][kk], acc[(mibase) + mi2][ni2], 0, 0, 0);
#define MM1(mibase) \
  _Pragma("unroll") for (int mi2 = 0; mi2 < 4; ++mi2) \
  _Pragma("unroll") for (int kk = 0; kk < 2; ++kk) \
    acc[(mibase) + mi2][2] = __builtin_amdgcn_mfma_f32_16x16x32_bf16( \
        af[mi2][kk], bf[2][kk], acc[(mibase) + mi2][2], 0, 0, 0);

  STGA(brow,       0, &LA[0][0]);
  STGA(brow + 128, 0, &LA[0][0] + 128 * 64);
  STGB128(0,  &LB[0][0]);
  STGB64(0,   &LB[0][0] + 128 * 64);
  STGB128(64, &LB[1][0]);
  STGB64(64,  &LB[1][0] + 128 * 64);
  WAITVM(3);
  BARRAW;

  for (int t = 0; t < NT; t += 2){
    const int kn1 = (t + 1) * 64;
    const int kn2 = (t + 2) * 64;
    const int kn3 = (t + 3) * 64;
    // ===== tile t (buf 0) =====
    RDA(0, 0); RDB2(0);
    STGA(brow, kn1, &LA[1][0]);
    BARRAW; PRIO1; MM2(0); PRIO0; BARRAW;
    RDB1(0);
    STGA(brow + 128, kn1, &LA[1][0] + 128 * 64);
    BARRAW; PRIO1; MM1(0); PRIO0; BARRAW;
    RDA(0, 4);
    if (t + 2 < NT) STGB128(kn2, &LB[0][0]);
    BARRAW; PRIO1; MM1(4); PRIO0; BARRAW;
    if (t + 2 < NT){ STGB64(kn2, &LB[0][0] + 128 * 64); WAITVM(3); }
    else            { WAITVM(0); }
    BARRAW; PRIO1; MM2(4); PRIO0; BARRAW;
    // ===== tile t+1 (buf 1) =====
    RDA(1, 0); RDB2(1);
    if (t + 2 < NT) STGA(brow, kn2, &LA[0][0]);
    BARRAW; PRIO1; MM2(0); PRIO0; BARRAW;
    RDB1(1);
    if (t + 2 < NT) STGA(brow + 128, kn2, &LA[0][0] + 128 * 64);
    BARRAW; PRIO1; MM1(0); PRIO0; BARRAW;
    RDA(1, 4);
    if (t + 3 < NT) STGB128(kn3, &LB[1][0]);
    BARRAW; PRIO1; MM1(4); PRIO0; BARRAW;
    if (t + 3 < NT){ STGB64(kn3, &LB[1][0] + 128 * 64); WAITVM(3); }
    else if (t + 2 < NT){ WAITVM(0); }
    BARRAW; PRIO1; MM2(4); PRIO0; BARRAW;
  }
#undef BPTR
#undef STGA
#undef STGB128
#undef STGB64
#undef RDA
#undef RDB2
#undef RDB1
#undef MM2
#undef MM1

#pragma unroll
  for (int mi = 0; mi < 8; ++mi)
#pragma unroll
    for (int ni = 0; ni < 3; ++ni){
      int colbase = bcol + wn * 48 + ni * 16;      // 2048-boundary is 16-aligned
      int proj = colbase >> 11;
      u16* Cb = proj == 0 ? C0 : proj == 1 ? C1 : C2;
      int lc = (colbase & 2047) + c15;
#pragma unroll
      for (int r = 0; r < 4; ++r){
        int row = brow + wm * 128 + mi * 16 + g * 4 + r;
        Cb[(size_t)row * 2048 + lc] = f2bf(acc[mi][ni][r]);
      }
    }
}

// ---------------- m97-style staging for 256-thread GEMM ----------------
static __device__ __forceinline__ void stage_g(const u16* __restrict__ A, const u16* __restrict__ B,
                                               int brow, int bcol, int k0,
                                               u16* __restrict__ as, u16* __restrict__ bs, int tid){
  const int wbase = tid & ~63;
#pragma unroll
  for (int it = 0; it < 2; ++it){
    int m = it * 256 + tid;
    int row = m >> 2, q = m & 3;
    gload16(A + (size_t)(brow + row) * 2048 + k0 + q * 8, as + (it * 256 + wbase) * 8);
    gload16(B + (size_t)(bcol + row) * 2048 + k0 + q * 8, bs + (it * 256 + wbase) * 8);
  }
}

// output GEMM, full K, counted-vmcnt 2-phase, direct f32 store: grid (16,16)
__global__ __launch_bounds__(256)
void k_gemm_out(const u16* __restrict__ A, const u16* __restrict__ B, float* __restrict__ C){
  __shared__ __align__(16) u16 As[2][128 * 32];
  __shared__ __align__(16) u16 Bs[2][128 * 32];
  const int tid = threadIdx.x;
  const int w = tid >> 6, lane = tid & 63;
  const int wr = w >> 1, wc = w & 1;
  const int g = lane >> 4, c15 = lane & 15;
  const int brow = blockIdx.y * 128, bcol = blockIdx.x * 128;

  f32x4 acc[4][4];
#pragma unroll
  for (int m = 0; m < 4; m++)
#pragma unroll
    for (int n = 0; n < 4; n++) acc[m][n] = (f32x4){0.f, 0.f, 0.f, 0.f};

  stage_g(A, B, brow, bcol, 0, As[0], Bs[0], tid);
  int cur = 0;
  for (int kt = 0; kt < 64; ++kt){
    if (kt + 1 < 64){ stage_g(A, B, brow, bcol, (kt + 1) * 32, As[cur ^ 1], Bs[cur ^ 1], tid);
                      WAITVM(4); }
    else            { WAITVM(0); }
    BARRAW;
    bf16x8 af[4], bfr[4];
#pragma unroll
    for (int m = 0; m < 4; m++) af[m] = *(const bf16x8*)(As[cur] + (wr * 64 + m * 16 + c15) * 32 + g * 8);
#pragma unroll
    for (int n = 0; n < 4; n++) bfr[n] = *(const bf16x8*)(Bs[cur] + (wc * 64 + n * 16 + c15) * 32 + g * 8);
    PRIO1;
#pragma unroll
    for (int m = 0; m < 4; m++)
#pragma unroll
      for (int n = 0; n < 4; n++)
        acc[m][n] = __builtin_amdgcn_mfma_f32_16x16x32_bf16(af[m], bfr[n], acc[m][n], 0, 0, 0);
    PRIO0;
    BARRAW;
    cur ^= 1;
  }
#pragma unroll
  for (int m = 0; m < 4; m++)
#pragma unroll
    for (int n = 0; n < 4; n++)
#pragma unroll
      for (int r = 0; r < 4; r++){
        int row = brow + wr * 64 + m * 16 + g * 4 + r;
        int col = bcol + wc * 64 + n * 16 + c15;
        C[(size_t)row * 2048 + col] = acc[m][n][r];
      }
}

// ---------------- transpose V: [2048 s][2048 hd] -> [2048 hd][2048 s] ----------------
__global__ void k_transpose_v(const u16* __restrict__ V, u16* __restrict__ Vt){
  __shared__ u16 t[32][33];
  int s0 = blockIdx.x * 32, c0 = blockIdx.y * 32;
  int tid = threadIdx.x;
  int r = tid >> 3, cc = (tid & 7) * 4;
  ushort4 v = *(const ushort4*)(V + (size_t)(s0 + r) * 2048 + c0 + cc);
  t[r][cc] = v.x; t[r][cc + 1] = v.y; t[r][cc + 2] = v.z; t[r][cc + 3] = v.w;
  __syncthreads();
  int co = tid >> 3, ro = (tid & 7) * 4;
  ushort4 o;
  o.x = t[ro][co]; o.y = t[ro + 1][co]; o.z = t[ro + 2][co]; o.w = t[ro + 3][co];
  *(ushort4*)(Vt + (size_t)(c0 + co) * 2048 + s0 + ro) = o;
}

// ---------------- pass 1a: rowsum of exp (causal), QBLK=128, counted-vmcnt ----------------
// grid (40, 16)
__global__ __launch_bounds__(512)
void k_pass1a(const u16* __restrict__ Q, const u16* __restrict__ K, float* __restrict__ rowsum){
  __shared__ __align__(16) u16 Qs[128 * 128];
  __shared__ __align__(16) u16 Ks[2][64 * 128];
  const int tid = threadIdx.x;
  const int wv = tid >> 6, lane = tid & 63;
  const int g = lane >> 4, c15 = lane & 15;
  const int h = blockIdx.y;
  int qb = 0, c = 0;
  { int rem = blockIdx.x; int q = 0;
    while (rem >= ((2 * q + 9) >> 3)){ rem -= (2 * q + 9) >> 3; q++; }
    qb = q; c = rem; }
  const int i0 = qb * 128;
  const int ktend = 2 * qb + 2;
  const int kt0 = c * 8;
  const int kt1 = (ktend < kt0 + 8) ? ktend : (kt0 + 8);
  const u16* Qh = Q + h * HDIM;
  const u16* Kh = K + h * HDIM;
  const float scale = 0.08838834764831845f;   // 1/sqrt(128)
  const int arow = wv * 16 + c15;

  stage128_512(Qh, i0, Qs, tid);              // 4 loads
  stage64_512(Kh, kt0 * 64, Ks[0], tid);      // 2 loads

  float lsum[4] = {0.f, 0.f, 0.f, 0.f};
  int cur = 0;
  for (int kt = kt0; kt < kt1; ++kt){
    if (kt + 1 < kt1){ stage64_512(Kh, (kt + 1) * 64, Ks[cur ^ 1], tid); WAITVM(2); }
    else             { WAITVM(0); }
    BARRAW;
    const int k0 = kt * 64;
    f32x4 sacc[4];
#pragma unroll
    for (int n = 0; n < 4; n++) sacc[n] = (f32x4){0.f, 0.f, 0.f, 0.f};
#pragma unroll
    for (int ks = 0; ks < 4; ++ks){
      bf16x8 a = *(const bf16x8*)(Qs + arow * 128 + ((ks * 32 + g * 8) ^ ((arow & 7) << 3)));
#pragma unroll
      for (int n = 0; n < 4; n++){
        int brw = n * 16 + c15;
        bf16x8 b = *(const bf16x8*)(Ks[cur] + brw * 128 + ((ks * 32 + g * 8) ^ ((brw & 7) << 3)));
        sacc[n] = __builtin_amdgcn_mfma_f32_16x16x32_bf16(a, b, sacc[n], 0, 0, 0);
      }
    }
    if (kt < 2 * qb){          // fully causal tile: no mask compare
#pragma unroll
      for (int n = 0; n < 4; n++)
#pragma unroll
        for (int r = 0; r < 4; r++)
          lsum[r] += __expf(sacc[n][r] * scale);
    } else {
#pragma unroll
      for (int n = 0; n < 4; n++){
        int col = k0 + n * 16 + c15;
#pragma unroll
        for (int r = 0; r < 4; r++){
          int rowg = i0 + wv * 16 + g * 4 + r;
          lsum[r] += (col <= rowg) ? __expf(sacc[n][r] * scale) : 0.f;
        }
      }
    }
    BARRAW;
    cur ^= 1;
  }
#pragma unroll
  for (int r = 0; r < 4; r++){
    float v = lsum[r];
    v += __shfl_xor(v, 1); v += __shfl_xor(v, 2);
    v += __shfl_xor(v, 4); v += __shfl_xor(v, 8);
    lsum[r] = v;
  }
  if (c15 == 0){
#pragma unroll
    for (int r = 0; r < 4; r++)
      atomicAdd(&rowsum[h * 2048 + i0 + wv * 16 + g * 4 + r], lsum[r]);
  }
}

// ---------------- pass 1b: colsum of normalized exp, KBLK=128, counted-vmcnt ----------------
// grid (40, 16)
__global__ __launch_bounds__(512)
void k_pass1b(const u16* __restrict__ Q, const u16* __restrict__ K,
              const float* __restrict__ rowsum, float* __restrict__ colsum){
  __shared__ __align__(16) u16 Ks[128 * 128];
  __shared__ __align__(16) u16 Qs[2][64 * 128];
  __shared__ float rsb[512];
  const int tid = threadIdx.x;
  const int wv = tid >> 6, lane = tid & 63;
  const int g = lane >> 4, c15 = lane & 15;
  const int h = blockIdx.y;
  int kb = 0, c = 0;
  { int rem = blockIdx.x; int q = 0;
    while (rem >= ((39 - 2 * q) >> 3)){ rem -= (39 - 2 * q) >> 3; q++; }
    kb = q; c = rem; }
  const int k0 = kb * 128;
  const int qt0 = 2 * kb + c * 8;
  const int qt1 = (2 * kb + c * 8 + 8 < 32) ? (2 * kb + c * 8 + 8) : 32;
  const u16* Qh = Q + h * HDIM;
  const u16* Kh = K + h * HDIM;
  const float scale = 0.08838834764831845f;
  const int bcol = wv * 16 + c15;

  // rinv table for the whole block's q-rows (issued first so its use-wait is precise)
  { int row = qt0 * 64 + tid;
    float rv = (row < 2048) ? rowsum[h * 2048 + row] : 1.0f;
    rsb[tid] = 1.0f / rv; }
  stage128_512(Kh, k0, Ks, tid);              // 4 loads
  stage64_512(Qh, qt0 * 64, Qs[0], tid);      // 2 loads
  LGKM0RAW;                                   // rsb ds_write drained before first barrier

  float racc = 0.f;
  int cur = 0;
  for (int qt = qt0; qt < qt1; ++qt){
    if (qt + 1 < qt1){ stage64_512(Qh, (qt + 1) * 64, Qs[cur ^ 1], tid); WAITVM(2); }
    else             { WAITVM(0); }
    BARRAW;
    const int i0q = qt * 64;
    f32x4 sacc[4];
#pragma unroll
    for (int m = 0; m < 4; m++) sacc[m] = (f32x4){0.f, 0.f, 0.f, 0.f};
#pragma unroll
    for (int ks = 0; ks < 4; ++ks){
      bf16x8 b = *(const bf16x8*)(Ks + bcol * 128 + ((ks * 32 + g * 8) ^ ((bcol & 7) << 3)));
#pragma unroll
      for (int m = 0; m < 4; m++){
        int arw = m * 16 + c15;
        bf16x8 a = *(const bf16x8*)(Qs[cur] + arw * 128 + ((ks * 32 + g * 8) ^ ((arw & 7) << 3)));
        sacc[m] = __builtin_amdgcn_mfma_f32_16x16x32_bf16(a, b, sacc[m], 0, 0, 0);
      }
    }
    const int rbase = (qt - qt0) * 64;
    if (qt >= 2 * kb + 2){     // fully causal: no mask compare
#pragma unroll
      for (int m = 0; m < 4; m++)
#pragma unroll
        for (int r = 0; r < 4; r++){
          int rl = m * 16 + g * 4 + r;
          racc += __expf(sacc[m][r] * scale) * rsb[rbase + rl];
        }
    } else {
      const int col = k0 + bcol;
#pragma unroll
      for (int m = 0; m < 4; m++)
#pragma unroll
        for (int r = 0; r < 4; r++){
          int rl = m * 16 + g * 4 + r;
          int rowg = i0q + rl;
          racc += (col <= rowg) ? __expf(sacc[m][r] * scale) * rsb[rbase + rl] : 0.f;
        }
    }
    BARRAW;
    cur ^= 1;
  }
  racc += __shfl_xor(racc, 16);
  racc += __shfl_xor(racc, 32);
  if (g == 0) atomicAdd(&colsum[h * 2048 + k0 + bcol], racc);
}

// ---------------- top-k (204) per head: value-sort + ascending index list ----------------
__global__ __launch_bounds__(1024)
void k_topk(const float* __restrict__ colsum, short* __restrict__ cidx){
  __shared__ float v[2048];
  __shared__ short ix[2048];
  __shared__ short sx[256];
  const int tid = threadIdx.x;
  const int h = blockIdx.x;
  for (int i = tid; i < 2048; i += 1024){ v[i] = colsum[h * 2048 + i]; ix[i] = (short)i; }
  __syncthreads();
  for (int k = 2; k <= 2048; k <<= 1){
    for (int j = k >> 1; j > 0; j >>= 1){
      int i = ((tid / j) * (j << 1)) + (tid % j);
      int l = i + j;
      float vi = v[i], vl = v[l];
      short ii = ix[i], il = ix[l];
      bool before_i = (vi > vl) || (vi == vl && ii < il);
      bool dir = (i & k) == 0;
      if (dir ? !before_i : before_i){ v[i] = vl; v[l] = vi; ix[i] = il; ix[l] = ii; }
      __syncthreads();
    }
  }
  if (tid < 256) sx[tid] = (tid < HEAVY) ? ix[tid] : (short)32767;
  __syncthreads();
  for (int k = 2; k <= 256; k <<= 1){
    for (int j = k >> 1; j > 0; j >>= 1){
      if (tid < 128){
        int i = ((tid / j) * (j << 1)) + (tid % j);
        int l = i + j;
        short a = sx[i], b = sx[l];
        bool asc = (i & k) == 0;
        if (asc ? (a > b) : (a < b)){ sx[i] = b; sx[l] = a; }
      }
      __syncthreads();
    }
  }
  if (tid < 256) cidx[h * 256 + tid] = sx[tid];
}

// ---------------- gather heavy K rows: Kg[h][slot][d] ----------------
__global__ void k_gatherK(const u16* __restrict__ Kb, const short* __restrict__ cidx,
                          u16* __restrict__ Kg){
  int gid = blockIdx.x * 256 + threadIdx.x;    // 16h * 256slot * 16chunk = 65536
  int h = gid >> 12, rem = gid & 4095;
  int slot = rem >> 4, cp = rem & 15;
  int cid = cidx[h * 256 + slot];
  bf16x8 z = (bf16x8){0,0,0,0,0,0,0,0};
  bf16x8 val = (cid < 2048) ? *(const bf16x8*)(Kb + (size_t)cid * 2048 + h * 128 + cp * 8) : z;
  *(bf16x8*)(Kg + ((size_t)h * 256 + slot) * 128 + cp * 8) = val;
}

// ---------------- gather heavy V cols (transposed): Vg[h][d][slot] ----------------
__global__ void k_gatherV(const u16* __restrict__ Vb, const short* __restrict__ cidx,
                          u16* __restrict__ Vg){
  __shared__ __align__(16) u16 t[32][136];
  int h = blockIdx.x >> 3, s0 = (blockIdx.x & 7) * 32;
  int tid = threadIdx.x;
#pragma unroll
  for (int it = 0; it < 2; ++it){
    int m = it * 256 + tid;                    // 512 chunks = 32 slots x 16 chunks
    int s = m >> 4, cp = m & 15;
    int cid = cidx[h * 256 + s0 + s];
    bf16x8 z = (bf16x8){0,0,0,0,0,0,0,0};
    bf16x8 val = (cid < 2048) ? *(const bf16x8*)(Vb + (size_t)cid * 2048 + h * 128 + cp * 8) : z;
    *(bf16x8*)(&t[s][cp * 8]) = val;
  }
  __syncthreads();
#pragma unroll
  for (int i = 0; i < 16; ++i){
    int idx = i * 256 + tid;                   // 4096 = 128 d x 32 s
    int d = idx >> 5, s = idx & 31;
    Vg[((size_t)h * 128 + d) * 256 + s0 + s] = t[s][d];
  }
}

// V fragments for one tile (register-resident)
static __device__ __forceinline__ void load_vf(const u16* __restrict__ Vt,
                                               const u16* __restrict__ Vg,
                                               int h, int e, int g, int c15,
                                               bf16x8 vf[2][8]){
  const bool isg = (e >= 100);
#pragma unroll
  for (int ks2 = 0; ks2 < 2; ++ks2)
#pragma unroll
    for (int f = 0; f < 8; ++f){
      int vrow = f * 16 + c15;
      vf[ks2][f] = isg
        ? *(const bf16x8*)(Vg + ((size_t)h * 128 + vrow) * 256 + (e - 100) * 64 + ks2 * 32 + g * 8)
        : *(const bf16x8*)(Vt + ((size_t)h * 128 + vrow) * 2048 + e * 64 + ks2 * 32 + g * 8);
    }
}

// ---------------- pass 2: band + gathered-heavy masked attention, counted-vmcnt ----
// grid (32, 16), 256 thr
__global__ __launch_bounds__(256)
void k_pass2(const u16* __restrict__ Q, const u16* __restrict__ K, const u16* __restrict__ Vt,
             const u16* __restrict__ Kg, const u16* __restrict__ Vg,
             const short* __restrict__ cidx, u16* __restrict__ attn){
  __shared__ __align__(16) u16 Qs[64 * 128];
  __shared__ __align__(16) u16 Ks[2][64 * 128];
  __shared__ __align__(16) u16 Ps[4][16 * 64];
  __shared__ short cids[256];
  __shared__ int lists[12];
  __shared__ int nact_s;
  const int tid = threadIdx.x;
  const int w = tid >> 6, lane = tid & 63;
  const int g = lane >> 4, c15 = lane & 15;
  const int qb = blockIdx.x, h = blockIdx.y;
  const int i0 = qb * 64;
  const u16* Qh = Q + h * HDIM;
  const u16* Kh = K + h * HDIM;
  const u16* Kgh = Kg + (size_t)h * 256 * 128;
  const float scale = 0.08838834764831845f;
  const int arow = w * 16 + c15;

  if (tid < 256) cids[tid] = cidx[h * 256 + tid];
  __syncthreads();
  if (tid == 0){
    int n = 0;
    int ktb0 = (i0 > RECENT) ? ((i0 - RECENT) >> 6) : 0;
    for (int kt = ktb0; kt <= qb; ++kt) lists[n++] = kt;
    for (int gt = 0; gt < 4; ++gt)
      if ((int)cids[gt * 64] <= i0 - RECENT + 62) lists[n++] = 100 + gt;
    nact_s = n;
  }
  __syncthreads();
  const int nact = nact_s;

  // prologue: Q (4) + K(list0) (4) + vf(list0) (16) -> WAITVM(16) retires Q,K0
  stage_tile(Qh, 2048, i0, Qs, tid);
  { int e = lists[0];
    if (e < 100) stage_tile(Kh, 2048, e * 64, Ks[0], tid);
    else         stage_tile(Kgh, 128, (e - 100) * 64, Ks[0], tid); }
  bf16x8 vf[2][8];
  load_vf(Vt, Vg, h, lists[0], g, c15, vf);
  WAITVM(16);
  BARRAW;

  f32x4 oacc[8];
#pragma unroll
  for (int f = 0; f < 8; f++) oacc[f] = (f32x4){0.f, 0.f, 0.f, 0.f};
  float lsum[4] = {0.f, 0.f, 0.f, 0.f};

  int cur = 0;
  for (int i = 0; i < nact; ++i){
    const int e = lists[i];
    const bool isg = (e >= 100);
    const bool nxt = (i + 1 < nact);
    if (nxt){
      int e2 = lists[i + 1];
      if (e2 < 100) stage_tile(Kh, 2048, e2 * 64, Ks[cur ^ 1], tid);
      else          stage_tile(Kgh, 128, (e2 - 100) * 64, Ks[cur ^ 1], tid);
      WAITVM(20);              // retire K(i); keep vf(i)+K(i+1) in flight
    } else {
      WAITVM(16);              // retire K(last); keep vf(last)
    }
    BARRAW;
    // QK^T
    f32x4 sacc[4];
#pragma unroll
    for (int n = 0; n < 4; n++) sacc[n] = (f32x4){0.f, 0.f, 0.f, 0.f};
#pragma unroll
    for (int ks = 0; ks < 4; ++ks){
      bf16x8 a = *(const bf16x8*)(Qs + arow * 128 + ((ks * 32 + g * 8) ^ ((arow & 7) << 3)));
#pragma unroll
      for (int n = 0; n < 4; n++){
        int brw = n * 16 + c15;
        bf16x8 b = *(const bf16x8*)(Ks[cur] + brw * 128 + ((ks * 32 + g * 8) ^ ((brw & 7) << 3)));
        sacc[n] = __builtin_amdgcn_mfma_f32_16x16x32_bf16(a, b, sacc[n], 0, 0, 0);
      }
    }
    // masked exp -> P (LDS, wave-private), row sums
#pragma unroll
    for (int n = 0; n < 4; n++){
      int cid = isg ? (int)cids[(e - 100) * 64 + n * 16 + c15] : (e * 64 + n * 16 + c15);
#pragma unroll
      for (int r = 0; r < 4; r++){
        int rowg = i0 + w * 16 + g * 4 + r;
        int dist = rowg - cid;
        bool valid = (cid <= rowg) && (isg ? (dist > RECENT) : (dist <= RECENT));
        float ev = valid ? __expf(sacc[n][r] * scale) : 0.f;
        lsum[r] += ev;
        int prow = g * 4 + r;
        Ps[w][prow * 64 + ((n * 16 + c15) ^ ((prow & 7) << 3))] = f2bf(ev);
      }
    }
    // retire vf(i) under the exp phase, then PV
    if (nxt) WAITVM(4); else WAITVM(0);
    PRIO1;
#pragma unroll
    for (int ks2 = 0; ks2 < 2; ++ks2){
      bf16x8 pa = *(const bf16x8*)(&Ps[w][c15 * 64 + ((ks2 * 32 + g * 8) ^ ((c15 & 7) << 3))]);
#pragma unroll
      for (int f = 0; f < 8; ++f)
        oacc[f] = __builtin_amdgcn_mfma_f32_16x16x32_bf16(pa, vf[ks2][f], oacc[f], 0, 0, 0);
    }
    PRIO0;
    if (nxt) load_vf(Vt, Vg, h, lists[i + 1], g, c15, vf);   // vf(i+1) in flight across barrier
    BARRAW;
    cur ^= 1;
  }
  float rinv[4];
#pragma unroll
  for (int r = 0; r < 4; r++){
    float v = lsum[r];
    v += __shfl_xor(v, 1); v += __shfl_xor(v, 2);
    v += __shfl_xor(v, 4); v += __shfl_xor(v, 8);
    rinv[r] = 1.0f / v;
  }
#pragma unroll
  for (int f = 0; f < 8; f++)
#pragma unroll
    for (int r = 0; r < 4; r++){
      int rowg = i0 + w * 16 + g * 4 + r;
      attn[(size_t)rowg * 2048 + h * HDIM + f * 16 + c15] = f2bf(oacc[f][r] * rinv[r]);
    }
}

// ---------------- host launcher ----------------
extern "C" void kernel_launch(void* const* d_in, const int* in_sizes, int n_in,
                              void* d_out, int out_size, void* d_ws, size_t ws_size,
                              hipStream_t stream){
  const float* X  = (const float*)d_in[0];
  const float* Wq = (const float*)d_in[1];
  const float* Wk = (const float*)d_in[2];
  const float* Wv = (const float*)d_in[3];
  const float* Wo = (const float*)d_in[4];

  char* w = (char*)d_ws;
  const size_t MB8 = (size_t)2048 * 2048 * 2;   // one bf16 matrix = 8 MiB
  u16* Xb  = (u16*)(w);
  u16* Wqb = (u16*)(w + 1 * MB8);
  u16* Wkb = (u16*)(w + 2 * MB8);
  u16* Wvb = (u16*)(w + 3 * MB8);
  u16* Wob = (u16*)(w + 4 * MB8);
  u16* Qb  = (u16*)(w + 5 * MB8);
  u16* Kb  = (u16*)(w + 6 * MB8);
  u16* Vb  = (u16*)(w + 7 * MB8);
  u16* Vtb   = Wqb;   // Wq dead after projections
  u16* attnb = Xb;    // X dead after projections
  char* p = w + 8 * MB8;
  float* cosT = (float*)p;              p += 524288;
  float* sinT = (float*)p;              p += 524288;
  float* colsum = (float*)p;            p += 131072;   // zeroed
  float* rowsum = (float*)p;            p += 131072;   // zeroed
  short* cidx  = (short*)p;             p += 16 * 256 * 2;
  u16*   Kg    = (u16*)p;               p += (size_t)16 * 256 * 128 * 2;
  u16*   Vg    = (u16*)p;

  dim3 b256(256);

  k_cvt5<<<20480, b256, 0, stream>>>(X, Wq, Wk, Wv, Wo, Xb);
  k_rope_tab<<<512, b256, 0, stream>>>(cosT, sinT);
  k_zero4<<<64, b256, 0, stream>>>(colsum, 65536 / 4);

  k_g256<<<dim3(32, 8), dim3(512), 0, stream>>>(Xb, Wqb, Wkb, Wvb, Qb, Kb, Vb);
  k_rope2<<<4096, b256, 0, stream>>>(Qb, Kb, cosT, sinT);
  k_transpose_v<<<dim3(64, 64), b256, 0, stream>>>(Vb, Vtb);

  k_pass1a<<<dim3(40, 16), dim3(512), 0, stream>>>(Qb, Kb, rowsum);
  k_pass1b<<<dim3(40, 16), dim3(512), 0, stream>>>(Qb, Kb, rowsum, colsum);
  k_topk<<<16, dim3(1024), 0, stream>>>(colsum, cidx);
  k_gatherK<<<256, b256, 0, stream>>>(Kb, cidx, Kg);
  k_gatherV<<<128, b256, 0, stream>>>(Vb, cidx, Vg);
  k_pass2<<<dim3(32, 16), b256, 0, stream>>>(Qb, Kb, Vtb, Kg, Vg, cidx, attnb);

  k_gemm_out<<<dim3(16, 16), b256, 0, stream>>>(attnb, Wob, (float*)d_out);
}

// Round 8
// 262.352 us; speedup vs baseline: 1.5385x; 1.0631x over previous
//
#include <hip/hip_runtime.h>
#include <hip/hip_bf16.h>
#include <stdint.h>

// Problem constants: b=1, s=2048, hidden=2048, H=16, d=128
#define SEQ   2048
#define HIDN  2048
#define NHEAD 16
#define HDIM  128
#define HEAVY 204   // int(0.1*2048)
#define RECENT 204

typedef __attribute__((ext_vector_type(4))) float f32x4;
typedef __attribute__((ext_vector_type(8))) short bf16x8;
typedef unsigned short u16;
typedef unsigned int   u32;

static __device__ __forceinline__ u16 f2bf(float f){
  union { float f; u32 u; } v; v.f = f;
  u32 r = (v.u + 0x7FFFu + ((v.u >> 16) & 1u)) >> 16;
  return (u16)r;
}
static __device__ __forceinline__ float bf2f(u16 u){
  union { u32 u; float f; } v; v.u = ((u32)u) << 16;
  return v.f;
}

// global -> LDS direct 16B load (dest is wave-uniform base + lane*16)
static __device__ __forceinline__ void gload16(const void* g, void* l){
  __builtin_amdgcn_global_load_lds((const __attribute__((address_space(1))) u32*)g,
                                   (__attribute__((address_space(3))) u32*)l, 16, 0, 0);
}

#define WAITVM(N) asm volatile("s_waitcnt vmcnt(" #N ")" ::: "memory")
#define BARRAW    __builtin_amdgcn_s_barrier()
#define PRIO1     __builtin_amdgcn_s_setprio(1)
#define PRIO0     __builtin_amdgcn_s_setprio(0)

// stage a 64x128 bf16 tile with 256 threads, runtime row stride (XOR-swizzled source)
static __device__ __forceinline__ void stage_tile(const u16* __restrict__ base, size_t stride,
                                                  int row0, u16* __restrict__ lds, int tid){
  const int wbase = tid & ~63;
#pragma unroll
  for (int it = 0; it < 4; ++it){
    int m = it * 256 + tid;
    int row = m >> 4, cp = m & 15;
    gload16(base + (size_t)(row0 + row) * stride + ((cp ^ (row & 7)) * 8),
            lds + (it * 256 + wbase) * 8);
  }
}

// ---------------- prep: cvt5 + rope tables + zero colsum (fused) ----------------
__global__ void k_prep(const float* __restrict__ A0, const float* __restrict__ A1,
                       const float* __restrict__ A2, const float* __restrict__ A3,
                       const float* __restrict__ A4, u16* __restrict__ out,
                       float* __restrict__ cosT, float* __restrict__ sinT,
                       float* __restrict__ colsum){
  int b = blockIdx.x, tid = threadIdx.x;
  if (b < 20480){
    int id = b * 256 + tid;
    int sel = id >> 20, off = (id & 1048575) * 4;
    const float* src = sel == 0 ? A0 : sel == 1 ? A1 : sel == 2 ? A2 : sel == 3 ? A3 : A4;
    float4 v = *(const float4*)(src + off);
    ushort4 o;
    o.x = f2bf(v.x); o.y = f2bf(v.y); o.z = f2bf(v.z); o.w = f2bf(v.w);
    *(ushort4*)(out + (size_t)sel * 4194304 + off) = o;
  } else if (b < 20992){
    int i = (b - 20480) * 256 + tid;           // 2048*64
    int pos = i >> 6, j = i & 63;
    float invf = powf(10000.0f, -(float)j * (1.0f / 64.0f));
    float a = (float)pos * invf;
    cosT[i] = cosf(a);
    sinT[i] = sinf(a);
  } else {
    int i = (b - 20992) * 256 + tid;           // 16384 float4
    if (i < 16384) ((float4*)colsum)[i] = (float4){0.f, 0.f, 0.f, 0.f};
  }
}

// ---------------- post: rope on Q,K + transpose V (fused) ----------------
__global__ void k_post(u16* __restrict__ Qm, u16* __restrict__ Km,
                       const float* __restrict__ cosT, const float* __restrict__ sinT,
                       const u16* __restrict__ V, u16* __restrict__ Vt){
  __shared__ u16 t[32][33];
  int b = blockIdx.x, tid = threadIdx.x;
  if (b < 4096){
    int gid = b * 256 + tid;                   // 2 * 524288
    u16* M = (gid < 524288) ? Qm : Km;
    int id = gid & 524287;
    int pos = id >> 8, rem = id & 255;
    int h = rem >> 4, j4 = (rem & 15) * 4;
    u16* p = M + (size_t)pos * HIDN + h * HDIM + j4;
    ushort4 lo = *(ushort4*)p;
    ushort4 hi = *(ushort4*)(p + 64);
    float4 c = *(const float4*)(cosT + pos * 64 + j4);
    float4 s = *(const float4*)(sinT + pos * 64 + j4);
    float l0 = bf2f(lo.x), l1 = bf2f(lo.y), l2 = bf2f(lo.z), l3 = bf2f(lo.w);
    float h0 = bf2f(hi.x), h1 = bf2f(hi.y), h2 = bf2f(hi.z), h3 = bf2f(hi.w);
    ushort4 nlo, nhi;
    nlo.x = f2bf(l0 * c.x - h0 * s.x);  nhi.x = f2bf(h0 * c.x + l0 * s.x);
    nlo.y = f2bf(l1 * c.y - h1 * s.y);  nhi.y = f2bf(h1 * c.y + l1 * s.y);
    nlo.z = f2bf(l2 * c.z - h2 * s.z);  nhi.z = f2bf(h2 * c.z + l2 * s.z);
    nlo.w = f2bf(l3 * c.w - h3 * s.w);  nhi.w = f2bf(h3 * c.w + l3 * s.w);
    *(ushort4*)p = nlo;
    *(ushort4*)(p + 64) = nhi;
  } else {
    int b2 = b - 4096;
    int s0 = (b2 & 63) * 32, c0 = (b2 >> 6) * 32;
    int r = tid >> 3, cc = (tid & 7) * 4;
    ushort4 v = *(const ushort4*)(V + (size_t)(s0 + r) * 2048 + c0 + cc);
    t[r][cc] = v.x; t[r][cc + 1] = v.y; t[r][cc + 2] = v.z; t[r][cc + 3] = v.w;
    __syncthreads();
    int co = tid >> 3, ro = (tid & 7) * 4;
    ushort4 o;
    o.x = t[ro][co]; o.y = t[ro + 1][co]; o.z = t[ro + 2][co]; o.w = t[ro + 3][co];
    *(ushort4*)(Vt + (size_t)(c0 + co) * 2048 + s0 + ro) = o;
  }
}

// ---------------- fused projection GEMM: C[2048][6144] = X @ [Wq;Wk;Wv]^T ----------------
// 256x192 tile, BK=64, 8 waves (2M x 4N, 3 N-frags/wave), 8-phase, counted vmcnt.
// grid (32, 8) = 256 perfectly balanced blocks -> full CU fill.
__global__ __launch_bounds__(512, 1)
void k_g256(const u16* __restrict__ X, const u16* __restrict__ Wq, const u16* __restrict__ Wk,
            const u16* __restrict__ Wv, u16* __restrict__ C0, u16* __restrict__ C1,
            u16* __restrict__ C2){
  __shared__ __align__(16) u16 LA[2][256 * 64];
  __shared__ __align__(16) u16 LB[2][192 * 64];
  const int tid = threadIdx.x;
  const int lane = tid & 63, wvi = tid >> 6;
  const int wm = wvi >> 2, wn = wvi & 3;
  const int g = lane >> 4, c15 = lane & 15;
  const int brow = blockIdx.y * 256;       // [0,2048)
  const int bcol = blockIdx.x * 192;       // [0,6144)
  const int NT = 32;

  f32x4 acc[8][3];
#pragma unroll
  for (int m = 0; m < 8; m++)
#pragma unroll
    for (int n = 0; n < 3; n++) acc[m][n] = (f32x4){0.f, 0.f, 0.f, 0.f};

  const int cc0 = ((g ^ (c15 & 7)) * 8);
  bf16x8 af[4][2], bf[3][2];

#define BPTR(rB_) (rB_ < 2048 ? Wq + (size_t)(rB_) * 2048 \
                 : rB_ < 4096 ? Wk + (size_t)((rB_) - 2048) * 2048 \
                              : Wv + (size_t)((rB_) - 4096) * 2048)
#define STGA(grow0, gcol0, ldsb) do { \
  _Pragma("unroll") for (int it = 0; it < 2; ++it){ \
    int m_ = it * 512 + tid; \
    int row_ = m_ >> 3, cp_ = m_ & 7; \
    gload16(X + (size_t)((grow0) + row_) * 2048 + (gcol0) + ((cp_ ^ (row_ & 7)) * 8), \
            (ldsb) + (it * 512 + (tid & ~63)) * 8); \
  } } while(0)
#define STGB128(gcol0, ldsb) do { \
  _Pragma("unroll") for (int it = 0; it < 2; ++it){ \
    int m_ = it * 512 + tid; \
    int row_ = m_ >> 3, cp_ = m_ & 7; \
    int rB_ = bcol + row_; \
    const u16* bp_ = BPTR(rB_); \
    gload16(bp_ + (gcol0) + ((cp_ ^ (row_ & 7)) * 8), \
            (ldsb) + (it * 512 + (tid & ~63)) * 8); \
  } } while(0)
#define STGB64(gcol0, ldsb) do { \
    int row_ = 128 + (tid >> 3), cp_ = tid & 7; \
    int rB_ = bcol + row_; \
    const u16* bp_ = BPTR(rB_); \
    gload16(bp_ + (gcol0) + ((cp_ ^ (row_ & 7)) * 8), \
            (ldsb) + (tid & ~63) * 8); \
  } while(0)
#define RDA(buf, mibase) \
  _Pragma("unroll") for (int mi2 = 0; mi2 < 4; ++mi2){ \
    const u16* pr = &LA[buf][0] + (size_t)(wm * 128 + ((mibase) + mi2) * 16 + c15) * 64; \
    af[mi2][0] = *(const bf16x8*)(pr + cc0); \
    af[mi2][1] = *(const bf16x8*)(pr + (cc0 ^ 32)); \
  }
#define RDB2(buf) \
  _Pragma("unroll") for (int ni2 = 0; ni2 < 2; ++ni2){ \
    const u16* pr = &LB[buf][0] + (size_t)(wn * 48 + ni2 * 16 + c15) * 64; \
    bf[ni2][0] = *(const bf16x8*)(pr + cc0); \
    bf[ni2][1] = *(const bf16x8*)(pr + (cc0 ^ 32)); \
  }
#define RDB1(buf) do { \
    const u16* pr = &LB[buf][0] + (size_t)(wn * 48 + 32 + c15) * 64; \
    bf[2][0] = *(const bf16x8*)(pr + cc0); \
    bf[2][1] = *(const bf16x8*)(pr + (cc0 ^ 32)); \
  } while(0)
#define MM2(mibase) \
  _Pragma("unroll") for (int mi2 = 0; mi2 < 4; ++mi2) \
  _Pragma("unroll") for (int ni2 = 0; ni2 < 2; ++ni2) \
  _Pragma("unroll") for (int kk = 0; kk < 2; ++kk) \
    acc[(mibase) + mi2][ni2] = __builtin_amdgcn_mfma_f32_16x16x32_bf16( \
        af[mi2][kk], bf[ni2][kk], acc[(mibase) + mi2][ni2], 0, 0, 0);
#define MM1(mibase) \
  _Pragma("unroll") for (int mi2 = 0; mi2 < 4; ++mi2) \
  _Pragma("unroll") for (int kk = 0; kk < 2; ++kk) \
    acc[(mibase) + mi2][2] = __builtin_amdgcn_mfma_f32_16x16x32_bf16( \
        af[mi2][kk], bf[2][kk], acc[(mibase) + mi2][2], 0, 0, 0);

  STGA(brow,       0, &LA[0][0]);
  STGA(brow + 128, 0, &LA[0][0] + 128 * 64);
  STGB128(0,  &LB[0][0]);
  STGB64(0,   &LB[0][0] + 128 * 64);
  STGB128(64, &LB[1][0]);
  STGB64(64,  &LB[1][0] + 128 * 64);
  WAITVM(3);
  BARRAW;

  for (int t = 0; t < NT; t += 2){
    const int kn1 = (t + 1) * 64;
    const int kn2 = (t + 2) * 64;
    const int kn3 = (t + 3) * 64;
    // ===== tile t (buf 0) =====
    RDA(0, 0); RDB2(0);
    STGA(brow, kn1, &LA[1][0]);
    BARRAW; PRIO1; MM2(0); PRIO0; BARRAW;
    RDB1(0);
    STGA(brow + 128, kn1, &LA[1][0] + 128 * 64);
    BARRAW; PRIO1; MM1(0); PRIO0; BARRAW;
    RDA(0, 4);
    if (t + 2 < NT) STGB128(kn2, &LB[0][0]);
    BARRAW; PRIO1; MM1(4); PRIO0; BARRAW;
    if (t + 2 < NT){ STGB64(kn2, &LB[0][0] + 128 * 64); WAITVM(3); }
    else            { WAITVM(0); }
    BARRAW; PRIO1; MM2(4); PRIO0; BARRAW;
    // ===== tile t+1 (buf 1) =====
    RDA(1, 0); RDB2(1);
    if (t + 2 < NT) STGA(brow, kn2, &LA[0][0]);
    BARRAW; PRIO1; MM2(0); PRIO0; BARRAW;
    RDB1(1);
    if (t + 2 < NT) STGA(brow + 128, kn2, &LA[0][0] + 128 * 64);
    BARRAW; PRIO1; MM1(0); PRIO0; BARRAW;
    RDA(1, 4);
    if (t + 3 < NT) STGB128(kn3, &LB[1][0]);
    BARRAW; PRIO1; MM1(4); PRIO0; BARRAW;
    if (t + 3 < NT){ STGB64(kn3, &LB[1][0] + 128 * 64); WAITVM(3); }
    else if (t + 2 < NT){ WAITVM(0); }
    BARRAW; PRIO1; MM2(4); PRIO0; BARRAW;
  }
#undef BPTR
#undef STGA
#undef STGB128
#undef STGB64
#undef RDA
#undef RDB2
#undef RDB1
#undef MM2
#undef MM1

#pragma unroll
  for (int mi = 0; mi < 8; ++mi)
#pragma unroll
    for (int ni = 0; ni < 3; ++ni){
      int colbase = bcol + wn * 48 + ni * 16;      // 2048-boundary is 16-aligned
      int proj = colbase >> 11;
      u16* Cb = proj == 0 ? C0 : proj == 1 ? C1 : C2;
      int lc = (colbase & 2047) + c15;
#pragma unroll
      for (int r = 0; r < 4; ++r){
        int row = brow + wm * 128 + mi * 16 + g * 4 + r;
        Cb[(size_t)row * 2048 + lc] = f2bf(acc[mi][ni][r]);
      }
    }
}

// ---------------- m97-style staging for 256-thread GEMM ----------------
static __device__ __forceinline__ void stage_g(const u16* __restrict__ A, const u16* __restrict__ B,
                                               int brow, int bcol, int k0,
                                               u16* __restrict__ as, u16* __restrict__ bs, int tid){
  const int wbase = tid & ~63;
#pragma unroll
  for (int it = 0; it < 2; ++it){
    int m = it * 256 + tid;
    int row = m >> 2, q = m & 3;
    gload16(A + (size_t)(brow + row) * 2048 + k0 + q * 8, as + (it * 256 + wbase) * 8);
    gload16(B + (size_t)(bcol + row) * 2048 + k0 + q * 8, bs + (it * 256 + wbase) * 8);
  }
}

// output GEMM, full K, counted-vmcnt 2-phase, direct f32 store: grid (16,16)
__global__ __launch_bounds__(256)
void k_gemm_out(const u16* __restrict__ A, const u16* __restrict__ B, float* __restrict__ C){
  __shared__ __align__(16) u16 As[2][128 * 32];
  __shared__ __align__(16) u16 Bs[2][128 * 32];
  const int tid = threadIdx.x;
  const int w = tid >> 6, lane = tid & 63;
  const int wr = w >> 1, wc = w & 1;
  const int g = lane >> 4, c15 = lane & 15;
  const int brow = blockIdx.y * 128, bcol = blockIdx.x * 128;

  f32x4 acc[4][4];
#pragma unroll
  for (int m = 0; m < 4; m++)
#pragma unroll
    for (int n = 0; n < 4; n++) acc[m][n] = (f32x4){0.f, 0.f, 0.f, 0.f};

  stage_g(A, B, brow, bcol, 0, As[0], Bs[0], tid);
  int cur = 0;
  for (int kt = 0; kt < 64; ++kt){
    if (kt + 1 < 64){ stage_g(A, B, brow, bcol, (kt + 1) * 32, As[cur ^ 1], Bs[cur ^ 1], tid);
                      WAITVM(4); }
    else            { WAITVM(0); }
    BARRAW;
    bf16x8 af[4], bfr[4];
#pragma unroll
    for (int m = 0; m < 4; m++) af[m] = *(const bf16x8*)(As[cur] + (wr * 64 + m * 16 + c15) * 32 + g * 8);
#pragma unroll
    for (int n = 0; n < 4; n++) bfr[n] = *(const bf16x8*)(Bs[cur] + (wc * 64 + n * 16 + c15) * 32 + g * 8);
    PRIO1;
#pragma unroll
    for (int m = 0; m < 4; m++)
#pragma unroll
      for (int n = 0; n < 4; n++)
        acc[m][n] = __builtin_amdgcn_mfma_f32_16x16x32_bf16(af[m], bfr[n], acc[m][n], 0, 0, 0);
    PRIO0;
    BARRAW;
    cur ^= 1;
  }
#pragma unroll
  for (int m = 0; m < 4; m++)
#pragma unroll
    for (int n = 0; n < 4; n++)
#pragma unroll
      for (int r = 0; r < 4; r++){
        int row = brow + wr * 64 + m * 16 + g * 4 + r;
        int col = bcol + wc * 64 + n * 16 + c15;
        C[(size_t)row * 2048 + col] = acc[m][n][r];
      }
}

// ---------------- pass 1a: rowsum of exp (causal), Q-in-registers ----------------
// grid (40, 16), 256 thr (4 waves x 32 q-rows); K 64x128 LDS dbuf, counted vmcnt.
__global__ __launch_bounds__(256)
void k_pass1a(const u16* __restrict__ Q, const u16* __restrict__ K, float* __restrict__ rowsum){
  __shared__ __align__(16) u16 Ks[2][64 * 128];
  const int tid = threadIdx.x;
  const int wv = tid >> 6, lane = tid & 63;
  const int g = lane >> 4, c15 = lane & 15;
  const int h = blockIdx.y;
  int qb = 0, c = 0;
  { int rem = blockIdx.x; int q = 0;
    while (rem >= ((2 * q + 9) >> 3)){ rem -= (2 * q + 9) >> 3; q++; }
    qb = q; c = rem; }
  const int i0 = qb * 128;
  const int ktend = 2 * qb + 2;
  const int kt0 = c * 8;
  const int kt1 = (ktend < kt0 + 8) ? ktend : (kt0 + 8);
  const u16* Qh = Q + h * HDIM;
  const u16* Kh = K + h * HDIM;
  const float scale = 0.08838834764831845f;   // 1/sqrt(128)
  const int wb = wv * 32;

  // Q fragments in registers: rows i0+wb+m*16+c15, k-span ks*32+g*8
  bf16x8 qfr[2][4];
#pragma unroll
  for (int m = 0; m < 2; m++)
#pragma unroll
    for (int ks = 0; ks < 4; ks++)
      qfr[m][ks] = *(const bf16x8*)(Qh + (size_t)(i0 + wb + m * 16 + c15) * 2048 + ks * 32 + g * 8);

  stage_tile(Kh, 2048, kt0 * 64, Ks[0], tid);

  float rs[2][4] = {{0.f,0.f,0.f,0.f},{0.f,0.f,0.f,0.f}};
  int cur = 0;
  for (int kt = kt0; kt < kt1; ++kt){
    if (kt + 1 < kt1){ stage_tile(Kh, 2048, (kt + 1) * 64, Ks[cur ^ 1], tid); WAITVM(4); }
    else             { WAITVM(0); }
    BARRAW;
    const int k0 = kt * 64;
    f32x4 sacc[2][4];
#pragma unroll
    for (int m = 0; m < 2; m++)
#pragma unroll
      for (int n = 0; n < 4; n++) sacc[m][n] = (f32x4){0.f, 0.f, 0.f, 0.f};
#pragma unroll
    for (int ks = 0; ks < 4; ++ks){
#pragma unroll
      for (int n = 0; n < 4; n++){
        int brw = n * 16 + c15;
        bf16x8 b = *(const bf16x8*)(Ks[cur] + brw * 128 + ((ks * 32 + g * 8) ^ ((brw & 7) << 3)));
#pragma unroll
        for (int m = 0; m < 2; m++)
          sacc[m][n] = __builtin_amdgcn_mfma_f32_16x16x32_bf16(qfr[m][ks], b, sacc[m][n], 0, 0, 0);
      }
    }
    if (kt < 2 * qb){            // fully causal tile: no mask compare
#pragma unroll
      for (int m = 0; m < 2; m++)
#pragma unroll
        for (int n = 0; n < 4; n++)
#pragma unroll
          for (int r = 0; r < 4; r++)
            rs[m][r] += __expf(sacc[m][n][r] * scale);
    } else {
#pragma unroll
      for (int n = 0; n < 4; n++){
        int col = k0 + n * 16 + c15;
#pragma unroll
        for (int m = 0; m < 2; m++)
#pragma unroll
          for (int r = 0; r < 4; r++){
            int rowg = i0 + wb + m * 16 + g * 4 + r;
            rs[m][r] += (col <= rowg) ? __expf(sacc[m][n][r] * scale) : 0.f;
          }
      }
    }
    BARRAW;
    cur ^= 1;
  }
#pragma unroll
  for (int m = 0; m < 2; m++)
#pragma unroll
    for (int r = 0; r < 4; r++){
      float v = rs[m][r];
      v += __shfl_xor(v, 1); v += __shfl_xor(v, 2);
      v += __shfl_xor(v, 4); v += __shfl_xor(v, 8);
      if (c15 == 0)
        atomicAdd(&rowsum[h * 2048 + i0 + wb + m * 16 + g * 4 + r], v);
    }
}

// ---------------- pass 1b: colsum of normalized exp, K-in-registers ----------------
// grid (40, 16), 256 thr (4 waves x 32 k-rows); Q 64x128 LDS dbuf, counted vmcnt.
__global__ __launch_bounds__(256)
void k_pass1b(const u16* __restrict__ Q, const u16* __restrict__ K,
              const float* __restrict__ rowsum, float* __restrict__ colsum){
  __shared__ __align__(16) u16 Qs[2][64 * 128];
  const int tid = threadIdx.x;
  const int wv = tid >> 6, lane = tid & 63;
  const int g = lane >> 4, c15 = lane & 15;
  const int h = blockIdx.y;
  int kb = 0, c = 0;
  { int rem = blockIdx.x; int q = 0;
    while (rem >= ((39 - 2 * q) >> 3)){ rem -= (39 - 2 * q) >> 3; q++; }
    kb = q; c = rem; }
  const int k0 = kb * 128;
  const int qt0 = 2 * kb + c * 8;
  const int qt1 = (2 * kb + c * 8 + 8 < 32) ? (2 * kb + c * 8 + 8) : 32;
  const u16* Qh = Q + h * HDIM;
  const u16* Kh = K + h * HDIM;
  const float scale = 0.08838834764831845f;
  const int wb = wv * 32;
  const float* rsrow = rowsum + h * 2048;

  // K fragments in registers: rows k0+wb+m*16+c15
  bf16x8 kfr[2][4];
#pragma unroll
  for (int m = 0; m < 2; m++)
#pragma unroll
    for (int ks = 0; ks < 4; ks++)
      kfr[m][ks] = *(const bf16x8*)(Kh + (size_t)(k0 + wb + m * 16 + c15) * 2048 + ks * 32 + g * 8);

  stage_tile(Qh, 2048, qt0 * 64, Qs[0], tid);

  float racc[2][4] = {{0.f,0.f,0.f,0.f},{0.f,0.f,0.f,0.f}};
  int cur = 0;
  for (int qt = qt0; qt < qt1; ++qt){
    if (qt + 1 < qt1){ stage_tile(Qh, 2048, (qt + 1) * 64, Qs[cur ^ 1], tid); WAITVM(4); }
    else             { WAITVM(0); }
    BARRAW;
    const int i0q = qt * 64;
    float rw[4];
#pragma unroll
    for (int n = 0; n < 4; n++)
      rw[n] = 1.0f / rsrow[i0q + n * 16 + c15];
    f32x4 sacc[2][4];
#pragma unroll
    for (int m = 0; m < 2; m++)
#pragma unroll
      for (int n = 0; n < 4; n++) sacc[m][n] = (f32x4){0.f, 0.f, 0.f, 0.f};
#pragma unroll
    for (int ks = 0; ks < 4; ++ks){
#pragma unroll
      for (int n = 0; n < 4; n++){
        int brw = n * 16 + c15;
        bf16x8 b = *(const bf16x8*)(Qs[cur] + brw * 128 + ((ks * 32 + g * 8) ^ ((brw & 7) << 3)));
#pragma unroll
        for (int m = 0; m < 2; m++)
          sacc[m][n] = __builtin_amdgcn_mfma_f32_16x16x32_bf16(kfr[m][ks], b, sacc[m][n], 0, 0, 0);
      }
    }
    if (qt >= 2 * kb + 2){       // fully causal: no mask compare
#pragma unroll
      for (int m = 0; m < 2; m++)
#pragma unroll
        for (int n = 0; n < 4; n++)
#pragma unroll
          for (int r = 0; r < 4; r++)
            racc[m][r] += __expf(sacc[m][n][r] * scale) * rw[n];
    } else {
#pragma unroll
      for (int n = 0; n < 4; n++){
        int colq = i0q + n * 16 + c15;
#pragma unroll
        for (int m = 0; m < 2; m++)
#pragma unroll
          for (int r = 0; r < 4; r++){
            int rowk = k0 + wb + m * 16 + g * 4 + r;
            racc[m][r] += (rowk <= colq) ? __expf(sacc[m][n][r] * scale) * rw[n] : 0.f;
          }
      }
    }
    BARRAW;
    cur ^= 1;
  }
#pragma unroll
  for (int m = 0; m < 2; m++)
#pragma unroll
    for (int r = 0; r < 4; r++){
      float v = racc[m][r];
      v += __shfl_xor(v, 1); v += __shfl_xor(v, 2);
      v += __shfl_xor(v, 4); v += __shfl_xor(v, 8);
      if (c15 == 0)
        atomicAdd(&colsum[h * 2048 + k0 + wb + m * 16 + g * 4 + r], v);
    }
}

// ---------------- top-k (204) per head: value-sort + ascending index list ----------------
__global__ __launch_bounds__(1024)
void k_topk(const float* __restrict__ colsum, short* __restrict__ cidx){
  __shared__ float v[2048];
  __shared__ short ix[2048];
  __shared__ short sx[256];
  const int tid = threadIdx.x;
  const int h = blockIdx.x;
  for (int i = tid; i < 2048; i += 1024){ v[i] = colsum[h * 2048 + i]; ix[i] = (short)i; }
  __syncthreads();
  for (int k = 2; k <= 2048; k <<= 1){
    for (int j = k >> 1; j > 0; j >>= 1){
      int i = ((tid / j) * (j << 1)) + (tid % j);
      int l = i + j;
      float vi = v[i], vl = v[l];
      short ii = ix[i], il = ix[l];
      bool before_i = (vi > vl) || (vi == vl && ii < il);
      bool dir = (i & k) == 0;
      if (dir ? !before_i : before_i){ v[i] = vl; v[l] = vi; ix[i] = il; ix[l] = ii; }
      __syncthreads();
    }
  }
  if (tid < 256) sx[tid] = (tid < HEAVY) ? ix[tid] : (short)32767;
  __syncthreads();
  for (int k = 2; k <= 256; k <<= 1){
    for (int j = k >> 1; j > 0; j >>= 1){
      if (tid < 128){
        int i = ((tid / j) * (j << 1)) + (tid % j);
        int l = i + j;
        short a = sx[i], b = sx[l];
        bool asc = (i & k) == 0;
        if (asc ? (a > b) : (a < b)){ sx[i] = b; sx[l] = a; }
      }
      __syncthreads();
    }
  }
  if (tid < 256) cidx[h * 256 + tid] = sx[tid];
}

// ---------------- gather heavy K rows + V cols (fused) ----------------
__global__ void k_gatherKV(const u16* __restrict__ Kb, const u16* __restrict__ Vb,
                           const short* __restrict__ cidx,
                           u16* __restrict__ Kg, u16* __restrict__ Vg){
  __shared__ __align__(16) u16 t[32][136];
  int b = blockIdx.x, tid = threadIdx.x;
  if (b < 256){
    int gid = b * 256 + tid;                   // 16h * 256slot * 16chunk = 65536
    int h = gid >> 12, rem = gid & 4095;
    int slot = rem >> 4, cp = rem & 15;
    int cid = cidx[h * 256 + slot];
    bf16x8 z = (bf16x8){0,0,0,0,0,0,0,0};
    bf16x8 val = (cid < 2048) ? *(const bf16x8*)(Kb + (size_t)cid * 2048 + h * 128 + cp * 8) : z;
    *(bf16x8*)(Kg + ((size_t)h * 256 + slot) * 128 + cp * 8) = val;
  } else {
    int b2 = b - 256;
    int h = b2 >> 3, s0 = (b2 & 7) * 32;
#pragma unroll
    for (int it = 0; it < 2; ++it){
      int m = it * 256 + tid;                  // 512 chunks = 32 slots x 16 chunks
      int s = m >> 4, cp = m & 15;
      int cid = cidx[h * 256 + s0 + s];
      bf16x8 z = (bf16x8){0,0,0,0,0,0,0,0};
      bf16x8 val = (cid < 2048) ? *(const bf16x8*)(Vb + (size_t)cid * 2048 + h * 128 + cp * 8) : z;
      *(bf16x8*)(&t[s][cp * 8]) = val;
    }
    __syncthreads();
#pragma unroll
    for (int i = 0; i < 16; ++i){
      int idx = i * 256 + tid;                 // 4096 = 128 d x 32 s
      int d = idx >> 5, s = idx & 31;
      Vg[((size_t)h * 128 + d) * 256 + s0 + s] = t[s][d];
    }
  }
}

// V fragments for one tile (register-resident)
static __device__ __forceinline__ void load_vf(const u16* __restrict__ Vt,
                                               const u16* __restrict__ Vg,
                                               int h, int e, int g, int c15,
                                               bf16x8 vf[2][8]){
  const bool isg = (e >= 100);
#pragma unroll
  for (int ks2 = 0; ks2 < 2; ++ks2)
#pragma unroll
    for (int f = 0; f < 8; ++f){
      int vrow = f * 16 + c15;
      vf[ks2][f] = isg
        ? *(const bf16x8*)(Vg + ((size_t)h * 128 + vrow) * 256 + (e - 100) * 64 + ks2 * 32 + g * 8)
        : *(const bf16x8*)(Vt + ((size_t)h * 128 + vrow) * 2048 + e * 64 + ks2 * 32 + g * 8);
    }
}

// ---------------- pass 2: band + gathered-heavy masked attention, counted-vmcnt ----
// grid (32, 16), 256 thr
__global__ __launch_bounds__(256)
void k_pass2(const u16* __restrict__ Q, const u16* __restrict__ K, const u16* __restrict__ Vt,
             const u16* __restrict__ Kg, const u16* __restrict__ Vg,
             const short* __restrict__ cidx, u16* __restrict__ attn){
  __shared__ __align__(16) u16 Qs[64 * 128];
  __shared__ __align__(16) u16 Ks[2][64 * 128];
  __shared__ __align__(16) u16 Ps[4][16 * 64];
  __shared__ short cids[256];
  __shared__ int lists[12];
  __shared__ int nact_s;
  const int tid = threadIdx.x;
  const int w = tid >> 6, lane = tid & 63;
  const int g = lane >> 4, c15 = lane & 15;
  const int qb = blockIdx.x, h = blockIdx.y;
  const int i0 = qb * 64;
  const u16* Qh = Q + h * HDIM;
  const u16* Kh = K + h * HDIM;
  const u16* Kgh = Kg + (size_t)h * 256 * 128;
  const float scale = 0.08838834764831845f;
  const int arow = w * 16 + c15;

  if (tid < 256) cids[tid] = cidx[h * 256 + tid];
  __syncthreads();
  if (tid == 0){
    int n = 0;
    int ktb0 = (i0 > RECENT) ? ((i0 - RECENT) >> 6) : 0;
    for (int kt = ktb0; kt <= qb; ++kt) lists[n++] = kt;
    for (int gt = 0; gt < 4; ++gt)
      if ((int)cids[gt * 64] <= i0 - RECENT + 62) lists[n++] = 100 + gt;
    nact_s = n;
  }
  __syncthreads();
  const int nact = nact_s;

  // prologue: Q (4) + K(list0) (4) + vf(list0) (16) -> WAITVM(16) retires Q,K0
  stage_tile(Qh, 2048, i0, Qs, tid);
  { int e = lists[0];
    if (e < 100) stage_tile(Kh, 2048, e * 64, Ks[0], tid);
    else         stage_tile(Kgh, 128, (e - 100) * 64, Ks[0], tid); }
  bf16x8 vf[2][8];
  load_vf(Vt, Vg, h, lists[0], g, c15, vf);
  WAITVM(16);
  BARRAW;

  f32x4 oacc[8];
#pragma unroll
  for (int f = 0; f < 8; f++) oacc[f] = (f32x4){0.f, 0.f, 0.f, 0.f};
  float lsum[4] = {0.f, 0.f, 0.f, 0.f};

  int cur = 0;
  for (int i = 0; i < nact; ++i){
    const int e = lists[i];
    const bool isg = (e >= 100);
    const bool nxt = (i + 1 < nact);
    if (nxt){
      int e2 = lists[i + 1];
      if (e2 < 100) stage_tile(Kh, 2048, e2 * 64, Ks[cur ^ 1], tid);
      else          stage_tile(Kgh, 128, (e2 - 100) * 64, Ks[cur ^ 1], tid);
      WAITVM(20);              // retire K(i); keep vf(i)+K(i+1) in flight
    } else {
      WAITVM(16);              // retire K(last); keep vf(last)
    }
    BARRAW;
    // QK^T
    f32x4 sacc[4];
#pragma unroll
    for (int n = 0; n < 4; n++) sacc[n] = (f32x4){0.f, 0.f, 0.f, 0.f};
#pragma unroll
    for (int ks = 0; ks < 4; ++ks){
      bf16x8 a = *(const bf16x8*)(Qs + arow * 128 + ((ks * 32 + g * 8) ^ ((arow & 7) << 3)));
#pragma unroll
      for (int n = 0; n < 4; n++){
        int brw = n * 16 + c15;
        bf16x8 b = *(const bf16x8*)(Ks[cur] + brw * 128 + ((ks * 32 + g * 8) ^ ((brw & 7) << 3)));
        sacc[n] = __builtin_amdgcn_mfma_f32_16x16x32_bf16(a, b, sacc[n], 0, 0, 0);
      }
    }
    // masked exp -> P (LDS, wave-private), row sums
#pragma unroll
    for (int n = 0; n < 4; n++){
      int cid = isg ? (int)cids[(e - 100) * 64 + n * 16 + c15] : (e * 64 + n * 16 + c15);
#pragma unroll
      for (int r = 0; r < 4; r++){
        int rowg = i0 + w * 16 + g * 4 + r;
        int dist = rowg - cid;
        bool valid = (cid <= rowg) && (isg ? (dist > RECENT) : (dist <= RECENT));
        float ev = valid ? __expf(sacc[n][r] * scale) : 0.f;
        lsum[r] += ev;
        int prow = g * 4 + r;
        Ps[w][prow * 64 + ((n * 16 + c15) ^ ((prow & 7) << 3))] = f2bf(ev);
      }
    }
    // retire vf(i) under the exp phase, then PV
    if (nxt) WAITVM(4); else WAITVM(0);
    PRIO1;
#pragma unroll
    for (int ks2 = 0; ks2 < 2; ++ks2){
      bf16x8 pa = *(const bf16x8*)(&Ps[w][c15 * 64 + ((ks2 * 32 + g * 8) ^ ((c15 & 7) << 3))]);
#pragma unroll
      for (int f = 0; f < 8; ++f)
        oacc[f] = __builtin_amdgcn_mfma_f32_16x16x32_bf16(pa, vf[ks2][f], oacc[f], 0, 0, 0);
    }
    PRIO0;
    if (nxt) load_vf(Vt, Vg, h, lists[i + 1], g, c15, vf);   // vf(i+1) in flight across barrier
    BARRAW;
    cur ^= 1;
  }
  float rinv[4];
#pragma unroll
  for (int r = 0; r < 4; r++){
    float v = lsum[r];
    v += __shfl_xor(v, 1); v += __shfl_xor(v, 2);
    v += __shfl_xor(v, 4); v += __shfl_xor(v, 8);
    rinv[r] = 1.0f / v;
  }
#pragma unroll
  for (int f = 0; f < 8; f++)
#pragma unroll
    for (int r = 0; r < 4; r++){
      int rowg = i0 + w * 16 + g * 4 + r;
      attn[(size_t)rowg * 2048 + h * HDIM + f * 16 + c15] = f2bf(oacc[f][r] * rinv[r]);
    }
}

// ---------------- host launcher ----------------
extern "C" void kernel_launch(void* const* d_in, const int* in_sizes, int n_in,
                              void* d_out, int out_size, void* d_ws, size_t ws_size,
                              hipStream_t stream){
  const float* X  = (const float*)d_in[0];
  const float* Wq = (const float*)d_in[1];
  const float* Wk = (const float*)d_in[2];
  const float* Wv = (const float*)d_in[3];
  const float* Wo = (const float*)d_in[4];

  char* w = (char*)d_ws;
  const size_t MB8 = (size_t)2048 * 2048 * 2;   // one bf16 matrix = 8 MiB
  u16* Xb  = (u16*)(w);
  u16* Wqb = (u16*)(w + 1 * MB8);
  u16* Wkb = (u16*)(w + 2 * MB8);
  u16* Wvb = (u16*)(w + 3 * MB8);
  u16* Wob = (u16*)(w + 4 * MB8);
  u16* Qb  = (u16*)(w + 5 * MB8);
  u16* Kb  = (u16*)(w + 6 * MB8);
  u16* Vb  = (u16*)(w + 7 * MB8);
  u16* Vtb   = Wqb;   // Wq dead after projections
  u16* attnb = Xb;    // X dead after projections
  char* p = w + 8 * MB8;
  float* cosT = (float*)p;              p += 524288;
  float* sinT = (float*)p;              p += 524288;
  float* colsum = (float*)p;            p += 131072;   // zeroed in k_prep
  float* rowsum = (float*)p;            p += 131072;   // overwritten by atomic adds from zero? no — see below
  short* cidx  = (short*)p;             p += 16 * 256 * 2;
  u16*   Kg    = (u16*)p;               p += (size_t)16 * 256 * 128 * 2;
  u16*   Vg    = (u16*)p;

  dim3 b256(256);

  // NOTE: rowsum also needs zeroing (atomicAdd accumulation). Fold into prep's zero range:
  // prep zeroes colsum AND rowsum contiguously (256 KiB total = 16384 float4).
  k_prep<<<21056, b256, 0, stream>>>(X, Wq, Wk, Wv, Wo, Xb, cosT, sinT, colsum);

  k_g256<<<dim3(32, 8), dim3(512), 0, stream>>>(Xb, Wqb, Wkb, Wvb, Qb, Kb, Vb);
  k_post<<<8192, b256, 0, stream>>>(Qb, Kb, cosT, sinT, Vb, Vtb);

  k_pass1a<<<dim3(40, 16), b256, 0, stream>>>(Qb, Kb, rowsum);
  k_pass1b<<<dim3(40, 16), b256, 0, stream>>>(Qb, Kb, rowsum, colsum);
  k_topk<<<16, dim3(1024), 0, stream>>>(colsum, cidx);
  k_gatherKV<<<384, b256, 0, stream>>>(Kb, Vb, cidx, Kg, Vg);
  k_pass2<<<dim3(32, 16), b256, 0, stream>>>(Qb, Kb, Vtb, Kg, Vg, cidx, attnb);

  k_gemm_out<<<dim3(16, 16), b256, 0, stream>>>(attnb, Wob, (float*)d_out);
}

// Round 9
// 246.931 us; speedup vs baseline: 1.6346x; 1.0625x over previous
//
#include <hip/hip_runtime.h>
#include <hip/hip_bf16.h>
#include <stdint.h>

// Problem constants: b=1, s=2048, hidden=2048, H=16, d=128
#define SEQ   2048
#define HIDN  2048
#define NHEAD 16
#define HDIM  128
#define HEAVY 204   // int(0.1*2048)
#define RECENT 204

typedef __attribute__((ext_vector_type(4))) float f32x4;
typedef __attribute__((ext_vector_type(8))) short bf16x8;
typedef unsigned short u16;
typedef unsigned int   u32;

static __device__ __forceinline__ u16 f2bf(float f){
  union { float f; u32 u; } v; v.f = f;
  u32 r = (v.u + 0x7FFFu + ((v.u >> 16) & 1u)) >> 16;
  return (u16)r;
}
static __device__ __forceinline__ float bf2f(u16 u){
  union { u32 u; float f; } v; v.u = ((u32)u) << 16;
  return v.f;
}

// global -> LDS direct 16B load (dest is wave-uniform base + lane*16)
static __device__ __forceinline__ void gload16(const void* g, void* l){
  __builtin_amdgcn_global_load_lds((const __attribute__((address_space(1))) u32*)g,
                                   (__attribute__((address_space(3))) u32*)l, 16, 0, 0);
}

#define WAITVM(N) asm volatile("s_waitcnt vmcnt(" #N ")" ::: "memory")
#define BARRAW    __builtin_amdgcn_s_barrier()
#define PRIO1     __builtin_amdgcn_s_setprio(1)
#define PRIO0     __builtin_amdgcn_s_setprio(0)

// stage a 64x128 bf16 tile with 256 threads, runtime row stride (XOR-swizzled source)
static __device__ __forceinline__ void stage_tile(const u16* __restrict__ base, size_t stride,
                                                  int row0, u16* __restrict__ lds, int tid){
  const int wbase = tid & ~63;
#pragma unroll
  for (int it = 0; it < 4; ++it){
    int m = it * 256 + tid;
    int row = m >> 4, cp = m & 15;
    gload16(base + (size_t)(row0 + row) * stride + ((cp ^ (row & 7)) * 8),
            lds + (it * 256 + wbase) * 8);
  }
}

// stage 64x128 tile with 512 threads, runtime stride
static __device__ __forceinline__ void stageK512(const u16* __restrict__ base, size_t stride,
                                                 int row0, u16* __restrict__ lds, int tid){
#pragma unroll
  for (int it = 0; it < 2; ++it){
    int m = it * 512 + tid;
    int row = m >> 4, cp = m & 15;
    gload16(base + (size_t)(row0 + row) * stride + ((cp ^ (row & 7)) * 8),
            lds + (it * 512 + (tid & ~63)) * 8);
  }
}
// stage 128-row x 64-col tile (col offset c0) with 512 threads, runtime stride
static __device__ __forceinline__ void stageV512(const u16* __restrict__ base, size_t stride,
                                                 int c0, u16* __restrict__ lds, int tid){
#pragma unroll
  for (int it = 0; it < 2; ++it){
    int m = it * 512 + tid;
    int row = m >> 3, cp = m & 7;
    gload16(base + (size_t)row * stride + c0 + ((cp ^ (row & 7)) * 8),
            lds + (it * 512 + (tid & ~63)) * 8);
  }
}

// ---------------- prep: cvt5 + rope tables + zero colsum/rowsum (fused) ----------------
__global__ void k_prep(const float* __restrict__ A0, const float* __restrict__ A1,
                       const float* __restrict__ A2, const float* __restrict__ A3,
                       const float* __restrict__ A4, u16* __restrict__ out,
                       float* __restrict__ cosT, float* __restrict__ sinT,
                       float* __restrict__ colsum){
  int b = blockIdx.x, tid = threadIdx.x;
  if (b < 20480){
    int id = b * 256 + tid;
    int sel = id >> 20, off = (id & 1048575) * 4;
    const float* src = sel == 0 ? A0 : sel == 1 ? A1 : sel == 2 ? A2 : sel == 3 ? A3 : A4;
    float4 v = *(const float4*)(src + off);
    ushort4 o;
    o.x = f2bf(v.x); o.y = f2bf(v.y); o.z = f2bf(v.z); o.w = f2bf(v.w);
    *(ushort4*)(out + (size_t)sel * 4194304 + off) = o;
  } else if (b < 20992){
    int i = (b - 20480) * 256 + tid;           // 2048*64
    int pos = i >> 6, j = i & 63;
    float invf = powf(10000.0f, -(float)j * (1.0f / 64.0f));
    float a = (float)pos * invf;
    cosT[i] = cosf(a);
    sinT[i] = sinf(a);
  } else {
    int i = (b - 20992) * 256 + tid;           // 16384 float4 = colsum+rowsum (contiguous)
    if (i < 16384) ((float4*)colsum)[i] = (float4){0.f, 0.f, 0.f, 0.f};
  }
}

// ---------------- post: rope on Q,K + transpose V (fused) ----------------
__global__ void k_post(u16* __restrict__ Qm, u16* __restrict__ Km,
                       const float* __restrict__ cosT, const float* __restrict__ sinT,
                       const u16* __restrict__ V, u16* __restrict__ Vt){
  __shared__ u16 t[32][33];
  int b = blockIdx.x, tid = threadIdx.x;
  if (b < 4096){
    int gid = b * 256 + tid;                   // 2 * 524288
    u16* M = (gid < 524288) ? Qm : Km;
    int id = gid & 524287;
    int pos = id >> 8, rem = id & 255;
    int h = rem >> 4, j4 = (rem & 15) * 4;
    u16* p = M + (size_t)pos * HIDN + h * HDIM + j4;
    ushort4 lo = *(ushort4*)p;
    ushort4 hi = *(ushort4*)(p + 64);
    float4 c = *(const float4*)(cosT + pos * 64 + j4);
    float4 s = *(const float4*)(sinT + pos * 64 + j4);
    float l0 = bf2f(lo.x), l1 = bf2f(lo.y), l2 = bf2f(lo.z), l3 = bf2f(lo.w);
    float h0 = bf2f(hi.x), h1 = bf2f(hi.y), h2 = bf2f(hi.z), h3 = bf2f(hi.w);
    ushort4 nlo, nhi;
    nlo.x = f2bf(l0 * c.x - h0 * s.x);  nhi.x = f2bf(h0 * c.x + l0 * s.x);
    nlo.y = f2bf(l1 * c.y - h1 * s.y);  nhi.y = f2bf(h1 * c.y + l1 * s.y);
    nlo.z = f2bf(l2 * c.z - h2 * s.z);  nhi.z = f2bf(h2 * c.z + l2 * s.z);
    nlo.w = f2bf(l3 * c.w - h3 * s.w);  nhi.w = f2bf(h3 * c.w + l3 * s.w);
    *(ushort4*)p = nlo;
    *(ushort4*)(p + 64) = nhi;
  } else {
    int b2 = b - 4096;
    int s0 = (b2 & 63) * 32, c0 = (b2 >> 6) * 32;
    int r = tid >> 3, cc = (tid & 7) * 4;
    ushort4 v = *(const ushort4*)(V + (size_t)(s0 + r) * 2048 + c0 + cc);
    t[r][cc] = v.x; t[r][cc + 1] = v.y; t[r][cc + 2] = v.z; t[r][cc + 3] = v.w;
    __syncthreads();
    int co = tid >> 3, ro = (tid & 7) * 4;
    ushort4 o;
    o.x = t[ro][co]; o.y = t[ro + 1][co]; o.z = t[ro + 2][co]; o.w = t[ro + 3][co];
    *(ushort4*)(Vt + (size_t)(c0 + co) * 2048 + s0 + ro) = o;
  }
}

// ---------------- fused projection GEMM: C[2048][6144] = X @ [Wq;Wk;Wv]^T ----------------
// 256x192 tile, BK=64, 8 waves, 8-phase, counted vmcnt. grid (32,8) = 256 blocks.
__global__ __launch_bounds__(512, 1)
void k_g256(const u16* __restrict__ X, const u16* __restrict__ Wq, const u16* __restrict__ Wk,
            const u16* __restrict__ Wv, u16* __restrict__ C0, u16* __restrict__ C1,
            u16* __restrict__ C2){
  __shared__ __align__(16) u16 LA[2][256 * 64];
  __shared__ __align__(16) u16 LB[2][192 * 64];
  const int tid = threadIdx.x;
  const int lane = tid & 63, wvi = tid >> 6;
  const int wm = wvi >> 2, wn = wvi & 3;
  const int g = lane >> 4, c15 = lane & 15;
  const int brow = blockIdx.y * 256;       // [0,2048)
  const int bcol = blockIdx.x * 192;       // [0,6144)
  const int NT = 32;

  f32x4 acc[8][3];
#pragma unroll
  for (int m = 0; m < 8; m++)
#pragma unroll
    for (int n = 0; n < 3; n++) acc[m][n] = (f32x4){0.f, 0.f, 0.f, 0.f};

  const int cc0 = ((g ^ (c15 & 7)) * 8);
  bf16x8 af[4][2], bf[3][2];

#define BPTR(rB_) (rB_ < 2048 ? Wq + (size_t)(rB_) * 2048 \
                 : rB_ < 4096 ? Wk + (size_t)((rB_) - 2048) * 2048 \
                              : Wv + (size_t)((rB_) - 4096) * 2048)
#define STGA(grow0, gcol0, ldsb) do { \
  _Pragma("unroll") for (int it = 0; it < 2; ++it){ \
    int m_ = it * 512 + tid; \
    int row_ = m_ >> 3, cp_ = m_ & 7; \
    gload16(X + (size_t)((grow0) + row_) * 2048 + (gcol0) + ((cp_ ^ (row_ & 7)) * 8), \
            (ldsb) + (it * 512 + (tid & ~63)) * 8); \
  } } while(0)
#define STGB128(gcol0, ldsb) do { \
  _Pragma("unroll") for (int it = 0; it < 2; ++it){ \
    int m_ = it * 512 + tid; \
    int row_ = m_ >> 3, cp_ = m_ & 7; \
    int rB_ = bcol + row_; \
    const u16* bp_ = BPTR(rB_); \
    gload16(bp_ + (gcol0) + ((cp_ ^ (row_ & 7)) * 8), \
            (ldsb) + (it * 512 + (tid & ~63)) * 8); \
  } } while(0)
#define STGB64(gcol0, ldsb) do { \
    int row_ = 128 + (tid >> 3), cp_ = tid & 7; \
    int rB_ = bcol + row_; \
    const u16* bp_ = BPTR(rB_); \
    gload16(bp_ + (gcol0) + ((cp_ ^ (row_ & 7)) * 8), \
            (ldsb) + (tid & ~63) * 8); \
  } while(0)
#define RDA(buf, mibase) \
  _Pragma("unroll") for (int mi2 = 0; mi2 < 4; ++mi2){ \
    const u16* pr = &LA[buf][0] + (size_t)(wm * 128 + ((mibase) + mi2) * 16 + c15) * 64; \
    af[mi2][0] = *(const bf16x8*)(pr + cc0); \
    af[mi2][1] = *(const bf16x8*)(pr + (cc0 ^ 32)); \
  }
#define RDB2(buf) \
  _Pragma("unroll") for (int ni2 = 0; ni2 < 2; ++ni2){ \
    const u16* pr = &LB[buf][0] + (size_t)(wn * 48 + ni2 * 16 + c15) * 64; \
    bf[ni2][0] = *(const bf16x8*)(pr + cc0); \
    bf[ni2][1] = *(const bf16x8*)(pr + (cc0 ^ 32)); \
  }
#define RDB1(buf) do { \
    const u16* pr = &LB[buf][0] + (size_t)(wn * 48 + 32 + c15) * 64; \
    bf[2][0] = *(const bf16x8*)(pr + cc0); \
    bf[2][1] = *(const bf16x8*)(pr + (cc0 ^ 32)); \
  } while(0)
#define MM2(mibase) \
  _Pragma("unroll") for (int mi2 = 0; mi2 < 4; ++mi2) \
  _Pragma("unroll") for (int ni2 = 0; ni2 < 2; ++ni2) \
  _Pragma("unroll") for (int kk = 0; kk < 2; ++kk) \
    acc[(mibase) + mi2][ni2] = __builtin_amdgcn_mfma_f32_16x16x32_bf16( \
        af[mi2][kk], bf[ni2][kk], acc[(mibase) + mi2][ni2], 0, 0, 0);
#define MM1(mibase) \
  _Pragma("unroll") for (int mi2 = 0; mi2 < 4; ++mi2) \
  _Pragma("unroll") for (int kk = 0; kk < 2; ++kk) \
    acc[(mibase) + mi2][2] = __builtin_amdgcn_mfma_f32_16x16x32_bf16( \
        af[mi2][kk], bf[2][kk], acc[(mibase) + mi2][2], 0, 0, 0);

  STGA(brow,       0, &LA[0][0]);
  STGA(brow + 128, 0, &LA[0][0] + 128 * 64);
  STGB128(0,  &LB[0][0]);
  STGB64(0,   &LB[0][0] + 128 * 64);
  STGB128(64, &LB[1][0]);
  STGB64(64,  &LB[1][0] + 128 * 64);
  WAITVM(3);
  BARRAW;

  for (int t = 0; t < NT; t += 2){
    const int kn1 = (t + 1) * 64;
    const int kn2 = (t + 2) * 64;
    const int kn3 = (t + 3) * 64;
    // ===== tile t (buf 0) =====
    RDA(0, 0); RDB2(0);
    STGA(brow, kn1, &LA[1][0]);
    BARRAW; PRIO1; MM2(0); PRIO0; BARRAW;
    RDB1(0);
    STGA(brow + 128, kn1, &LA[1][0] + 128 * 64);
    BARRAW; PRIO1; MM1(0); PRIO0; BARRAW;
    RDA(0, 4);
    if (t + 2 < NT) STGB128(kn2, &LB[0][0]);
    BARRAW; PRIO1; MM1(4); PRIO0; BARRAW;
    if (t + 2 < NT){ STGB64(kn2, &LB[0][0] + 128 * 64); WAITVM(3); }
    else            { WAITVM(0); }
    BARRAW; PRIO1; MM2(4); PRIO0; BARRAW;
    // ===== tile t+1 (buf 1) =====
    RDA(1, 0); RDB2(1);
    if (t + 2 < NT) STGA(brow, kn2, &LA[0][0]);
    BARRAW; PRIO1; MM2(0); PRIO0; BARRAW;
    RDB1(1);
    if (t + 2 < NT) STGA(brow + 128, kn2, &LA[0][0] + 128 * 64);
    BARRAW; PRIO1; MM1(0); PRIO0; BARRAW;
    RDA(1, 4);
    if (t + 3 < NT) STGB128(kn3, &LB[1][0]);
    BARRAW; PRIO1; MM1(4); PRIO0; BARRAW;
    if (t + 3 < NT){ STGB64(kn3, &LB[1][0] + 128 * 64); WAITVM(3); }
    else if (t + 2 < NT){ WAITVM(0); }
    BARRAW; PRIO1; MM2(4); PRIO0; BARRAW;
  }
#undef BPTR
#undef STGA
#undef STGB128
#undef STGB64
#undef RDA
#undef RDB2
#undef RDB1
#undef MM2
#undef MM1

#pragma unroll
  for (int mi = 0; mi < 8; ++mi)
#pragma unroll
    for (int ni = 0; ni < 3; ++ni){
      int colbase = bcol + wn * 48 + ni * 16;      // 2048-boundary is 16-aligned
      int proj = colbase >> 11;
      u16* Cb = proj == 0 ? C0 : proj == 1 ? C1 : C2;
      int lc = (colbase & 2047) + c15;
#pragma unroll
      for (int r = 0; r < 4; ++r){
        int row = brow + wm * 128 + mi * 16 + g * 4 + r;
        Cb[(size_t)row * 2048 + lc] = f2bf(acc[mi][ni][r]);
      }
    }
}

// ---------------- output GEMM: 128x128 tile, BK=64, 8 waves, counted vmcnt ----------------
// grid (16,16) = 256 blocks, 512 thr = 2 waves/SIMD (vs old 1 — latency hiding)
__global__ __launch_bounds__(512)
void k_gemm_out(const u16* __restrict__ A, const u16* __restrict__ B, float* __restrict__ C){
  __shared__ __align__(16) u16 As[2][128 * 64];
  __shared__ __align__(16) u16 Bs[2][128 * 64];
  const int tid = threadIdx.x;
  const int w = tid >> 6, lane = tid & 63;
  const int wm = w >> 1, wn = w & 1;
  const int g = lane >> 4, c15 = lane & 15;
  const int brow = blockIdx.y * 128, bcol = blockIdx.x * 128;
  const int cc0 = ((g ^ (c15 & 7)) * 8);

  f32x4 acc[2][4];
#pragma unroll
  for (int m = 0; m < 2; m++)
#pragma unroll
    for (int n = 0; n < 4; n++) acc[m][n] = (f32x4){0.f, 0.f, 0.f, 0.f};

#define STG_O(k0, buf) do { \
  _Pragma("unroll") for (int it = 0; it < 2; ++it){ \
    int m_ = it * 512 + tid; \
    int row_ = m_ >> 3, cp_ = m_ & 7; \
    gload16(A + (size_t)(brow + row_) * 2048 + (k0) + ((cp_ ^ (row_ & 7)) * 8), \
            As[buf] + (it * 512 + (tid & ~63)) * 8); \
    gload16(B + (size_t)(bcol + row_) * 2048 + (k0) + ((cp_ ^ (row_ & 7)) * 8), \
            Bs[buf] + (it * 512 + (tid & ~63)) * 8); \
  } } while(0)

  STG_O(0, 0);
  int cur = 0;
  for (int kt = 0; kt < 32; ++kt){
    if (kt + 1 < 32){ STG_O((kt + 1) * 64, cur ^ 1); WAITVM(4); }
    else            { WAITVM(0); }
    BARRAW;
    bf16x8 af[2][2], bfr[4][2];
#pragma unroll
    for (int mi = 0; mi < 2; ++mi){
      const u16* pr = As[cur] + (size_t)(wm * 32 + mi * 16 + c15) * 64;
      af[mi][0] = *(const bf16x8*)(pr + cc0);
      af[mi][1] = *(const bf16x8*)(pr + (cc0 ^ 32));
    }
#pragma unroll
    for (int ni = 0; ni < 4; ++ni){
      const u16* pr = Bs[cur] + (size_t)(wn * 64 + ni * 16 + c15) * 64;
      bfr[ni][0] = *(const bf16x8*)(pr + cc0);
      bfr[ni][1] = *(const bf16x8*)(pr + (cc0 ^ 32));
    }
    PRIO1;
#pragma unroll
    for (int mi = 0; mi < 2; ++mi)
#pragma unroll
      for (int ni = 0; ni < 4; ++ni)
#pragma unroll
        for (int kk = 0; kk < 2; ++kk)
          acc[mi][ni] = __builtin_amdgcn_mfma_f32_16x16x32_bf16(af[mi][kk], bfr[ni][kk],
                                                                acc[mi][ni], 0, 0, 0);
    PRIO0;
    BARRAW;
    cur ^= 1;
  }
#undef STG_O
#pragma unroll
  for (int mi = 0; mi < 2; ++mi)
#pragma unroll
    for (int ni = 0; ni < 4; ++ni)
#pragma unroll
      for (int r = 0; r < 4; ++r){
        int row = brow + wm * 32 + mi * 16 + g * 4 + r;
        int col = bcol + wn * 64 + ni * 16 + c15;
        C[(size_t)row * 2048 + col] = acc[mi][ni][r];
      }
}

// ---------------- pass 1a: rowsum of exp (causal), Q-in-registers ----------------
// grid (40, 16), 256 thr (4 waves x 32 q-rows); K 64x128 LDS dbuf, counted vmcnt.
__global__ __launch_bounds__(256)
void k_pass1a(const u16* __restrict__ Q, const u16* __restrict__ K, float* __restrict__ rowsum){
  __shared__ __align__(16) u16 Ks[2][64 * 128];
  const int tid = threadIdx.x;
  const int wv = tid >> 6, lane = tid & 63;
  const int g = lane >> 4, c15 = lane & 15;
  const int h = blockIdx.y;
  int qb = 0, c = 0;
  { int rem = blockIdx.x; int q = 0;
    while (rem >= ((2 * q + 9) >> 3)){ rem -= (2 * q + 9) >> 3; q++; }
    qb = q; c = rem; }
  const int i0 = qb * 128;
  const int ktend = 2 * qb + 2;
  const int kt0 = c * 8;
  const int kt1 = (ktend < kt0 + 8) ? ktend : (kt0 + 8);
  const u16* Qh = Q + h * HDIM;
  const u16* Kh = K + h * HDIM;
  const float scale = 0.08838834764831845f;   // 1/sqrt(128)
  const int wb = wv * 32;

  bf16x8 qfr[2][4];
#pragma unroll
  for (int m = 0; m < 2; m++)
#pragma unroll
    for (int ks = 0; ks < 4; ks++)
      qfr[m][ks] = *(const bf16x8*)(Qh + (size_t)(i0 + wb + m * 16 + c15) * 2048 + ks * 32 + g * 8);

  stage_tile(Kh, 2048, kt0 * 64, Ks[0], tid);

  float rs[2][4] = {{0.f,0.f,0.f,0.f},{0.f,0.f,0.f,0.f}};
  int cur = 0;
  for (int kt = kt0; kt < kt1; ++kt){
    if (kt + 1 < kt1){ stage_tile(Kh, 2048, (kt + 1) * 64, Ks[cur ^ 1], tid); WAITVM(4); }
    else             { WAITVM(0); }
    BARRAW;
    const int k0 = kt * 64;
    f32x4 sacc[2][4];
#pragma unroll
    for (int m = 0; m < 2; m++)
#pragma unroll
      for (int n = 0; n < 4; n++) sacc[m][n] = (f32x4){0.f, 0.f, 0.f, 0.f};
#pragma unroll
    for (int ks = 0; ks < 4; ++ks){
#pragma unroll
      for (int n = 0; n < 4; n++){
        int brw = n * 16 + c15;
        bf16x8 b = *(const bf16x8*)(Ks[cur] + brw * 128 + ((ks * 32 + g * 8) ^ ((brw & 7) << 3)));
#pragma unroll
        for (int m = 0; m < 2; m++)
          sacc[m][n] = __builtin_amdgcn_mfma_f32_16x16x32_bf16(qfr[m][ks], b, sacc[m][n], 0, 0, 0);
      }
    }
    if (kt < 2 * qb){            // fully causal tile: no mask compare
#pragma unroll
      for (int m = 0; m < 2; m++)
#pragma unroll
        for (int n = 0; n < 4; n++)
#pragma unroll
          for (int r = 0; r < 4; r++)
            rs[m][r] += __expf(sacc[m][n][r] * scale);
    } else {
#pragma unroll
      for (int n = 0; n < 4; n++){
        int col = k0 + n * 16 + c15;
#pragma unroll
        for (int m = 0; m < 2; m++)
#pragma unroll
          for (int r = 0; r < 4; r++){
            int rowg = i0 + wb + m * 16 + g * 4 + r;
            rs[m][r] += (col <= rowg) ? __expf(sacc[m][n][r] * scale) : 0.f;
          }
      }
    }
    BARRAW;
    cur ^= 1;
  }
#pragma unroll
  for (int m = 0; m < 2; m++)
#pragma unroll
    for (int r = 0; r < 4; r++){
      float v = rs[m][r];
      v += __shfl_xor(v, 1); v += __shfl_xor(v, 2);
      v += __shfl_xor(v, 4); v += __shfl_xor(v, 8);
      if (c15 == 0)
        atomicAdd(&rowsum[h * 2048 + i0 + wb + m * 16 + g * 4 + r], v);
    }
}

// ---------------- pass 1b: colsum of normalized exp, K-in-registers ----------------
// grid (40, 16), 256 thr (4 waves x 32 k-rows); Q 64x128 LDS dbuf, counted vmcnt.
__global__ __launch_bounds__(256)
void k_pass1b(const u16* __restrict__ Q, const u16* __restrict__ K,
              const float* __restrict__ rowsum, float* __restrict__ colsum){
  __shared__ __align__(16) u16 Qs[2][64 * 128];
  const int tid = threadIdx.x;
  const int wv = tid >> 6, lane = tid & 63;
  const int g = lane >> 4, c15 = lane & 15;
  const int h = blockIdx.y;
  int kb = 0, c = 0;
  { int rem = blockIdx.x; int q = 0;
    while (rem >= ((39 - 2 * q) >> 3)){ rem -= (39 - 2 * q) >> 3; q++; }
    kb = q; c = rem; }
  const int k0 = kb * 128;
  const int qt0 = 2 * kb + c * 8;
  const int qt1 = (2 * kb + c * 8 + 8 < 32) ? (2 * kb + c * 8 + 8) : 32;
  const u16* Qh = Q + h * HDIM;
  const u16* Kh = K + h * HDIM;
  const float scale = 0.08838834764831845f;
  const int wb = wv * 32;
  const float* rsrow = rowsum + h * 2048;

  bf16x8 kfr[2][4];
#pragma unroll
  for (int m = 0; m < 2; m++)
#pragma unroll
    for (int ks = 0; ks < 4; ks++)
      kfr[m][ks] = *(const bf16x8*)(Kh + (size_t)(k0 + wb + m * 16 + c15) * 2048 + ks * 32 + g * 8);

  stage_tile(Qh, 2048, qt0 * 64, Qs[0], tid);

  float racc[2][4] = {{0.f,0.f,0.f,0.f},{0.f,0.f,0.f,0.f}};
  int cur = 0;
  for (int qt = qt0; qt < qt1; ++qt){
    if (qt + 1 < qt1){ stage_tile(Qh, 2048, (qt + 1) * 64, Qs[cur ^ 1], tid); WAITVM(4); }
    else             { WAITVM(0); }
    BARRAW;
    const int i0q = qt * 64;
    float rw[4];
#pragma unroll
    for (int n = 0; n < 4; n++)
      rw[n] = 1.0f / rsrow[i0q + n * 16 + c15];
    f32x4 sacc[2][4];
#pragma unroll
    for (int m = 0; m < 2; m++)
#pragma unroll
      for (int n = 0; n < 4; n++) sacc[m][n] = (f32x4){0.f, 0.f, 0.f, 0.f};
#pragma unroll
    for (int ks = 0; ks < 4; ++ks){
#pragma unroll
      for (int n = 0; n < 4; n++){
        int brw = n * 16 + c15;
        bf16x8 b = *(const bf16x8*)(Qs[cur] + brw * 128 + ((ks * 32 + g * 8) ^ ((brw & 7) << 3)));
#pragma unroll
        for (int m = 0; m < 2; m++)
          sacc[m][n] = __builtin_amdgcn_mfma_f32_16x16x32_bf16(kfr[m][ks], b, sacc[m][n], 0, 0, 0);
      }
    }
    if (qt >= 2 * kb + 2){       // fully causal: no mask compare
#pragma unroll
      for (int m = 0; m < 2; m++)
#pragma unroll
        for (int n = 0; n < 4; n++)
#pragma unroll
          for (int r = 0; r < 4; r++)
            racc[m][r] += __expf(sacc[m][n][r] * scale) * rw[n];
    } else {
#pragma unroll
      for (int n = 0; n < 4; n++){
        int colq = i0q + n * 16 + c15;
#pragma unroll
        for (int m = 0; m < 2; m++)
#pragma unroll
          for (int r = 0; r < 4; r++){
            int rowk = k0 + wb + m * 16 + g * 4 + r;
            racc[m][r] += (rowk <= colq) ? __expf(sacc[m][n][r] * scale) * rw[n] : 0.f;
          }
      }
    }
    BARRAW;
    cur ^= 1;
  }
#pragma unroll
  for (int m = 0; m < 2; m++)
#pragma unroll
    for (int r = 0; r < 4; r++){
      float v = racc[m][r];
      v += __shfl_xor(v, 1); v += __shfl_xor(v, 2);
      v += __shfl_xor(v, 4); v += __shfl_xor(v, 8);
      if (c15 == 0)
        atomicAdd(&colsum[h * 2048 + k0 + wb + m * 16 + g * 4 + r], v);
    }
}

// ---------------- top-k via exact radix-select + fused K/V gather ----------------
// Positive floats are order-isomorphic to their u32 bits. T = 204th value;
// take all >T plus smallest-index ties — exactly lax.top_k's index set.
__global__ __launch_bounds__(1024)
void k_topkg(const float* __restrict__ colsum, const u16* __restrict__ Kb,
             const u16* __restrict__ Vb, short* __restrict__ cidx,
             u16* __restrict__ Kg, u16* __restrict__ Vg){
  __shared__ u32 keys[2048];
  __shared__ int hist[256];
  __shared__ int chunkCnt[32];
  __shared__ short cidL[256];
  __shared__ u32 Tacc_s;
  __shared__ int rem_s;
  __shared__ __align__(16) u16 t[32][136];
  const int tid = threadIdx.x;
  const int h = blockIdx.x;
  const int w = tid >> 6, lane = tid & 63;

  for (int i = tid; i < 2048; i += 1024) keys[i] = ((const u32*)colsum)[h * 2048 + i];
  if (tid == 0){ Tacc_s = 0; rem_s = HEAVY; }
  __syncthreads();

  for (int s = 24; s >= 0; s -= 8){
    if (tid < 256) hist[tid] = 0;
    __syncthreads();
    u32 T = Tacc_s;
    for (int i = tid; i < 2048; i += 1024){
      u32 k = keys[i];
      bool match = (s == 24) ? true : (((k ^ T) >> (s + 8)) == 0);
      if (match) atomicAdd(&hist[(k >> s) & 255], 1);
    }
    __syncthreads();
    if (tid == 0){
      int rem = rem_s, acc = 0, b = 255;
      for (; b > 0; --b){
        int c2 = hist[b];
        if (acc + c2 >= rem) break;
        acc += c2;
      }
      Tacc_s = T | ((u32)b << s);
      rem_s = rem - acc;
    }
    __syncthreads();
  }
  const u32 T = Tacc_s;
  const int need = rem_s;                 // take this many smallest-index among == T
  const u32 kA = keys[tid], kB = keys[tid + 1024];
  const bool eqA = (kA == T), eqB = (kB == T);
  unsigned long long ebA = __ballot(eqA);
  unsigned long long ebB = __ballot(eqB);
  if (lane == 0){ chunkCnt[w] = __popcll(ebA); chunkCnt[16 + w] = __popcll(ebB); }
  __syncthreads();
  if (tid == 0){
    int s2 = 0;
    for (int i2 = 0; i2 < 32; ++i2){ int c2 = chunkCnt[i2]; chunkCnt[i2] = s2; s2 += c2; }
  }
  __syncthreads();
  const unsigned long long below = (1ull << lane) - 1ull;
  const int eqrA = chunkCnt[w] + __popcll(ebA & below);
  const int eqrB = chunkCnt[16 + w] + __popcll(ebB & below);
  const bool hvA = (kA > T) || (eqA && eqrA < need);
  const bool hvB = (kB > T) || (eqB && eqrB < need);
  __syncthreads();                        // before reusing chunkCnt
  unsigned long long hbA = __ballot(hvA);
  unsigned long long hbB = __ballot(hvB);
  if (lane == 0){ chunkCnt[w] = __popcll(hbA); chunkCnt[16 + w] = __popcll(hbB); }
  if (tid >= HEAVY && tid < 256) cidL[tid] = 32767;
  __syncthreads();
  if (tid == 0){
    int s2 = 0;
    for (int i2 = 0; i2 < 32; ++i2){ int c2 = chunkCnt[i2]; chunkCnt[i2] = s2; s2 += c2; }
  }
  __syncthreads();
  if (hvA) cidL[chunkCnt[w] + __popcll(hbA & below)] = (short)tid;
  if (hvB) cidL[chunkCnt[16 + w] + __popcll(hbB & below)] = (short)(tid + 1024);
  __syncthreads();
  if (tid < 256) cidx[h * 256 + tid] = cidL[tid];

  // gather K: 256 slots x 16 chunks
  for (int i = tid; i < 4096; i += 1024){
    int slot = i >> 4, cp = i & 15;
    int cid = cidL[slot];
    bf16x8 z = (bf16x8){0,0,0,0,0,0,0,0};
    bf16x8 val = (cid < 2048) ? *(const bf16x8*)(Kb + (size_t)cid * 2048 + h * 128 + cp * 8) : z;
    *(bf16x8*)(Kg + ((size_t)h * 256 + slot) * 128 + cp * 8) = val;
  }
  // gather V transposed (8 groups of 32 slots through LDS)
  for (int grp = 0; grp < 8; ++grp){
    int s0 = grp * 32;
    if (tid < 512){
      int s2 = tid >> 4, cp = tid & 15;
      int cid = cidL[s0 + s2];
      bf16x8 z = (bf16x8){0,0,0,0,0,0,0,0};
      bf16x8 val = (cid < 2048) ? *(const bf16x8*)(Vb + (size_t)cid * 2048 + h * 128 + cp * 8) : z;
      *(bf16x8*)(&t[s2][cp * 8]) = val;
    }
    __syncthreads();
    for (int i = tid; i < 4096; i += 1024){
      int d = i >> 5, s2 = i & 31;
      Vg[((size_t)h * 128 + d) * 256 + s0 + s2] = t[s2][d];
    }
    __syncthreads();
  }
}

// ---------------- pass 2: QBLK=128, Q-in-reg, K+V LDS dbuf, counted vmcnt ----------------
// grid (16, 16) = 256 blocks, 512 thr (8 waves: 2 q-halves x 4 strips)
__global__ __launch_bounds__(512)
void k_pass2(const u16* __restrict__ Q, const u16* __restrict__ K, const u16* __restrict__ Vt,
             const u16* __restrict__ Kg, const u16* __restrict__ Vg,
             const short* __restrict__ cidx, u16* __restrict__ attn){
  __shared__ __align__(16) u16 Ks[2][64 * 128];
  __shared__ __align__(16) u16 Vs[2][128 * 64];
  __shared__ __align__(16) u16 Ps[8][16 * 64];
  __shared__ short cids[256];
  __shared__ int lists[12];
  __shared__ int nact_s;
  const int tid = threadIdx.x;
  const int w = tid >> 6, lane = tid & 63;
  const int g = lane >> 4, c15 = lane & 15;
  const int qb = blockIdx.x, h = blockIdx.y;
  const int i0 = qb * 128;
  const int wq = w >> 2, w4 = w & 3;
  const int rowbase = i0 + wq * 64 + w4 * 16;
  const u16* Qh = Q + h * HDIM;
  const u16* Kh = K + h * HDIM;
  const u16* Kgh = Kg + (size_t)h * 256 * 128;
  const u16* Vth = Vt + (size_t)h * 128 * 2048;
  const u16* Vgh = Vg + (size_t)h * 128 * 256;
  const float scale = 0.08838834764831845f;

  if (tid < 256) cids[tid] = cidx[h * 256 + tid];
  // Q fragments in registers (rows rowbase + c15)
  bf16x8 qfr[4];
#pragma unroll
  for (int ks = 0; ks < 4; ks++)
    qfr[ks] = *(const bf16x8*)(Qh + (size_t)(rowbase + c15) * 2048 + ks * 32 + g * 8);
  __syncthreads();
  if (tid == 0){
    int n = 0;
    int ktb0 = (i0 > RECENT) ? ((i0 - RECENT) >> 6) : 0;
    int ktmax = (i0 + 127) >> 6;
    for (int kt = ktb0; kt <= ktmax; ++kt) lists[n++] = kt;
    for (int gt = 0; gt < 4; ++gt)
      if ((int)cids[gt * 64] <= i0 + 127 - RECENT - 1) lists[n++] = 100 + gt;
    nact_s = n;
  }
  __syncthreads();
  const int nact = nact_s;

  // prologue: K0 (2) + V0 (2); WAITVM(2) retires everything older + K0, keeps V0
  { int e = lists[0];
    if (e < 100){ stageK512(Kh, 2048, e * 64, Ks[0], tid);
                  stageV512(Vth, 2048, e * 64, Vs[0], tid); }
    else        { stageK512(Kgh, 128, (e - 100) * 64, Ks[0], tid);
                  stageV512(Vgh, 256, (e - 100) * 64, Vs[0], tid); } }
  WAITVM(2);
  BARRAW;

  f32x4 oacc[8];
#pragma unroll
  for (int f = 0; f < 8; f++) oacc[f] = (f32x4){0.f, 0.f, 0.f, 0.f};
  float lsum[4] = {0.f, 0.f, 0.f, 0.f};

  int cur = 0;
  for (int i = 0; i < nact; ++i){
    const int e = lists[i];
    const bool isg = (e >= 100);
    const bool nxt = (i + 1 < nact);
    if (nxt){
      int e2 = lists[i + 1];
      if (e2 < 100){ stageK512(Kh, 2048, e2 * 64, Ks[cur ^ 1], tid);
                     stageV512(Vth, 2048, e2 * 64, Vs[cur ^ 1], tid); }
      else         { stageK512(Kgh, 128, (e2 - 100) * 64, Ks[cur ^ 1], tid);
                     stageV512(Vgh, 256, (e2 - 100) * 64, Vs[cur ^ 1], tid); }
      WAITVM(6);               // retire K(i); keep V(i)+K(i+1)+V(i+1)
    } else {
      WAITVM(2);               // retire K(last); keep V(last)
    }
    BARRAW;
    // QK^T
    f32x4 sacc[4];
#pragma unroll
    for (int n = 0; n < 4; n++) sacc[n] = (f32x4){0.f, 0.f, 0.f, 0.f};
#pragma unroll
    for (int ks = 0; ks < 4; ++ks){
#pragma unroll
      for (int n = 0; n < 4; n++){
        int brw = n * 16 + c15;
        bf16x8 b = *(const bf16x8*)(Ks[cur] + brw * 128 + ((ks * 32 + g * 8) ^ ((brw & 7) << 3)));
        sacc[n] = __builtin_amdgcn_mfma_f32_16x16x32_bf16(qfr[ks], b, sacc[n], 0, 0, 0);
      }
    }
    // masked exp -> P (LDS, wave-private), row sums
#pragma unroll
    for (int n = 0; n < 4; n++){
      int cid = isg ? (int)cids[(e - 100) * 64 + n * 16 + c15] : (e * 64 + n * 16 + c15);
#pragma unroll
      for (int r = 0; r < 4; r++){
        int rowg = rowbase + g * 4 + r;
        int dist = rowg - cid;
        bool valid = (cid <= rowg) && (isg ? (dist > RECENT) : (dist <= RECENT));
        float ev = valid ? __expf(sacc[n][r] * scale) : 0.f;
        lsum[r] += ev;
        int prow = g * 4 + r;
        Ps[w][prow * 64 + ((n * 16 + c15) ^ ((prow & 7) << 3))] = f2bf(ev);
      }
    }
    // retire V(i) under the exp phase, then PV from LDS
    if (nxt) WAITVM(4); else WAITVM(0);
    BARRAW;
    PRIO1;
#pragma unroll
    for (int ks2 = 0; ks2 < 2; ++ks2){
      bf16x8 pa = *(const bf16x8*)(&Ps[w][c15 * 64 + ((ks2 * 32 + g * 8) ^ ((c15 & 7) << 3))]);
#pragma unroll
      for (int f = 0; f < 8; ++f){
        int vrow = f * 16 + c15;
        bf16x8 vb = *(const bf16x8*)(Vs[cur] + vrow * 64 + ((ks2 * 32 + g * 8) ^ ((vrow & 7) << 3)));
        oacc[f] = __builtin_amdgcn_mfma_f32_16x16x32_bf16(pa, vb, oacc[f], 0, 0, 0);
      }
    }
    PRIO0;
    BARRAW;
    cur ^= 1;
  }
  float rinv[4];
#pragma unroll
  for (int r = 0; r < 4; r++){
    float v = lsum[r];
    v += __shfl_xor(v, 1); v += __shfl_xor(v, 2);
    v += __shfl_xor(v, 4); v += __shfl_xor(v, 8);
    rinv[r] = 1.0f / v;
  }
#pragma unroll
  for (int f = 0; f < 8; f++)
#pragma unroll
    for (int r = 0; r < 4; r++){
      int rowg = rowbase + g * 4 + r;
      attn[(size_t)rowg * 2048 + h * HDIM + f * 16 + c15] = f2bf(oacc[f][r] * rinv[r]);
    }
}

// ---------------- host launcher ----------------
extern "C" void kernel_launch(void* const* d_in, const int* in_sizes, int n_in,
                              void* d_out, int out_size, void* d_ws, size_t ws_size,
                              hipStream_t stream){
  const float* X  = (const float*)d_in[0];
  const float* Wq = (const float*)d_in[1];
  const float* Wk = (const float*)d_in[2];
  const float* Wv = (const float*)d_in[3];
  const float* Wo = (const float*)d_in[4];

  char* w = (char*)d_ws;
  const size_t MB8 = (size_t)2048 * 2048 * 2;   // one bf16 matrix = 8 MiB
  u16* Xb  = (u16*)(w);
  u16* Wqb = (u16*)(w + 1 * MB8);
  u16* Wkb = (u16*)(w + 2 * MB8);
  u16* Wvb = (u16*)(w + 3 * MB8);
  u16* Wob = (u16*)(w + 4 * MB8);
  u16* Qb  = (u16*)(w + 5 * MB8);
  u16* Kb  = (u16*)(w + 6 * MB8);
  u16* Vb  = (u16*)(w + 7 * MB8);
  u16* Vtb   = Wqb;   // Wq dead after projections
  u16* attnb = Xb;    // X dead after projections
  char* p = w + 8 * MB8;
  float* cosT = (float*)p;              p += 524288;
  float* sinT = (float*)p;              p += 524288;
  float* colsum = (float*)p;            p += 131072;   // zeroed in k_prep (with rowsum)
  float* rowsum = (float*)p;            p += 131072;
  short* cidx  = (short*)p;             p += 16 * 256 * 2;
  u16*   Kg    = (u16*)p;               p += (size_t)16 * 256 * 128 * 2;
  u16*   Vg    = (u16*)p;

  dim3 b256(256);

  k_prep<<<21056, b256, 0, stream>>>(X, Wq, Wk, Wv, Wo, Xb, cosT, sinT, colsum);

  k_g256<<<dim3(32, 8), dim3(512), 0, stream>>>(Xb, Wqb, Wkb, Wvb, Qb, Kb, Vb);
  k_post<<<8192, b256, 0, stream>>>(Qb, Kb, cosT, sinT, Vb, Vtb);

  k_pass1a<<<dim3(40, 16), b256, 0, stream>>>(Qb, Kb, rowsum);
  k_pass1b<<<dim3(40, 16), b256, 0, stream>>>(Qb, Kb, rowsum, colsum);
  k_topkg<<<16, dim3(1024), 0, stream>>>(colsum, Kb, Vb, cidx, Kg, Vg);
  k_pass2<<<dim3(16, 16), dim3(512), 0, stream>>>(Qb, Kb, Vtb, Kg, Vg, cidx, attnb);

  k_gemm_out<<<dim3(16, 16), dim3(512), 0, stream>>>(attnb, Wob, (float*)d_out);
}

// Round 10
// 243.028 us; speedup vs baseline: 1.6609x; 1.0161x over previous
//
#include <hip/hip_runtime.h>
#include <hip/hip_bf16.h>
#include <stdint.h>

// Problem constants: b=1, s=2048, hidden=2048, H=16, d=128
#define SEQ   2048
#define HIDN  2048
#define NHEAD 16
#define HDIM  128
#define HEAVY 204   // int(0.1*2048)
#define RECENT 204

typedef __attribute__((ext_vector_type(4))) float f32x4;
typedef __attribute__((ext_vector_type(8))) short bf16x8;
typedef unsigned short u16;
typedef unsigned int   u32;

static __device__ __forceinline__ u16 f2bf(float f){
  union { float f; u32 u; } v; v.f = f;
  u32 r = (v.u + 0x7FFFu + ((v.u >> 16) & 1u)) >> 16;
  return (u16)r;
}
static __device__ __forceinline__ float bf2f(u16 u){
  union { u32 u; float f; } v; v.u = ((u32)u) << 16;
  return v.f;
}

// global -> LDS direct 16B load (dest is wave-uniform base + lane*16)
static __device__ __forceinline__ void gload16(const void* g, void* l){
  __builtin_amdgcn_global_load_lds((const __attribute__((address_space(1))) u32*)g,
                                   (__attribute__((address_space(3))) u32*)l, 16, 0, 0);
}

#define WAITVM(N) asm volatile("s_waitcnt vmcnt(" #N ")" ::: "memory")
#define BARRAW    __builtin_amdgcn_s_barrier()
#define PRIO1     __builtin_amdgcn_s_setprio(1)
#define PRIO0     __builtin_amdgcn_s_setprio(0)

// stage a 64x128 bf16 tile with 256 threads, runtime row stride (XOR-swizzled source)
static __device__ __forceinline__ void stage_tile(const u16* __restrict__ base, size_t stride,
                                                  int row0, u16* __restrict__ lds, int tid){
  const int wbase = tid & ~63;
#pragma unroll
  for (int it = 0; it < 4; ++it){
    int m = it * 256 + tid;
    int row = m >> 4, cp = m & 15;
    gload16(base + (size_t)(row0 + row) * stride + ((cp ^ (row & 7)) * 8),
            lds + (it * 256 + wbase) * 8);
  }
}

// stage 64x128 tile with 512 threads, runtime stride
static __device__ __forceinline__ void stageK512(const u16* __restrict__ base, size_t stride,
                                                 int row0, u16* __restrict__ lds, int tid){
#pragma unroll
  for (int it = 0; it < 2; ++it){
    int m = it * 512 + tid;
    int row = m >> 4, cp = m & 15;
    gload16(base + (size_t)(row0 + row) * stride + ((cp ^ (row & 7)) * 8),
            lds + (it * 512 + (tid & ~63)) * 8);
  }
}
// stage 128-row x 64-col tile (col offset c0) with 512 threads, runtime stride
static __device__ __forceinline__ void stageV512(const u16* __restrict__ base, size_t stride,
                                                 int c0, u16* __restrict__ lds, int tid){
#pragma unroll
  for (int it = 0; it < 2; ++it){
    int m = it * 512 + tid;
    int row = m >> 3, cp = m & 7;
    gload16(base + (size_t)row * stride + c0 + ((cp ^ (row & 7)) * 8),
            lds + (it * 512 + (tid & ~63)) * 8);
  }
}

// ---------------- prep: cvt5 + rope tables + zero colsum/rowsum (fused) ----------------
__global__ void k_prep(const float* __restrict__ A0, const float* __restrict__ A1,
                       const float* __restrict__ A2, const float* __restrict__ A3,
                       const float* __restrict__ A4, u16* __restrict__ out,
                       float* __restrict__ cosT, float* __restrict__ sinT,
                       float* __restrict__ colsum){
  int b = blockIdx.x, tid = threadIdx.x;
  if (b < 20480){
    int id = b * 256 + tid;
    int sel = id >> 20, off = (id & 1048575) * 4;
    const float* src = sel == 0 ? A0 : sel == 1 ? A1 : sel == 2 ? A2 : sel == 3 ? A3 : A4;
    float4 v = *(const float4*)(src + off);
    ushort4 o;
    o.x = f2bf(v.x); o.y = f2bf(v.y); o.z = f2bf(v.z); o.w = f2bf(v.w);
    *(ushort4*)(out + (size_t)sel * 4194304 + off) = o;
  } else if (b < 20992){
    int i = (b - 20480) * 256 + tid;           // 2048*64
    int pos = i >> 6, j = i & 63;
    float invf = powf(10000.0f, -(float)j * (1.0f / 64.0f));
    float a = (float)pos * invf;
    cosT[i] = cosf(a);
    sinT[i] = sinf(a);
  } else {
    int i = (b - 20992) * 256 + tid;           // 16384 float4 = colsum+rowsum (contiguous)
    if (i < 16384) ((float4*)colsum)[i] = (float4){0.f, 0.f, 0.f, 0.f};
  }
}

// ---------------- post: rope on Q,K + transpose V (fused) ----------------
__global__ void k_post(u16* __restrict__ Qm, u16* __restrict__ Km,
                       const float* __restrict__ cosT, const float* __restrict__ sinT,
                       const u16* __restrict__ V, u16* __restrict__ Vt){
  __shared__ u16 t[32][33];
  int b = blockIdx.x, tid = threadIdx.x;
  if (b < 4096){
    int gid = b * 256 + tid;                   // 2 * 524288
    u16* M = (gid < 524288) ? Qm : Km;
    int id = gid & 524287;
    int pos = id >> 8, rem = id & 255;
    int h = rem >> 4, j4 = (rem & 15) * 4;
    u16* p = M + (size_t)pos * HIDN + h * HDIM + j4;
    ushort4 lo = *(ushort4*)p;
    ushort4 hi = *(ushort4*)(p + 64);
    float4 c = *(const float4*)(cosT + pos * 64 + j4);
    float4 s = *(const float4*)(sinT + pos * 64 + j4);
    float l0 = bf2f(lo.x), l1 = bf2f(lo.y), l2 = bf2f(lo.z), l3 = bf2f(lo.w);
    float h0 = bf2f(hi.x), h1 = bf2f(hi.y), h2 = bf2f(hi.z), h3 = bf2f(hi.w);
    ushort4 nlo, nhi;
    nlo.x = f2bf(l0 * c.x - h0 * s.x);  nhi.x = f2bf(h0 * c.x + l0 * s.x);
    nlo.y = f2bf(l1 * c.y - h1 * s.y);  nhi.y = f2bf(h1 * c.y + l1 * s.y);
    nlo.z = f2bf(l2 * c.z - h2 * s.z);  nhi.z = f2bf(h2 * c.z + l2 * s.z);
    nlo.w = f2bf(l3 * c.w - h3 * s.w);  nhi.w = f2bf(h3 * c.w + l3 * s.w);
    *(ushort4*)p = nlo;
    *(ushort4*)(p + 64) = nhi;
  } else {
    int b2 = b - 4096;
    int s0 = (b2 & 63) * 32, c0 = (b2 >> 6) * 32;
    int r = tid >> 3, cc = (tid & 7) * 4;
    ushort4 v = *(const ushort4*)(V + (size_t)(s0 + r) * 2048 + c0 + cc);
    t[r][cc] = v.x; t[r][cc + 1] = v.y; t[r][cc + 2] = v.z; t[r][cc + 3] = v.w;
    __syncthreads();
    int co = tid >> 3, ro = (tid & 7) * 4;
    ushort4 o;
    o.x = t[ro][co]; o.y = t[ro + 1][co]; o.z = t[ro + 2][co]; o.w = t[ro + 3][co];
    *(ushort4*)(Vt + (size_t)(c0 + co) * 2048 + s0 + ro) = o;
  }
}

// ---------------- fused projection GEMM: C[2048][6144] = X @ [Wq;Wk;Wv]^T ----------------
// 256x192 tile, BK=64, 8 waves, 3 uniform 16-MFMA phases/tile (6 barriers/tile),
// counted vmcnt. grid (32,8) = 256 blocks, full fill.
__global__ __launch_bounds__(512, 1)
void k_g256(const u16* __restrict__ X, const u16* __restrict__ Wq, const u16* __restrict__ Wk,
            const u16* __restrict__ Wv, u16* __restrict__ C0, u16* __restrict__ C1,
            u16* __restrict__ C2){
  __shared__ __align__(16) u16 LA[2][256 * 64];
  __shared__ __align__(16) u16 LB[2][192 * 64];
  const int tid = threadIdx.x;
  const int lane = tid & 63, wvi = tid >> 6;
  const int wm = wvi >> 2, wn = wvi & 3;
  const int g = lane >> 4, c15 = lane & 15;
  const int brow = blockIdx.y * 256;       // [0,2048)
  const int bcol = blockIdx.x * 192;       // [0,6144)
  const int NT = 32;

  f32x4 acc[8][3];
#pragma unroll
  for (int m = 0; m < 8; m++)
#pragma unroll
    for (int n = 0; n < 3; n++) acc[m][n] = (f32x4){0.f, 0.f, 0.f, 0.f};

  const int cc0 = ((g ^ (c15 & 7)) * 8);
  bf16x8 af[4][2], af2[4][2], bf[3][2];

#define BPTR(rB_) (rB_ < 2048 ? Wq + (size_t)(rB_) * 2048 \
                 : rB_ < 4096 ? Wk + (size_t)((rB_) - 2048) * 2048 \
                              : Wv + (size_t)((rB_) - 4096) * 2048)
#define STGA(grow0, gcol0, ldsb) do { \
  _Pragma("unroll") for (int it = 0; it < 2; ++it){ \
    int m_ = it * 512 + tid; \
    int row_ = m_ >> 3, cp_ = m_ & 7; \
    gload16(X + (size_t)((grow0) + row_) * 2048 + (gcol0) + ((cp_ ^ (row_ & 7)) * 8), \
            (ldsb) + (it * 512 + (tid & ~63)) * 8); \
  } } while(0)
#define STGB128(gcol0, ldsb) do { \
  _Pragma("unroll") for (int it = 0; it < 2; ++it){ \
    int m_ = it * 512 + tid; \
    int row_ = m_ >> 3, cp_ = m_ & 7; \
    int rB_ = bcol + row_; \
    const u16* bp_ = BPTR(rB_); \
    gload16(bp_ + (gcol0) + ((cp_ ^ (row_ & 7)) * 8), \
            (ldsb) + (it * 512 + (tid & ~63)) * 8); \
  } } while(0)
#define STGB64(gcol0, ldsb) do { \
    int row_ = 128 + (tid >> 3), cp_ = tid & 7; \
    int rB_ = bcol + row_; \
    const u16* bp_ = BPTR(rB_); \
    gload16(bp_ + (gcol0) + ((cp_ ^ (row_ & 7)) * 8), \
            (ldsb) + (tid & ~63) * 8); \
  } while(0)
#define RDA(buf) \
  _Pragma("unroll") for (int mi2 = 0; mi2 < 4; ++mi2){ \
    const u16* pr = &LA[buf][0] + (size_t)(wm * 128 + mi2 * 16 + c15) * 64; \
    af[mi2][0] = *(const bf16x8*)(pr + cc0); \
    af[mi2][1] = *(const bf16x8*)(pr + (cc0 ^ 32)); \
  }
#define RDA2(buf) \
  _Pragma("unroll") for (int mi2 = 0; mi2 < 4; ++mi2){ \
    const u16* pr = &LA[buf][0] + (size_t)(wm * 128 + (4 + mi2) * 16 + c15) * 64; \
    af2[mi2][0] = *(const bf16x8*)(pr + cc0); \
    af2[mi2][1] = *(const bf16x8*)(pr + (cc0 ^ 32)); \
  }
#define RDB2(buf) \
  _Pragma("unroll") for (int ni2 = 0; ni2 < 2; ++ni2){ \
    const u16* pr = &LB[buf][0] + (size_t)(wn * 48 + ni2 * 16 + c15) * 64; \
    bf[ni2][0] = *(const bf16x8*)(pr + cc0); \
    bf[ni2][1] = *(const bf16x8*)(pr + (cc0 ^ 32)); \
  }
#define RDB1(buf) do { \
    const u16* pr = &LB[buf][0] + (size_t)(wn * 48 + 32 + c15) * 64; \
    bf[2][0] = *(const bf16x8*)(pr + cc0); \
    bf[2][1] = *(const bf16x8*)(pr + (cc0 ^ 32)); \
  } while(0)
// 16-MFMA clusters
#define MM2A \
  _Pragma("unroll") for (int mi2 = 0; mi2 < 4; ++mi2) \
  _Pragma("unroll") for (int ni2 = 0; ni2 < 2; ++ni2) \
  _Pragma("unroll") for (int kk = 0; kk < 2; ++kk) \
    acc[mi2][ni2] = __builtin_amdgcn_mfma_f32_16x16x32_bf16( \
        af[mi2][kk], bf[ni2][kk], acc[mi2][ni2], 0, 0, 0);
#define MM1AB \
  _Pragma("unroll") for (int mi2 = 0; mi2 < 4; ++mi2) \
  _Pragma("unroll") for (int kk = 0; kk < 2; ++kk){ \
    acc[mi2][2] = __builtin_amdgcn_mfma_f32_16x16x32_bf16( \
        af[mi2][kk], bf[2][kk], acc[mi2][2], 0, 0, 0); \
    acc[4 + mi2][2] = __builtin_amdgcn_mfma_f32_16x16x32_bf16( \
        af2[mi2][kk], bf[2][kk], acc[4 + mi2][2], 0, 0, 0); \
  }
#define MM2B \
  _Pragma("unroll") for (int mi2 = 0; mi2 < 4; ++mi2) \
  _Pragma("unroll") for (int ni2 = 0; ni2 < 2; ++ni2) \
  _Pragma("unroll") for (int kk = 0; kk < 2; ++kk) \
    acc[4 + mi2][ni2] = __builtin_amdgcn_mfma_f32_16x16x32_bf16( \
        af2[mi2][kk], bf[ni2][kk], acc[4 + mi2][ni2], 0, 0, 0);

// one tile = 3 phases; A(t+1) staged P1/P2 -> LA[buf^1]; B(t+2) staged P3 -> LB[buf]
#define TILE(t, buf) do { \
    const int kn1 = ((t) + 1) * 64; \
    const int kn2 = ((t) + 2) * 64; \
    /* P1 */ \
    RDA(buf); RDB2(buf); \
    if ((t) + 1 < NT) STGA(brow, kn1, &LA[buf ^ 1][0]); \
    BARRAW; PRIO1; MM2A; PRIO0; BARRAW; \
    /* P2 */ \
    RDB1(buf); RDA2(buf); \
    if ((t) + 1 < NT) STGA(brow + 128, kn1, &LA[buf ^ 1][0] + 128 * 64); \
    BARRAW; PRIO1; MM1AB; PRIO0; BARRAW; \
    /* P3 */ \
    if ((t) + 2 < NT){ STGB128(kn2, &LB[buf][0]); STGB64(kn2, &LB[buf][0] + 128 * 64); \
                       WAITVM(3); } \
    else             { WAITVM(0); } \
    BARRAW; PRIO1; MM2B; PRIO0; BARRAW; \
  } while(0)

  // prologue: A(0) 4 loads, B(0) 3, B(1) 3; WAITVM(3) retires A0,B0, keeps B1
  STGA(brow,       0, &LA[0][0]);
  STGA(brow + 128, 0, &LA[0][0] + 128 * 64);
  STGB128(0,  &LB[0][0]);
  STGB64(0,   &LB[0][0] + 128 * 64);
  STGB128(64, &LB[1][0]);
  STGB64(64,  &LB[1][0] + 128 * 64);
  WAITVM(3);
  BARRAW;

  for (int t = 0; t < NT; t += 2){
    TILE(t, 0);
    TILE(t + 1, 1);
  }
#undef TILE
#undef BPTR
#undef STGA
#undef STGB128
#undef STGB64
#undef RDA
#undef RDA2
#undef RDB2
#undef RDB1
#undef MM2A
#undef MM1AB
#undef MM2B

#pragma unroll
  for (int mi = 0; mi < 8; ++mi)
#pragma unroll
    for (int ni = 0; ni < 3; ++ni){
      int colbase = bcol + wn * 48 + ni * 16;      // 2048-boundary is 16-aligned
      int proj = colbase >> 11;
      u16* Cb = proj == 0 ? C0 : proj == 1 ? C1 : C2;
      int lc = (colbase & 2047) + c15;
#pragma unroll
      for (int r = 0; r < 4; ++r){
        int row = brow + wm * 128 + mi * 16 + g * 4 + r;
        Cb[(size_t)row * 2048 + lc] = f2bf(acc[mi][ni][r]);
      }
    }
}

// ---------------- output GEMM: 128x128 tile, BK=64, 8 waves, counted vmcnt ----------------
// grid (16,16) = 256 blocks, 512 thr = 2 waves/SIMD
__global__ __launch_bounds__(512)
void k_gemm_out(const u16* __restrict__ A, const u16* __restrict__ B, float* __restrict__ C){
  __shared__ __align__(16) u16 As[2][128 * 64];
  __shared__ __align__(16) u16 Bs[2][128 * 64];
  const int tid = threadIdx.x;
  const int w = tid >> 6, lane = tid & 63;
  const int wm = w >> 1, wn = w & 1;
  const int g = lane >> 4, c15 = lane & 15;
  const int brow = blockIdx.y * 128, bcol = blockIdx.x * 128;
  const int cc0 = ((g ^ (c15 & 7)) * 8);

  f32x4 acc[2][4];
#pragma unroll
  for (int m = 0; m < 2; m++)
#pragma unroll
    for (int n = 0; n < 4; n++) acc[m][n] = (f32x4){0.f, 0.f, 0.f, 0.f};

#define STG_O(k0, buf) do { \
  _Pragma("unroll") for (int it = 0; it < 2; ++it){ \
    int m_ = it * 512 + tid; \
    int row_ = m_ >> 3, cp_ = m_ & 7; \
    gload16(A + (size_t)(brow + row_) * 2048 + (k0) + ((cp_ ^ (row_ & 7)) * 8), \
            As[buf] + (it * 512 + (tid & ~63)) * 8); \
    gload16(B + (size_t)(bcol + row_) * 2048 + (k0) + ((cp_ ^ (row_ & 7)) * 8), \
            Bs[buf] + (it * 512 + (tid & ~63)) * 8); \
  } } while(0)

  STG_O(0, 0);
  int cur = 0;
  for (int kt = 0; kt < 32; ++kt){
    if (kt + 1 < 32){ STG_O((kt + 1) * 64, cur ^ 1); WAITVM(4); }
    else            { WAITVM(0); }
    BARRAW;
    bf16x8 af[2][2], bfr[4][2];
#pragma unroll
    for (int mi = 0; mi < 2; ++mi){
      const u16* pr = As[cur] + (size_t)(wm * 32 + mi * 16 + c15) * 64;
      af[mi][0] = *(const bf16x8*)(pr + cc0);
      af[mi][1] = *(const bf16x8*)(pr + (cc0 ^ 32));
    }
#pragma unroll
    for (int ni = 0; ni < 4; ++ni){
      const u16* pr = Bs[cur] + (size_t)(wn * 64 + ni * 16 + c15) * 64;
      bfr[ni][0] = *(const bf16x8*)(pr + cc0);
      bfr[ni][1] = *(const bf16x8*)(pr + (cc0 ^ 32));
    }
    PRIO1;
#pragma unroll
    for (int mi = 0; mi < 2; ++mi)
#pragma unroll
      for (int ni = 0; ni < 4; ++ni)
#pragma unroll
        for (int kk = 0; kk < 2; ++kk)
          acc[mi][ni] = __builtin_amdgcn_mfma_f32_16x16x32_bf16(af[mi][kk], bfr[ni][kk],
                                                                acc[mi][ni], 0, 0, 0);
    PRIO0;
    BARRAW;
    cur ^= 1;
  }
#undef STG_O
#pragma unroll
  for (int mi = 0; mi < 2; ++mi)
#pragma unroll
    for (int ni = 0; ni < 4; ++ni)
#pragma unroll
      for (int r = 0; r < 4; ++r){
        int row = brow + wm * 32 + mi * 16 + g * 4 + r;
        int col = bcol + wn * 64 + ni * 16 + c15;
        C[(size_t)row * 2048 + col] = acc[mi][ni][r];
      }
}

// ---------------- pass 1a: rowsum of exp (causal), Q-in-registers ----------------
// grid (40, 16), 256 thr (4 waves x 32 q-rows); K 64x128 LDS dbuf, counted vmcnt.
__global__ __launch_bounds__(256)
void k_pass1a(const u16* __restrict__ Q, const u16* __restrict__ K, float* __restrict__ rowsum){
  __shared__ __align__(16) u16 Ks[2][64 * 128];
  const int tid = threadIdx.x;
  const int wv = tid >> 6, lane = tid & 63;
  const int g = lane >> 4, c15 = lane & 15;
  const int h = blockIdx.y;
  int qb = 0, c = 0;
  { int rem = blockIdx.x; int q = 0;
    while (rem >= ((2 * q + 9) >> 3)){ rem -= (2 * q + 9) >> 3; q++; }
    qb = q; c = rem; }
  const int i0 = qb * 128;
  const int ktend = 2 * qb + 2;
  const int kt0 = c * 8;
  const int kt1 = (ktend < kt0 + 8) ? ktend : (kt0 + 8);
  const u16* Qh = Q + h * HDIM;
  const u16* Kh = K + h * HDIM;
  const float scale = 0.08838834764831845f;   // 1/sqrt(128)
  const int wb = wv * 32;

  bf16x8 qfr[2][4];
#pragma unroll
  for (int m = 0; m < 2; m++)
#pragma unroll
    for (int ks = 0; ks < 4; ks++)
      qfr[m][ks] = *(const bf16x8*)(Qh + (size_t)(i0 + wb + m * 16 + c15) * 2048 + ks * 32 + g * 8);

  stage_tile(Kh, 2048, kt0 * 64, Ks[0], tid);

  float rs[2][4] = {{0.f,0.f,0.f,0.f},{0.f,0.f,0.f,0.f}};
  int cur = 0;
  for (int kt = kt0; kt < kt1; ++kt){
    if (kt + 1 < kt1){ stage_tile(Kh, 2048, (kt + 1) * 64, Ks[cur ^ 1], tid); WAITVM(4); }
    else             { WAITVM(0); }
    BARRAW;
    const int k0 = kt * 64;
    f32x4 sacc[2][4];
#pragma unroll
    for (int m = 0; m < 2; m++)
#pragma unroll
      for (int n = 0; n < 4; n++) sacc[m][n] = (f32x4){0.f, 0.f, 0.f, 0.f};
#pragma unroll
    for (int ks = 0; ks < 4; ++ks){
#pragma unroll
      for (int n = 0; n < 4; n++){
        int brw = n * 16 + c15;
        bf16x8 b = *(const bf16x8*)(Ks[cur] + brw * 128 + ((ks * 32 + g * 8) ^ ((brw & 7) << 3)));
#pragma unroll
        for (int m = 0; m < 2; m++)
          sacc[m][n] = __builtin_amdgcn_mfma_f32_16x16x32_bf16(qfr[m][ks], b, sacc[m][n], 0, 0, 0);
      }
    }
    if (kt < 2 * qb){            // fully causal tile: no mask compare
#pragma unroll
      for (int m = 0; m < 2; m++)
#pragma unroll
        for (int n = 0; n < 4; n++)
#pragma unroll
          for (int r = 0; r < 4; r++)
            rs[m][r] += __expf(sacc[m][n][r] * scale);
    } else {
#pragma unroll
      for (int n = 0; n < 4; n++){
        int col = k0 + n * 16 + c15;
#pragma unroll
        for (int m = 0; m < 2; m++)
#pragma unroll
          for (int r = 0; r < 4; r++){
            int rowg = i0 + wb + m * 16 + g * 4 + r;
            rs[m][r] += (col <= rowg) ? __expf(sacc[m][n][r] * scale) : 0.f;
          }
      }
    }
    BARRAW;
    cur ^= 1;
  }
#pragma unroll
  for (int m = 0; m < 2; m++)
#pragma unroll
    for (int r = 0; r < 4; r++){
      float v = rs[m][r];
      v += __shfl_xor(v, 1); v += __shfl_xor(v, 2);
      v += __shfl_xor(v, 4); v += __shfl_xor(v, 8);
      if (c15 == 0)
        atomicAdd(&rowsum[h * 2048 + i0 + wb + m * 16 + g * 4 + r], v);
    }
}

// ---------------- pass 1b: colsum of normalized exp, K-in-registers ----------------
// grid (40, 16), 256 thr (4 waves x 32 k-rows); Q 64x128 LDS dbuf, counted vmcnt.
__global__ __launch_bounds__(256)
void k_pass1b(const u16* __restrict__ Q, const u16* __restrict__ K,
              const float* __restrict__ rowsum, float* __restrict__ colsum){
  __shared__ __align__(16) u16 Qs[2][64 * 128];
  const int tid = threadIdx.x;
  const int wv = tid >> 6, lane = tid & 63;
  const int g = lane >> 4, c15 = lane & 15;
  const int h = blockIdx.y;
  int kb = 0, c = 0;
  { int rem = blockIdx.x; int q = 0;
    while (rem >= ((39 - 2 * q) >> 3)){ rem -= (39 - 2 * q) >> 3; q++; }
    kb = q; c = rem; }
  const int k0 = kb * 128;
  const int qt0 = 2 * kb + c * 8;
  const int qt1 = (2 * kb + c * 8 + 8 < 32) ? (2 * kb + c * 8 + 8) : 32;
  const u16* Qh = Q + h * HDIM;
  const u16* Kh = K + h * HDIM;
  const float scale = 0.08838834764831845f;
  const int wb = wv * 32;
  const float* rsrow = rowsum + h * 2048;

  bf16x8 kfr[2][4];
#pragma unroll
  for (int m = 0; m < 2; m++)
#pragma unroll
    for (int ks = 0; ks < 4; ks++)
      kfr[m][ks] = *(const bf16x8*)(Kh + (size_t)(k0 + wb + m * 16 + c15) * 2048 + ks * 32 + g * 8);

  stage_tile(Qh, 2048, qt0 * 64, Qs[0], tid);

  float racc[2][4] = {{0.f,0.f,0.f,0.f},{0.f,0.f,0.f,0.f}};
  int cur = 0;
  for (int qt = qt0; qt < qt1; ++qt){
    if (qt + 1 < qt1){ stage_tile(Qh, 2048, (qt + 1) * 64, Qs[cur ^ 1], tid); WAITVM(4); }
    else             { WAITVM(0); }
    BARRAW;
    const int i0q = qt * 64;
    float rw[4];
#pragma unroll
    for (int n = 0; n < 4; n++)
      rw[n] = 1.0f / rsrow[i0q + n * 16 + c15];
    f32x4 sacc[2][4];
#pragma unroll
    for (int m = 0; m < 2; m++)
#pragma unroll
      for (int n = 0; n < 4; n++) sacc[m][n] = (f32x4){0.f, 0.f, 0.f, 0.f};
#pragma unroll
    for (int ks = 0; ks < 4; ++ks){
#pragma unroll
      for (int n = 0; n < 4; n++){
        int brw = n * 16 + c15;
        bf16x8 b = *(const bf16x8*)(Qs[cur] + brw * 128 + ((ks * 32 + g * 8) ^ ((brw & 7) << 3)));
#pragma unroll
        for (int m = 0; m < 2; m++)
          sacc[m][n] = __builtin_amdgcn_mfma_f32_16x16x32_bf16(kfr[m][ks], b, sacc[m][n], 0, 0, 0);
      }
    }
    if (qt >= 2 * kb + 2){       // fully causal: no mask compare
#pragma unroll
      for (int m = 0; m < 2; m++)
#pragma unroll
        for (int n = 0; n < 4; n++)
#pragma unroll
          for (int r = 0; r < 4; r++)
            racc[m][r] += __expf(sacc[m][n][r] * scale) * rw[n];
    } else {
#pragma unroll
      for (int n = 0; n < 4; n++){
        int colq = i0q + n * 16 + c15;
#pragma unroll
        for (int m = 0; m < 2; m++)
#pragma unroll
          for (int r = 0; r < 4; r++){
            int rowk = k0 + wb + m * 16 + g * 4 + r;
            racc[m][r] += (rowk <= colq) ? __expf(sacc[m][n][r] * scale) * rw[n] : 0.f;
          }
      }
    }
    BARRAW;
    cur ^= 1;
  }
#pragma unroll
  for (int m = 0; m < 2; m++)
#pragma unroll
    for (int r = 0; r < 4; r++){
      float v = racc[m][r];
      v += __shfl_xor(v, 1); v += __shfl_xor(v, 2);
      v += __shfl_xor(v, 4); v += __shfl_xor(v, 8);
      if (c15 == 0)
        atomicAdd(&colsum[h * 2048 + k0 + wb + m * 16 + g * 4 + r], v);
    }
}

// ---------------- top-k via exact radix-select (select only, 16 blocks) ----------------
__global__ __launch_bounds__(1024)
void k_topk(const float* __restrict__ colsum, short* __restrict__ cidx){
  __shared__ u32 keys[2048];
  __shared__ int hist[256];
  __shared__ int chunkCnt[32];
  __shared__ short cidL[256];
  __shared__ u32 Tacc_s;
  __shared__ int rem_s;
  const int tid = threadIdx.x;
  const int h = blockIdx.x;
  const int w = tid >> 6, lane = tid & 63;

  for (int i = tid; i < 2048; i += 1024) keys[i] = ((const u32*)colsum)[h * 2048 + i];
  if (tid == 0){ Tacc_s = 0; rem_s = HEAVY; }
  __syncthreads();

  for (int s = 24; s >= 0; s -= 8){
    if (tid < 256) hist[tid] = 0;
    __syncthreads();
    u32 T = Tacc_s;
    for (int i = tid; i < 2048; i += 1024){
      u32 k = keys[i];
      bool match = (s == 24) ? true : (((k ^ T) >> (s + 8)) == 0);
      if (match) atomicAdd(&hist[(k >> s) & 255], 1);
    }
    __syncthreads();
    if (tid == 0){
      int rem = rem_s, acc = 0, b = 255;
      for (; b > 0; --b){
        int c2 = hist[b];
        if (acc + c2 >= rem) break;
        acc += c2;
      }
      Tacc_s = T | ((u32)b << s);
      rem_s = rem - acc;
    }
    __syncthreads();
  }
  const u32 T = Tacc_s;
  const int need = rem_s;                 // smallest-index ties among == T
  const u32 kA = keys[tid], kB = keys[tid + 1024];
  const bool eqA = (kA == T), eqB = (kB == T);
  unsigned long long ebA = __ballot(eqA);
  unsigned long long ebB = __ballot(eqB);
  if (lane == 0){ chunkCnt[w] = __popcll(ebA); chunkCnt[16 + w] = __popcll(ebB); }
  __syncthreads();
  if (tid == 0){
    int s2 = 0;
    for (int i2 = 0; i2 < 32; ++i2){ int c2 = chunkCnt[i2]; chunkCnt[i2] = s2; s2 += c2; }
  }
  __syncthreads();
  const unsigned long long below = (1ull << lane) - 1ull;
  const int eqrA = chunkCnt[w] + __popcll(ebA & below);
  const int eqrB = chunkCnt[16 + w] + __popcll(ebB & below);
  const bool hvA = (kA > T) || (eqA && eqrA < need);
  const bool hvB = (kB > T) || (eqB && eqrB < need);
  __syncthreads();                        // before reusing chunkCnt
  unsigned long long hbA = __ballot(hvA);
  unsigned long long hbB = __ballot(hvB);
  if (lane == 0){ chunkCnt[w] = __popcll(hbA); chunkCnt[16 + w] = __popcll(hbB); }
  if (tid >= HEAVY && tid < 256) cidL[tid] = 32767;
  __syncthreads();
  if (tid == 0){
    int s2 = 0;
    for (int i2 = 0; i2 < 32; ++i2){ int c2 = chunkCnt[i2]; chunkCnt[i2] = s2; s2 += c2; }
  }
  __syncthreads();
  if (hvA) cidL[chunkCnt[w] + __popcll(hbA & below)] = (short)tid;
  if (hvB) cidL[chunkCnt[16 + w] + __popcll(hbB & below)] = (short)(tid + 1024);
  __syncthreads();
  if (tid < 256) cidx[h * 256 + tid] = cidL[tid];
}

// ---------------- gather heavy K rows + V cols (full-grid, 384 blocks) ----------------
__global__ void k_gath(const u16* __restrict__ Kb, const u16* __restrict__ Vb,
                       const short* __restrict__ cidx,
                       u16* __restrict__ Kg, u16* __restrict__ Vg){
  __shared__ __align__(16) u16 t[32][136];
  int b = blockIdx.x, tid = threadIdx.x;
  if (b < 256){
    int gid = b * 256 + tid;                   // 16h * 256slot * 16chunk = 65536
    int h = gid >> 12, rem = gid & 4095;
    int slot = rem >> 4, cp = rem & 15;
    int cid = cidx[h * 256 + slot];
    bf16x8 z = (bf16x8){0,0,0,0,0,0,0,0};
    bf16x8 val = (cid < 2048) ? *(const bf16x8*)(Kb + (size_t)cid * 2048 + h * 128 + cp * 8) : z;
    *(bf16x8*)(Kg + ((size_t)h * 256 + slot) * 128 + cp * 8) = val;
  } else {
    int b2 = b - 256;
    int h = b2 >> 3, s0 = (b2 & 7) * 32;
#pragma unroll
    for (int it = 0; it < 2; ++it){
      int m = it * 256 + tid;                  // 512 chunks = 32 slots x 16 chunks
      int s = m >> 4, cp = m & 15;
      int cid = cidx[h * 256 + s0 + s];
      bf16x8 z = (bf16x8){0,0,0,0,0,0,0,0};
      bf16x8 val = (cid < 2048) ? *(const bf16x8*)(Vb + (size_t)cid * 2048 + h * 128 + cp * 8) : z;
      *(bf16x8*)(&t[s][cp * 8]) = val;
    }
    __syncthreads();
#pragma unroll
    for (int i = 0; i < 16; ++i){
      int idx = i * 256 + tid;                 // 4096 = 128 d x 32 s
      int d = idx >> 5, s = idx & 31;
      Vg[((size_t)h * 128 + d) * 256 + s0 + s] = t[s][d];
    }
  }
}

// ---------------- pass 2: QBLK=128, Q-in-reg, K+V LDS dbuf, counted vmcnt ----------------
// grid (16, 16) = 256 blocks, 512 thr (8 waves: 2 q-halves x 4 strips)
__global__ __launch_bounds__(512)
void k_pass2(const u16* __restrict__ Q, const u16* __restrict__ K, const u16* __restrict__ Vt,
             const u16* __restrict__ Kg, const u16* __restrict__ Vg,
             const short* __restrict__ cidx, u16* __restrict__ attn){
  __shared__ __align__(16) u16 Ks[2][64 * 128];
  __shared__ __align__(16) u16 Vs[2][128 * 64];
  __shared__ __align__(16) u16 Ps[8][16 * 64];
  __shared__ short cids[256];
  __shared__ int lists[12];
  __shared__ int nact_s;
  const int tid = threadIdx.x;
  const int w = tid >> 6, lane = tid & 63;
  const int g = lane >> 4, c15 = lane & 15;
  const int qb = blockIdx.x, h = blockIdx.y;
  const int i0 = qb * 128;
  const int wq = w >> 2, w4 = w & 3;
  const int rowbase = i0 + wq * 64 + w4 * 16;
  const u16* Qh = Q + h * HDIM;
  const u16* Kh = K + h * HDIM;
  const u16* Kgh = Kg + (size_t)h * 256 * 128;
  const u16* Vth = Vt + (size_t)h * 128 * 2048;
  const u16* Vgh = Vg + (size_t)h * 128 * 256;
  const float scale = 0.08838834764831845f;

  if (tid < 256) cids[tid] = cidx[h * 256 + tid];
  // Q fragments in registers (rows rowbase + c15)
  bf16x8 qfr[4];
#pragma unroll
  for (int ks = 0; ks < 4; ks++)
    qfr[ks] = *(const bf16x8*)(Qh + (size_t)(rowbase + c15) * 2048 + ks * 32 + g * 8);
  __syncthreads();
  if (tid == 0){
    int n = 0;
    int ktb0 = (i0 > RECENT) ? ((i0 - RECENT) >> 6) : 0;
    int ktmax = (i0 + 127) >> 6;
    for (int kt = ktb0; kt <= ktmax; ++kt) lists[n++] = kt;
    for (int gt = 0; gt < 4; ++gt)
      if ((int)cids[gt * 64] <= i0 + 127 - RECENT - 1) lists[n++] = 100 + gt;
    nact_s = n;
  }
  __syncthreads();
  const int nact = nact_s;

  // prologue: K0 (2) + V0 (2); WAITVM(2) retires K0, keeps V0
  { int e = lists[0];
    if (e < 100){ stageK512(Kh, 2048, e * 64, Ks[0], tid);
                  stageV512(Vth, 2048, e * 64, Vs[0], tid); }
    else        { stageK512(Kgh, 128, (e - 100) * 64, Ks[0], tid);
                  stageV512(Vgh, 256, (e - 100) * 64, Vs[0], tid); } }
  WAITVM(2);
  BARRAW;

  f32x4 oacc[8];
#pragma unroll
  for (int f = 0; f < 8; f++) oacc[f] = (f32x4){0.f, 0.f, 0.f, 0.f};
  float lsum[4] = {0.f, 0.f, 0.f, 0.f};

  int cur = 0;
  for (int i = 0; i < nact; ++i){
    const int e = lists[i];
    const bool isg = (e >= 100);
    const bool nxt = (i + 1 < nact);
    if (nxt){
      int e2 = lists[i + 1];
      if (e2 < 100){ stageK512(Kh, 2048, e2 * 64, Ks[cur ^ 1], tid);
                     stageV512(Vth, 2048, e2 * 64, Vs[cur ^ 1], tid); }
      else         { stageK512(Kgh, 128, (e2 - 100) * 64, Ks[cur ^ 1], tid);
                     stageV512(Vgh, 256, (e2 - 100) * 64, Vs[cur ^ 1], tid); }
      WAITVM(6);               // retire K(i); keep V(i)+K(i+1)+V(i+1)
    } else {
      WAITVM(2);               // retire K(last); keep V(last)
    }
    BARRAW;
    // QK^T
    f32x4 sacc[4];
#pragma unroll
    for (int n = 0; n < 4; n++) sacc[n] = (f32x4){0.f, 0.f, 0.f, 0.f};
#pragma unroll
    for (int ks = 0; ks < 4; ++ks){
#pragma unroll
      for (int n = 0; n < 4; n++){
        int brw = n * 16 + c15;
        bf16x8 b = *(const bf16x8*)(Ks[cur] + brw * 128 + ((ks * 32 + g * 8) ^ ((brw & 7) << 3)));
        sacc[n] = __builtin_amdgcn_mfma_f32_16x16x32_bf16(qfr[ks], b, sacc[n], 0, 0, 0);
      }
    }
    // masked exp -> P (LDS, wave-private), row sums
#pragma unroll
    for (int n = 0; n < 4; n++){
      int cid = isg ? (int)cids[(e - 100) * 64 + n * 16 + c15] : (e * 64 + n * 16 + c15);
#pragma unroll
      for (int r = 0; r < 4; r++){
        int rowg = rowbase + g * 4 + r;
        int dist = rowg - cid;
        bool valid = (cid <= rowg) && (isg ? (dist > RECENT) : (dist <= RECENT));
        float ev = valid ? __expf(sacc[n][r] * scale) : 0.f;
        lsum[r] += ev;
        int prow = g * 4 + r;
        Ps[w][prow * 64 + ((n * 16 + c15) ^ ((prow & 7) << 3))] = f2bf(ev);
      }
    }
    // retire V(i) under the exp phase, then PV from LDS
    if (nxt) WAITVM(4); else WAITVM(0);
    BARRAW;
    PRIO1;
#pragma unroll
    for (int ks2 = 0; ks2 < 2; ++ks2){
      bf16x8 pa = *(const bf16x8*)(&Ps[w][c15 * 64 + ((ks2 * 32 + g * 8) ^ ((c15 & 7) << 3))]);
#pragma unroll
      for (int f = 0; f < 8; ++f){
        int vrow = f * 16 + c15;
        bf16x8 vb = *(const bf16x8*)(Vs[cur] + vrow * 64 + ((ks2 * 32 + g * 8) ^ ((vrow & 7) << 3)));
        oacc[f] = __builtin_amdgcn_mfma_f32_16x16x32_bf16(pa, vb, oacc[f], 0, 0, 0);
      }
    }
    PRIO0;
    BARRAW;
    cur ^= 1;
  }
  float rinv[4];
#pragma unroll
  for (int r = 0; r < 4; r++){
    float v = lsum[r];
    v += __shfl_xor(v, 1); v += __shfl_xor(v, 2);
    v += __shfl_xor(v, 4); v += __shfl_xor(v, 8);
    rinv[r] = 1.0f / v;
  }
#pragma unroll
  for (int f = 0; f < 8; f++)
#pragma unroll
    for (int r = 0; r < 4; r++){
      int rowg = rowbase + g * 4 + r;
      attn[(size_t)rowg * 2048 + h * HDIM + f * 16 + c15] = f2bf(oacc[f][r] * rinv[r]);
    }
}

// ---------------- host launcher ----------------
extern "C" void kernel_launch(void* const* d_in, const int* in_sizes, int n_in,
                              void* d_out, int out_size, void* d_ws, size_t ws_size,
                              hipStream_t stream){
  const float* X  = (const float*)d_in[0];
  const float* Wq = (const float*)d_in[1];
  const float* Wk = (const float*)d_in[2];
  const float* Wv = (const float*)d_in[3];
  const float* Wo = (const float*)d_in[4];

  char* w = (char*)d_ws;
  const size_t MB8 = (size_t)2048 * 2048 * 2;   // one bf16 matrix = 8 MiB
  u16* Xb  = (u16*)(w);
  u16* Wqb = (u16*)(w + 1 * MB8);
  u16* Wkb = (u16*)(w + 2 * MB8);
  u16* Wvb = (u16*)(w + 3 * MB8);
  u16* Wob = (u16*)(w + 4 * MB8);
  u16* Qb  = (u16*)(w + 5 * MB8);
  u16* Kb  = (u16*)(w + 6 * MB8);
  u16* Vb  = (u16*)(w + 7 * MB8);
  u16* Vtb   = Wqb;   // Wq dead after projections
  u16* attnb = Xb;    // X dead after projections
  char* p = w + 8 * MB8;
  float* cosT = (float*)p;              p += 524288;
  float* sinT = (float*)p;              p += 524288;
  float* colsum = (float*)p;            p += 131072;   // zeroed in k_prep (with rowsum)
  float* rowsum = (float*)p;            p += 131072;
  short* cidx  = (short*)p;             p += 16 * 256 * 2;
  u16*   Kg    = (u16*)p;               p += (size_t)16 * 256 * 128 * 2;
  u16*   Vg    = (u16*)p;

  dim3 b256(256);

  k_prep<<<21056, b256, 0, stream>>>(X, Wq, Wk, Wv, Wo, Xb, cosT, sinT, colsum);

  k_g256<<<dim3(32, 8), dim3(512), 0, stream>>>(Xb, Wqb, Wkb, Wvb, Qb, Kb, Vb);
  k_post<<<8192, b256, 0, stream>>>(Qb, Kb, cosT, sinT, Vb, Vtb);

  k_pass1a<<<dim3(40, 16), b256, 0, stream>>>(Qb, Kb, rowsum);
  k_pass1b<<<dim3(40, 16), b256, 0, stream>>>(Qb, Kb, rowsum, colsum);
  k_topk<<<16, dim3(1024), 0, stream>>>(colsum, cidx);
  k_gath<<<384, b256, 0, stream>>>(Kb, Vb, cidx, Kg, Vg);
  k_pass2<<<dim3(16, 16), dim3(512), 0, stream>>>(Qb, Kb, Vtb, Kg, Vg, cidx, attnb);

  k_gemm_out<<<dim3(16, 16), dim3(512), 0, stream>>>(attnb, Wob, (float*)d_out);
}

// Round 11
// 239.233 us; speedup vs baseline: 1.6872x; 1.0159x over previous
//
#include <hip/hip_runtime.h>
#include <hip/hip_bf16.h>
#include <stdint.h>

// Problem constants: b=1, s=2048, hidden=2048, H=16, d=128
#define SEQ   2048
#define HIDN  2048
#define NHEAD 16
#define HDIM  128
#define HEAVY 204   // int(0.1*2048)
#define RECENT 204

typedef __attribute__((ext_vector_type(4))) float f32x4;
typedef __attribute__((ext_vector_type(8))) short bf16x8;
typedef unsigned short u16;
typedef unsigned int   u32;

static __device__ __forceinline__ u16 f2bf(float f){
  union { float f; u32 u; } v; v.f = f;
  u32 r = (v.u + 0x7FFFu + ((v.u >> 16) & 1u)) >> 16;
  return (u16)r;
}
static __device__ __forceinline__ float bf2f(u16 u){
  union { u32 u; float f; } v; v.u = ((u32)u) << 16;
  return v.f;
}

// global -> LDS direct 16B load (dest is wave-uniform base + lane*16)
static __device__ __forceinline__ void gload16(const void* g, void* l){
  __builtin_amdgcn_global_load_lds((const __attribute__((address_space(1))) u32*)g,
                                   (__attribute__((address_space(3))) u32*)l, 16, 0, 0);
}

#define WAITVM(N) asm volatile("s_waitcnt vmcnt(" #N ")" ::: "memory")
#define BARRAW    __builtin_amdgcn_s_barrier()
#define PRIO1     __builtin_amdgcn_s_setprio(1)
#define PRIO0     __builtin_amdgcn_s_setprio(0)

// stage a 64x128 bf16 tile with 256 threads, runtime row stride (XOR-swizzled source)
static __device__ __forceinline__ void stage_tile(const u16* __restrict__ base, size_t stride,
                                                  int row0, u16* __restrict__ lds, int tid){
  const int wbase = tid & ~63;
#pragma unroll
  for (int it = 0; it < 4; ++it){
    int m = it * 256 + tid;
    int row = m >> 4, cp = m & 15;
    gload16(base + (size_t)(row0 + row) * stride + ((cp ^ (row & 7)) * 8),
            lds + (it * 256 + wbase) * 8);
  }
}

// stage 64x128 tile with 512 threads, runtime stride
static __device__ __forceinline__ void stageK512(const u16* __restrict__ base, size_t stride,
                                                 int row0, u16* __restrict__ lds, int tid){
#pragma unroll
  for (int it = 0; it < 2; ++it){
    int m = it * 512 + tid;
    int row = m >> 4, cp = m & 15;
    gload16(base + (size_t)(row0 + row) * stride + ((cp ^ (row & 7)) * 8),
            lds + (it * 512 + (tid & ~63)) * 8);
  }
}
// stage 128-row x 64-col tile (col offset c0) with 512 threads, runtime stride
static __device__ __forceinline__ void stageV512(const u16* __restrict__ base, size_t stride,
                                                 int c0, u16* __restrict__ lds, int tid){
#pragma unroll
  for (int it = 0; it < 2; ++it){
    int m = it * 512 + tid;
    int row = m >> 3, cp = m & 7;
    gload16(base + (size_t)row * stride + c0 + ((cp ^ (row & 7)) * 8),
            lds + (it * 512 + (tid & ~63)) * 8);
  }
}

// ---------------- prep: cvt5 + rope tables + zero colsum/rowsum (fused) ----------------
__global__ void k_prep(const float* __restrict__ A0, const float* __restrict__ A1,
                       const float* __restrict__ A2, const float* __restrict__ A3,
                       const float* __restrict__ A4, u16* __restrict__ out,
                       float* __restrict__ cosT, float* __restrict__ sinT,
                       float* __restrict__ colsum){
  int b = blockIdx.x, tid = threadIdx.x;
  if (b < 20480){
    int id = b * 256 + tid;
    int sel = id >> 20, off = (id & 1048575) * 4;
    const float* src = sel == 0 ? A0 : sel == 1 ? A1 : sel == 2 ? A2 : sel == 3 ? A3 : A4;
    float4 v = *(const float4*)(src + off);
    ushort4 o;
    o.x = f2bf(v.x); o.y = f2bf(v.y); o.z = f2bf(v.z); o.w = f2bf(v.w);
    *(ushort4*)(out + (size_t)sel * 4194304 + off) = o;
  } else if (b < 20992){
    int i = (b - 20480) * 256 + tid;           // 2048*64
    int pos = i >> 6, j = i & 63;
    float invf = powf(10000.0f, -(float)j * (1.0f / 64.0f));
    float a = (float)pos * invf;
    cosT[i] = cosf(a);
    sinT[i] = sinf(a);
  } else {
    int i = (b - 20992) * 256 + tid;           // 16384 float4 = colsum+rowsum (contiguous)
    if (i < 16384) ((float4*)colsum)[i] = (float4){0.f, 0.f, 0.f, 0.f};
  }
}

// ---------------- post: rope on Q,K + transpose V (fused) ----------------
__global__ void k_post(u16* __restrict__ Qm, u16* __restrict__ Km,
                       const float* __restrict__ cosT, const float* __restrict__ sinT,
                       const u16* __restrict__ V, u16* __restrict__ Vt){
  __shared__ u16 t[32][33];
  int b = blockIdx.x, tid = threadIdx.x;
  if (b < 4096){
    int gid = b * 256 + tid;                   // 2 * 524288
    u16* M = (gid < 524288) ? Qm : Km;
    int id = gid & 524287;
    int pos = id >> 8, rem = id & 255;
    int h = rem >> 4, j4 = (rem & 15) * 4;
    u16* p = M + (size_t)pos * HIDN + h * HDIM + j4;
    ushort4 lo = *(ushort4*)p;
    ushort4 hi = *(ushort4*)(p + 64);
    float4 c = *(const float4*)(cosT + pos * 64 + j4);
    float4 s = *(const float4*)(sinT + pos * 64 + j4);
    float l0 = bf2f(lo.x), l1 = bf2f(lo.y), l2 = bf2f(lo.z), l3 = bf2f(lo.w);
    float h0 = bf2f(hi.x), h1 = bf2f(hi.y), h2 = bf2f(hi.z), h3 = bf2f(hi.w);
    ushort4 nlo, nhi;
    nlo.x = f2bf(l0 * c.x - h0 * s.x);  nhi.x = f2bf(h0 * c.x + l0 * s.x);
    nlo.y = f2bf(l1 * c.y - h1 * s.y);  nhi.y = f2bf(h1 * c.y + l1 * s.y);
    nlo.z = f2bf(l2 * c.z - h2 * s.z);  nhi.z = f2bf(h2 * c.z + l2 * s.z);
    nlo.w = f2bf(l3 * c.w - h3 * s.w);  nhi.w = f2bf(h3 * c.w + l3 * s.w);
    *(ushort4*)p = nlo;
    *(ushort4*)(p + 64) = nhi;
  } else {
    int b2 = b - 4096;
    int s0 = (b2 & 63) * 32, c0 = (b2 >> 6) * 32;
    int r = tid >> 3, cc = (tid & 7) * 4;
    ushort4 v = *(const ushort4*)(V + (size_t)(s0 + r) * 2048 + c0 + cc);
    t[r][cc] = v.x; t[r][cc + 1] = v.y; t[r][cc + 2] = v.z; t[r][cc + 3] = v.w;
    __syncthreads();
    int co = tid >> 3, ro = (tid & 7) * 4;
    ushort4 o;
    o.x = t[ro][co]; o.y = t[ro + 1][co]; o.z = t[ro + 2][co]; o.w = t[ro + 3][co];
    *(ushort4*)(Vt + (size_t)(c0 + co) * 2048 + s0 + ro) = o;
  }
}

// ---------------- fused projection GEMM: C[2048][6144] = X @ [Wq;Wk;Wv]^T ----------------
// 256x192 tile, BK=64, 8 waves, 2 barriers/tile (reads+MFMA overlap via compiler lgkmcnt),
// counted vmcnt. grid (32,8) = 256 blocks, full fill.
__global__ __launch_bounds__(512, 1)
void k_g256(const u16* __restrict__ X, const u16* __restrict__ Wq, const u16* __restrict__ Wk,
            const u16* __restrict__ Wv, u16* __restrict__ C0, u16* __restrict__ C1,
            u16* __restrict__ C2){
  __shared__ __align__(16) u16 LA[2][256 * 64];
  __shared__ __align__(16) u16 LB[2][192 * 64];
  const int tid = threadIdx.x;
  const int lane = tid & 63, wvi = tid >> 6;
  const int wm = wvi >> 2, wn = wvi & 3;
  const int g = lane >> 4, c15 = lane & 15;
  const int brow = blockIdx.y * 256;       // [0,2048)
  const int bcol = blockIdx.x * 192;       // [0,6144)
  const int NT = 32;

  f32x4 acc[8][3];
#pragma unroll
  for (int m = 0; m < 8; m++)
#pragma unroll
    for (int n = 0; n < 3; n++) acc[m][n] = (f32x4){0.f, 0.f, 0.f, 0.f};

  const int cc0 = ((g ^ (c15 & 7)) * 8);
  bf16x8 af[4][2], af2[4][2], bf[3][2];

#define BPTR(rB_) (rB_ < 2048 ? Wq + (size_t)(rB_) * 2048 \
                 : rB_ < 4096 ? Wk + (size_t)((rB_) - 2048) * 2048 \
                              : Wv + (size_t)((rB_) - 4096) * 2048)
#define STGA(grow0, gcol0, ldsb) do { \
  _Pragma("unroll") for (int it = 0; it < 2; ++it){ \
    int m_ = it * 512 + tid; \
    int row_ = m_ >> 3, cp_ = m_ & 7; \
    gload16(X + (size_t)((grow0) + row_) * 2048 + (gcol0) + ((cp_ ^ (row_ & 7)) * 8), \
            (ldsb) + (it * 512 + (tid & ~63)) * 8); \
  } } while(0)
#define STGB128(gcol0, ldsb) do { \
  _Pragma("unroll") for (int it = 0; it < 2; ++it){ \
    int m_ = it * 512 + tid; \
    int row_ = m_ >> 3, cp_ = m_ & 7; \
    int rB_ = bcol + row_; \
    const u16* bp_ = BPTR(rB_); \
    gload16(bp_ + (gcol0) + ((cp_ ^ (row_ & 7)) * 8), \
            (ldsb) + (it * 512 + (tid & ~63)) * 8); \
  } } while(0)
#define STGB64(gcol0, ldsb) do { \
    int row_ = 128 + (tid >> 3), cp_ = tid & 7; \
    int rB_ = bcol + row_; \
    const u16* bp_ = BPTR(rB_); \
    gload16(bp_ + (gcol0) + ((cp_ ^ (row_ & 7)) * 8), \
            (ldsb) + (tid & ~63) * 8); \
  } while(0)
#define RDA(buf) \
  _Pragma("unroll") for (int mi2 = 0; mi2 < 4; ++mi2){ \
    const u16* pr = &LA[buf][0] + (size_t)(wm * 128 + mi2 * 16 + c15) * 64; \
    af[mi2][0] = *(const bf16x8*)(pr + cc0); \
    af[mi2][1] = *(const bf16x8*)(pr + (cc0 ^ 32)); \
  }
#define RDA2(buf) \
  _Pragma("unroll") for (int mi2 = 0; mi2 < 4; ++mi2){ \
    const u16* pr = &LA[buf][0] + (size_t)(wm * 128 + (4 + mi2) * 16 + c15) * 64; \
    af2[mi2][0] = *(const bf16x8*)(pr + cc0); \
    af2[mi2][1] = *(const bf16x8*)(pr + (cc0 ^ 32)); \
  }
#define RDB2(buf) \
  _Pragma("unroll") for (int ni2 = 0; ni2 < 2; ++ni2){ \
    const u16* pr = &LB[buf][0] + (size_t)(wn * 48 + ni2 * 16 + c15) * 64; \
    bf[ni2][0] = *(const bf16x8*)(pr + cc0); \
    bf[ni2][1] = *(const bf16x8*)(pr + (cc0 ^ 32)); \
  }
#define RDB1(buf) do { \
    const u16* pr = &LB[buf][0] + (size_t)(wn * 48 + 32 + c15) * 64; \
    bf[2][0] = *(const bf16x8*)(pr + cc0); \
    bf[2][1] = *(const bf16x8*)(pr + (cc0 ^ 32)); \
  } while(0)
// MFMA clusters
#define MM2A \
  _Pragma("unroll") for (int mi2 = 0; mi2 < 4; ++mi2) \
  _Pragma("unroll") for (int ni2 = 0; ni2 < 2; ++ni2) \
  _Pragma("unroll") for (int kk = 0; kk < 2; ++kk) \
    acc[mi2][ni2] = __builtin_amdgcn_mfma_f32_16x16x32_bf16( \
        af[mi2][kk], bf[ni2][kk], acc[mi2][ni2], 0, 0, 0);
#define MM1AB \
  _Pragma("unroll") for (int mi2 = 0; mi2 < 4; ++mi2) \
  _Pragma("unroll") for (int kk = 0; kk < 2; ++kk){ \
    acc[mi2][2] = __builtin_amdgcn_mfma_f32_16x16x32_bf16( \
        af[mi2][kk], bf[2][kk], acc[mi2][2], 0, 0, 0); \
    acc[4 + mi2][2] = __builtin_amdgcn_mfma_f32_16x16x32_bf16( \
        af2[mi2][kk], bf[2][kk], acc[4 + mi2][2], 0, 0, 0); \
  }
#define MM2B \
  _Pragma("unroll") for (int mi2 = 0; mi2 < 4; ++mi2) \
  _Pragma("unroll") for (int ni2 = 0; ni2 < 2; ++ni2) \
  _Pragma("unroll") for (int kk = 0; kk < 2; ++kk) \
    acc[4 + mi2][ni2] = __builtin_amdgcn_mfma_f32_16x16x32_bf16( \
        af2[mi2][kk], bf[ni2][kk], acc[4 + mi2][ni2], 0, 0, 0);

// one tile = 2 barriers. Reads+STGA up front; barrier #1 after the 32-MFMA block
// (all LDS reads consumed => serviced); STGB into freed LB[buf] overlaps reg-only MM2B;
// WAITVM(3) retires STGA(t+1), keeps STGB(t+2) in flight across barrier #2.
#define TILE(t, buf) do { \
    const int kn1 = ((t) + 1) * 64; \
    const int kn2 = ((t) + 2) * 64; \
    RDA(buf); RDB2(buf); RDA2(buf); RDB1(buf); \
    if ((t) + 1 < NT){ STGA(brow, kn1, &LA[buf ^ 1][0]); \
                       STGA(brow + 128, kn1, &LA[buf ^ 1][0] + 128 * 64); } \
    PRIO1; MM2A; MM1AB; PRIO0; \
    BARRAW; \
    if ((t) + 2 < NT){ STGB128(kn2, &LB[buf][0]); STGB64(kn2, &LB[buf][0] + 128 * 64); } \
    PRIO1; MM2B; PRIO0; \
    if ((t) + 2 < NT){ WAITVM(3); } \
    else if ((t) + 1 < NT){ WAITVM(0); } \
    BARRAW; \
  } while(0)

  // prologue: A(0) 4 loads, B(0) 3, B(1) 3; WAITVM(3) retires A0,B0, keeps B1
  STGA(brow,       0, &LA[0][0]);
  STGA(brow + 128, 0, &LA[0][0] + 128 * 64);
  STGB128(0,  &LB[0][0]);
  STGB64(0,   &LB[0][0] + 128 * 64);
  STGB128(64, &LB[1][0]);
  STGB64(64,  &LB[1][0] + 128 * 64);
  WAITVM(3);
  BARRAW;

  for (int t = 0; t < NT; t += 2){
    TILE(t, 0);
    TILE(t + 1, 1);
  }
#undef TILE
#undef BPTR
#undef STGA
#undef STGB128
#undef STGB64
#undef RDA
#undef RDA2
#undef RDB2
#undef RDB1
#undef MM2A
#undef MM1AB
#undef MM2B

#pragma unroll
  for (int mi = 0; mi < 8; ++mi)
#pragma unroll
    for (int ni = 0; ni < 3; ++ni){
      int colbase = bcol + wn * 48 + ni * 16;      // 2048-boundary is 16-aligned
      int proj = colbase >> 11;
      u16* Cb = proj == 0 ? C0 : proj == 1 ? C1 : C2;
      int lc = (colbase & 2047) + c15;
#pragma unroll
      for (int r = 0; r < 4; ++r){
        int row = brow + wm * 128 + mi * 16 + g * 4 + r;
        Cb[(size_t)row * 2048 + lc] = f2bf(acc[mi][ni][r]);
      }
    }
}

// ---------------- output GEMM: 128x128 tile, BK=64, 8 waves, counted vmcnt ----------------
// grid (16,16) = 256 blocks, 512 thr = 2 waves/SIMD
__global__ __launch_bounds__(512)
void k_gemm_out(const u16* __restrict__ A, const u16* __restrict__ B, float* __restrict__ C){
  __shared__ __align__(16) u16 As[2][128 * 64];
  __shared__ __align__(16) u16 Bs[2][128 * 64];
  const int tid = threadIdx.x;
  const int w = tid >> 6, lane = tid & 63;
  const int wm = w >> 1, wn = w & 1;
  const int g = lane >> 4, c15 = lane & 15;
  const int brow = blockIdx.y * 128, bcol = blockIdx.x * 128;
  const int cc0 = ((g ^ (c15 & 7)) * 8);

  f32x4 acc[2][4];
#pragma unroll
  for (int m = 0; m < 2; m++)
#pragma unroll
    for (int n = 0; n < 4; n++) acc[m][n] = (f32x4){0.f, 0.f, 0.f, 0.f};

#define STG_O(k0, buf) do { \
  _Pragma("unroll") for (int it = 0; it < 2; ++it){ \
    int m_ = it * 512 + tid; \
    int row_ = m_ >> 3, cp_ = m_ & 7; \
    gload16(A + (size_t)(brow + row_) * 2048 + (k0) + ((cp_ ^ (row_ & 7)) * 8), \
            As[buf] + (it * 512 + (tid & ~63)) * 8); \
    gload16(B + (size_t)(bcol + row_) * 2048 + (k0) + ((cp_ ^ (row_ & 7)) * 8), \
            Bs[buf] + (it * 512 + (tid & ~63)) * 8); \
  } } while(0)

  STG_O(0, 0);
  int cur = 0;
  for (int kt = 0; kt < 32; ++kt){
    if (kt + 1 < 32){ STG_O((kt + 1) * 64, cur ^ 1); WAITVM(4); }
    else            { WAITVM(0); }
    BARRAW;
    bf16x8 af[2][2], bfr[4][2];
#pragma unroll
    for (int mi = 0; mi < 2; ++mi){
      const u16* pr = As[cur] + (size_t)(wm * 32 + mi * 16 + c15) * 64;
      af[mi][0] = *(const bf16x8*)(pr + cc0);
      af[mi][1] = *(const bf16x8*)(pr + (cc0 ^ 32));
    }
#pragma unroll
    for (int ni = 0; ni < 4; ++ni){
      const u16* pr = Bs[cur] + (size_t)(wn * 64 + ni * 16 + c15) * 64;
      bfr[ni][0] = *(const bf16x8*)(pr + cc0);
      bfr[ni][1] = *(const bf16x8*)(pr + (cc0 ^ 32));
    }
    PRIO1;
#pragma unroll
    for (int mi = 0; mi < 2; ++mi)
#pragma unroll
      for (int ni = 0; ni < 4; ++ni)
#pragma unroll
        for (int kk = 0; kk < 2; ++kk)
          acc[mi][ni] = __builtin_amdgcn_mfma_f32_16x16x32_bf16(af[mi][kk], bfr[ni][kk],
                                                                acc[mi][ni], 0, 0, 0);
    PRIO0;
    BARRAW;
    cur ^= 1;
  }
#undef STG_O
#pragma unroll
  for (int mi = 0; mi < 2; ++mi)
#pragma unroll
    for (int ni = 0; ni < 4; ++ni)
#pragma unroll
      for (int r = 0; r < 4; ++r){
        int row = brow + wm * 32 + mi * 16 + g * 4 + r;
        int col = bcol + wn * 64 + ni * 16 + c15;
        C[(size_t)row * 2048 + col] = acc[mi][ni][r];
      }
}

// ---------------- pass 1a: rowsum of exp (causal), Q-in-registers ----------------
// grid (40, 16), 256 thr; K triple-buffered LDS stream, 1 barrier/iter.
__global__ __launch_bounds__(256)
void k_pass1a(const u16* __restrict__ Q, const u16* __restrict__ K, float* __restrict__ rowsum){
  __shared__ __align__(16) u16 Ks[3][64 * 128];
  const int tid = threadIdx.x;
  const int wv = tid >> 6, lane = tid & 63;
  const int g = lane >> 4, c15 = lane & 15;
  const int h = blockIdx.y;
  int qb = 0, c = 0;
  { int rem = blockIdx.x; int q = 0;
    while (rem >= ((2 * q + 9) >> 3)){ rem -= (2 * q + 9) >> 3; q++; }
    qb = q; c = rem; }
  const int i0 = qb * 128;
  const int ktend = 2 * qb + 2;
  const int kt0 = c * 8;
  const int kt1 = (ktend < kt0 + 8) ? ktend : (kt0 + 8);
  const u16* Qh = Q + h * HDIM;
  const u16* Kh = K + h * HDIM;
  const float scale = 0.08838834764831845f;   // 1/sqrt(128)
  const int wb = wv * 32;

  bf16x8 qfr[2][4];
#pragma unroll
  for (int m = 0; m < 2; m++)
#pragma unroll
    for (int ks = 0; ks < 4; ks++)
      qfr[m][ks] = *(const bf16x8*)(Qh + (size_t)(i0 + wb + m * 16 + c15) * 2048 + ks * 32 + g * 8);

  stage_tile(Kh, 2048, kt0 * 64, Ks[0], tid);
  if (kt0 + 1 < kt1) stage_tile(Kh, 2048, (kt0 + 1) * 64, Ks[1], tid);

  float rs[2][4] = {{0.f,0.f,0.f,0.f},{0.f,0.f,0.f,0.f}};
  for (int kt = kt0; kt < kt1; ++kt){
    const int bi = (kt - kt0) % 3;
    if (kt + 1 < kt1){ WAITVM(4); } else { WAITVM(0); }
    BARRAW;
    if (kt + 2 < kt1) stage_tile(Kh, 2048, (kt + 2) * 64, Ks[(kt - kt0 + 2) % 3], tid);
    const int k0 = kt * 64;
    f32x4 sacc[2][4];
#pragma unroll
    for (int m = 0; m < 2; m++)
#pragma unroll
      for (int n = 0; n < 4; n++) sacc[m][n] = (f32x4){0.f, 0.f, 0.f, 0.f};
#pragma unroll
    for (int ks = 0; ks < 4; ++ks){
#pragma unroll
      for (int n = 0; n < 4; n++){
        int brw = n * 16 + c15;
        bf16x8 b = *(const bf16x8*)(Ks[bi] + brw * 128 + ((ks * 32 + g * 8) ^ ((brw & 7) << 3)));
#pragma unroll
        for (int m = 0; m < 2; m++)
          sacc[m][n] = __builtin_amdgcn_mfma_f32_16x16x32_bf16(qfr[m][ks], b, sacc[m][n], 0, 0, 0);
      }
    }
    if (kt < 2 * qb){            // fully causal tile: no mask compare
#pragma unroll
      for (int m = 0; m < 2; m++)
#pragma unroll
        for (int n = 0; n < 4; n++)
#pragma unroll
          for (int r = 0; r < 4; r++)
            rs[m][r] += __expf(sacc[m][n][r] * scale);
    } else {
#pragma unroll
      for (int n = 0; n < 4; n++){
        int col = k0 + n * 16 + c15;
#pragma unroll
        for (int m = 0; m < 2; m++)
#pragma unroll
          for (int r = 0; r < 4; r++){
            int rowg = i0 + wb + m * 16 + g * 4 + r;
            rs[m][r] += (col <= rowg) ? __expf(sacc[m][n][r] * scale) : 0.f;
          }
      }
    }
  }
#pragma unroll
  for (int m = 0; m < 2; m++)
#pragma unroll
    for (int r = 0; r < 4; r++){
      float v = rs[m][r];
      v += __shfl_xor(v, 1); v += __shfl_xor(v, 2);
      v += __shfl_xor(v, 4); v += __shfl_xor(v, 8);
      if (c15 == 0)
        atomicAdd(&rowsum[h * 2048 + i0 + wb + m * 16 + g * 4 + r], v);
    }
}

// ---------------- pass 1b: colsum of normalized exp, K-in-registers ----------------
// grid (40, 16), 256 thr; Q triple-buffered LDS stream, 1 barrier/iter.
__global__ __launch_bounds__(256)
void k_pass1b(const u16* __restrict__ Q, const u16* __restrict__ K,
              const float* __restrict__ rowsum, float* __restrict__ colsum){
  __shared__ __align__(16) u16 Qs[3][64 * 128];
  const int tid = threadIdx.x;
  const int wv = tid >> 6, lane = tid & 63;
  const int g = lane >> 4, c15 = lane & 15;
  const int h = blockIdx.y;
  int kb = 0, c = 0;
  { int rem = blockIdx.x; int q = 0;
    while (rem >= ((39 - 2 * q) >> 3)){ rem -= (39 - 2 * q) >> 3; q++; }
    kb = q; c = rem; }
  const int k0 = kb * 128;
  const int qt0 = 2 * kb + c * 8;
  const int qt1 = (2 * kb + c * 8 + 8 < 32) ? (2 * kb + c * 8 + 8) : 32;
  const u16* Qh = Q + h * HDIM;
  const u16* Kh = K + h * HDIM;
  const float scale = 0.08838834764831845f;
  const int wb = wv * 32;
  const float* rsrow = rowsum + h * 2048;

  bf16x8 kfr[2][4];
#pragma unroll
  for (int m = 0; m < 2; m++)
#pragma unroll
    for (int ks = 0; ks < 4; ks++)
      kfr[m][ks] = *(const bf16x8*)(Kh + (size_t)(k0 + wb + m * 16 + c15) * 2048 + ks * 32 + g * 8);

  stage_tile(Qh, 2048, qt0 * 64, Qs[0], tid);
  if (qt0 + 1 < qt1) stage_tile(Qh, 2048, (qt0 + 1) * 64, Qs[1], tid);

  float racc[2][4] = {{0.f,0.f,0.f,0.f},{0.f,0.f,0.f,0.f}};
  for (int qt = qt0; qt < qt1; ++qt){
    const int bi = (qt - qt0) % 3;
    if (qt + 1 < qt1){ WAITVM(4); } else { WAITVM(0); }
    BARRAW;
    if (qt + 2 < qt1) stage_tile(Qh, 2048, (qt + 2) * 64, Qs[(qt - qt0 + 2) % 3], tid);
    const int i0q = qt * 64;
    float rw[4];
#pragma unroll
    for (int n = 0; n < 4; n++)
      rw[n] = 1.0f / rsrow[i0q + n * 16 + c15];
    f32x4 sacc[2][4];
#pragma unroll
    for (int m = 0; m < 2; m++)
#pragma unroll
      for (int n = 0; n < 4; n++) sacc[m][n] = (f32x4){0.f, 0.f, 0.f, 0.f};
#pragma unroll
    for (int ks = 0; ks < 4; ++ks){
#pragma unroll
      for (int n = 0; n < 4; n++){
        int brw = n * 16 + c15;
        bf16x8 b = *(const bf16x8*)(Qs[bi] + brw * 128 + ((ks * 32 + g * 8) ^ ((brw & 7) << 3)));
#pragma unroll
        for (int m = 0; m < 2; m++)
          sacc[m][n] = __builtin_amdgcn_mfma_f32_16x16x32_bf16(kfr[m][ks], b, sacc[m][n], 0, 0, 0);
      }
    }
    if (qt >= 2 * kb + 2){       // fully causal: no mask compare
#pragma unroll
      for (int m = 0; m < 2; m++)
#pragma unroll
        for (int n = 0; n < 4; n++)
#pragma unroll
          for (int r = 0; r < 4; r++)
            racc[m][r] += __expf(sacc[m][n][r] * scale) * rw[n];
    } else {
#pragma unroll
      for (int n = 0; n < 4; n++){
        int colq = i0q + n * 16 + c15;
#pragma unroll
        for (int m = 0; m < 2; m++)
#pragma unroll
          for (int r = 0; r < 4; r++){
            int rowk = k0 + wb + m * 16 + g * 4 + r;
            racc[m][r] += (rowk <= colq) ? __expf(sacc[m][n][r] * scale) * rw[n] : 0.f;
          }
      }
    }
  }
#pragma unroll
  for (int m = 0; m < 2; m++)
#pragma unroll
    for (int r = 0; r < 4; r++){
      float v = racc[m][r];
      v += __shfl_xor(v, 1); v += __shfl_xor(v, 2);
      v += __shfl_xor(v, 4); v += __shfl_xor(v, 8);
      if (c15 == 0)
        atomicAdd(&colsum[h * 2048 + k0 + wb + m * 16 + g * 4 + r], v);
    }
}

// ---------------- top-k via exact radix-select (select only, 16 blocks) ----------------
__global__ __launch_bounds__(1024)
void k_topk(const float* __restrict__ colsum, short* __restrict__ cidx){
  __shared__ u32 keys[2048];
  __shared__ int hist[256];
  __shared__ int chunkCnt[32];
  __shared__ short cidL[256];
  __shared__ u32 Tacc_s;
  __shared__ int rem_s;
  const int tid = threadIdx.x;
  const int h = blockIdx.x;
  const int w = tid >> 6, lane = tid & 63;

  for (int i = tid; i < 2048; i += 1024) keys[i] = ((const u32*)colsum)[h * 2048 + i];
  if (tid == 0){ Tacc_s = 0; rem_s = HEAVY; }
  __syncthreads();

  for (int s = 24; s >= 0; s -= 8){
    if (tid < 256) hist[tid] = 0;
    __syncthreads();
    u32 T = Tacc_s;
    for (int i = tid; i < 2048; i += 1024){
      u32 k = keys[i];
      bool match = (s == 24) ? true : (((k ^ T) >> (s + 8)) == 0);
      if (match) atomicAdd(&hist[(k >> s) & 255], 1);
    }
    __syncthreads();
    if (tid == 0){
      int rem = rem_s, acc = 0, b = 255;
      for (; b > 0; --b){
        int c2 = hist[b];
        if (acc + c2 >= rem) break;
        acc += c2;
      }
      Tacc_s = T | ((u32)b << s);
      rem_s = rem - acc;
    }
    __syncthreads();
  }
  const u32 T = Tacc_s;
  const int need = rem_s;                 // smallest-index ties among == T
  const u32 kA = keys[tid], kB = keys[tid + 1024];
  const bool eqA = (kA == T), eqB = (kB == T);
  unsigned long long ebA = __ballot(eqA);
  unsigned long long ebB = __ballot(eqB);
  if (lane == 0){ chunkCnt[w] = __popcll(ebA); chunkCnt[16 + w] = __popcll(ebB); }
  __syncthreads();
  if (tid == 0){
    int s2 = 0;
    for (int i2 = 0; i2 < 32; ++i2){ int c2 = chunkCnt[i2]; chunkCnt[i2] = s2; s2 += c2; }
  }
  __syncthreads();
  const unsigned long long below = (1ull << lane) - 1ull;
  const int eqrA = chunkCnt[w] + __popcll(ebA & below);
  const int eqrB = chunkCnt[16 + w] + __popcll(ebB & below);
  const bool hvA = (kA > T) || (eqA && eqrA < need);
  const bool hvB = (kB > T) || (eqB && eqrB < need);
  __syncthreads();                        // before reusing chunkCnt
  unsigned long long hbA = __ballot(hvA);
  unsigned long long hbB = __ballot(hvB);
  if (lane == 0){ chunkCnt[w] = __popcll(hbA); chunkCnt[16 + w] = __popcll(hbB); }
  if (tid >= HEAVY && tid < 256) cidL[tid] = 32767;
  __syncthreads();
  if (tid == 0){
    int s2 = 0;
    for (int i2 = 0; i2 < 32; ++i2){ int c2 = chunkCnt[i2]; chunkCnt[i2] = s2; s2 += c2; }
  }
  __syncthreads();
  if (hvA) cidL[chunkCnt[w] + __popcll(hbA & below)] = (short)tid;
  if (hvB) cidL[chunkCnt[16 + w] + __popcll(hbB & below)] = (short)(tid + 1024);
  __syncthreads();
  if (tid < 256) cidx[h * 256 + tid] = cidL[tid];
}

// ---------------- gather heavy K rows + V cols (full-grid, 384 blocks) ----------------
__global__ void k_gath(const u16* __restrict__ Kb, const u16* __restrict__ Vb,
                       const short* __restrict__ cidx,
                       u16* __restrict__ Kg, u16* __restrict__ Vg){
  __shared__ __align__(16) u16 t[32][136];
  int b = blockIdx.x, tid = threadIdx.x;
  if (b < 256){
    int gid = b * 256 + tid;                   // 16h * 256slot * 16chunk = 65536
    int h = gid >> 12, rem = gid & 4095;
    int slot = rem >> 4, cp = rem & 15;
    int cid = cidx[h * 256 + slot];
    bf16x8 z = (bf16x8){0,0,0,0,0,0,0,0};
    bf16x8 val = (cid < 2048) ? *(const bf16x8*)(Kb + (size_t)cid * 2048 + h * 128 + cp * 8) : z;
    *(bf16x8*)(Kg + ((size_t)h * 256 + slot) * 128 + cp * 8) = val;
  } else {
    int b2 = b - 256;
    int h = b2 >> 3, s0 = (b2 & 7) * 32;
#pragma unroll
    for (int it = 0; it < 2; ++it){
      int m = it * 256 + tid;                  // 512 chunks = 32 slots x 16 chunks
      int s = m >> 4, cp = m & 15;
      int cid = cidx[h * 256 + s0 + s];
      bf16x8 z = (bf16x8){0,0,0,0,0,0,0,0};
      bf16x8 val = (cid < 2048) ? *(const bf16x8*)(Vb + (size_t)cid * 2048 + h * 128 + cp * 8) : z;
      *(bf16x8*)(&t[s][cp * 8]) = val;
    }
    __syncthreads();
#pragma unroll
    for (int i = 0; i < 16; ++i){
      int idx = i * 256 + tid;                 // 4096 = 128 d x 32 s
      int d = idx >> 5, s = idx & 31;
      Vg[((size_t)h * 128 + d) * 256 + s0 + s] = t[s][d];
    }
  }
}

// ---------------- pass 2: QBLK=128, Q-in-reg, K+V LDS dbuf, 2 barriers/iter ----------------
// grid (16, 16) = 256 blocks, 512 thr (8 waves: 2 q-halves x 4 strips)
__global__ __launch_bounds__(512)
void k_pass2(const u16* __restrict__ Q, const u16* __restrict__ K, const u16* __restrict__ Vt,
             const u16* __restrict__ Kg, const u16* __restrict__ Vg,
             const short* __restrict__ cidx, u16* __restrict__ attn){
  __shared__ __align__(16) u16 Ks[2][64 * 128];
  __shared__ __align__(16) u16 Vs[2][128 * 64];
  __shared__ __align__(16) u16 Ps[8][16 * 64];
  __shared__ short cids[256];
  __shared__ int lists[12];
  __shared__ int nact_s;
  const int tid = threadIdx.x;
  const int w = tid >> 6, lane = tid & 63;
  const int g = lane >> 4, c15 = lane & 15;
  const int qb = blockIdx.x, h = blockIdx.y;
  const int i0 = qb * 128;
  const int wq = w >> 2, w4 = w & 3;
  const int rowbase = i0 + wq * 64 + w4 * 16;
  const u16* Qh = Q + h * HDIM;
  const u16* Kh = K + h * HDIM;
  const u16* Kgh = Kg + (size_t)h * 256 * 128;
  const u16* Vth = Vt + (size_t)h * 128 * 2048;
  const u16* Vgh = Vg + (size_t)h * 128 * 256;
  const float scale = 0.08838834764831845f;

  if (tid < 256) cids[tid] = cidx[h * 256 + tid];
  // Q fragments in registers (rows rowbase + c15)
  bf16x8 qfr[4];
#pragma unroll
  for (int ks = 0; ks < 4; ks++)
    qfr[ks] = *(const bf16x8*)(Qh + (size_t)(rowbase + c15) * 2048 + ks * 32 + g * 8);
  __syncthreads();
  if (tid == 0){
    int n = 0;
    int ktb0 = (i0 > RECENT) ? ((i0 - RECENT) >> 6) : 0;
    int ktmax = (i0 + 127) >> 6;
    for (int kt = ktb0; kt <= ktmax; ++kt) lists[n++] = kt;
    for (int gt = 0; gt < 4; ++gt)
      if ((int)cids[gt * 64] <= i0 + 127 - RECENT - 1) lists[n++] = 100 + gt;
    nact_s = n;
  }
  __syncthreads();
  const int nact = nact_s;

  // prologue: stage K0 (2) + V0 (2) only
  { int e = lists[0];
    if (e < 100){ stageK512(Kh, 2048, e * 64, Ks[0], tid);
                  stageV512(Vth, 2048, e * 64, Vs[0], tid); }
    else        { stageK512(Kgh, 128, (e - 100) * 64, Ks[0], tid);
                  stageV512(Vgh, 256, (e - 100) * 64, Vs[0], tid); } }

  f32x4 oacc[8];
#pragma unroll
  for (int f = 0; f < 8; f++) oacc[f] = (f32x4){0.f, 0.f, 0.f, 0.f};
  float lsum[4] = {0.f, 0.f, 0.f, 0.f};

  int cur = 0;
  for (int i = 0; i < nact; ++i){
    const int e = lists[i];
    const bool isg = (e >= 100);
    const bool nxt = (i + 1 < nact);
    WAITVM(2);                 // retire K(i); keep V(i)
    BARRAW;
    if (nxt){                  // stage K/V(i+1) AFTER barrier (no race vs iter i-1 reads)
      int e2 = lists[i + 1];
      if (e2 < 100){ stageK512(Kh, 2048, e2 * 64, Ks[cur ^ 1], tid);
                     stageV512(Vth, 2048, e2 * 64, Vs[cur ^ 1], tid); }
      else         { stageK512(Kgh, 128, (e2 - 100) * 64, Ks[cur ^ 1], tid);
                     stageV512(Vgh, 256, (e2 - 100) * 64, Vs[cur ^ 1], tid); }
    }
    // QK^T
    f32x4 sacc[4];
#pragma unroll
    for (int n = 0; n < 4; n++) sacc[n] = (f32x4){0.f, 0.f, 0.f, 0.f};
#pragma unroll
    for (int ks = 0; ks < 4; ++ks){
#pragma unroll
      for (int n = 0; n < 4; n++){
        int brw = n * 16 + c15;
        bf16x8 b = *(const bf16x8*)(Ks[cur] + brw * 128 + ((ks * 32 + g * 8) ^ ((brw & 7) << 3)));
        sacc[n] = __builtin_amdgcn_mfma_f32_16x16x32_bf16(qfr[ks], b, sacc[n], 0, 0, 0);
      }
    }
    // masked exp -> P (LDS, wave-private), row sums
#pragma unroll
    for (int n = 0; n < 4; n++){
      int cid = isg ? (int)cids[(e - 100) * 64 + n * 16 + c15] : (e * 64 + n * 16 + c15);
#pragma unroll
      for (int r = 0; r < 4; r++){
        int rowg = rowbase + g * 4 + r;
        int dist = rowg - cid;
        bool valid = (cid <= rowg) && (isg ? (dist > RECENT) : (dist <= RECENT));
        float ev = valid ? __expf(sacc[n][r] * scale) : 0.f;
        lsum[r] += ev;
        int prow = g * 4 + r;
        Ps[w][prow * 64 + ((n * 16 + c15) ^ ((prow & 7) << 3))] = f2bf(ev);
      }
    }
    // retire V(i) (keep K/V(i+1)), then PV from LDS
    if (nxt) WAITVM(4); else WAITVM(0);
    BARRAW;
    PRIO1;
#pragma unroll
    for (int ks2 = 0; ks2 < 2; ++ks2){
      bf16x8 pa = *(const bf16x8*)(&Ps[w][c15 * 64 + ((ks2 * 32 + g * 8) ^ ((c15 & 7) << 3))]);
#pragma unroll
      for (int f = 0; f < 8; ++f){
        int vrow = f * 16 + c15;
        bf16x8 vb = *(const bf16x8*)(Vs[cur] + vrow * 64 + ((ks2 * 32 + g * 8) ^ ((vrow & 7) << 3)));
        oacc[f] = __builtin_amdgcn_mfma_f32_16x16x32_bf16(pa, vb, oacc[f], 0, 0, 0);
      }
    }
    PRIO0;
    cur ^= 1;
  }
  float rinv[4];
#pragma unroll
  for (int r = 0; r < 4; r++){
    float v = lsum[r];
    v += __shfl_xor(v, 1); v += __shfl_xor(v, 2);
    v += __shfl_xor(v, 4); v += __shfl_xor(v, 8);
    rinv[r] = 1.0f / v;
  }
#pragma unroll
  for (int f = 0; f < 8; f++)
#pragma unroll
    for (int r = 0; r < 4; r++){
      int rowg = rowbase + g * 4 + r;
      attn[(size_t)rowg * 2048 + h * HDIM + f * 16 + c15] = f2bf(oacc[f][r] * rinv[r]);
    }
}

// ---------------- host launcher ----------------
extern "C" void kernel_launch(void* const* d_in, const int* in_sizes, int n_in,
                              void* d_out, int out_size, void* d_ws, size_t ws_size,
                              hipStream_t stream){
  const float* X  = (const float*)d_in[0];
  const float* Wq = (const float*)d_in[1];
  const float* Wk = (const float*)d_in[2];
  const float* Wv = (const float*)d_in[3];
  const float* Wo = (const float*)d_in[4];

  char* w = (char*)d_ws;
  const size_t MB8 = (size_t)2048 * 2048 * 2;   // one bf16 matrix = 8 MiB
  u16* Xb  = (u16*)(w);
  u16* Wqb = (u16*)(w + 1 * MB8);
  u16* Wkb = (u16*)(w + 2 * MB8);
  u16* Wvb = (u16*)(w + 3 * MB8);
  u16* Wob = (u16*)(w + 4 * MB8);
  u16* Qb  = (u16*)(w + 5 * MB8);
  u16* Kb  = (u16*)(w + 6 * MB8);
  u16* Vb  = (u16*)(w + 7 * MB8);
  u16* Vtb   = Wqb;   // Wq dead after projections
  u16* attnb = Xb;    // X dead after projections
  char* p = w + 8 * MB8;
  float* cosT = (float*)p;              p += 524288;
  float* sinT = (float*)p;              p += 524288;
  float* colsum = (float*)p;            p += 131072;   // zeroed in k_prep (with rowsum)
  float* rowsum = (float*)p;            p += 131072;
  short* cidx  = (short*)p;             p += 16 * 256 * 2;
  u16*   Kg    = (u16*)p;               p += (size_t)16 * 256 * 128 * 2;
  u16*   Vg    = (u16*)p;

  dim3 b256(256);

  k_prep<<<21056, b256, 0, stream>>>(X, Wq, Wk, Wv, Wo, Xb, cosT, sinT, colsum);

  k_g256<<<dim3(32, 8), dim3(512), 0, stream>>>(Xb, Wqb, Wkb, Wvb, Qb, Kb, Vb);
  k_post<<<8192, b256, 0, stream>>>(Qb, Kb, cosT, sinT, Vb, Vtb);

  k_pass1a<<<dim3(40, 16), b256, 0, stream>>>(Qb, Kb, rowsum);
  k_pass1b<<<dim3(40, 16), b256, 0, stream>>>(Qb, Kb, rowsum, colsum);
  k_topk<<<16, dim3(1024), 0, stream>>>(colsum, cidx);
  k_gath<<<384, b256, 0, stream>>>(Kb, Vb, cidx, Kg, Vg);
  k_pass2<<<dim3(16, 16), dim3(512), 0, stream>>>(Qb, Kb, Vtb, Kg, Vg, cidx, attnb);

  k_gemm_out<<<dim3(16, 16), dim3(512), 0, stream>>>(attnb, Wob, (float*)d_out);
}